// Round 5
// baseline (504.818 us; speedup 1.0000x reference)
//
#include <hip/hip_runtime.h>
#include <cstddef>

// Problem constants
#define TT 2048
#define BB 2
#define CC 768
#define NH 12
#define HD 64
#define N3 2304          // 3*NH*HD
#define Y_ELEMS (BB*TT*CC)          // 3145728
#define M_ELEMS (BB*TT*TT)          // 8388608
#define PROWS 1536                  // rows 512..2047 use partials

typedef __attribute__((ext_vector_type(8))) short bf16x8;
typedef __attribute__((ext_vector_type(4))) float f32x4;

__device__ inline unsigned short f2b(float f) {
  union { float f; unsigned u; } v; v.f = f;
  unsigned r = (v.u + 0x7FFFu + ((v.u >> 16) & 1u)) >> 16;
  return (unsigned short)r;
}
__device__ inline float b2f(unsigned short u) {
  union { unsigned u; float f; } v; v.u = (unsigned)u << 16; return v.f;
}

// ---------------------------------------------------------------------------
// pack x (fp32) -> xb (bf16). 8 elems/thread.
// ---------------------------------------------------------------------------
__global__ __launch_bounds__(256) void pack_x(
    const float* __restrict__ x, unsigned short* __restrict__ xb) {
  size_t i = ((size_t)blockIdx.x * 256 + threadIdx.x) * 8;
  float4 a = *(const float4*)(x + i);
  float4 b = *(const float4*)(x + i + 4);
  ushort4 o0, o1;
  o0.x = f2b(a.x); o0.y = f2b(a.y); o0.z = f2b(a.z); o0.w = f2b(a.w);
  o1.x = f2b(b.x); o1.y = f2b(b.y); o1.z = f2b(b.z); o1.w = f2b(b.w);
  *(ushort4*)(xb + i) = o0;
  *(ushort4*)(xb + i + 4) = o1;
}

// ---------------------------------------------------------------------------
// W [768][N] fp32 -> WT [N][768] bf16 (transposed pack). Block=(kt,nt) 64x64.
// ---------------------------------------------------------------------------
__global__ __launch_bounds__(256) void transpose_pack(
    const float* __restrict__ W, unsigned short* __restrict__ WT, int N) {
  __shared__ float tile[64][65];
  int kt = blockIdx.x, nt = blockIdx.y;
  int tid = threadIdx.x;
  int r = tid >> 4, c4 = (tid & 15) << 2;
#pragma unroll
  for (int rep = 0; rep < 4; ++rep) {
    int row = rep * 16 + r;
    float4 v = *(const float4*)(W + (size_t)(kt * 64 + row) * N + nt * 64 + c4);
    tile[row][c4 + 0] = v.x; tile[row][c4 + 1] = v.y;
    tile[row][c4 + 2] = v.z; tile[row][c4 + 3] = v.w;
  }
  __syncthreads();
#pragma unroll
  for (int rep = 0; rep < 4; ++rep) {
    int nrow = rep * 16 + r;
    ushort4 o;
    o.x = f2b(tile[c4 + 0][nrow]); o.y = f2b(tile[c4 + 1][nrow]);
    o.z = f2b(tile[c4 + 2][nrow]); o.w = f2b(tile[c4 + 3][nrow]);
    *(ushort4*)(WT + (size_t)(nt * 64 + nrow) * CC + kt * 64 + c4) = o;
  }
}

// ---------------------------------------------------------------------------
// bf16 MFMA GEMM: qkv = xb @ wbT^T + b_attn -> packed Qb (pre-scaled 1/8),
// Kb, Vt (transposed via LDS). Grid (32 mtiles of 128, 36 ntiles of 64).
// ---------------------------------------------------------------------------
__global__ __launch_bounds__(256, 2) void gemm_qkv_bf16(
    const unsigned short* __restrict__ xb, const unsigned short* __restrict__ wbT,
    const float* __restrict__ b_attn,
    unsigned short* __restrict__ Qb, unsigned short* __restrict__ Kb,
    unsigned short* __restrict__ Vt) {
  __shared__ __align__(16) unsigned short Vlds[128][72];
  int mt = blockIdx.x, nt = blockIdx.y;
  int sec = nt / NH, h = nt % NH;
  int wave = threadIdx.x >> 6, lane = threadIdx.x & 63;
  int lr = lane & 15, lg = lane >> 4;
  int m0 = mt * 128 + wave * 32;
  int n0 = nt * 64;
  const unsigned short* Ab = xb + (size_t)m0 * CC;
  const unsigned short* Bb = wbT + (size_t)n0 * CC;

  f32x4 acc[2][4];
#pragma unroll
  for (int mi = 0; mi < 2; ++mi)
#pragma unroll
    for (int nj = 0; nj < 4; ++nj) acc[mi][nj] = (f32x4){0.f, 0.f, 0.f, 0.f};

#pragma unroll
  for (int ks = 0; ks < 24; ++ks) {
    int k0 = ks * 32;
    bf16x8 af[2], bf[4];
#pragma unroll
    for (int mi = 0; mi < 2; ++mi)
      af[mi] = *(const bf16x8*)(Ab + (size_t)(mi * 16 + lr) * CC + k0 + lg * 8);
#pragma unroll
    for (int nj = 0; nj < 4; ++nj)
      bf[nj] = *(const bf16x8*)(Bb + (size_t)(nj * 16 + lr) * CC + k0 + lg * 8);
#pragma unroll
    for (int nj = 0; nj < 4; ++nj)
#pragma unroll
      for (int mi = 0; mi < 2; ++mi)
        acc[mi][nj] = __builtin_amdgcn_mfma_f32_16x16x32_bf16(af[mi], bf[nj], acc[mi][nj], 0, 0, 0);
  }

  int b = m0 >> 11;
  int bh = b * NH + h;
  float bias[4];
#pragma unroll
  for (int nj = 0; nj < 4; ++nj) bias[nj] = b_attn[n0 + nj * 16 + lr];

  if (sec < 2) {
    // Q is pre-scaled by 1/8 (exact in bf16: exponent shift only)
    float qscale = (sec == 0) ? 0.125f : 1.0f;
    unsigned short* Out = (sec == 0 ? Qb : Kb) + (size_t)bh * TT * HD;
    int tbase = (m0 & 2047) + lg * 4;
#pragma unroll
    for (int mi = 0; mi < 2; ++mi)
#pragma unroll
      for (int r = 0; r < 4; ++r) {
        int t = tbase + mi * 16 + r;
#pragma unroll
        for (int nj = 0; nj < 4; ++nj)
          Out[(size_t)t * HD + nj * 16 + lr] = f2b((acc[mi][nj][r] + bias[nj]) * qscale);
      }
  } else {
    int tl = wave * 32 + lg * 4;
#pragma unroll
    for (int mi = 0; mi < 2; ++mi)
#pragma unroll
      for (int r = 0; r < 4; ++r)
#pragma unroll
        for (int nj = 0; nj < 4; ++nj)
          Vlds[tl + mi * 16 + r][nj * 16 + lr] = f2b(acc[mi][nj][r] + bias[nj]);
    __syncthreads();
    int d = threadIdx.x & 63, tc = threadIdx.x >> 6;
    int tblk = (mt * 128) & 2047;
    unsigned short* Ov = Vt + ((size_t)bh * HD + d) * TT + tblk + tc * 32;
#pragma unroll
    for (int i8 = 0; i8 < 4; ++i8) {
      ushort4 o0, o1;
      o0.x = Vlds[tc * 32 + i8 * 8 + 0][d]; o0.y = Vlds[tc * 32 + i8 * 8 + 1][d];
      o0.z = Vlds[tc * 32 + i8 * 8 + 2][d]; o0.w = Vlds[tc * 32 + i8 * 8 + 3][d];
      o1.x = Vlds[tc * 32 + i8 * 8 + 4][d]; o1.y = Vlds[tc * 32 + i8 * 8 + 5][d];
      o1.z = Vlds[tc * 32 + i8 * 8 + 6][d]; o1.w = Vlds[tc * 32 + i8 * 8 + 7][d];
      *(ushort4*)(Ov + i8 * 8) = o0;
      *(ushort4*)(Ov + i8 * 8 + 4) = o1;
    }
  }
}

// ---------------------------------------------------------------------------
// bf16 MFMA GEMM: y = yhb @ wpT^T + b_proj (fp32 out). Grid (32, 12).
// ---------------------------------------------------------------------------
__global__ __launch_bounds__(256, 2) void gemm_proj_bf16(
    const unsigned short* __restrict__ yhb, const unsigned short* __restrict__ wpT,
    const float* __restrict__ b_proj, float* __restrict__ y) {
  int mt = blockIdx.x, nt = blockIdx.y;
  int wave = threadIdx.x >> 6, lane = threadIdx.x & 63;
  int lr = lane & 15, lg = lane >> 4;
  int m0 = mt * 128 + wave * 32;
  int n0 = nt * 64;
  const unsigned short* Ab = yhb + (size_t)m0 * CC;
  const unsigned short* Bb = wpT + (size_t)n0 * CC;

  f32x4 acc[2][4];
#pragma unroll
  for (int mi = 0; mi < 2; ++mi)
#pragma unroll
    for (int nj = 0; nj < 4; ++nj) acc[mi][nj] = (f32x4){0.f, 0.f, 0.f, 0.f};

#pragma unroll
  for (int ks = 0; ks < 24; ++ks) {
    int k0 = ks * 32;
    bf16x8 af[2], bf[4];
#pragma unroll
    for (int mi = 0; mi < 2; ++mi)
      af[mi] = *(const bf16x8*)(Ab + (size_t)(mi * 16 + lr) * CC + k0 + lg * 8);
#pragma unroll
    for (int nj = 0; nj < 4; ++nj)
      bf[nj] = *(const bf16x8*)(Bb + (size_t)(nj * 16 + lr) * CC + k0 + lg * 8);
#pragma unroll
    for (int nj = 0; nj < 4; ++nj)
#pragma unroll
      for (int mi = 0; mi < 2; ++mi)
        acc[mi][nj] = __builtin_amdgcn_mfma_f32_16x16x32_bf16(af[mi], bf[nj], acc[mi][nj], 0, 0, 0);
  }

  float bias[4];
#pragma unroll
  for (int nj = 0; nj < 4; ++nj) bias[nj] = b_proj[n0 + nj * 16 + lr];
#pragma unroll
  for (int mi = 0; mi < 2; ++mi)
#pragma unroll
    for (int r = 0; r < 4; ++r) {
      int m = m0 + mi * 16 + lg * 4 + r;
#pragma unroll
      for (int nj = 0; nj < 4; ++nj)
        y[(size_t)m * CC + n0 + nj * 16 + lr] = acc[mi][nj][r] + bias[nj];
    }
}

// ---------------------------------------------------------------------------
// fp32 GEMM for head-0 q,k only (precision-critical FF path). Grid (64, 2).
// ---------------------------------------------------------------------------
__global__ __launch_bounds__(256) void sgemm_qk0(
    const float* __restrict__ x, const float* __restrict__ w_attn,
    const float* __restrict__ b_attn, float* __restrict__ q0,
    float* __restrict__ k0) {
  __shared__ float As[16][64];
  __shared__ float Bs[16][64];
  int sec = blockIdx.y;
  const float* Bw = w_attn + sec * CC;
  float* Out = sec ? k0 : q0;
  int tid = threadIdx.x;
  int tx = tid & 15, ty = tid >> 4;
  int m0 = blockIdx.x * 64;

  int arow = tid >> 2;
  int acol4 = (tid & 3) << 2;
  int brow = tid >> 4;
  int bcol4 = (tid & 15) << 2;

  const float* Aptr = x + (size_t)(m0 + arow) * CC + acol4;
  const float* Bptr = Bw + (size_t)brow * N3 + bcol4;

  float acc[4][4] = {};

  for (int k0_ = 0; k0_ < CC; k0_ += 16) {
    float4 av = *(const float4*)(Aptr + k0_);
    float4 bv = *(const float4*)(Bptr + (size_t)k0_ * N3);
    As[acol4 + 0][arow] = av.x;
    As[acol4 + 1][arow] = av.y;
    As[acol4 + 2][arow] = av.z;
    As[acol4 + 3][arow] = av.w;
    *(float4*)&Bs[brow][bcol4] = bv;
    __syncthreads();
#pragma unroll
    for (int kk = 0; kk < 16; ++kk) {
      float4 a4 = *(const float4*)&As[kk][ty << 2];
      float4 b4 = *(const float4*)&Bs[kk][tx << 2];
      float a[4] = {a4.x, a4.y, a4.z, a4.w};
      float b[4] = {b4.x, b4.y, b4.z, b4.w};
#pragma unroll
      for (int ii = 0; ii < 4; ++ii)
#pragma unroll
        for (int jj = 0; jj < 4; ++jj) acc[ii][jj] += a[ii] * b[jj];
    }
    __syncthreads();
  }

  float4 bv = *(const float4*)(b_attn + sec * CC + (tx << 2));
#pragma unroll
  for (int ii = 0; ii < 4; ++ii) {
    int m = m0 + (ty << 2) + ii;
    float4 o;
    o.x = acc[ii][0] + bv.x;
    o.y = acc[ii][1] + bv.y;
    o.z = acc[ii][2] + bv.z;
    o.w = acc[ii][3] + bv.w;
    *(float4*)(Out + (size_t)m * HD + (tx << 2)) = o;
  }
}

// ---------------------------------------------------------------------------
// Head-0 scores (fp32): Sbuf[b,i,j] = relu(dot(q0,k0)/8), lower-tri tiles.
// ---------------------------------------------------------------------------
__global__ __launch_bounds__(256) void score0_kernel(
    const float* __restrict__ q0, const float* __restrict__ k0,
    float* __restrict__ Sbuf) {
  int it = blockIdx.x, jt = blockIdx.y, b = blockIdx.z;
  if (jt > it) return;
  __shared__ float Qs[64][64];
  __shared__ float Ks[64][64];
  int tid = threadIdx.x;
  int row = tid >> 2;
  int dq = (tid & 3) << 2;
  int i0 = it * 64, j0 = jt * 64;
  const float* qb = q0 + (size_t)((b * TT) + i0 + row) * HD;
  const float* kb = k0 + (size_t)((b * TT) + j0 + row) * HD;
#pragma unroll
  for (int rep = 0; rep < 4; ++rep) {
    int d = dq + rep * 16;
    float4 qv = *(const float4*)(qb + d);
    float4 kv = *(const float4*)(kb + d);
    Qs[d + 0][row] = qv.x; Qs[d + 1][row] = qv.y;
    Qs[d + 2][row] = qv.z; Qs[d + 3][row] = qv.w;
    Ks[d + 0][row] = kv.x; Ks[d + 1][row] = kv.y;
    Ks[d + 2][row] = kv.z; Ks[d + 3][row] = kv.w;
  }
  __syncthreads();
  int tx = tid & 15, ty = tid >> 4;
  float acc[4][4] = {};
#pragma unroll 8
  for (int kk = 0; kk < 64; ++kk) {
    float4 a4 = *(const float4*)&Qs[kk][ty << 2];
    float4 b4 = *(const float4*)&Ks[kk][tx << 2];
    float a[4] = {a4.x, a4.y, a4.z, a4.w};
    float b[4] = {b4.x, b4.y, b4.z, b4.w};
#pragma unroll
    for (int ii = 0; ii < 4; ++ii)
#pragma unroll
      for (int jj = 0; jj < 4; ++jj) acc[ii][jj] += a[ii] * b[jj];
  }
#pragma unroll
  for (int ii = 0; ii < 4; ++ii) {
    int gi = (b * TT) + i0 + (ty << 2) + ii;
    float4 o;
    o.x = fmaxf(acc[ii][0] * 0.125f, 0.f);
    o.y = fmaxf(acc[ii][1] * 0.125f, 0.f);
    o.z = fmaxf(acc[ii][2] * 0.125f, 0.f);
    o.w = fmaxf(acc[ii][3] * 0.125f, 0.f);
    *(float4*)(Sbuf + (size_t)gi * TT + j0 + (tx << 2)) = o;
  }
}

// ---------------------------------------------------------------------------
// Column-wise exclusive prefix scan over rows (chunked, two passes).
// ---------------------------------------------------------------------------
__global__ __launch_bounds__(256) void scan_partial(
    const float* __restrict__ Sbuf, float* __restrict__ partials) {
  int j = blockIdx.x * 256 + threadIdx.x;
  int chunk = blockIdx.y, b = blockIdx.z;
  int r0 = chunk * 128;
  const float* base = Sbuf + (size_t)(b * TT + r0) * TT + j;
  float sum = 0.f;
  for (int rr = 0; rr < 128; ++rr) {
    int r = r0 + rr;
    float v = (j >= 1 && j < r) ? base[(size_t)rr * TT] : 0.f;
    sum += v;
  }
  partials[(size_t)(b * 16 + chunk) * TT + j] = sum;
}

__global__ __launch_bounds__(256) void scan_write(
    float* __restrict__ Sbuf, const float* __restrict__ partials) {
  int j = blockIdx.x * 256 + threadIdx.x;
  int chunk = blockIdx.y, b = blockIdx.z;
  float run = 0.f;
  for (int c = 0; c < chunk; ++c) run += partials[(size_t)(b * 16 + c) * TT + j];
  int r0 = chunk * 128;
  float* base = Sbuf + (size_t)(b * TT + r0) * TT + j;
  for (int rr = 0; rr < 128; ++rr) {
    int r = r0 + rr;
    float v = (j >= 1 && j < r) ? base[(size_t)rr * TT] : 0.f;
    base[(size_t)rr * TT] = run;
    run += v;
  }
}

// ---------------------------------------------------------------------------
// FF_sum[b,i] = sum_j clip(FF[b,i,j], 0, 1)
// ---------------------------------------------------------------------------
__global__ __launch_bounds__(256) void ffsum_kernel(
    const float* __restrict__ FF, float* __restrict__ ffsum) {
  int i = blockIdx.x, b = blockIdx.y;
  const float4* row = (const float4*)(FF + (size_t)(b * TT + i) * TT);
  float s = 0.f;
  for (int r = threadIdx.x; r < TT / 4; r += 256) {
    float4 v = row[r];
    s += fminf(fmaxf(v.x, 0.f), 1.f) + fminf(fmaxf(v.y, 0.f), 1.f) +
         fminf(fmaxf(v.z, 0.f), 1.f) + fminf(fmaxf(v.w, 0.f), 1.f);
  }
#pragma unroll
  for (int o = 1; o < 64; o <<= 1) s += __shfl_xor(s, o);
  __shared__ float ws[4];
  if ((threadIdx.x & 63) == 0) ws[threadIdx.x >> 6] = s;
  __syncthreads();
  if (threadIdx.x == 0) ffsum[b * TT + i] = ws[0] + ws[1] + ws[2] + ws[3];
}

// ---------------------------------------------------------------------------
// Split-K bf16 MFMA flash attention. Block = (pair, h, b); pair decodes to
// (g4 = 64-row q-block, c = chunk of <=8 k-tiles). 4 waves x 16 q-rows.
// Q pre-scaled by 1/8. nc==1 rows finalize to yhb; else partials (bf16 acc,
// fp32 m/l) for combine_kernel. Defer-max skips rescale when no new max.
// ---------------------------------------------------------------------------
__global__ __launch_bounds__(256, 4) void attn_mfma(
    const unsigned short* __restrict__ Qb, const unsigned short* __restrict__ Kb,
    const unsigned short* __restrict__ Vt, const float* __restrict__ FF,
    unsigned short* __restrict__ yhb, unsigned short* __restrict__ pacc,
    float* __restrict__ pml) {
  int idx = blockIdx.x;
  int c, g4;
  if (idx < 32)      { c = 0; g4 = idx; }
  else if (idx < 56) { c = 1; g4 = idx - 24; }
  else if (idx < 72) { c = 2; g4 = idx - 40; }
  else               { c = 3; g4 = idx - 48; }
  int h = blockIdx.y, b = blockIdx.z;
  int nc = (g4 >> 3) + 1;
  int ktstart = c * 8;
  int ktlast = min(ktstart + 7, g4);

  int wave = threadIdx.x >> 6, lane = threadIdx.x & 63;
  int lr = lane & 15, lg = lane >> 4;
  int i0 = g4 * 64 + wave * 16;
  int bh = b * NH + h;
  const unsigned short* Qh = Qb + (size_t)bh * TT * HD;
  const unsigned short* Kh = Kb + (size_t)bh * TT * HD;
  const unsigned short* Vh = Vt + (size_t)bh * HD * TT;

  __shared__ __align__(16) unsigned short Plds[4][16][80];

  bf16x8 qf[2];
#pragma unroll
  for (int ks = 0; ks < 2; ++ks)
    qf[ks] = *(const bf16x8*)(Qh + (size_t)(i0 + lr) * HD + ks * 32 + lg * 8);

  f32x4 acc[4];
  float mrun[4], lrun[4];
#pragma unroll
  for (int q = 0; q < 4; ++q) {
    acc[q] = (f32x4){0.f, 0.f, 0.f, 0.f};
    mrun[q] = -1e30f;
    lrun[q] = 0.f;
  }

  // Prefetch K fragments for first tile
  bf16x8 kf[4][2];
#pragma unroll
  for (int nj = 0; nj < 4; ++nj) {
    kf[nj][0] = *(const bf16x8*)(Kh + (size_t)(ktstart * 64 + nj * 16 + lr) * HD + lg * 8);
    kf[nj][1] = *(const bf16x8*)(Kh + (size_t)(ktstart * 64 + nj * 16 + lr) * HD + 32 + lg * 8);
  }

  for (int kt = ktstart; kt <= ktlast; ++kt) {
    int j0 = kt * 64;
    bf16x8 vf[4][2];
#pragma unroll
    for (int nd = 0; nd < 4; ++nd)
#pragma unroll
      for (int ks = 0; ks < 2; ++ks)
        vf[nd][ks] = *(const bf16x8*)(Vh + (size_t)(nd * 16 + lr) * TT + j0 + ks * 32 + lg * 8);
    const float* ffb = FF + ((size_t)(b * TT) + i0 + lg * 4) * TT + j0 + lr;
    float ff[4][4];
#pragma unroll
    for (int r = 0; r < 4; ++r)
#pragma unroll
      for (int nj = 0; nj < 4; ++nj)
        ff[r][nj] = ffb[(size_t)r * TT + nj * 16];

    f32x4 s[4];
#pragma unroll
    for (int nj = 0; nj < 4; ++nj) {
      f32x4 z = (f32x4){0.f, 0.f, 0.f, 0.f};
      z = __builtin_amdgcn_mfma_f32_16x16x32_bf16(qf[0], kf[nj][0], z, 0, 0, 0);
      s[nj] = __builtin_amdgcn_mfma_f32_16x16x32_bf16(qf[1], kf[nj][1], z, 0, 0, 0);
    }
    if (kt < ktlast) {
      int jn = j0 + 64;
#pragma unroll
      for (int nj = 0; nj < 4; ++nj) {
        kf[nj][0] = *(const bf16x8*)(Kh + (size_t)(jn + nj * 16 + lr) * HD + lg * 8);
        kf[nj][1] = *(const bf16x8*)(Kh + (size_t)(jn + nj * 16 + lr) * HD + 32 + lg * 8);
      }
    }

    int ibase = i0 + lg * 4;
    float mt[4];
    if (kt == g4) {
      // diagonal tile: apply causal mask
#pragma unroll
      for (int r = 0; r < 4; ++r) mt[r] = -1e30f;
#pragma unroll
      for (int nj = 0; nj < 4; ++nj)
#pragma unroll
        for (int r = 0; r < 4; ++r) {
          int ig = ibase + r, jg = j0 + nj * 16 + lr;
          float lv = (jg <= ig) ? s[nj][r] - ff[r][nj] : -1e30f;
          s[nj][r] = lv;
          mt[r] = fmaxf(mt[r], lv);
        }
    } else {
#pragma unroll
      for (int r = 0; r < 4; ++r) mt[r] = -1e30f;
#pragma unroll
      for (int nj = 0; nj < 4; ++nj)
#pragma unroll
        for (int r = 0; r < 4; ++r) {
          float lv = s[nj][r] - ff[r][nj];
          s[nj][r] = lv;
          mt[r] = fmaxf(mt[r], lv);
        }
    }
    float needup = -1.f;
#pragma unroll
    for (int r = 0; r < 4; ++r) {
      mt[r] = fmaxf(mt[r], __shfl_xor(mt[r], 1));
      mt[r] = fmaxf(mt[r], __shfl_xor(mt[r], 2));
      mt[r] = fmaxf(mt[r], __shfl_xor(mt[r], 4));
      mt[r] = fmaxf(mt[r], __shfl_xor(mt[r], 8));
      needup = fmaxf(needup, mt[r] - mrun[r]);
    }
    if (__any(needup > 0.f)) {
#pragma unroll
      for (int r = 0; r < 4; ++r) {
        float mnew = fmaxf(mrun[r], mt[r]);
        float scl = __expf(mrun[r] - mnew);
        mrun[r] = mnew;
        lrun[r] *= scl;
#pragma unroll
        for (int nd = 0; nd < 4; ++nd) acc[nd][r] *= scl;
      }
    }
    float ps[4] = {0.f, 0.f, 0.f, 0.f};
#pragma unroll
    for (int nj = 0; nj < 4; ++nj)
#pragma unroll
      for (int r = 0; r < 4; ++r) {
        float p = __expf(s[nj][r] - mrun[r]);
        ps[r] += p;
        Plds[wave][lg * 4 + r][nj * 16 + lr] = f2b(p);
      }
#pragma unroll
    for (int r = 0; r < 4; ++r) {
      ps[r] += __shfl_xor(ps[r], 1);
      ps[r] += __shfl_xor(ps[r], 2);
      ps[r] += __shfl_xor(ps[r], 4);
      ps[r] += __shfl_xor(ps[r], 8);
      lrun[r] += ps[r];
    }

    bf16x8 pa[2];
    pa[0] = *(const bf16x8*)&Plds[wave][lr][lg * 8];
    pa[1] = *(const bf16x8*)&Plds[wave][lr][32 + lg * 8];
#pragma unroll
    for (int nd = 0; nd < 4; ++nd) {
      acc[nd] = __builtin_amdgcn_mfma_f32_16x16x32_bf16(pa[0], vf[nd][0], acc[nd], 0, 0, 0);
      acc[nd] = __builtin_amdgcn_mfma_f32_16x16x32_bf16(pa[1], vf[nd][1], acc[nd], 0, 0, 0);
    }
  }

  if (nc == 1) {
    // single chunk: finalize directly
#pragma unroll
    for (int r = 0; r < 4; ++r) {
      float inv = 1.f / lrun[r];
      int ig = i0 + lg * 4 + r;
      unsigned short* ob = yhb + (size_t)(b * TT + ig) * CC + h * HD;
#pragma unroll
      for (int nd = 0; nd < 4; ++nd)
        ob[nd * 16 + lr] = f2b(acc[nd][r] * inv);
    }
  } else {
    // write partials (rows >= 512): pacc bf16 unnormalized, pml (m,l) fp32
#pragma unroll
    for (int r = 0; r < 4; ++r) {
      int rloc = i0 + lg * 4 + r - 512;
      size_t base = ((size_t)(c * (BB * NH) + bh) * PROWS + rloc);
      unsigned short* pa_ = pacc + base * HD;
#pragma unroll
      for (int nd = 0; nd < 4; ++nd)
        pa_[nd * 16 + lr] = f2b(acc[nd][r]);
      if (lr == 0) {
        pml[base * 2 + 0] = mrun[r];
        pml[base * 2 + 1] = lrun[r];
      }
    }
  }
}

// ---------------------------------------------------------------------------
// Combine partials for rows 512..2047: yhb = (sum_c e^{m_c-m} acc_c) / l.
// Block = 4 waves, one row each; lane = d. Grid (384, 12, 2).
// ---------------------------------------------------------------------------
__global__ __launch_bounds__(256) void combine_kernel(
    const unsigned short* __restrict__ pacc, const float* __restrict__ pml,
    unsigned short* __restrict__ yhb) {
  int h = blockIdx.y, b = blockIdx.z;
  int wave = threadIdx.x >> 6, lane = threadIdx.x & 63;
  int rloc = blockIdx.x * 4 + wave;
  int i = 512 + rloc;
  int g4 = i >> 6;
  int nc = (g4 >> 3) + 1;
  int bh = b * NH + h;

  float mv[4], m = -1e30f;
#pragma unroll 4
  for (int c = 0; c < nc; ++c) {
    mv[c] = pml[((size_t)(c * (BB * NH) + bh) * PROWS + rloc) * 2 + 0];
    m = fmaxf(m, mv[c]);
  }
  float accv = 0.f, l = 0.f;
#pragma unroll 4
  for (int c = 0; c < nc; ++c) {
    size_t base = (size_t)(c * (BB * NH) + bh) * PROWS + rloc;
    float w = __expf(mv[c] - m);
    accv += w * b2f(pacc[base * HD + lane]);
    l += w * pml[base * 2 + 1];
  }
  yhb[(size_t)(b * TT + i) * CC + h * HD + lane] = f2b(accv / l);
}

// ---------------------------------------------------------------------------
// M[0,b,i,j] = i - ffsum[b,j]
// ---------------------------------------------------------------------------
__global__ __launch_bounds__(256) void m_kernel(
    const float* __restrict__ ffsum, float* __restrict__ Mout) {
  int idx = blockIdx.x * blockDim.x + threadIdx.x;
  int stride = gridDim.x * blockDim.x;
  for (; idx < M_ELEMS; idx += stride) {
    int j = idx & (TT - 1);
    int i = (idx >> 11) & (TT - 1);
    int b = idx >> 22;
    Mout[idx] = (float)i - ffsum[(b << 11) + j];
  }
}

// ---------------------------------------------------------------------------
extern "C" void kernel_launch(void* const* d_in, const int* in_sizes, int n_in,
                              void* d_out, int out_size, void* d_ws, size_t ws_size,
                              hipStream_t stream) {
  const float* x      = (const float*)d_in[0];
  const float* w_attn = (const float*)d_in[1];
  const float* b_attn = (const float*)d_in[2];
  const float* w_proj = (const float*)d_in[3];
  const float* b_proj = (const float*)d_in[4];

  float* y    = (float*)d_out;          // [B,T,C]
  float* Mreg = y + Y_ELEMS;            // [B,T,T]: S0 -> FF (scratch) -> M (final)

  float* ws = (float*)d_ws;
  float* q0       = ws;                         // B*T*64
  float* k0       = q0 + (size_t)BB * TT * HD;
  float* partials = k0 + (size_t)BB * TT * HD;  // B*16*T
  float* ffsum    = partials + BB * 16 * TT;    // B*T
  unsigned short* xb  = (unsigned short*)(ffsum + BB * TT);   // B*T*C
  unsigned short* wbT = xb + (size_t)Y_ELEMS;                 // 2304*768
  unsigned short* wpT = wbT + (size_t)N3 * CC;                // 768*768
  unsigned short* Qb  = wpT + (size_t)CC * CC;                // B*NH*T*HD
  unsigned short* Kb  = Qb + (size_t)BB * NH * TT * HD;
  unsigned short* Vt  = Kb + (size_t)BB * NH * TT * HD;
  unsigned short* yhb = Vt + (size_t)BB * NH * TT * HD;       // B*T*C
  unsigned short* pacc = yhb + (size_t)Y_ELEMS;               // 4*24*1536*64 bf16
  float* pml = (float*)(pacc + (size_t)4 * BB * NH * PROWS * HD);  // *2 f32
  // total ws usage ~= 59 MB

  // 1. packs: x -> bf16; weights -> transposed bf16
  pack_x<<<Y_ELEMS / (256 * 8), 256, 0, stream>>>(x, xb);
  transpose_pack<<<dim3(CC / 64, N3 / 64), 256, 0, stream>>>(w_attn, wbT, N3);
  transpose_pack<<<dim3(CC / 64, CC / 64), 256, 0, stream>>>(w_proj, wpT, CC);
  // 2. bf16 MFMA QKV GEMM -> packed Qb (pre-scaled 1/8) / Kb / Vt
  gemm_qkv_bf16<<<dim3(32, 36), 256, 0, stream>>>(xb, wbT, b_attn, Qb, Kb, Vt);
  // 3. fp32 head-0 q,k (precision-critical FF path)
  sgemm_qk0<<<dim3(64, 2), 256, 0, stream>>>(x, w_attn, b_attn, q0, k0);
  // 4. head-0 scores (relu'd, fp32) into Mreg
  score0_kernel<<<dim3(32, 32, BB), 256, 0, stream>>>(q0, k0, Mreg);
  // 5. column-wise exclusive scan (in place): Mreg = FF
  scan_partial<<<dim3(8, 16, BB), 256, 0, stream>>>(Mreg, partials);
  scan_write<<<dim3(8, 16, BB), 256, 0, stream>>>(Mreg, partials);
  // 6. FF_sum
  ffsum_kernel<<<dim3(TT, BB), 256, 0, stream>>>(Mreg, ffsum);
  // 7. split-K MFMA flash attention (reads FF from Mreg)
  attn_mfma<<<dim3(80, NH, BB), 256, 0, stream>>>(Qb, Kb, Vt, Mreg, yhb, pacc, pml);
  // 8. combine partials for rows 512..2047
  combine_kernel<<<dim3(PROWS / 4, NH, BB), 256, 0, stream>>>(pacc, pml, yhb);
  // 9. M output (overwrites Mreg AFTER attention consumed FF)
  m_kernel<<<4096, 256, 0, stream>>>(ffsum, Mreg);
  // 10. y = yhb @ w_proj + b_proj (bf16 MFMA)
  gemm_proj_bf16<<<dim3(32, 12), 256, 0, stream>>>(yhb, wpT, b_proj, y);
}

// Round 6
// 447.818 us; speedup vs baseline: 1.1273x; 1.1273x over previous
//
#include <hip/hip_runtime.h>
#include <cstddef>

// Problem constants
#define TT 2048
#define BB 2
#define CC 768
#define NH 12
#define HD 64
#define N3 2304          // 3*NH*HD
#define Y_ELEMS (BB*TT*CC)          // 3145728
#define M_ELEMS (BB*TT*TT)          // 8388608

typedef __attribute__((ext_vector_type(8))) short bf16x8;
typedef __attribute__((ext_vector_type(4))) float f32x4;

__device__ inline unsigned short f2b(float f) {
  union { float f; unsigned u; } v; v.f = f;
  unsigned r = (v.u + 0x7FFFu + ((v.u >> 16) & 1u)) >> 16;
  return (unsigned short)r;
}
__device__ inline float b2f(unsigned short u) {
  union { unsigned u; float f; } v; v.u = (unsigned)u << 16; return v.f;
}

// ---------------------------------------------------------------------------
// pack x (fp32) -> xb (bf16). 8 elems/thread.
// ---------------------------------------------------------------------------
__global__ __launch_bounds__(256) void pack_x(
    const float* __restrict__ x, unsigned short* __restrict__ xb) {
  size_t i = ((size_t)blockIdx.x * 256 + threadIdx.x) * 8;
  float4 a = *(const float4*)(x + i);
  float4 b = *(const float4*)(x + i + 4);
  ushort4 o0, o1;
  o0.x = f2b(a.x); o0.y = f2b(a.y); o0.z = f2b(a.z); o0.w = f2b(a.w);
  o1.x = f2b(b.x); o1.y = f2b(b.y); o1.z = f2b(b.z); o1.w = f2b(b.w);
  *(ushort4*)(xb + i) = o0;
  *(ushort4*)(xb + i + 4) = o1;
}

// ---------------------------------------------------------------------------
// W [768][N] fp32 -> WT [N][768] bf16 (transposed pack). Block=(kt,nt) 64x64.
// ---------------------------------------------------------------------------
__global__ __launch_bounds__(256) void transpose_pack(
    const float* __restrict__ W, unsigned short* __restrict__ WT, int N) {
  __shared__ float tile[64][65];
  int kt = blockIdx.x, nt = blockIdx.y;
  int tid = threadIdx.x;
  int r = tid >> 4, c4 = (tid & 15) << 2;
#pragma unroll
  for (int rep = 0; rep < 4; ++rep) {
    int row = rep * 16 + r;
    float4 v = *(const float4*)(W + (size_t)(kt * 64 + row) * N + nt * 64 + c4);
    tile[row][c4 + 0] = v.x; tile[row][c4 + 1] = v.y;
    tile[row][c4 + 2] = v.z; tile[row][c4 + 3] = v.w;
  }
  __syncthreads();
#pragma unroll
  for (int rep = 0; rep < 4; ++rep) {
    int nrow = rep * 16 + r;
    ushort4 o;
    o.x = f2b(tile[c4 + 0][nrow]); o.y = f2b(tile[c4 + 1][nrow]);
    o.z = f2b(tile[c4 + 2][nrow]); o.w = f2b(tile[c4 + 3][nrow]);
    *(ushort4*)(WT + (size_t)(nt * 64 + nrow) * CC + kt * 64 + c4) = o;
  }
}

// ---------------------------------------------------------------------------
// bf16 MFMA GEMM: qkv = xb @ wbT^T + b_attn -> packed Qb (pre-scaled 1/8),
// Kb, Vt (transposed via LDS). Grid (32 mtiles of 128, 36 ntiles of 64).
// ---------------------------------------------------------------------------
__global__ __launch_bounds__(256, 2) void gemm_qkv_bf16(
    const unsigned short* __restrict__ xb, const unsigned short* __restrict__ wbT,
    const float* __restrict__ b_attn,
    unsigned short* __restrict__ Qb, unsigned short* __restrict__ Kb,
    unsigned short* __restrict__ Vt) {
  __shared__ __align__(16) unsigned short Vlds[128][72];
  int mt = blockIdx.x, nt = blockIdx.y;
  int sec = nt / NH, h = nt % NH;
  int wave = threadIdx.x >> 6, lane = threadIdx.x & 63;
  int lr = lane & 15, lg = lane >> 4;
  int m0 = mt * 128 + wave * 32;
  int n0 = nt * 64;
  const unsigned short* Ab = xb + (size_t)m0 * CC;
  const unsigned short* Bb = wbT + (size_t)n0 * CC;

  f32x4 acc[2][4];
#pragma unroll
  for (int mi = 0; mi < 2; ++mi)
#pragma unroll
    for (int nj = 0; nj < 4; ++nj) acc[mi][nj] = (f32x4){0.f, 0.f, 0.f, 0.f};

#pragma unroll
  for (int ks = 0; ks < 24; ++ks) {
    int k0 = ks * 32;
    bf16x8 af[2], bf[4];
#pragma unroll
    for (int mi = 0; mi < 2; ++mi)
      af[mi] = *(const bf16x8*)(Ab + (size_t)(mi * 16 + lr) * CC + k0 + lg * 8);
#pragma unroll
    for (int nj = 0; nj < 4; ++nj)
      bf[nj] = *(const bf16x8*)(Bb + (size_t)(nj * 16 + lr) * CC + k0 + lg * 8);
#pragma unroll
    for (int nj = 0; nj < 4; ++nj)
#pragma unroll
      for (int mi = 0; mi < 2; ++mi)
        acc[mi][nj] = __builtin_amdgcn_mfma_f32_16x16x32_bf16(af[mi], bf[nj], acc[mi][nj], 0, 0, 0);
  }

  int b = m0 >> 11;
  int bh = b * NH + h;
  float bias[4];
#pragma unroll
  for (int nj = 0; nj < 4; ++nj) bias[nj] = b_attn[n0 + nj * 16 + lr];

  if (sec < 2) {
    // Q is pre-scaled by 1/8 (exact in bf16: exponent shift only)
    float qscale = (sec == 0) ? 0.125f : 1.0f;
    unsigned short* Out = (sec == 0 ? Qb : Kb) + (size_t)bh * TT * HD;
    int tbase = (m0 & 2047) + lg * 4;
#pragma unroll
    for (int mi = 0; mi < 2; ++mi)
#pragma unroll
      for (int r = 0; r < 4; ++r) {
        int t = tbase + mi * 16 + r;
#pragma unroll
        for (int nj = 0; nj < 4; ++nj)
          Out[(size_t)t * HD + nj * 16 + lr] = f2b((acc[mi][nj][r] + bias[nj]) * qscale);
      }
  } else {
    int tl = wave * 32 + lg * 4;
#pragma unroll
    for (int mi = 0; mi < 2; ++mi)
#pragma unroll
      for (int r = 0; r < 4; ++r)
#pragma unroll
        for (int nj = 0; nj < 4; ++nj)
          Vlds[tl + mi * 16 + r][nj * 16 + lr] = f2b(acc[mi][nj][r] + bias[nj]);
    __syncthreads();
    int d = threadIdx.x & 63, tc = threadIdx.x >> 6;
    int tblk = (mt * 128) & 2047;
    unsigned short* Ov = Vt + ((size_t)bh * HD + d) * TT + tblk + tc * 32;
#pragma unroll
    for (int i8 = 0; i8 < 4; ++i8) {
      ushort4 o0, o1;
      o0.x = Vlds[tc * 32 + i8 * 8 + 0][d]; o0.y = Vlds[tc * 32 + i8 * 8 + 1][d];
      o0.z = Vlds[tc * 32 + i8 * 8 + 2][d]; o0.w = Vlds[tc * 32 + i8 * 8 + 3][d];
      o1.x = Vlds[tc * 32 + i8 * 8 + 4][d]; o1.y = Vlds[tc * 32 + i8 * 8 + 5][d];
      o1.z = Vlds[tc * 32 + i8 * 8 + 6][d]; o1.w = Vlds[tc * 32 + i8 * 8 + 7][d];
      *(ushort4*)(Ov + i8 * 8) = o0;
      *(ushort4*)(Ov + i8 * 8 + 4) = o1;
    }
  }
}

// ---------------------------------------------------------------------------
// bf16 MFMA GEMM: y = yhb @ wpT^T + b_proj (fp32 out). Grid (32, 12).
// ---------------------------------------------------------------------------
__global__ __launch_bounds__(256, 2) void gemm_proj_bf16(
    const unsigned short* __restrict__ yhb, const unsigned short* __restrict__ wpT,
    const float* __restrict__ b_proj, float* __restrict__ y) {
  int mt = blockIdx.x, nt = blockIdx.y;
  int wave = threadIdx.x >> 6, lane = threadIdx.x & 63;
  int lr = lane & 15, lg = lane >> 4;
  int m0 = mt * 128 + wave * 32;
  int n0 = nt * 64;
  const unsigned short* Ab = yhb + (size_t)m0 * CC;
  const unsigned short* Bb = wpT + (size_t)n0 * CC;

  f32x4 acc[2][4];
#pragma unroll
  for (int mi = 0; mi < 2; ++mi)
#pragma unroll
    for (int nj = 0; nj < 4; ++nj) acc[mi][nj] = (f32x4){0.f, 0.f, 0.f, 0.f};

#pragma unroll
  for (int ks = 0; ks < 24; ++ks) {
    int k0 = ks * 32;
    bf16x8 af[2], bf[4];
#pragma unroll
    for (int mi = 0; mi < 2; ++mi)
      af[mi] = *(const bf16x8*)(Ab + (size_t)(mi * 16 + lr) * CC + k0 + lg * 8);
#pragma unroll
    for (int nj = 0; nj < 4; ++nj)
      bf[nj] = *(const bf16x8*)(Bb + (size_t)(nj * 16 + lr) * CC + k0 + lg * 8);
#pragma unroll
    for (int nj = 0; nj < 4; ++nj)
#pragma unroll
      for (int mi = 0; mi < 2; ++mi)
        acc[mi][nj] = __builtin_amdgcn_mfma_f32_16x16x32_bf16(af[mi], bf[nj], acc[mi][nj], 0, 0, 0);
  }

  float bias[4];
#pragma unroll
  for (int nj = 0; nj < 4; ++nj) bias[nj] = b_proj[n0 + nj * 16 + lr];
#pragma unroll
  for (int mi = 0; mi < 2; ++mi)
#pragma unroll
    for (int r = 0; r < 4; ++r) {
      int m = m0 + mi * 16 + lg * 4 + r;
#pragma unroll
      for (int nj = 0; nj < 4; ++nj)
        y[(size_t)m * CC + n0 + nj * 16 + lr] = acc[mi][nj][r] + bias[nj];
    }
}

// ---------------------------------------------------------------------------
// fp32 GEMM for head-0 q,k only (precision-critical FF path). Grid (64, 2).
// ---------------------------------------------------------------------------
__global__ __launch_bounds__(256) void sgemm_qk0(
    const float* __restrict__ x, const float* __restrict__ w_attn,
    const float* __restrict__ b_attn, float* __restrict__ q0,
    float* __restrict__ k0) {
  __shared__ float As[16][64];
  __shared__ float Bs[16][64];
  int sec = blockIdx.y;
  const float* Bw = w_attn + sec * CC;
  float* Out = sec ? k0 : q0;
  int tid = threadIdx.x;
  int tx = tid & 15, ty = tid >> 4;
  int m0 = blockIdx.x * 64;

  int arow = tid >> 2;
  int acol4 = (tid & 3) << 2;
  int brow = tid >> 4;
  int bcol4 = (tid & 15) << 2;

  const float* Aptr = x + (size_t)(m0 + arow) * CC + acol4;
  const float* Bptr = Bw + (size_t)brow * N3 + bcol4;

  float acc[4][4] = {};

  for (int k0_ = 0; k0_ < CC; k0_ += 16) {
    float4 av = *(const float4*)(Aptr + k0_);
    float4 bv = *(const float4*)(Bptr + (size_t)k0_ * N3);
    As[acol4 + 0][arow] = av.x;
    As[acol4 + 1][arow] = av.y;
    As[acol4 + 2][arow] = av.z;
    As[acol4 + 3][arow] = av.w;
    *(float4*)&Bs[brow][bcol4] = bv;
    __syncthreads();
#pragma unroll
    for (int kk = 0; kk < 16; ++kk) {
      float4 a4 = *(const float4*)&As[kk][ty << 2];
      float4 b4 = *(const float4*)&Bs[kk][tx << 2];
      float a[4] = {a4.x, a4.y, a4.z, a4.w};
      float b[4] = {b4.x, b4.y, b4.z, b4.w};
#pragma unroll
      for (int ii = 0; ii < 4; ++ii)
#pragma unroll
        for (int jj = 0; jj < 4; ++jj) acc[ii][jj] += a[ii] * b[jj];
    }
    __syncthreads();
  }

  float4 bv = *(const float4*)(b_attn + sec * CC + (tx << 2));
#pragma unroll
  for (int ii = 0; ii < 4; ++ii) {
    int m = m0 + (ty << 2) + ii;
    float4 o;
    o.x = acc[ii][0] + bv.x;
    o.y = acc[ii][1] + bv.y;
    o.z = acc[ii][2] + bv.z;
    o.w = acc[ii][3] + bv.w;
    *(float4*)(Out + (size_t)m * HD + (tx << 2)) = o;
  }
}

// ---------------------------------------------------------------------------
// Head-0 scores (fp32): Sbuf[b,i,j] = relu(dot(q0,k0)/8), lower-tri tiles.
// ---------------------------------------------------------------------------
__global__ __launch_bounds__(256) void score0_kernel(
    const float* __restrict__ q0, const float* __restrict__ k0,
    float* __restrict__ Sbuf) {
  int it = blockIdx.x, jt = blockIdx.y, b = blockIdx.z;
  if (jt > it) return;
  __shared__ float Qs[64][64];
  __shared__ float Ks[64][64];
  int tid = threadIdx.x;
  int row = tid >> 2;
  int dq = (tid & 3) << 2;
  int i0 = it * 64, j0 = jt * 64;
  const float* qb = q0 + (size_t)((b * TT) + i0 + row) * HD;
  const float* kb = k0 + (size_t)((b * TT) + j0 + row) * HD;
#pragma unroll
  for (int rep = 0; rep < 4; ++rep) {
    int d = dq + rep * 16;
    float4 qv = *(const float4*)(qb + d);
    float4 kv = *(const float4*)(kb + d);
    Qs[d + 0][row] = qv.x; Qs[d + 1][row] = qv.y;
    Qs[d + 2][row] = qv.z; Qs[d + 3][row] = qv.w;
    Ks[d + 0][row] = kv.x; Ks[d + 1][row] = kv.y;
    Ks[d + 2][row] = kv.z; Ks[d + 3][row] = kv.w;
  }
  __syncthreads();
  int tx = tid & 15, ty = tid >> 4;
  float acc[4][4] = {};
#pragma unroll 8
  for (int kk = 0; kk < 64; ++kk) {
    float4 a4 = *(const float4*)&Qs[kk][ty << 2];
    float4 b4 = *(const float4*)&Ks[kk][tx << 2];
    float a[4] = {a4.x, a4.y, a4.z, a4.w};
    float b[4] = {b4.x, b4.y, b4.z, b4.w};
#pragma unroll
    for (int ii = 0; ii < 4; ++ii)
#pragma unroll
      for (int jj = 0; jj < 4; ++jj) acc[ii][jj] += a[ii] * b[jj];
  }
#pragma unroll
  for (int ii = 0; ii < 4; ++ii) {
    int gi = (b * TT) + i0 + (ty << 2) + ii;
    float4 o;
    o.x = fmaxf(acc[ii][0] * 0.125f, 0.f);
    o.y = fmaxf(acc[ii][1] * 0.125f, 0.f);
    o.z = fmaxf(acc[ii][2] * 0.125f, 0.f);
    o.w = fmaxf(acc[ii][3] * 0.125f, 0.f);
    *(float4*)(Sbuf + (size_t)gi * TT + j0 + (tx << 2)) = o;
  }
}

// ---------------------------------------------------------------------------
// Column-wise exclusive prefix scan over rows (chunked, two passes).
// scan_write also emits E = exp(-FF) in bf16 with a j-swizzled layout:
// within each 64-col tile, element j is stored at ((j&15)<<2)|((j>>4)&3)
// so the attention lane's 4 columns {lr,16+lr,32+lr,48+lr} are contiguous.
// ---------------------------------------------------------------------------
__global__ __launch_bounds__(256) void scan_partial(
    const float* __restrict__ Sbuf, float* __restrict__ partials) {
  int j = blockIdx.x * 256 + threadIdx.x;
  int chunk = blockIdx.y, b = blockIdx.z;
  int r0 = chunk * 128;
  const float* base = Sbuf + (size_t)(b * TT + r0) * TT + j;
  float sum = 0.f;
  for (int rr = 0; rr < 128; ++rr) {
    int r = r0 + rr;
    float v = (j >= 1 && j < r) ? base[(size_t)rr * TT] : 0.f;
    sum += v;
  }
  partials[(size_t)(b * 16 + chunk) * TT + j] = sum;
}

__global__ __launch_bounds__(256) void scan_write(
    float* __restrict__ Sbuf, const float* __restrict__ partials,
    unsigned short* __restrict__ Eb) {
  int j = blockIdx.x * 256 + threadIdx.x;
  int chunk = blockIdx.y, b = blockIdx.z;
  float run = 0.f;
  for (int c = 0; c < chunk; ++c) run += partials[(size_t)(b * 16 + c) * TT + j];
  int r0 = chunk * 128;
  int jswz = (j & ~63) | ((j & 15) << 2) | ((j >> 4) & 3);
  float* base = Sbuf + (size_t)(b * TT + r0) * TT + j;
  unsigned short* ebase = Eb + (size_t)(b * TT + r0) * TT + jswz;
  for (int rr = 0; rr < 128; ++rr) {
    int r = r0 + rr;
    float v = (j >= 1 && j < r) ? base[(size_t)rr * TT] : 0.f;
    base[(size_t)rr * TT] = run;                 // FF (fp32, for ffsum/M)
    ebase[(size_t)rr * TT] = f2b(__expf(-run));  // E (bf16, for attention)
    run += v;
  }
}

// ---------------------------------------------------------------------------
// FF_sum[b,i] = sum_j clip(FF[b,i,j], 0, 1)
// ---------------------------------------------------------------------------
__global__ __launch_bounds__(256) void ffsum_kernel(
    const float* __restrict__ FF, float* __restrict__ ffsum) {
  int i = blockIdx.x, b = blockIdx.y;
  const float4* row = (const float4*)(FF + (size_t)(b * TT + i) * TT);
  float s = 0.f;
  for (int r = threadIdx.x; r < TT / 4; r += 256) {
    float4 v = row[r];
    s += fminf(fmaxf(v.x, 0.f), 1.f) + fminf(fmaxf(v.y, 0.f), 1.f) +
         fminf(fmaxf(v.z, 0.f), 1.f) + fminf(fmaxf(v.w, 0.f), 1.f);
  }
#pragma unroll
  for (int o = 1; o < 64; o <<= 1) s += __shfl_xor(s, o);
  __shared__ float ws[4];
  if ((threadIdx.x & 63) == 0) ws[threadIdx.x >> 6] = s;
  __syncthreads();
  if (threadIdx.x == 0) ffsum[b * TT + i] = ws[0] + ws[1] + ws[2] + ws[3];
}

// ---------------------------------------------------------------------------
// bf16 MFMA flash attention with multiplicative E = exp(-FF) penalty.
// Grid (24, 32): x encodes (b,h) so that XCD = x%8 serves ONE batch and 3
// heads (K/V/Q working set 2.3MB fits the 4MB XCD L2); y = reversed g4.
// 4 waves x 16 q-rows. Per-wave pipeline: K-frags and E prefetched one tile
// ahead (ping-pong, no rotate); V at tile top; setprio around MFMA.
// Softmax: m tracks raw s only (E<=1 bounds P; col0 has E=1 so l>0).
// ---------------------------------------------------------------------------
__global__ __launch_bounds__(256, 3) void attn_mfma(
    const unsigned short* __restrict__ Qb, const unsigned short* __restrict__ Kb,
    const unsigned short* __restrict__ Vt, const unsigned short* __restrict__ Eb,
    unsigned short* __restrict__ yhb) {
  int xbh = blockIdx.x;
  int b = (xbh >> 2) & 1;
  int h = ((xbh >> 3) << 2) | (xbh & 3);
  int g4 = 31 - (int)blockIdx.y;
  int wave = threadIdx.x >> 6, lane = threadIdx.x & 63;
  int lr = lane & 15, lg = lane >> 4;
  int i0 = g4 * 64 + wave * 16;
  int bh = b * NH + h;
  const unsigned short* Qh = Qb + (size_t)bh * TT * HD;
  const unsigned short* Kh = Kb + (size_t)bh * TT * HD;
  const unsigned short* Vh = Vt + (size_t)bh * HD * TT;
  const unsigned short* Erow = Eb + ((size_t)(b * TT) + i0 + lg * 4) * TT + 4 * lr;

  __shared__ __align__(16) unsigned short Plds[4][16][80];

  bf16x8 qf[2];
#pragma unroll
  for (int ks = 0; ks < 2; ++ks)
    qf[ks] = *(const bf16x8*)(Qh + (size_t)(i0 + lr) * HD + ks * 32 + lg * 8);

  f32x4 acc[4];
  float mrun[4], lrun[4];
#pragma unroll
  for (int q = 0; q < 4; ++q) {
    acc[q] = (f32x4){0.f, 0.f, 0.f, 0.f};
    mrun[q] = -1e30f;
    lrun[q] = 0.f;
  }

  bf16x8 kfA[4][2], kfB[4][2], vf[4][2];
  ushort4 evA[4], evB[4];
  // prologue: prefetch tile 0 into A
#pragma unroll
  for (int nj = 0; nj < 4; ++nj) {
    kfA[nj][0] = *(const bf16x8*)(Kh + (size_t)(nj * 16 + lr) * HD + lg * 8);
    kfA[nj][1] = *(const bf16x8*)(Kh + (size_t)(nj * 16 + lr) * HD + 32 + lg * 8);
  }
#pragma unroll
  for (int r = 0; r < 4; ++r)
    evA[r] = *(const ushort4*)(Erow + (size_t)r * TT);

#define TILE_STEP(KFU, EVU, KFP, EVP, KT)                                       \
  {                                                                             \
    const int j0_ = (KT) * 64;                                                  \
    /* V for current tile (cover: QK + softmax; L2-resident) */                 \
    _Pragma("unroll")                                                           \
    for (int nd = 0; nd < 4; ++nd) {                                            \
      vf[nd][0] = *(const bf16x8*)(Vh + (size_t)(nd * 16 + lr) * TT + j0_ + lg * 8);        \
      vf[nd][1] = *(const bf16x8*)(Vh + (size_t)(nd * 16 + lr) * TT + j0_ + 32 + lg * 8);   \
    }                                                                           \
    /* prefetch next tile's K and E */                                          \
    if ((KT) < g4) {                                                            \
      const int jn_ = j0_ + 64;                                                 \
      _Pragma("unroll")                                                         \
      for (int nj = 0; nj < 4; ++nj) {                                          \
        KFP[nj][0] = *(const bf16x8*)(Kh + (size_t)(jn_ + nj * 16 + lr) * HD + lg * 8);     \
        KFP[nj][1] = *(const bf16x8*)(Kh + (size_t)(jn_ + nj * 16 + lr) * HD + 32 + lg * 8);\
      }                                                                         \
      _Pragma("unroll")                                                         \
      for (int r = 0; r < 4; ++r)                                               \
        EVP[r] = *(const ushort4*)(Erow + (size_t)r * TT + jn_);                \
    }                                                                           \
    f32x4 s[4];                                                                 \
    __builtin_amdgcn_s_setprio(1);                                              \
    _Pragma("unroll")                                                           \
    for (int nj = 0; nj < 4; ++nj) {                                            \
      f32x4 z = (f32x4){0.f, 0.f, 0.f, 0.f};                                    \
      z = __builtin_amdgcn_mfma_f32_16x16x32_bf16(qf[0], KFU[nj][0], z, 0, 0, 0);           \
      s[nj] = __builtin_amdgcn_mfma_f32_16x16x32_bf16(qf[1], KFU[nj][1], z, 0, 0, 0);       \
    }                                                                           \
    __builtin_amdgcn_s_setprio(0);                                              \
    const int ibase_ = i0 + lg * 4;                                             \
    float mt[4] = {-1e30f, -1e30f, -1e30f, -1e30f};                             \
    if ((KT) == g4) {                                                           \
      _Pragma("unroll")                                                         \
      for (int nj = 0; nj < 4; ++nj)                                            \
        _Pragma("unroll")                                                       \
        for (int r = 0; r < 4; ++r) {                                           \
          float lv = (j0_ + nj * 16 + lr <= ibase_ + r) ? s[nj][r] : -1e30f;    \
          s[nj][r] = lv;                                                        \
          mt[r] = fmaxf(mt[r], lv);                                             \
        }                                                                       \
    } else {                                                                    \
      _Pragma("unroll")                                                         \
      for (int nj = 0; nj < 4; ++nj)                                            \
        _Pragma("unroll")                                                       \
        for (int r = 0; r < 4; ++r) mt[r] = fmaxf(mt[r], s[nj][r]);             \
    }                                                                           \
    float needup = -1.f;                                                        \
    _Pragma("unroll")                                                           \
    for (int r = 0; r < 4; ++r) {                                               \
      mt[r] = fmaxf(mt[r], __shfl_xor(mt[r], 1));                               \
      mt[r] = fmaxf(mt[r], __shfl_xor(mt[r], 2));                               \
      mt[r] = fmaxf(mt[r], __shfl_xor(mt[r], 4));                               \
      mt[r] = fmaxf(mt[r], __shfl_xor(mt[r], 8));                               \
      needup = fmaxf(needup, mt[r] - mrun[r]);                                  \
    }                                                                           \
    if (__any(needup > 0.f)) {                                                  \
      _Pragma("unroll")                                                         \
      for (int r = 0; r < 4; ++r) {                                             \
        float mnew = fmaxf(mrun[r], mt[r]);                                     \
        float scl = __expf(mrun[r] - mnew);                                     \
        mrun[r] = mnew;                                                         \
        lrun[r] *= scl;                                                         \
        _Pragma("unroll")                                                       \
        for (int nd = 0; nd < 4; ++nd) acc[nd][r] *= scl;                       \
      }                                                                         \
    }                                                                           \
    float ps[4] = {0.f, 0.f, 0.f, 0.f};                                         \
    _Pragma("unroll")                                                           \
    for (int r = 0; r < 4; ++r) {                                               \
      float e0 = b2f(EVU[r].x), e1 = b2f(EVU[r].y);                             \
      float e2 = b2f(EVU[r].z), e3 = b2f(EVU[r].w);                             \
      float p0 = e0 * __expf(s[0][r] - mrun[r]);                                \
      float p1 = e1 * __expf(s[1][r] - mrun[r]);                                \
      float p2 = e2 * __expf(s[2][r] - mrun[r]);                                \
      float p3 = e3 * __expf(s[3][r] - mrun[r]);                                \
      ps[r] = p0 + p1 + p2 + p3;                                                \
      Plds[wave][lg * 4 + r][0 * 16 + lr] = f2b(p0);                            \
      Plds[wave][lg * 4 + r][1 * 16 + lr] = f2b(p1);                            \
      Plds[wave][lg * 4 + r][2 * 16 + lr] = f2b(p2);                            \
      Plds[wave][lg * 4 + r][3 * 16 + lr] = f2b(p3);                            \
    }                                                                           \
    _Pragma("unroll")                                                           \
    for (int r = 0; r < 4; ++r) {                                               \
      ps[r] += __shfl_xor(ps[r], 1);                                            \
      ps[r] += __shfl_xor(ps[r], 2);                                            \
      ps[r] += __shfl_xor(ps[r], 4);                                            \
      ps[r] += __shfl_xor(ps[r], 8);                                            \
      lrun[r] += ps[r];                                                         \
    }                                                                           \
    bf16x8 pa0 = *(const bf16x8*)&Plds[wave][lr][lg * 8];                       \
    bf16x8 pa1 = *(const bf16x8*)&Plds[wave][lr][32 + lg * 8];                  \
    __builtin_amdgcn_s_setprio(1);                                              \
    _Pragma("unroll")                                                           \
    for (int nd = 0; nd < 4; ++nd) {                                            \
      acc[nd] = __builtin_amdgcn_mfma_f32_16x16x32_bf16(pa0, vf[nd][0], acc[nd], 0, 0, 0);  \
      acc[nd] = __builtin_amdgcn_mfma_f32_16x16x32_bf16(pa1, vf[nd][1], acc[nd], 0, 0, 0);  \
    }                                                                           \
    __builtin_amdgcn_s_setprio(0);                                              \
  }

  for (int kt = 0; kt <= g4; kt += 2) {
    TILE_STEP(kfA, evA, kfB, evB, kt)
    if (kt + 1 <= g4) {
      TILE_STEP(kfB, evB, kfA, evA, kt + 1)
    }
  }
#undef TILE_STEP

  // epilogue: normalize and store bf16
#pragma unroll
  for (int r = 0; r < 4; ++r) {
    float inv = 1.f / lrun[r];
    int ig = i0 + lg * 4 + r;
    unsigned short* ob = yhb + (size_t)(b * TT + ig) * CC + h * HD;
#pragma unroll
    for (int nd = 0; nd < 4; ++nd)
      ob[nd * 16 + lr] = f2b(acc[nd][r] * inv);
  }
}

// ---------------------------------------------------------------------------
// M[0,b,i,j] = i - ffsum[b,j]
// ---------------------------------------------------------------------------
__global__ __launch_bounds__(256) void m_kernel(
    const float* __restrict__ ffsum, float* __restrict__ Mout) {
  int idx = blockIdx.x * blockDim.x + threadIdx.x;
  int stride = gridDim.x * blockDim.x;
  for (; idx < M_ELEMS; idx += stride) {
    int j = idx & (TT - 1);
    int i = (idx >> 11) & (TT - 1);
    int b = idx >> 22;
    Mout[idx] = (float)i - ffsum[(b << 11) + j];
  }
}

// ---------------------------------------------------------------------------
extern "C" void kernel_launch(void* const* d_in, const int* in_sizes, int n_in,
                              void* d_out, int out_size, void* d_ws, size_t ws_size,
                              hipStream_t stream) {
  const float* x      = (const float*)d_in[0];
  const float* w_attn = (const float*)d_in[1];
  const float* b_attn = (const float*)d_in[2];
  const float* w_proj = (const float*)d_in[3];
  const float* b_proj = (const float*)d_in[4];

  float* y    = (float*)d_out;          // [B,T,C]
  float* Mreg = y + Y_ELEMS;            // [B,T,T]: S0 -> FF (scratch) -> M (final)

  float* ws = (float*)d_ws;
  float* q0       = ws;                         // B*T*64
  float* k0       = q0 + (size_t)BB * TT * HD;
  float* partials = k0 + (size_t)BB * TT * HD;  // B*16*T
  float* ffsum    = partials + BB * 16 * TT;    // B*T
  unsigned short* xb  = (unsigned short*)(ffsum + BB * TT);   // B*T*C
  unsigned short* wbT = xb + (size_t)Y_ELEMS;                 // 2304*768
  unsigned short* wpT = wbT + (size_t)N3 * CC;                // 768*768
  unsigned short* Qb  = wpT + (size_t)CC * CC;                // B*NH*T*HD
  unsigned short* Kb  = Qb + (size_t)BB * NH * TT * HD;
  unsigned short* Vt  = Kb + (size_t)BB * NH * TT * HD;
  unsigned short* yhb = Vt + (size_t)BB * NH * TT * HD;       // B*T*C
  unsigned short* Eb  = yhb + (size_t)Y_ELEMS;                // B*T*T bf16 (16.8MB)
  // total ws usage ~= 46 MB

  // 1. packs: x -> bf16; weights -> transposed bf16
  pack_x<<<Y_ELEMS / (256 * 8), 256, 0, stream>>>(x, xb);
  transpose_pack<<<dim3(CC / 64, N3 / 64), 256, 0, stream>>>(w_attn, wbT, N3);
  transpose_pack<<<dim3(CC / 64, CC / 64), 256, 0, stream>>>(w_proj, wpT, CC);
  // 2. bf16 MFMA QKV GEMM -> packed Qb (pre-scaled 1/8) / Kb / Vt
  gemm_qkv_bf16<<<dim3(32, 36), 256, 0, stream>>>(xb, wbT, b_attn, Qb, Kb, Vt);
  // 3. fp32 head-0 q,k (precision-critical FF path)
  sgemm_qk0<<<dim3(64, 2), 256, 0, stream>>>(x, w_attn, b_attn, q0, k0);
  // 4. head-0 scores (relu'd, fp32) into Mreg
  score0_kernel<<<dim3(32, 32, BB), 256, 0, stream>>>(q0, k0, Mreg);
  // 5. column-wise exclusive scan (in place): Mreg = FF; also E = exp(-FF) bf16
  scan_partial<<<dim3(8, 16, BB), 256, 0, stream>>>(Mreg, partials);
  scan_write<<<dim3(8, 16, BB), 256, 0, stream>>>(Mreg, partials, Eb);
  // 6. FF_sum (reads fp32 FF)
  ffsum_kernel<<<dim3(TT, BB), 256, 0, stream>>>(Mreg, ffsum);
  // 7. M output (attention no longer reads Mreg — only Eb)
  m_kernel<<<4096, 256, 0, stream>>>(ffsum, Mreg);
  // 8. MFMA flash attention (XCD-partitioned grid, E-multiplicative softmax)
  attn_mfma<<<dim3(24, 32), 256, 0, stream>>>(Qb, Kb, Vt, Eb, yhb);
  // 9. y = yhb @ w_proj + b_proj (bf16 MFMA)
  gemm_proj_bf16<<<dim3(32, 12), 256, 0, stream>>>(yhb, wpT, b_proj, y);
}

// Round 7
// 311.127 us; speedup vs baseline: 1.6225x; 1.4393x over previous
//
#include <hip/hip_runtime.h>
#include <cstddef>

// Problem constants
#define TT 2048
#define BB 2
#define CC 768
#define NH 12
#define HD 64
#define N3 2304          // 3*NH*HD
#define Y_ELEMS (BB*TT*CC)          // 3145728
#define M_ELEMS (BB*TT*TT)          // 8388608

typedef __attribute__((ext_vector_type(8))) short bf16x8;
typedef __attribute__((ext_vector_type(4))) float f32x4;

__device__ inline unsigned short f2b(float f) {
  union { float f; unsigned u; } v; v.f = f;
  unsigned r = (v.u + 0x7FFFu + ((v.u >> 16) & 1u)) >> 16;
  return (unsigned short)r;
}
__device__ inline float b2f(unsigned short u) {
  union { unsigned u; float f; } v; v.u = (unsigned)u << 16; return v.f;
}

// async global -> LDS, 16B per lane; lds dest is wave-uniform base, HW adds lane*16
__device__ inline void gload_lds16(const unsigned short* g, unsigned short* l) {
  __builtin_amdgcn_global_load_lds(
      (const __attribute__((address_space(1))) unsigned int*)g,
      (__attribute__((address_space(3))) unsigned int*)l, 16, 0, 0);
}

// ---------------------------------------------------------------------------
// pack x (fp32) -> xb (bf16). 8 elems/thread.
// ---------------------------------------------------------------------------
__global__ __launch_bounds__(256) void pack_x(
    const float* __restrict__ x, unsigned short* __restrict__ xb) {
  size_t i = ((size_t)blockIdx.x * 256 + threadIdx.x) * 8;
  float4 a = *(const float4*)(x + i);
  float4 b = *(const float4*)(x + i + 4);
  ushort4 o0, o1;
  o0.x = f2b(a.x); o0.y = f2b(a.y); o0.z = f2b(a.z); o0.w = f2b(a.w);
  o1.x = f2b(b.x); o1.y = f2b(b.y); o1.z = f2b(b.z); o1.w = f2b(b.w);
  *(ushort4*)(xb + i) = o0;
  *(ushort4*)(xb + i + 4) = o1;
}

// ---------------------------------------------------------------------------
// W [768][N] fp32 -> WT [N][768] bf16 (transposed pack). Block=(kt,nt) 64x64.
// ---------------------------------------------------------------------------
__global__ __launch_bounds__(256) void transpose_pack(
    const float* __restrict__ W, unsigned short* __restrict__ WT, int N) {
  __shared__ float tile[64][65];
  int kt = blockIdx.x, nt = blockIdx.y;
  int tid = threadIdx.x;
  int r = tid >> 4, c4 = (tid & 15) << 2;
#pragma unroll
  for (int rep = 0; rep < 4; ++rep) {
    int row = rep * 16 + r;
    float4 v = *(const float4*)(W + (size_t)(kt * 64 + row) * N + nt * 64 + c4);
    tile[row][c4 + 0] = v.x; tile[row][c4 + 1] = v.y;
    tile[row][c4 + 2] = v.z; tile[row][c4 + 3] = v.w;
  }
  __syncthreads();
#pragma unroll
  for (int rep = 0; rep < 4; ++rep) {
    int nrow = rep * 16 + r;
    ushort4 o;
    o.x = f2b(tile[c4 + 0][nrow]); o.y = f2b(tile[c4 + 1][nrow]);
    o.z = f2b(tile[c4 + 2][nrow]); o.w = f2b(tile[c4 + 3][nrow]);
    *(ushort4*)(WT + (size_t)(nt * 64 + nrow) * CC + kt * 64 + c4) = o;
  }
}

// ---------------------------------------------------------------------------
// bf16 MFMA GEMM: qkv = xb @ wbT^T + b_attn -> packed Qb (pre-scaled 1/8),
// Kb, Vt (transposed via LDS). Grid (32 mtiles of 128, 36 ntiles of 64).
// ---------------------------------------------------------------------------
__global__ __launch_bounds__(256, 2) void gemm_qkv_bf16(
    const unsigned short* __restrict__ xb, const unsigned short* __restrict__ wbT,
    const float* __restrict__ b_attn,
    unsigned short* __restrict__ Qb, unsigned short* __restrict__ Kb,
    unsigned short* __restrict__ Vt) {
  __shared__ __align__(16) unsigned short Vlds[128][72];
  int mt = blockIdx.x, nt = blockIdx.y;
  int sec = nt / NH, h = nt % NH;
  int wave = threadIdx.x >> 6, lane = threadIdx.x & 63;
  int lr = lane & 15, lg = lane >> 4;
  int m0 = mt * 128 + wave * 32;
  int n0 = nt * 64;
  const unsigned short* Ab = xb + (size_t)m0 * CC;
  const unsigned short* Bb = wbT + (size_t)n0 * CC;

  f32x4 acc[2][4];
#pragma unroll
  for (int mi = 0; mi < 2; ++mi)
#pragma unroll
    for (int nj = 0; nj < 4; ++nj) acc[mi][nj] = (f32x4){0.f, 0.f, 0.f, 0.f};

#pragma unroll
  for (int ks = 0; ks < 24; ++ks) {
    int k0 = ks * 32;
    bf16x8 af[2], bf[4];
#pragma unroll
    for (int mi = 0; mi < 2; ++mi)
      af[mi] = *(const bf16x8*)(Ab + (size_t)(mi * 16 + lr) * CC + k0 + lg * 8);
#pragma unroll
    for (int nj = 0; nj < 4; ++nj)
      bf[nj] = *(const bf16x8*)(Bb + (size_t)(nj * 16 + lr) * CC + k0 + lg * 8);
#pragma unroll
    for (int nj = 0; nj < 4; ++nj)
#pragma unroll
      for (int mi = 0; mi < 2; ++mi)
        acc[mi][nj] = __builtin_amdgcn_mfma_f32_16x16x32_bf16(af[mi], bf[nj], acc[mi][nj], 0, 0, 0);
  }

  int b = m0 >> 11;
  int bh = b * NH + h;
  float bias[4];
#pragma unroll
  for (int nj = 0; nj < 4; ++nj) bias[nj] = b_attn[n0 + nj * 16 + lr];

  if (sec < 2) {
    // Q is pre-scaled by 1/8 (exact in bf16: exponent shift only)
    float qscale = (sec == 0) ? 0.125f : 1.0f;
    unsigned short* Out = (sec == 0 ? Qb : Kb) + (size_t)bh * TT * HD;
    int tbase = (m0 & 2047) + lg * 4;
#pragma unroll
    for (int mi = 0; mi < 2; ++mi)
#pragma unroll
      for (int r = 0; r < 4; ++r) {
        int t = tbase + mi * 16 + r;
#pragma unroll
        for (int nj = 0; nj < 4; ++nj)
          Out[(size_t)t * HD + nj * 16 + lr] = f2b((acc[mi][nj][r] + bias[nj]) * qscale);
      }
  } else {
    int tl = wave * 32 + lg * 4;
#pragma unroll
    for (int mi = 0; mi < 2; ++mi)
#pragma unroll
      for (int r = 0; r < 4; ++r)
#pragma unroll
        for (int nj = 0; nj < 4; ++nj)
          Vlds[tl + mi * 16 + r][nj * 16 + lr] = f2b(acc[mi][nj][r] + bias[nj]);
    __syncthreads();
    int d = threadIdx.x & 63, tc = threadIdx.x >> 6;
    int tblk = (mt * 128) & 2047;
    unsigned short* Ov = Vt + ((size_t)bh * HD + d) * TT + tblk + tc * 32;
#pragma unroll
    for (int i8 = 0; i8 < 4; ++i8) {
      ushort4 o0, o1;
      o0.x = Vlds[tc * 32 + i8 * 8 + 0][d]; o0.y = Vlds[tc * 32 + i8 * 8 + 1][d];
      o0.z = Vlds[tc * 32 + i8 * 8 + 2][d]; o0.w = Vlds[tc * 32 + i8 * 8 + 3][d];
      o1.x = Vlds[tc * 32 + i8 * 8 + 4][d]; o1.y = Vlds[tc * 32 + i8 * 8 + 5][d];
      o1.z = Vlds[tc * 32 + i8 * 8 + 6][d]; o1.w = Vlds[tc * 32 + i8 * 8 + 7][d];
      *(ushort4*)(Ov + i8 * 8) = o0;
      *(ushort4*)(Ov + i8 * 8 + 4) = o1;
    }
  }
}

// ---------------------------------------------------------------------------
// bf16 MFMA GEMM: y = yhb @ wpT^T + b_proj (fp32 out). Grid (32, 12).
// ---------------------------------------------------------------------------
__global__ __launch_bounds__(256, 2) void gemm_proj_bf16(
    const unsigned short* __restrict__ yhb, const unsigned short* __restrict__ wpT,
    const float* __restrict__ b_proj, float* __restrict__ y) {
  int mt = blockIdx.x, nt = blockIdx.y;
  int wave = threadIdx.x >> 6, lane = threadIdx.x & 63;
  int lr = lane & 15, lg = lane >> 4;
  int m0 = mt * 128 + wave * 32;
  int n0 = nt * 64;
  const unsigned short* Ab = yhb + (size_t)m0 * CC;
  const unsigned short* Bb = wpT + (size_t)n0 * CC;

  f32x4 acc[2][4];
#pragma unroll
  for (int mi = 0; mi < 2; ++mi)
#pragma unroll
    for (int nj = 0; nj < 4; ++nj) acc[mi][nj] = (f32x4){0.f, 0.f, 0.f, 0.f};

#pragma unroll
  for (int ks = 0; ks < 24; ++ks) {
    int k0 = ks * 32;
    bf16x8 af[2], bf[4];
#pragma unroll
    for (int mi = 0; mi < 2; ++mi)
      af[mi] = *(const bf16x8*)(Ab + (size_t)(mi * 16 + lr) * CC + k0 + lg * 8);
#pragma unroll
    for (int nj = 0; nj < 4; ++nj)
      bf[nj] = *(const bf16x8*)(Bb + (size_t)(nj * 16 + lr) * CC + k0 + lg * 8);
#pragma unroll
    for (int nj = 0; nj < 4; ++nj)
#pragma unroll
      for (int mi = 0; mi < 2; ++mi)
        acc[mi][nj] = __builtin_amdgcn_mfma_f32_16x16x32_bf16(af[mi], bf[nj], acc[mi][nj], 0, 0, 0);
  }

  float bias[4];
#pragma unroll
  for (int nj = 0; nj < 4; ++nj) bias[nj] = b_proj[n0 + nj * 16 + lr];
#pragma unroll
  for (int mi = 0; mi < 2; ++mi)
#pragma unroll
    for (int r = 0; r < 4; ++r) {
      int m = m0 + mi * 16 + lg * 4 + r;
#pragma unroll
      for (int nj = 0; nj < 4; ++nj)
        y[(size_t)m * CC + n0 + nj * 16 + lr] = acc[mi][nj][r] + bias[nj];
    }
}

// ---------------------------------------------------------------------------
// fp32 GEMM for head-0 q,k only (precision-critical FF path). Grid (64, 2).
// ---------------------------------------------------------------------------
__global__ __launch_bounds__(256) void sgemm_qk0(
    const float* __restrict__ x, const float* __restrict__ w_attn,
    const float* __restrict__ b_attn, float* __restrict__ q0,
    float* __restrict__ k0) {
  __shared__ float As[16][64];
  __shared__ float Bs[16][64];
  int sec = blockIdx.y;
  const float* Bw = w_attn + sec * CC;
  float* Out = sec ? k0 : q0;
  int tid = threadIdx.x;
  int tx = tid & 15, ty = tid >> 4;
  int m0 = blockIdx.x * 64;

  int arow = tid >> 2;
  int acol4 = (tid & 3) << 2;
  int brow = tid >> 4;
  int bcol4 = (tid & 15) << 2;

  const float* Aptr = x + (size_t)(m0 + arow) * CC + acol4;
  const float* Bptr = Bw + (size_t)brow * N3 + bcol4;

  float acc[4][4] = {};

  for (int k0_ = 0; k0_ < CC; k0_ += 16) {
    float4 av = *(const float4*)(Aptr + k0_);
    float4 bv = *(const float4*)(Bptr + (size_t)k0_ * N3);
    As[acol4 + 0][arow] = av.x;
    As[acol4 + 1][arow] = av.y;
    As[acol4 + 2][arow] = av.z;
    As[acol4 + 3][arow] = av.w;
    *(float4*)&Bs[brow][bcol4] = bv;
    __syncthreads();
#pragma unroll
    for (int kk = 0; kk < 16; ++kk) {
      float4 a4 = *(const float4*)&As[kk][ty << 2];
      float4 b4 = *(const float4*)&Bs[kk][tx << 2];
      float a[4] = {a4.x, a4.y, a4.z, a4.w};
      float b[4] = {b4.x, b4.y, b4.z, b4.w};
#pragma unroll
      for (int ii = 0; ii < 4; ++ii)
#pragma unroll
        for (int jj = 0; jj < 4; ++jj) acc[ii][jj] += a[ii] * b[jj];
    }
    __syncthreads();
  }

  float4 bv = *(const float4*)(b_attn + sec * CC + (tx << 2));
#pragma unroll
  for (int ii = 0; ii < 4; ++ii) {
    int m = m0 + (ty << 2) + ii;
    float4 o;
    o.x = acc[ii][0] + bv.x;
    o.y = acc[ii][1] + bv.y;
    o.z = acc[ii][2] + bv.z;
    o.w = acc[ii][3] + bv.w;
    *(float4*)(Out + (size_t)m * HD + (tx << 2)) = o;
  }
}

// ---------------------------------------------------------------------------
// Head-0 scores (fp32): Sbuf[b,i,j] = relu(dot(q0,k0)/8), lower-tri tiles.
// ---------------------------------------------------------------------------
__global__ __launch_bounds__(256) void score0_kernel(
    const float* __restrict__ q0, const float* __restrict__ k0,
    float* __restrict__ Sbuf) {
  int it = blockIdx.x, jt = blockIdx.y, b = blockIdx.z;
  if (jt > it) return;
  __shared__ float Qs[64][64];
  __shared__ float Ks[64][64];
  int tid = threadIdx.x;
  int row = tid >> 2;
  int dq = (tid & 3) << 2;
  int i0 = it * 64, j0 = jt * 64;
  const float* qb = q0 + (size_t)((b * TT) + i0 + row) * HD;
  const float* kb = k0 + (size_t)((b * TT) + j0 + row) * HD;
#pragma unroll
  for (int rep = 0; rep < 4; ++rep) {
    int d = dq + rep * 16;
    float4 qv = *(const float4*)(qb + d);
    float4 kv = *(const float4*)(kb + d);
    Qs[d + 0][row] = qv.x; Qs[d + 1][row] = qv.y;
    Qs[d + 2][row] = qv.z; Qs[d + 3][row] = qv.w;
    Ks[d + 0][row] = kv.x; Ks[d + 1][row] = kv.y;
    Ks[d + 2][row] = kv.z; Ks[d + 3][row] = kv.w;
  }
  __syncthreads();
  int tx = tid & 15, ty = tid >> 4;
  float acc[4][4] = {};
#pragma unroll 8
  for (int kk = 0; kk < 64; ++kk) {
    float4 a4 = *(const float4*)&Qs[kk][ty << 2];
    float4 b4 = *(const float4*)&Ks[kk][tx << 2];
    float a[4] = {a4.x, a4.y, a4.z, a4.w};
    float b[4] = {b4.x, b4.y, b4.z, b4.w};
#pragma unroll
    for (int ii = 0; ii < 4; ++ii)
#pragma unroll
      for (int jj = 0; jj < 4; ++jj) acc[ii][jj] += a[ii] * b[jj];
  }
#pragma unroll
  for (int ii = 0; ii < 4; ++ii) {
    int gi = (b * TT) + i0 + (ty << 2) + ii;
    float4 o;
    o.x = fmaxf(acc[ii][0] * 0.125f, 0.f);
    o.y = fmaxf(acc[ii][1] * 0.125f, 0.f);
    o.z = fmaxf(acc[ii][2] * 0.125f, 0.f);
    o.w = fmaxf(acc[ii][3] * 0.125f, 0.f);
    *(float4*)(Sbuf + (size_t)gi * TT + j0 + (tx << 2)) = o;
  }
}

// ---------------------------------------------------------------------------
// Column-wise exclusive prefix scan over rows (chunked, two passes).
// scan_write also emits E = exp(-FF) in bf16 with a j-swizzled layout:
// within each 64-col tile, element j is stored at ((j&15)<<2)|((j>>4)&3)
// so the attention lane's 4 columns {lr,16+lr,32+lr,48+lr} are contiguous.
// ---------------------------------------------------------------------------
__global__ __launch_bounds__(256) void scan_partial(
    const float* __restrict__ Sbuf, float* __restrict__ partials) {
  int j = blockIdx.x * 256 + threadIdx.x;
  int chunk = blockIdx.y, b = blockIdx.z;
  int r0 = chunk * 128;
  const float* base = Sbuf + (size_t)(b * TT + r0) * TT + j;
  float sum = 0.f;
  for (int rr = 0; rr < 128; ++rr) {
    int r = r0 + rr;
    float v = (j >= 1 && j < r) ? base[(size_t)rr * TT] : 0.f;
    sum += v;
  }
  partials[(size_t)(b * 16 + chunk) * TT + j] = sum;
}

__global__ __launch_bounds__(256) void scan_write(
    float* __restrict__ Sbuf, const float* __restrict__ partials,
    unsigned short* __restrict__ Eb) {
  int j = blockIdx.x * 256 + threadIdx.x;
  int chunk = blockIdx.y, b = blockIdx.z;
  float run = 0.f;
  for (int c = 0; c < chunk; ++c) run += partials[(size_t)(b * 16 + c) * TT + j];
  int r0 = chunk * 128;
  int jswz = (j & ~63) | ((j & 15) << 2) | ((j >> 4) & 3);
  float* base = Sbuf + (size_t)(b * TT + r0) * TT + j;
  unsigned short* ebase = Eb + (size_t)(b * TT + r0) * TT + jswz;
  for (int rr = 0; rr < 128; ++rr) {
    int r = r0 + rr;
    float v = (j >= 1 && j < r) ? base[(size_t)rr * TT] : 0.f;
    base[(size_t)rr * TT] = run;                 // FF (fp32, for ffsum/M)
    ebase[(size_t)rr * TT] = f2b(__expf(-run));  // E (bf16, for attention)
    run += v;
  }
}

// ---------------------------------------------------------------------------
// FF_sum[b,i] = sum_j clip(FF[b,i,j], 0, 1)
// ---------------------------------------------------------------------------
__global__ __launch_bounds__(256) void ffsum_kernel(
    const float* __restrict__ FF, float* __restrict__ ffsum) {
  int i = blockIdx.x, b = blockIdx.y;
  const float4* row = (const float4*)(FF + (size_t)(b * TT + i) * TT);
  float s = 0.f;
  for (int r = threadIdx.x; r < TT / 4; r += 256) {
    float4 v = row[r];
    s += fminf(fmaxf(v.x, 0.f), 1.f) + fminf(fmaxf(v.y, 0.f), 1.f) +
         fminf(fmaxf(v.z, 0.f), 1.f) + fminf(fmaxf(v.w, 0.f), 1.f);
  }
#pragma unroll
  for (int o = 1; o < 64; o <<= 1) s += __shfl_xor(s, o);
  __shared__ float ws[4];
  if ((threadIdx.x & 63) == 0) ws[threadIdx.x >> 6] = s;
  __syncthreads();
  if (threadIdx.x == 0) ffsum[b * TT + i] = ws[0] + ws[1] + ws[2] + ws[3];
}

// ---------------------------------------------------------------------------
// bf16 MFMA flash attention, E = exp(-FF) multiplicative penalty.
// Grid (24, 32): XCD = x%8 serves one batch / 3 heads (L2 locality).
// 4 waves x 16 q-rows. K/V staged to LDS via global_load_lds (16B), 2-phase
// double-buffer, XOR-swizzled both sides (linear dest + pre-swizzled global
// source + swizzled ds_read). One __syncthreads per tile.
// ---------------------------------------------------------------------------
__global__ __launch_bounds__(256, 3) void attn_mfma(
    const unsigned short* __restrict__ Qb, const unsigned short* __restrict__ Kb,
    const unsigned short* __restrict__ Vt, const unsigned short* __restrict__ Eb,
    unsigned short* __restrict__ yhb) {
  int xbh = blockIdx.x;
  int b = (xbh >> 2) & 1;
  int h = ((xbh >> 3) << 2) | (xbh & 3);
  int g4 = 31 - (int)blockIdx.y;
  int wave = threadIdx.x >> 6, lane = threadIdx.x & 63;
  int lr = lane & 15, lg = lane >> 4;
  int i0 = g4 * 64 + wave * 16;
  int bh = b * NH + h;
  const unsigned short* Qh = Qb + (size_t)bh * TT * HD;
  const unsigned short* Kh = Kb + (size_t)bh * TT * HD;
  const unsigned short* Vh = Vt + (size_t)bh * HD * TT;
  const unsigned short* Erow = Eb + ((size_t)(b * TT) + i0 + lg * 4) * TT + 4 * lr;

  // LDS: K/V double buffers (swizzled slots) + P tile. 42KB -> 3 blocks/CU.
  __shared__ __align__(16) unsigned short Ksh[2][64][64];
  __shared__ __align__(16) unsigned short Vsh[2][64][64];
  __shared__ __align__(16) unsigned short Plds[4][16][80];

  int rowoff = lane >> 3;            // 0..7 within an 8-row staging segment
  int sslot  = (lane & 7) ^ rowoff;  // pre-swizzled source slot (16B units)

  bf16x8 qf[2];
#pragma unroll
  for (int ks = 0; ks < 2; ++ks)
    qf[ks] = *(const bf16x8*)(Qh + (size_t)(i0 + lr) * HD + ks * 32 + lg * 8);

  f32x4 acc[4];
  float mrun[4], lrun[4];
#pragma unroll
  for (int q = 0; q < 4; ++q) {
    acc[q] = (f32x4){0.f, 0.f, 0.f, 0.f};
    mrun[q] = -1e30f;
    lrun[q] = 0.f;
  }

#define STAGE_KV(BUF, J0)                                                      \
  {                                                                            \
    _Pragma("unroll")                                                          \
    for (int p = 0; p < 2; ++p) {                                              \
      int r0 = wave * 16 + p * 8;                                              \
      gload_lds16(Kh + (size_t)((J0) + r0 + rowoff) * HD + sslot * 8,          \
                  &Ksh[BUF][r0][0]);                                           \
      gload_lds16(Vh + (size_t)(r0 + rowoff) * TT + (J0) + sslot * 8,          \
                  &Vsh[BUF][r0][0]);                                           \
    }                                                                          \
  }

  // prologue: stage tile 0 into buffer 0
  STAGE_KV(0, 0)
  __syncthreads();

  for (int kt = 0; kt <= g4; ++kt) {
    int cur = kt & 1;
    int j0 = kt * 64;
    if (kt < g4) STAGE_KV(cur ^ 1, j0 + 64)

    // E for current tile (4 x 8B vector loads, swizzled layout)
    ushort4 ev[4];
#pragma unroll
    for (int r = 0; r < 4; ++r)
      ev[r] = *(const ushort4*)(Erow + (size_t)r * TT + j0);

    // ---- QK^T from swizzled LDS ----
    f32x4 s[4];
    __builtin_amdgcn_s_setprio(1);
#pragma unroll
    for (int nj = 0; nj < 4; ++nj) {
      int row = nj * 16 + lr;
      int sw = row & 7;
      bf16x8 k0f = *(const bf16x8*)&Ksh[cur][row][(lg ^ sw) << 3];
      bf16x8 k1f = *(const bf16x8*)&Ksh[cur][row][((4 + lg) ^ sw) << 3];
      f32x4 z = (f32x4){0.f, 0.f, 0.f, 0.f};
      z = __builtin_amdgcn_mfma_f32_16x16x32_bf16(qf[0], k0f, z, 0, 0, 0);
      s[nj] = __builtin_amdgcn_mfma_f32_16x16x32_bf16(qf[1], k1f, z, 0, 0, 0);
    }
    __builtin_amdgcn_s_setprio(0);

    // ---- logits + online softmax ----
    int ibase = i0 + lg * 4;
    float mt[4] = {-1e30f, -1e30f, -1e30f, -1e30f};
    if (kt == g4) {
#pragma unroll
      for (int nj = 0; nj < 4; ++nj)
#pragma unroll
        for (int r = 0; r < 4; ++r) {
          float lv = (j0 + nj * 16 + lr <= ibase + r) ? s[nj][r] : -1e30f;
          s[nj][r] = lv;
          mt[r] = fmaxf(mt[r], lv);
        }
    } else {
#pragma unroll
      for (int nj = 0; nj < 4; ++nj)
#pragma unroll
        for (int r = 0; r < 4; ++r) mt[r] = fmaxf(mt[r], s[nj][r]);
    }
    float needup = -1.f;
#pragma unroll
    for (int r = 0; r < 4; ++r) {
      mt[r] = fmaxf(mt[r], __shfl_xor(mt[r], 1));
      mt[r] = fmaxf(mt[r], __shfl_xor(mt[r], 2));
      mt[r] = fmaxf(mt[r], __shfl_xor(mt[r], 4));
      mt[r] = fmaxf(mt[r], __shfl_xor(mt[r], 8));
      needup = fmaxf(needup, mt[r] - mrun[r]);
    }
    if (__any(needup > 0.f)) {
#pragma unroll
      for (int r = 0; r < 4; ++r) {
        float mnew = fmaxf(mrun[r], mt[r]);
        float scl = __expf(mrun[r] - mnew);
        mrun[r] = mnew;
        lrun[r] *= scl;
#pragma unroll
        for (int nd = 0; nd < 4; ++nd) acc[nd][r] *= scl;
      }
    }
    float ps[4];
#pragma unroll
    for (int r = 0; r < 4; ++r) {
      float e0 = b2f(ev[r].x), e1 = b2f(ev[r].y);
      float e2 = b2f(ev[r].z), e3 = b2f(ev[r].w);
      float p0 = e0 * __expf(s[0][r] - mrun[r]);
      float p1 = e1 * __expf(s[1][r] - mrun[r]);
      float p2 = e2 * __expf(s[2][r] - mrun[r]);
      float p3 = e3 * __expf(s[3][r] - mrun[r]);
      ps[r] = p0 + p1 + p2 + p3;
      Plds[wave][lg * 4 + r][0 * 16 + lr] = f2b(p0);
      Plds[wave][lg * 4 + r][1 * 16 + lr] = f2b(p1);
      Plds[wave][lg * 4 + r][2 * 16 + lr] = f2b(p2);
      Plds[wave][lg * 4 + r][3 * 16 + lr] = f2b(p3);
    }
#pragma unroll
    for (int r = 0; r < 4; ++r) {
      ps[r] += __shfl_xor(ps[r], 1);
      ps[r] += __shfl_xor(ps[r], 2);
      ps[r] += __shfl_xor(ps[r], 4);
      ps[r] += __shfl_xor(ps[r], 8);
      lrun[r] += ps[r];
    }

    // ---- PV from swizzled LDS ----
    bf16x8 pa0 = *(const bf16x8*)&Plds[wave][lr][lg * 8];
    bf16x8 pa1 = *(const bf16x8*)&Plds[wave][lr][32 + lg * 8];
    __builtin_amdgcn_s_setprio(1);
#pragma unroll
    for (int nd = 0; nd < 4; ++nd) {
      int row = nd * 16 + lr;
      int sw = row & 7;
      bf16x8 v0f = *(const bf16x8*)&Vsh[cur][row][(lg ^ sw) << 3];
      bf16x8 v1f = *(const bf16x8*)&Vsh[cur][row][((4 + lg) ^ sw) << 3];
      acc[nd] = __builtin_amdgcn_mfma_f32_16x16x32_bf16(pa0, v0f, acc[nd], 0, 0, 0);
      acc[nd] = __builtin_amdgcn_mfma_f32_16x16x32_bf16(pa1, v1f, acc[nd], 0, 0, 0);
    }
    __builtin_amdgcn_s_setprio(0);

    // staging for kt+1 complete (compiler drains vmcnt before barrier);
    // all waves done reading buf[cur] -> next tile may overwrite it.
    __syncthreads();
  }
#undef STAGE_KV

  // epilogue: normalize and store bf16
#pragma unroll
  for (int r = 0; r < 4; ++r) {
    float inv = 1.f / lrun[r];
    int ig = i0 + lg * 4 + r;
    unsigned short* ob = yhb + (size_t)(b * TT + ig) * CC + h * HD;
#pragma unroll
    for (int nd = 0; nd < 4; ++nd)
      ob[nd * 16 + lr] = f2b(acc[nd][r] * inv);
  }
}

// ---------------------------------------------------------------------------
// M[0,b,i,j] = i - ffsum[b,j]
// ---------------------------------------------------------------------------
__global__ __launch_bounds__(256) void m_kernel(
    const float* __restrict__ ffsum, float* __restrict__ Mout) {
  int idx = blockIdx.x * blockDim.x + threadIdx.x;
  int stride = gridDim.x * blockDim.x;
  for (; idx < M_ELEMS; idx += stride) {
    int j = idx & (TT - 1);
    int i = (idx >> 11) & (TT - 1);
    int b = idx >> 22;
    Mout[idx] = (float)i - ffsum[(b << 11) + j];
  }
}

// ---------------------------------------------------------------------------
extern "C" void kernel_launch(void* const* d_in, const int* in_sizes, int n_in,
                              void* d_out, int out_size, void* d_ws, size_t ws_size,
                              hipStream_t stream) {
  const float* x      = (const float*)d_in[0];
  const float* w_attn = (const float*)d_in[1];
  const float* b_attn = (const float*)d_in[2];
  const float* w_proj = (const float*)d_in[3];
  const float* b_proj = (const float*)d_in[4];

  float* y    = (float*)d_out;          // [B,T,C]
  float* Mreg = y + Y_ELEMS;            // [B,T,T]: S0 -> FF (scratch) -> M (final)

  float* ws = (float*)d_ws;
  float* q0       = ws;                         // B*T*64
  float* k0       = q0 + (size_t)BB * TT * HD;
  float* partials = k0 + (size_t)BB * TT * HD;  // B*16*T
  float* ffsum    = partials + BB * 16 * TT;    // B*T
  unsigned short* xb  = (unsigned short*)(ffsum + BB * TT);   // B*T*C
  unsigned short* wbT = xb + (size_t)Y_ELEMS;                 // 2304*768
  unsigned short* wpT = wbT + (size_t)N3 * CC;                // 768*768
  unsigned short* Qb  = wpT + (size_t)CC * CC;                // B*NH*T*HD
  unsigned short* Kb  = Qb + (size_t)BB * NH * TT * HD;
  unsigned short* Vt  = Kb + (size_t)BB * NH * TT * HD;
  unsigned short* yhb = Vt + (size_t)BB * NH * TT * HD;       // B*T*C
  unsigned short* Eb  = yhb + (size_t)Y_ELEMS;                // B*T*T bf16 (16.8MB)
  // total ws usage ~= 46 MB

  // 1. packs: x -> bf16; weights -> transposed bf16
  pack_x<<<Y_ELEMS / (256 * 8), 256, 0, stream>>>(x, xb);
  transpose_pack<<<dim3(CC / 64, N3 / 64), 256, 0, stream>>>(w_attn, wbT, N3);
  transpose_pack<<<dim3(CC / 64, CC / 64), 256, 0, stream>>>(w_proj, wpT, CC);
  // 2. bf16 MFMA QKV GEMM -> packed Qb (pre-scaled 1/8) / Kb / Vt
  gemm_qkv_bf16<<<dim3(32, 36), 256, 0, stream>>>(xb, wbT, b_attn, Qb, Kb, Vt);
  // 3. fp32 head-0 q,k (precision-critical FF path)
  sgemm_qk0<<<dim3(64, 2), 256, 0, stream>>>(x, w_attn, b_attn, q0, k0);
  // 4. head-0 scores (relu'd, fp32) into Mreg
  score0_kernel<<<dim3(32, 32, BB), 256, 0, stream>>>(q0, k0, Mreg);
  // 5. column-wise exclusive scan (in place): Mreg = FF; also E = exp(-FF) bf16
  scan_partial<<<dim3(8, 16, BB), 256, 0, stream>>>(Mreg, partials);
  scan_write<<<dim3(8, 16, BB), 256, 0, stream>>>(Mreg, partials, Eb);
  // 6. FF_sum (reads fp32 FF)
  ffsum_kernel<<<dim3(TT, BB), 256, 0, stream>>>(Mreg, ffsum);
  // 7. MFMA flash attention (LDS-staged K/V, XCD grid, E-softmax)
  attn_mfma<<<dim3(24, 32), 256, 0, stream>>>(Qb, Kb, Vt, Eb, yhb);
  // 8. M output (after attn so its dirty lines don't flush during attn)
  m_kernel<<<4096, 256, 0, stream>>>(ffsum, Mreg);
  // 9. y = yhb @ w_proj + b_proj (bf16 MFMA)
  gemm_proj_bf16<<<dim3(32, 12), 256, 0, stream>>>(yhb, wpT, b_proj, y);
}

// Round 8
// 237.776 us; speedup vs baseline: 2.1231x; 1.3085x over previous
//
#include <hip/hip_runtime.h>
#include <cstddef>

// Problem constants
#define TT 2048
#define BB 2
#define CC 768
#define NH 12
#define HD 64
#define N3 2304          // 3*NH*HD
#define Y_ELEMS (BB*TT*CC)          // 3145728
#define M_ELEMS (BB*TT*TT)          // 8388608

typedef __attribute__((ext_vector_type(8))) short bf16x8;
typedef __attribute__((ext_vector_type(4))) float f32x4;

__device__ inline unsigned short f2b(float f) {
  union { float f; unsigned u; } v; v.f = f;
  unsigned r = (v.u + 0x7FFFu + ((v.u >> 16) & 1u)) >> 16;
  return (unsigned short)r;
}
__device__ inline float b2f(unsigned short u) {
  union { unsigned u; float f; } v; v.u = (unsigned)u << 16; return v.f;
}

// async global -> LDS, 16B per lane; lds dest is wave-uniform base, HW adds lane*16
__device__ inline void gload_lds16(const unsigned short* g, unsigned short* l) {
  __builtin_amdgcn_global_load_lds(
      (const __attribute__((address_space(1))) unsigned int*)g,
      (__attribute__((address_space(3))) unsigned int*)l, 16, 0, 0);
}

// ---------------------------------------------------------------------------
// pack x (fp32) -> xb (bf16). 8 elems/thread.
// ---------------------------------------------------------------------------
__global__ __launch_bounds__(256) void pack_x(
    const float* __restrict__ x, unsigned short* __restrict__ xb) {
  size_t i = ((size_t)blockIdx.x * 256 + threadIdx.x) * 8;
  float4 a = *(const float4*)(x + i);
  float4 b = *(const float4*)(x + i + 4);
  ushort4 o0, o1;
  o0.x = f2b(a.x); o0.y = f2b(a.y); o0.z = f2b(a.z); o0.w = f2b(a.w);
  o1.x = f2b(b.x); o1.y = f2b(b.y); o1.z = f2b(b.z); o1.w = f2b(b.w);
  *(ushort4*)(xb + i) = o0;
  *(ushort4*)(xb + i + 4) = o1;
}

// ---------------------------------------------------------------------------
// W [768][N] fp32 -> WT [N][768] bf16 (transposed pack). Block=(kt,nt) 64x64.
// ---------------------------------------------------------------------------
__global__ __launch_bounds__(256) void transpose_pack(
    const float* __restrict__ W, unsigned short* __restrict__ WT, int N) {
  __shared__ float tile[64][65];
  int kt = blockIdx.x, nt = blockIdx.y;
  int tid = threadIdx.x;
  int r = tid >> 4, c4 = (tid & 15) << 2;
#pragma unroll
  for (int rep = 0; rep < 4; ++rep) {
    int row = rep * 16 + r;
    float4 v = *(const float4*)(W + (size_t)(kt * 64 + row) * N + nt * 64 + c4);
    tile[row][c4 + 0] = v.x; tile[row][c4 + 1] = v.y;
    tile[row][c4 + 2] = v.z; tile[row][c4 + 3] = v.w;
  }
  __syncthreads();
#pragma unroll
  for (int rep = 0; rep < 4; ++rep) {
    int nrow = rep * 16 + r;
    ushort4 o;
    o.x = f2b(tile[c4 + 0][nrow]); o.y = f2b(tile[c4 + 1][nrow]);
    o.z = f2b(tile[c4 + 2][nrow]); o.w = f2b(tile[c4 + 3][nrow]);
    *(ushort4*)(WT + (size_t)(nt * 64 + nrow) * CC + kt * 64 + c4) = o;
  }
}

// ---------------------------------------------------------------------------
// bf16 MFMA GEMM: qkv = xb @ wbT^T + b_attn -> packed Qb (pre-scaled 1/8),
// Kb, Vt (transposed via LDS). Grid (32 mtiles of 128, 36 ntiles of 64).
// A[128][32] and B[64][32] K-tiles staged to LDS (global_load_lds 16B),
// double-buffered, slot-swizzled both sides. One __syncthreads per K-step.
// ---------------------------------------------------------------------------
__global__ __launch_bounds__(256, 3) void gemm_qkv_bf16(
    const unsigned short* __restrict__ xb, const unsigned short* __restrict__ wbT,
    const float* __restrict__ b_attn,
    unsigned short* __restrict__ Qb, unsigned short* __restrict__ Kb,
    unsigned short* __restrict__ Vt) {
  __shared__ __align__(16) unsigned short Alds[2][128][32];
  __shared__ __align__(16) unsigned short Blds[2][64][32];
  __shared__ __align__(16) unsigned short Vlds[128][72];
  int mt = blockIdx.x, nt = blockIdx.y;
  int sec = nt / NH, h = nt % NH;
  int wave = threadIdx.x >> 6, lane = threadIdx.x & 63;
  int lr = lane & 15, lg = lane >> 4;
  int m0 = mt * 128;
  int n0 = nt * 64;

  int srow = lane >> 2;                 // 0..15 staging row within segment
  int sslot = (lane & 3) ^ (srow & 3);  // pre-swizzled source k-slot (16B units)

#define STAGE_AB(BUF, K0)                                                       \
  {                                                                             \
    _Pragma("unroll")                                                           \
    for (int p = 0; p < 2; ++p) {                                               \
      int ar = wave * 32 + p * 16 + srow;                                       \
      gload_lds16(xb + (size_t)(m0 + ar) * CC + (K0) + (sslot << 3),            \
                  &Alds[BUF][wave * 32 + p * 16][0]);                           \
    }                                                                           \
    int br = wave * 16 + srow;                                                  \
    gload_lds16(wbT + (size_t)(n0 + br) * CC + (K0) + (sslot << 3),             \
                &Blds[BUF][wave * 16][0]);                                      \
  }

  f32x4 acc[2][4];
#pragma unroll
  for (int mi = 0; mi < 2; ++mi)
#pragma unroll
    for (int nj = 0; nj < 4; ++nj) acc[mi][nj] = (f32x4){0.f, 0.f, 0.f, 0.f};

  STAGE_AB(0, 0)
  __syncthreads();

  int fslot = lg ^ (lr & 3);  // frag read slot (same involution)
  for (int kt = 0; kt < 24; ++kt) {
    int cur = kt & 1;
    if (kt < 23) STAGE_AB(cur ^ 1, (kt + 1) * 32)
    bf16x8 af[2], bf[4];
#pragma unroll
    for (int mi = 0; mi < 2; ++mi)
      af[mi] = *(const bf16x8*)&Alds[cur][wave * 32 + mi * 16 + lr][fslot << 3];
#pragma unroll
    for (int nj = 0; nj < 4; ++nj)
      bf[nj] = *(const bf16x8*)&Blds[cur][nj * 16 + lr][fslot << 3];
    __builtin_amdgcn_s_setprio(1);
#pragma unroll
    for (int nj = 0; nj < 4; ++nj)
#pragma unroll
      for (int mi = 0; mi < 2; ++mi)
        acc[mi][nj] = __builtin_amdgcn_mfma_f32_16x16x32_bf16(af[mi], bf[nj], acc[mi][nj], 0, 0, 0);
    __builtin_amdgcn_s_setprio(0);
    __syncthreads();
  }
#undef STAGE_AB

  int b = m0 >> 11;
  int bh = b * NH + h;
  float bias[4];
#pragma unroll
  for (int nj = 0; nj < 4; ++nj) bias[nj] = b_attn[n0 + nj * 16 + lr];

  if (sec < 2) {
    // Q is pre-scaled by 1/8 (exact in bf16: exponent shift only)
    float qscale = (sec == 0) ? 0.125f : 1.0f;
    unsigned short* Out = (sec == 0 ? Qb : Kb) + (size_t)bh * TT * HD;
    int tbase = (m0 & 2047) + wave * 32 + lg * 4;
#pragma unroll
    for (int mi = 0; mi < 2; ++mi)
#pragma unroll
      for (int r = 0; r < 4; ++r) {
        int t = tbase + mi * 16 + r;
#pragma unroll
        for (int nj = 0; nj < 4; ++nj)
          Out[(size_t)t * HD + nj * 16 + lr] = f2b((acc[mi][nj][r] + bias[nj]) * qscale);
      }
  } else {
    int tl = wave * 32 + lg * 4;
#pragma unroll
    for (int mi = 0; mi < 2; ++mi)
#pragma unroll
      for (int r = 0; r < 4; ++r)
#pragma unroll
        for (int nj = 0; nj < 4; ++nj)
          Vlds[tl + mi * 16 + r][nj * 16 + lr] = f2b(acc[mi][nj][r] + bias[nj]);
    __syncthreads();
    int d = threadIdx.x & 63, tc = threadIdx.x >> 6;
    int tblk = (mt * 128) & 2047;
    unsigned short* Ov = Vt + ((size_t)bh * HD + d) * TT + tblk + tc * 32;
#pragma unroll
    for (int i8 = 0; i8 < 4; ++i8) {
      ushort4 o0, o1;
      o0.x = Vlds[tc * 32 + i8 * 8 + 0][d]; o0.y = Vlds[tc * 32 + i8 * 8 + 1][d];
      o0.z = Vlds[tc * 32 + i8 * 8 + 2][d]; o0.w = Vlds[tc * 32 + i8 * 8 + 3][d];
      o1.x = Vlds[tc * 32 + i8 * 8 + 4][d]; o1.y = Vlds[tc * 32 + i8 * 8 + 5][d];
      o1.z = Vlds[tc * 32 + i8 * 8 + 6][d]; o1.w = Vlds[tc * 32 + i8 * 8 + 7][d];
      *(ushort4*)(Ov + i8 * 8) = o0;
      *(ushort4*)(Ov + i8 * 8 + 4) = o1;
    }
  }
}

// ---------------------------------------------------------------------------
// bf16 MFMA GEMM: y = yhb @ wpT^T + b_proj (fp32 out). Grid (32, 12).
// Same LDS-staged double-buffered structure as gemm_qkv_bf16.
// ---------------------------------------------------------------------------
__global__ __launch_bounds__(256, 3) void gemm_proj_bf16(
    const unsigned short* __restrict__ yhb, const unsigned short* __restrict__ wpT,
    const float* __restrict__ b_proj, float* __restrict__ y) {
  __shared__ __align__(16) unsigned short Alds[2][128][32];
  __shared__ __align__(16) unsigned short Blds[2][64][32];
  int mt = blockIdx.x, nt = blockIdx.y;
  int wave = threadIdx.x >> 6, lane = threadIdx.x & 63;
  int lr = lane & 15, lg = lane >> 4;
  int m0 = mt * 128;
  int n0 = nt * 64;

  int srow = lane >> 2;
  int sslot = (lane & 3) ^ (srow & 3);

#define STAGE_AB(BUF, K0)                                                       \
  {                                                                             \
    _Pragma("unroll")                                                           \
    for (int p = 0; p < 2; ++p) {                                               \
      int ar = wave * 32 + p * 16 + srow;                                       \
      gload_lds16(yhb + (size_t)(m0 + ar) * CC + (K0) + (sslot << 3),           \
                  &Alds[BUF][wave * 32 + p * 16][0]);                           \
    }                                                                           \
    int br = wave * 16 + srow;                                                  \
    gload_lds16(wpT + (size_t)(n0 + br) * CC + (K0) + (sslot << 3),             \
                &Blds[BUF][wave * 16][0]);                                      \
  }

  f32x4 acc[2][4];
#pragma unroll
  for (int mi = 0; mi < 2; ++mi)
#pragma unroll
    for (int nj = 0; nj < 4; ++nj) acc[mi][nj] = (f32x4){0.f, 0.f, 0.f, 0.f};

  STAGE_AB(0, 0)
  __syncthreads();

  int fslot = lg ^ (lr & 3);
  for (int kt = 0; kt < 24; ++kt) {
    int cur = kt & 1;
    if (kt < 23) STAGE_AB(cur ^ 1, (kt + 1) * 32)
    bf16x8 af[2], bf[4];
#pragma unroll
    for (int mi = 0; mi < 2; ++mi)
      af[mi] = *(const bf16x8*)&Alds[cur][wave * 32 + mi * 16 + lr][fslot << 3];
#pragma unroll
    for (int nj = 0; nj < 4; ++nj)
      bf[nj] = *(const bf16x8*)&Blds[cur][nj * 16 + lr][fslot << 3];
    __builtin_amdgcn_s_setprio(1);
#pragma unroll
    for (int nj = 0; nj < 4; ++nj)
#pragma unroll
      for (int mi = 0; mi < 2; ++mi)
        acc[mi][nj] = __builtin_amdgcn_mfma_f32_16x16x32_bf16(af[mi], bf[nj], acc[mi][nj], 0, 0, 0);
    __builtin_amdgcn_s_setprio(0);
    __syncthreads();
  }
#undef STAGE_AB

  float bias[4];
#pragma unroll
  for (int nj = 0; nj < 4; ++nj) bias[nj] = b_proj[n0 + nj * 16 + lr];
#pragma unroll
  for (int mi = 0; mi < 2; ++mi)
#pragma unroll
    for (int r = 0; r < 4; ++r) {
      int m = m0 + wave * 32 + mi * 16 + lg * 4 + r;
#pragma unroll
      for (int nj = 0; nj < 4; ++nj)
        y[(size_t)m * CC + n0 + nj * 16 + lr] = acc[mi][nj][r] + bias[nj];
    }
}

// ---------------------------------------------------------------------------
// fp32 GEMM for head-0 q,k only (precision-critical FF path). Grid (64, 2).
// ---------------------------------------------------------------------------
__global__ __launch_bounds__(256) void sgemm_qk0(
    const float* __restrict__ x, const float* __restrict__ w_attn,
    const float* __restrict__ b_attn, float* __restrict__ q0,
    float* __restrict__ k0) {
  __shared__ float As[16][64];
  __shared__ float Bs[16][64];
  int sec = blockIdx.y;
  const float* Bw = w_attn + sec * CC;
  float* Out = sec ? k0 : q0;
  int tid = threadIdx.x;
  int tx = tid & 15, ty = tid >> 4;
  int m0 = blockIdx.x * 64;

  int arow = tid >> 2;
  int acol4 = (tid & 3) << 2;
  int brow = tid >> 4;
  int bcol4 = (tid & 15) << 2;

  const float* Aptr = x + (size_t)(m0 + arow) * CC + acol4;
  const float* Bptr = Bw + (size_t)brow * N3 + bcol4;

  float acc[4][4] = {};

  for (int k0_ = 0; k0_ < CC; k0_ += 16) {
    float4 av = *(const float4*)(Aptr + k0_);
    float4 bv = *(const float4*)(Bptr + (size_t)k0_ * N3);
    As[acol4 + 0][arow] = av.x;
    As[acol4 + 1][arow] = av.y;
    As[acol4 + 2][arow] = av.z;
    As[acol4 + 3][arow] = av.w;
    *(float4*)&Bs[brow][bcol4] = bv;
    __syncthreads();
#pragma unroll
    for (int kk = 0; kk < 16; ++kk) {
      float4 a4 = *(const float4*)&As[kk][ty << 2];
      float4 b4 = *(const float4*)&Bs[kk][tx << 2];
      float a[4] = {a4.x, a4.y, a4.z, a4.w};
      float b[4] = {b4.x, b4.y, b4.z, b4.w};
#pragma unroll
      for (int ii = 0; ii < 4; ++ii)
#pragma unroll
        for (int jj = 0; jj < 4; ++jj) acc[ii][jj] += a[ii] * b[jj];
    }
    __syncthreads();
  }

  float4 bv = *(const float4*)(b_attn + sec * CC + (tx << 2));
#pragma unroll
  for (int ii = 0; ii < 4; ++ii) {
    int m = m0 + (ty << 2) + ii;
    float4 o;
    o.x = acc[ii][0] + bv.x;
    o.y = acc[ii][1] + bv.y;
    o.z = acc[ii][2] + bv.z;
    o.w = acc[ii][3] + bv.w;
    *(float4*)(Out + (size_t)m * HD + (tx << 2)) = o;
  }
}

// ---------------------------------------------------------------------------
// Head-0 scores (fp32): Sbuf[b,i,j] = relu(dot(q0,k0)/8), lower-tri tiles.
// ---------------------------------------------------------------------------
__global__ __launch_bounds__(256) void score0_kernel(
    const float* __restrict__ q0, const float* __restrict__ k0,
    float* __restrict__ Sbuf) {
  int it = blockIdx.x, jt = blockIdx.y, b = blockIdx.z;
  if (jt > it) return;
  __shared__ float Qs[64][64];
  __shared__ float Ks[64][64];
  int tid = threadIdx.x;
  int row = tid >> 2;
  int dq = (tid & 3) << 2;
  int i0 = it * 64, j0 = jt * 64;
  const float* qb = q0 + (size_t)((b * TT) + i0 + row) * HD;
  const float* kb = k0 + (size_t)((b * TT) + j0 + row) * HD;
#pragma unroll
  for (int rep = 0; rep < 4; ++rep) {
    int d = dq + rep * 16;
    float4 qv = *(const float4*)(qb + d);
    float4 kv = *(const float4*)(kb + d);
    Qs[d + 0][row] = qv.x; Qs[d + 1][row] = qv.y;
    Qs[d + 2][row] = qv.z; Qs[d + 3][row] = qv.w;
    Ks[d + 0][row] = kv.x; Ks[d + 1][row] = kv.y;
    Ks[d + 2][row] = kv.z; Ks[d + 3][row] = kv.w;
  }
  __syncthreads();
  int tx = tid & 15, ty = tid >> 4;
  float acc[4][4] = {};
#pragma unroll 8
  for (int kk = 0; kk < 64; ++kk) {
    float4 a4 = *(const float4*)&Qs[kk][ty << 2];
    float4 b4 = *(const float4*)&Ks[kk][tx << 2];
    float a[4] = {a4.x, a4.y, a4.z, a4.w};
    float b[4] = {b4.x, b4.y, b4.z, b4.w};
#pragma unroll
    for (int ii = 0; ii < 4; ++ii)
#pragma unroll
      for (int jj = 0; jj < 4; ++jj) acc[ii][jj] += a[ii] * b[jj];
  }
#pragma unroll
  for (int ii = 0; ii < 4; ++ii) {
    int gi = (b * TT) + i0 + (ty << 2) + ii;
    float4 o;
    o.x = fmaxf(acc[ii][0] * 0.125f, 0.f);
    o.y = fmaxf(acc[ii][1] * 0.125f, 0.f);
    o.z = fmaxf(acc[ii][2] * 0.125f, 0.f);
    o.w = fmaxf(acc[ii][3] * 0.125f, 0.f);
    *(float4*)(Sbuf + (size_t)gi * TT + j0 + (tx << 2)) = o;
  }
}

// ---------------------------------------------------------------------------
// Column-wise exclusive prefix scan over rows (chunked, two passes).
// scan_write also emits E = exp(-FF) in bf16 with a j-swizzled layout:
// within each 64-col tile, element j is stored at ((j&15)<<2)|((j>>4)&3)
// so the attention lane's 4 columns {lr,16+lr,32+lr,48+lr} are contiguous.
// ---------------------------------------------------------------------------
__global__ __launch_bounds__(256) void scan_partial(
    const float* __restrict__ Sbuf, float* __restrict__ partials) {
  int j = blockIdx.x * 256 + threadIdx.x;
  int chunk = blockIdx.y, b = blockIdx.z;
  int r0 = chunk * 128;
  const float* base = Sbuf + (size_t)(b * TT + r0) * TT + j;
  float sum = 0.f;
  for (int rr = 0; rr < 128; ++rr) {
    int r = r0 + rr;
    float v = (j >= 1 && j < r) ? base[(size_t)rr * TT] : 0.f;
    sum += v;
  }
  partials[(size_t)(b * 16 + chunk) * TT + j] = sum;
}

__global__ __launch_bounds__(256) void scan_write(
    float* __restrict__ Sbuf, const float* __restrict__ partials,
    unsigned short* __restrict__ Eb) {
  int j = blockIdx.x * 256 + threadIdx.x;
  int chunk = blockIdx.y, b = blockIdx.z;
  float run = 0.f;
  for (int c = 0; c < chunk; ++c) run += partials[(size_t)(b * 16 + c) * TT + j];
  int r0 = chunk * 128;
  int jswz = (j & ~63) | ((j & 15) << 2) | ((j >> 4) & 3);
  float* base = Sbuf + (size_t)(b * TT + r0) * TT + j;
  unsigned short* ebase = Eb + (size_t)(b * TT + r0) * TT + jswz;
  for (int rr = 0; rr < 128; ++rr) {
    int r = r0 + rr;
    float v = (j >= 1 && j < r) ? base[(size_t)rr * TT] : 0.f;
    base[(size_t)rr * TT] = run;                 // FF (fp32, for ffsum/M)
    ebase[(size_t)rr * TT] = f2b(__expf(-run));  // E (bf16, for attention)
    run += v;
  }
}

// ---------------------------------------------------------------------------
// FF_sum[b,i] = sum_j clip(FF[b,i,j], 0, 1)
// ---------------------------------------------------------------------------
__global__ __launch_bounds__(256) void ffsum_kernel(
    const float* __restrict__ FF, float* __restrict__ ffsum) {
  int i = blockIdx.x, b = blockIdx.y;
  const float4* row = (const float4*)(FF + (size_t)(b * TT + i) * TT);
  float s = 0.f;
  for (int r = threadIdx.x; r < TT / 4; r += 256) {
    float4 v = row[r];
    s += fminf(fmaxf(v.x, 0.f), 1.f) + fminf(fmaxf(v.y, 0.f), 1.f) +
         fminf(fmaxf(v.z, 0.f), 1.f) + fminf(fmaxf(v.w, 0.f), 1.f);
  }
#pragma unroll
  for (int o = 1; o < 64; o <<= 1) s += __shfl_xor(s, o);
  __shared__ float ws[4];
  if ((threadIdx.x & 63) == 0) ws[threadIdx.x >> 6] = s;
  __syncthreads();
  if (threadIdx.x == 0) ffsum[b * TT + i] = ws[0] + ws[1] + ws[2] + ws[3];
}

// ---------------------------------------------------------------------------
// bf16 MFMA flash attention, E = exp(-FF) multiplicative penalty.
// Grid (24, 32): XCD = x%8 serves one batch / 3 heads (L2 locality).
// 4 waves x 16 q-rows. K/V staged to LDS via global_load_lds (16B), 2-phase
// double-buffer, XOR-swizzled both sides. One __syncthreads per tile.
// ---------------------------------------------------------------------------
__global__ __launch_bounds__(256, 3) void attn_mfma(
    const unsigned short* __restrict__ Qb, const unsigned short* __restrict__ Kb,
    const unsigned short* __restrict__ Vt, const unsigned short* __restrict__ Eb,
    unsigned short* __restrict__ yhb) {
  int xbh = blockIdx.x;
  int b = (xbh >> 2) & 1;
  int h = ((xbh >> 3) << 2) | (xbh & 3);
  int g4 = 31 - (int)blockIdx.y;
  int wave = threadIdx.x >> 6, lane = threadIdx.x & 63;
  int lr = lane & 15, lg = lane >> 4;
  int i0 = g4 * 64 + wave * 16;
  int bh = b * NH + h;
  const unsigned short* Qh = Qb + (size_t)bh * TT * HD;
  const unsigned short* Kh = Kb + (size_t)bh * TT * HD;
  const unsigned short* Vh = Vt + (size_t)bh * HD * TT;
  const unsigned short* Erow = Eb + ((size_t)(b * TT) + i0 + lg * 4) * TT + 4 * lr;

  // LDS: K/V double buffers (swizzled slots) + P tile. 42KB -> 3 blocks/CU.
  __shared__ __align__(16) unsigned short Ksh[2][64][64];
  __shared__ __align__(16) unsigned short Vsh[2][64][64];
  __shared__ __align__(16) unsigned short Plds[4][16][80];

  int rowoff = lane >> 3;            // 0..7 within an 8-row staging segment
  int sslot  = (lane & 7) ^ rowoff;  // pre-swizzled source slot (16B units)

  bf16x8 qf[2];
#pragma unroll
  for (int ks = 0; ks < 2; ++ks)
    qf[ks] = *(const bf16x8*)(Qh + (size_t)(i0 + lr) * HD + ks * 32 + lg * 8);

  f32x4 acc[4];
  float mrun[4], lrun[4];
#pragma unroll
  for (int q = 0; q < 4; ++q) {
    acc[q] = (f32x4){0.f, 0.f, 0.f, 0.f};
    mrun[q] = -1e30f;
    lrun[q] = 0.f;
  }

#define STAGE_KV(BUF, J0)                                                      \
  {                                                                            \
    _Pragma("unroll")                                                          \
    for (int p = 0; p < 2; ++p) {                                              \
      int r0 = wave * 16 + p * 8;                                              \
      gload_lds16(Kh + (size_t)((J0) + r0 + rowoff) * HD + sslot * 8,          \
                  &Ksh[BUF][r0][0]);                                           \
      gload_lds16(Vh + (size_t)(r0 + rowoff) * TT + (J0) + sslot * 8,          \
                  &Vsh[BUF][r0][0]);                                           \
    }                                                                          \
  }

  // prologue: stage tile 0 into buffer 0
  STAGE_KV(0, 0)
  __syncthreads();

  for (int kt = 0; kt <= g4; ++kt) {
    int cur = kt & 1;
    int j0 = kt * 64;
    if (kt < g4) STAGE_KV(cur ^ 1, j0 + 64)

    // E for current tile (4 x 8B vector loads, swizzled layout)
    ushort4 ev[4];
#pragma unroll
    for (int r = 0; r < 4; ++r)
      ev[r] = *(const ushort4*)(Erow + (size_t)r * TT + j0);

    // ---- QK^T from swizzled LDS ----
    f32x4 s[4];
    __builtin_amdgcn_s_setprio(1);
#pragma unroll
    for (int nj = 0; nj < 4; ++nj) {
      int row = nj * 16 + lr;
      int sw = row & 7;
      bf16x8 k0f = *(const bf16x8*)&Ksh[cur][row][(lg ^ sw) << 3];
      bf16x8 k1f = *(const bf16x8*)&Ksh[cur][row][((4 + lg) ^ sw) << 3];
      f32x4 z = (f32x4){0.f, 0.f, 0.f, 0.f};
      z = __builtin_amdgcn_mfma_f32_16x16x32_bf16(qf[0], k0f, z, 0, 0, 0);
      s[nj] = __builtin_amdgcn_mfma_f32_16x16x32_bf16(qf[1], k1f, z, 0, 0, 0);
    }
    __builtin_amdgcn_s_setprio(0);

    // ---- logits + online softmax ----
    int ibase = i0 + lg * 4;
    float mt[4] = {-1e30f, -1e30f, -1e30f, -1e30f};
    if (kt == g4) {
#pragma unroll
      for (int nj = 0; nj < 4; ++nj)
#pragma unroll
        for (int r = 0; r < 4; ++r) {
          float lv = (j0 + nj * 16 + lr <= ibase + r) ? s[nj][r] : -1e30f;
          s[nj][r] = lv;
          mt[r] = fmaxf(mt[r], lv);
        }
    } else {
#pragma unroll
      for (int nj = 0; nj < 4; ++nj)
#pragma unroll
        for (int r = 0; r < 4; ++r) mt[r] = fmaxf(mt[r], s[nj][r]);
    }
    float needup = -1.f;
#pragma unroll
    for (int r = 0; r < 4; ++r) {
      mt[r] = fmaxf(mt[r], __shfl_xor(mt[r], 1));
      mt[r] = fmaxf(mt[r], __shfl_xor(mt[r], 2));
      mt[r] = fmaxf(mt[r], __shfl_xor(mt[r], 4));
      mt[r] = fmaxf(mt[r], __shfl_xor(mt[r], 8));
      needup = fmaxf(needup, mt[r] - mrun[r]);
    }
    if (__any(needup > 0.f)) {
#pragma unroll
      for (int r = 0; r < 4; ++r) {
        float mnew = fmaxf(mrun[r], mt[r]);
        float scl = __expf(mrun[r] - mnew);
        mrun[r] = mnew;
        lrun[r] *= scl;
#pragma unroll
        for (int nd = 0; nd < 4; ++nd) acc[nd][r] *= scl;
      }
    }
    float ps[4];
#pragma unroll
    for (int r = 0; r < 4; ++r) {
      float e0 = b2f(ev[r].x), e1 = b2f(ev[r].y);
      float e2 = b2f(ev[r].z), e3 = b2f(ev[r].w);
      float p0 = e0 * __expf(s[0][r] - mrun[r]);
      float p1 = e1 * __expf(s[1][r] - mrun[r]);
      float p2 = e2 * __expf(s[2][r] - mrun[r]);
      float p3 = e3 * __expf(s[3][r] - mrun[r]);
      ps[r] = p0 + p1 + p2 + p3;
      Plds[wave][lg * 4 + r][0 * 16 + lr] = f2b(p0);
      Plds[wave][lg * 4 + r][1 * 16 + lr] = f2b(p1);
      Plds[wave][lg * 4 + r][2 * 16 + lr] = f2b(p2);
      Plds[wave][lg * 4 + r][3 * 16 + lr] = f2b(p3);
    }
#pragma unroll
    for (int r = 0; r < 4; ++r) {
      ps[r] += __shfl_xor(ps[r], 1);
      ps[r] += __shfl_xor(ps[r], 2);
      ps[r] += __shfl_xor(ps[r], 4);
      ps[r] += __shfl_xor(ps[r], 8);
      lrun[r] += ps[r];
    }

    // ---- PV from swizzled LDS ----
    bf16x8 pa0 = *(const bf16x8*)&Plds[wave][lr][lg * 8];
    bf16x8 pa1 = *(const bf16x8*)&Plds[wave][lr][32 + lg * 8];
    __builtin_amdgcn_s_setprio(1);
#pragma unroll
    for (int nd = 0; nd < 4; ++nd) {
      int row = nd * 16 + lr;
      int sw = row & 7;
      bf16x8 v0f = *(const bf16x8*)&Vsh[cur][row][(lg ^ sw) << 3];
      bf16x8 v1f = *(const bf16x8*)&Vsh[cur][row][((4 + lg) ^ sw) << 3];
      acc[nd] = __builtin_amdgcn_mfma_f32_16x16x32_bf16(pa0, v0f, acc[nd], 0, 0, 0);
      acc[nd] = __builtin_amdgcn_mfma_f32_16x16x32_bf16(pa1, v1f, acc[nd], 0, 0, 0);
    }
    __builtin_amdgcn_s_setprio(0);

    // staging for kt+1 complete (compiler drains vmcnt before barrier);
    // all waves done reading buf[cur] -> next tile may overwrite it.
    __syncthreads();
  }
#undef STAGE_KV

  // epilogue: normalize and store bf16
#pragma unroll
  for (int r = 0; r < 4; ++r) {
    float inv = 1.f / lrun[r];
    int ig = i0 + lg * 4 + r;
    unsigned short* ob = yhb + (size_t)(b * TT + ig) * CC + h * HD;
#pragma unroll
    for (int nd = 0; nd < 4; ++nd)
      ob[nd * 16 + lr] = f2b(acc[nd][r] * inv);
  }
}

// ---------------------------------------------------------------------------
// M[0,b,i,j] = i - ffsum[b,j]
// ---------------------------------------------------------------------------
__global__ __launch_bounds__(256) void m_kernel(
    const float* __restrict__ ffsum, float* __restrict__ Mout) {
  int idx = blockIdx.x * blockDim.x + threadIdx.x;
  int stride = gridDim.x * blockDim.x;
  for (; idx < M_ELEMS; idx += stride) {
    int j = idx & (TT - 1);
    int i = (idx >> 11) & (TT - 1);
    int b = idx >> 22;
    Mout[idx] = (float)i - ffsum[(b << 11) + j];
  }
}

// ---------------------------------------------------------------------------
extern "C" void kernel_launch(void* const* d_in, const int* in_sizes, int n_in,
                              void* d_out, int out_size, void* d_ws, size_t ws_size,
                              hipStream_t stream) {
  const float* x      = (const float*)d_in[0];
  const float* w_attn = (const float*)d_in[1];
  const float* b_attn = (const float*)d_in[2];
  const float* w_proj = (const float*)d_in[3];
  const float* b_proj = (const float*)d_in[4];

  float* y    = (float*)d_out;          // [B,T,C]
  float* Mreg = y + Y_ELEMS;            // [B,T,T]: S0 -> FF (scratch) -> M (final)

  float* ws = (float*)d_ws;
  float* q0       = ws;                         // B*T*64
  float* k0       = q0 + (size_t)BB * TT * HD;
  float* partials = k0 + (size_t)BB * TT * HD;  // B*16*T
  float* ffsum    = partials + BB * 16 * TT;    // B*T
  unsigned short* xb  = (unsigned short*)(ffsum + BB * TT);   // B*T*C
  unsigned short* wbT = xb + (size_t)Y_ELEMS;                 // 2304*768
  unsigned short* wpT = wbT + (size_t)N3 * CC;                // 768*768
  unsigned short* Qb  = wpT + (size_t)CC * CC;                // B*NH*T*HD
  unsigned short* Kb  = Qb + (size_t)BB * NH * TT * HD;
  unsigned short* Vt  = Kb + (size_t)BB * NH * TT * HD;
  unsigned short* yhb = Vt + (size_t)BB * NH * TT * HD;       // B*T*C
  unsigned short* Eb  = yhb + (size_t)Y_ELEMS;                // B*T*T bf16 (16.8MB)
  // total ws usage ~= 46 MB

  // 1. packs: x -> bf16; weights -> transposed bf16
  pack_x<<<Y_ELEMS / (256 * 8), 256, 0, stream>>>(x, xb);
  transpose_pack<<<dim3(CC / 64, N3 / 64), 256, 0, stream>>>(w_attn, wbT, N3);
  transpose_pack<<<dim3(CC / 64, CC / 64), 256, 0, stream>>>(w_proj, wpT, CC);
  // 2. bf16 MFMA QKV GEMM (LDS-staged dbuf) -> packed Qb (1/8) / Kb / Vt
  gemm_qkv_bf16<<<dim3(32, 36), 256, 0, stream>>>(xb, wbT, b_attn, Qb, Kb, Vt);
  // 3. fp32 head-0 q,k (precision-critical FF path)
  sgemm_qk0<<<dim3(64, 2), 256, 0, stream>>>(x, w_attn, b_attn, q0, k0);
  // 4. head-0 scores (relu'd, fp32) into Mreg
  score0_kernel<<<dim3(32, 32, BB), 256, 0, stream>>>(q0, k0, Mreg);
  // 5. column-wise exclusive scan (in place): Mreg = FF; also E = exp(-FF) bf16
  scan_partial<<<dim3(8, 16, BB), 256, 0, stream>>>(Mreg, partials);
  scan_write<<<dim3(8, 16, BB), 256, 0, stream>>>(Mreg, partials, Eb);
  // 6. FF_sum (reads fp32 FF)
  ffsum_kernel<<<dim3(TT, BB), 256, 0, stream>>>(Mreg, ffsum);
  // 7. MFMA flash attention (LDS-staged K/V, XCD grid, E-softmax)
  attn_mfma<<<dim3(24, 32), 256, 0, stream>>>(Qb, Kb, Vt, Eb, yhb);
  // 8. M output (after attn so its dirty lines don't flush during attn)
  m_kernel<<<4096, 256, 0, stream>>>(ffsum, Mreg);
  // 9. y = yhb @ w_proj + b_proj (bf16 MFMA, LDS-staged dbuf)
  gemm_proj_bf16<<<dim3(32, 12), 256, 0, stream>>>(yhb, wpT, b_proj, y);
}

// Round 9
// 223.787 us; speedup vs baseline: 2.2558x; 1.0625x over previous
//
#include <hip/hip_runtime.h>
#include <cstddef>

// Problem constants
#define TT 2048
#define BB 2
#define CC 768
#define NH 12
#define HD 64
#define N3 2304          // 3*NH*HD
#define Y_ELEMS (BB*TT*CC)          // 3145728
#define M_ELEMS (BB*TT*TT)          // 8388608

typedef __attribute__((ext_vector_type(8))) short bf16x8;
typedef __attribute__((ext_vector_type(4))) float f32x4;

__device__ inline unsigned short f2b(float f) {
  union { float f; unsigned u; } v; v.f = f;
  unsigned r = (v.u + 0x7FFFu + ((v.u >> 16) & 1u)) >> 16;
  return (unsigned short)r;
}
__device__ inline float b2f(unsigned short u) {
  union { unsigned u; float f; } v; v.u = (unsigned)u << 16; return v.f;
}

// async global -> LDS, 16B per lane; lds dest is wave-uniform base, HW adds lane*16
__device__ inline void gload_lds16(const unsigned short* g, unsigned short* l) {
  __builtin_amdgcn_global_load_lds(
      (const __attribute__((address_space(1))) unsigned int*)g,
      (__attribute__((address_space(3))) unsigned int*)l, 16, 0, 0);
}

// ---------------------------------------------------------------------------
// pack x (fp32) -> xb (bf16). 8 elems/thread.
// ---------------------------------------------------------------------------
__global__ __launch_bounds__(256) void pack_x(
    const float* __restrict__ x, unsigned short* __restrict__ xb) {
  size_t i = ((size_t)blockIdx.x * 256 + threadIdx.x) * 8;
  float4 a = *(const float4*)(x + i);
  float4 b = *(const float4*)(x + i + 4);
  ushort4 o0, o1;
  o0.x = f2b(a.x); o0.y = f2b(a.y); o0.z = f2b(a.z); o0.w = f2b(a.w);
  o1.x = f2b(b.x); o1.y = f2b(b.y); o1.z = f2b(b.z); o1.w = f2b(b.w);
  *(ushort4*)(xb + i) = o0;
  *(ushort4*)(xb + i + 4) = o1;
}

// ---------------------------------------------------------------------------
// W [768][N] fp32 -> WT [N][768] bf16 (transposed pack). Block=(kt,nt) 64x64.
// ---------------------------------------------------------------------------
__global__ __launch_bounds__(256) void transpose_pack(
    const float* __restrict__ W, unsigned short* __restrict__ WT, int N) {
  __shared__ float tile[64][65];
  int kt = blockIdx.x, nt = blockIdx.y;
  int tid = threadIdx.x;
  int r = tid >> 4, c4 = (tid & 15) << 2;
#pragma unroll
  for (int rep = 0; rep < 4; ++rep) {
    int row = rep * 16 + r;
    float4 v = *(const float4*)(W + (size_t)(kt * 64 + row) * N + nt * 64 + c4);
    tile[row][c4 + 0] = v.x; tile[row][c4 + 1] = v.y;
    tile[row][c4 + 2] = v.z; tile[row][c4 + 3] = v.w;
  }
  __syncthreads();
#pragma unroll
  for (int rep = 0; rep < 4; ++rep) {
    int nrow = rep * 16 + r;
    ushort4 o;
    o.x = f2b(tile[c4 + 0][nrow]); o.y = f2b(tile[c4 + 1][nrow]);
    o.z = f2b(tile[c4 + 2][nrow]); o.w = f2b(tile[c4 + 3][nrow]);
    *(ushort4*)(WT + (size_t)(nt * 64 + nrow) * CC + kt * 64 + c4) = o;
  }
}

// ---------------------------------------------------------------------------
// bf16 MFMA GEMM: qkv = xb @ wbT^T + b_attn -> packed Qb (pre-scaled 1/8),
// Kb, Vt (transposed via LDS). Grid (32 mtiles of 128, 36 ntiles of 64).
// A[128][32] and B[64][32] K-tiles staged to LDS (global_load_lds 16B),
// double-buffered, slot-swizzled both sides. One __syncthreads per K-step.
// ---------------------------------------------------------------------------
__global__ __launch_bounds__(256, 3) void gemm_qkv_bf16(
    const unsigned short* __restrict__ xb, const unsigned short* __restrict__ wbT,
    const float* __restrict__ b_attn,
    unsigned short* __restrict__ Qb, unsigned short* __restrict__ Kb,
    unsigned short* __restrict__ Vt) {
  __shared__ __align__(16) unsigned short Alds[2][128][32];
  __shared__ __align__(16) unsigned short Blds[2][64][32];
  __shared__ __align__(16) unsigned short Vlds[128][72];
  int mt = blockIdx.x, nt = blockIdx.y;
  int sec = nt / NH, h = nt % NH;
  int wave = threadIdx.x >> 6, lane = threadIdx.x & 63;
  int lr = lane & 15, lg = lane >> 4;
  int m0 = mt * 128;
  int n0 = nt * 64;

  int srow = lane >> 2;                 // 0..15 staging row within segment
  int sslot = (lane & 3) ^ (srow & 3);  // pre-swizzled source k-slot (16B units)

#define STAGE_AB(BUF, K0)                                                       \
  {                                                                             \
    _Pragma("unroll")                                                           \
    for (int p = 0; p < 2; ++p) {                                               \
      int ar = wave * 32 + p * 16 + srow;                                       \
      gload_lds16(xb + (size_t)(m0 + ar) * CC + (K0) + (sslot << 3),            \
                  &Alds[BUF][wave * 32 + p * 16][0]);                           \
    }                                                                           \
    int br = wave * 16 + srow;                                                  \
    gload_lds16(wbT + (size_t)(n0 + br) * CC + (K0) + (sslot << 3),             \
                &Blds[BUF][wave * 16][0]);                                      \
  }

  f32x4 acc[2][4];
#pragma unroll
  for (int mi = 0; mi < 2; ++mi)
#pragma unroll
    for (int nj = 0; nj < 4; ++nj) acc[mi][nj] = (f32x4){0.f, 0.f, 0.f, 0.f};

  STAGE_AB(0, 0)
  __syncthreads();

  int fslot = lg ^ (lr & 3);  // frag read slot (same involution)
  for (int kt = 0; kt < 24; ++kt) {
    int cur = kt & 1;
    if (kt < 23) STAGE_AB(cur ^ 1, (kt + 1) * 32)
    bf16x8 af[2], bf[4];
#pragma unroll
    for (int mi = 0; mi < 2; ++mi)
      af[mi] = *(const bf16x8*)&Alds[cur][wave * 32 + mi * 16 + lr][fslot << 3];
#pragma unroll
    for (int nj = 0; nj < 4; ++nj)
      bf[nj] = *(const bf16x8*)&Blds[cur][nj * 16 + lr][fslot << 3];
    __builtin_amdgcn_s_setprio(1);
#pragma unroll
    for (int nj = 0; nj < 4; ++nj)
#pragma unroll
      for (int mi = 0; mi < 2; ++mi)
        acc[mi][nj] = __builtin_amdgcn_mfma_f32_16x16x32_bf16(af[mi], bf[nj], acc[mi][nj], 0, 0, 0);
    __builtin_amdgcn_s_setprio(0);
    __syncthreads();
  }
#undef STAGE_AB

  int b = m0 >> 11;
  int bh = b * NH + h;
  float bias[4];
#pragma unroll
  for (int nj = 0; nj < 4; ++nj) bias[nj] = b_attn[n0 + nj * 16 + lr];

  if (sec < 2) {
    // Q is pre-scaled by 1/8 (exact in bf16: exponent shift only)
    float qscale = (sec == 0) ? 0.125f : 1.0f;
    unsigned short* Out = (sec == 0 ? Qb : Kb) + (size_t)bh * TT * HD;
    int tbase = (m0 & 2047) + wave * 32 + lg * 4;
#pragma unroll
    for (int mi = 0; mi < 2; ++mi)
#pragma unroll
      for (int r = 0; r < 4; ++r) {
        int t = tbase + mi * 16 + r;
#pragma unroll
        for (int nj = 0; nj < 4; ++nj)
          Out[(size_t)t * HD + nj * 16 + lr] = f2b((acc[mi][nj][r] + bias[nj]) * qscale);
      }
  } else {
    int tl = wave * 32 + lg * 4;
#pragma unroll
    for (int mi = 0; mi < 2; ++mi)
#pragma unroll
      for (int r = 0; r < 4; ++r)
#pragma unroll
        for (int nj = 0; nj < 4; ++nj)
          Vlds[tl + mi * 16 + r][nj * 16 + lr] = f2b(acc[mi][nj][r] + bias[nj]);
    __syncthreads();
    int d = threadIdx.x & 63, tc = threadIdx.x >> 6;
    int tblk = (mt * 128) & 2047;
    unsigned short* Ov = Vt + ((size_t)bh * HD + d) * TT + tblk + tc * 32;
#pragma unroll
    for (int i8 = 0; i8 < 4; ++i8) {
      ushort4 o0, o1;
      o0.x = Vlds[tc * 32 + i8 * 8 + 0][d]; o0.y = Vlds[tc * 32 + i8 * 8 + 1][d];
      o0.z = Vlds[tc * 32 + i8 * 8 + 2][d]; o0.w = Vlds[tc * 32 + i8 * 8 + 3][d];
      o1.x = Vlds[tc * 32 + i8 * 8 + 4][d]; o1.y = Vlds[tc * 32 + i8 * 8 + 5][d];
      o1.z = Vlds[tc * 32 + i8 * 8 + 6][d]; o1.w = Vlds[tc * 32 + i8 * 8 + 7][d];
      *(ushort4*)(Ov + i8 * 8) = o0;
      *(ushort4*)(Ov + i8 * 8 + 4) = o1;
    }
  }
}

// ---------------------------------------------------------------------------
// bf16 MFMA GEMM: y = yhb @ wpT^T + b_proj (fp32 out). Grid (32, 12).
// Same LDS-staged double-buffered structure as gemm_qkv_bf16.
// ---------------------------------------------------------------------------
__global__ __launch_bounds__(256, 3) void gemm_proj_bf16(
    const unsigned short* __restrict__ yhb, const unsigned short* __restrict__ wpT,
    const float* __restrict__ b_proj, float* __restrict__ y) {
  __shared__ __align__(16) unsigned short Alds[2][128][32];
  __shared__ __align__(16) unsigned short Blds[2][64][32];
  int mt = blockIdx.x, nt = blockIdx.y;
  int wave = threadIdx.x >> 6, lane = threadIdx.x & 63;
  int lr = lane & 15, lg = lane >> 4;
  int m0 = mt * 128;
  int n0 = nt * 64;

  int srow = lane >> 2;
  int sslot = (lane & 3) ^ (srow & 3);

#define STAGE_AB(BUF, K0)                                                       \
  {                                                                             \
    _Pragma("unroll")                                                           \
    for (int p = 0; p < 2; ++p) {                                               \
      int ar = wave * 32 + p * 16 + srow;                                       \
      gload_lds16(yhb + (size_t)(m0 + ar) * CC + (K0) + (sslot << 3),           \
                  &Alds[BUF][wave * 32 + p * 16][0]);                           \
    }                                                                           \
    int br = wave * 16 + srow;                                                  \
    gload_lds16(wpT + (size_t)(n0 + br) * CC + (K0) + (sslot << 3),             \
                &Blds[BUF][wave * 16][0]);                                      \
  }

  f32x4 acc[2][4];
#pragma unroll
  for (int mi = 0; mi < 2; ++mi)
#pragma unroll
    for (int nj = 0; nj < 4; ++nj) acc[mi][nj] = (f32x4){0.f, 0.f, 0.f, 0.f};

  STAGE_AB(0, 0)
  __syncthreads();

  int fslot = lg ^ (lr & 3);
  for (int kt = 0; kt < 24; ++kt) {
    int cur = kt & 1;
    if (kt < 23) STAGE_AB(cur ^ 1, (kt + 1) * 32)
    bf16x8 af[2], bf[4];
#pragma unroll
    for (int mi = 0; mi < 2; ++mi)
      af[mi] = *(const bf16x8*)&Alds[cur][wave * 32 + mi * 16 + lr][fslot << 3];
#pragma unroll
    for (int nj = 0; nj < 4; ++nj)
      bf[nj] = *(const bf16x8*)&Blds[cur][nj * 16 + lr][fslot << 3];
    __builtin_amdgcn_s_setprio(1);
#pragma unroll
    for (int nj = 0; nj < 4; ++nj)
#pragma unroll
      for (int mi = 0; mi < 2; ++mi)
        acc[mi][nj] = __builtin_amdgcn_mfma_f32_16x16x32_bf16(af[mi], bf[nj], acc[mi][nj], 0, 0, 0);
    __builtin_amdgcn_s_setprio(0);
    __syncthreads();
  }
#undef STAGE_AB

  float bias[4];
#pragma unroll
  for (int nj = 0; nj < 4; ++nj) bias[nj] = b_proj[n0 + nj * 16 + lr];
#pragma unroll
  for (int mi = 0; mi < 2; ++mi)
#pragma unroll
    for (int r = 0; r < 4; ++r) {
      int m = m0 + wave * 32 + mi * 16 + lg * 4 + r;
#pragma unroll
      for (int nj = 0; nj < 4; ++nj)
        y[(size_t)m * CC + n0 + nj * 16 + lr] = acc[mi][nj][r] + bias[nj];
    }
}

// ---------------------------------------------------------------------------
// fp32 GEMM for head-0 q,k only (precision-critical FF path). Grid (64, 2).
// ---------------------------------------------------------------------------
__global__ __launch_bounds__(256) void sgemm_qk0(
    const float* __restrict__ x, const float* __restrict__ w_attn,
    const float* __restrict__ b_attn, float* __restrict__ q0,
    float* __restrict__ k0) {
  __shared__ float As[16][64];
  __shared__ float Bs[16][64];
  int sec = blockIdx.y;
  const float* Bw = w_attn + sec * CC;
  float* Out = sec ? k0 : q0;
  int tid = threadIdx.x;
  int tx = tid & 15, ty = tid >> 4;
  int m0 = blockIdx.x * 64;

  int arow = tid >> 2;
  int acol4 = (tid & 3) << 2;
  int brow = tid >> 4;
  int bcol4 = (tid & 15) << 2;

  const float* Aptr = x + (size_t)(m0 + arow) * CC + acol4;
  const float* Bptr = Bw + (size_t)brow * N3 + bcol4;

  float acc[4][4] = {};

  for (int k0_ = 0; k0_ < CC; k0_ += 16) {
    float4 av = *(const float4*)(Aptr + k0_);
    float4 bv = *(const float4*)(Bptr + (size_t)k0_ * N3);
    As[acol4 + 0][arow] = av.x;
    As[acol4 + 1][arow] = av.y;
    As[acol4 + 2][arow] = av.z;
    As[acol4 + 3][arow] = av.w;
    *(float4*)&Bs[brow][bcol4] = bv;
    __syncthreads();
#pragma unroll
    for (int kk = 0; kk < 16; ++kk) {
      float4 a4 = *(const float4*)&As[kk][ty << 2];
      float4 b4 = *(const float4*)&Bs[kk][tx << 2];
      float a[4] = {a4.x, a4.y, a4.z, a4.w};
      float b[4] = {b4.x, b4.y, b4.z, b4.w};
#pragma unroll
      for (int ii = 0; ii < 4; ++ii)
#pragma unroll
        for (int jj = 0; jj < 4; ++jj) acc[ii][jj] += a[ii] * b[jj];
    }
    __syncthreads();
  }

  float4 bv = *(const float4*)(b_attn + sec * CC + (tx << 2));
#pragma unroll
  for (int ii = 0; ii < 4; ++ii) {
    int m = m0 + (ty << 2) + ii;
    float4 o;
    o.x = acc[ii][0] + bv.x;
    o.y = acc[ii][1] + bv.y;
    o.z = acc[ii][2] + bv.z;
    o.w = acc[ii][3] + bv.w;
    *(float4*)(Out + (size_t)m * HD + (tx << 2)) = o;
  }
}

// ---------------------------------------------------------------------------
// Head-0 scores (fp32): Sbuf[b,i,j] = relu(dot(q0,k0)/8), lower-tri tiles.
// ---------------------------------------------------------------------------
__global__ __launch_bounds__(256) void score0_kernel(
    const float* __restrict__ q0, const float* __restrict__ k0,
    float* __restrict__ Sbuf) {
  int it = blockIdx.x, jt = blockIdx.y, b = blockIdx.z;
  if (jt > it) return;
  __shared__ float Qs[64][64];
  __shared__ float Ks[64][64];
  int tid = threadIdx.x;
  int row = tid >> 2;
  int dq = (tid & 3) << 2;
  int i0 = it * 64, j0 = jt * 64;
  const float* qb = q0 + (size_t)((b * TT) + i0 + row) * HD;
  const float* kb = k0 + (size_t)((b * TT) + j0 + row) * HD;
#pragma unroll
  for (int rep = 0; rep < 4; ++rep) {
    int d = dq + rep * 16;
    float4 qv = *(const float4*)(qb + d);
    float4 kv = *(const float4*)(kb + d);
    Qs[d + 0][row] = qv.x; Qs[d + 1][row] = qv.y;
    Qs[d + 2][row] = qv.z; Qs[d + 3][row] = qv.w;
    Ks[d + 0][row] = kv.x; Ks[d + 1][row] = kv.y;
    Ks[d + 2][row] = kv.z; Ks[d + 3][row] = kv.w;
  }
  __syncthreads();
  int tx = tid & 15, ty = tid >> 4;
  float acc[4][4] = {};
#pragma unroll 8
  for (int kk = 0; kk < 64; ++kk) {
    float4 a4 = *(const float4*)&Qs[kk][ty << 2];
    float4 b4 = *(const float4*)&Ks[kk][tx << 2];
    float a[4] = {a4.x, a4.y, a4.z, a4.w};
    float b[4] = {b4.x, b4.y, b4.z, b4.w};
#pragma unroll
    for (int ii = 0; ii < 4; ++ii)
#pragma unroll
      for (int jj = 0; jj < 4; ++jj) acc[ii][jj] += a[ii] * b[jj];
  }
#pragma unroll
  for (int ii = 0; ii < 4; ++ii) {
    int gi = (b * TT) + i0 + (ty << 2) + ii;
    float4 o;
    o.x = fmaxf(acc[ii][0] * 0.125f, 0.f);
    o.y = fmaxf(acc[ii][1] * 0.125f, 0.f);
    o.z = fmaxf(acc[ii][2] * 0.125f, 0.f);
    o.w = fmaxf(acc[ii][3] * 0.125f, 0.f);
    *(float4*)(Sbuf + (size_t)gi * TT + j0 + (tx << 2)) = o;
  }
}

// ---------------------------------------------------------------------------
// Column-wise exclusive prefix scan over rows (chunked, two passes).
// scan_write also emits E = exp(-FF) in bf16 with a j-swizzled layout:
// within each 64-col tile, element j is stored at ((j&15)<<2)|((j>>4)&3)
// so the attention lane's 4 columns {lr,16+lr,32+lr,48+lr} are contiguous.
// ---------------------------------------------------------------------------
__global__ __launch_bounds__(256) void scan_partial(
    const float* __restrict__ Sbuf, float* __restrict__ partials) {
  int j = blockIdx.x * 256 + threadIdx.x;
  int chunk = blockIdx.y, b = blockIdx.z;
  int r0 = chunk * 128;
  const float* base = Sbuf + (size_t)(b * TT + r0) * TT + j;
  float sum = 0.f;
  for (int rr = 0; rr < 128; ++rr) {
    int r = r0 + rr;
    float v = (j >= 1 && j < r) ? base[(size_t)rr * TT] : 0.f;
    sum += v;
  }
  partials[(size_t)(b * 16 + chunk) * TT + j] = sum;
}

__global__ __launch_bounds__(256) void scan_write(
    float* __restrict__ Sbuf, const float* __restrict__ partials,
    unsigned short* __restrict__ Eb) {
  int j = blockIdx.x * 256 + threadIdx.x;
  int chunk = blockIdx.y, b = blockIdx.z;
  float run = 0.f;
  for (int c = 0; c < chunk; ++c) run += partials[(size_t)(b * 16 + c) * TT + j];
  int r0 = chunk * 128;
  int jswz = (j & ~63) | ((j & 15) << 2) | ((j >> 4) & 3);
  float* base = Sbuf + (size_t)(b * TT + r0) * TT + j;
  unsigned short* ebase = Eb + (size_t)(b * TT + r0) * TT + jswz;
  for (int rr = 0; rr < 128; ++rr) {
    int r = r0 + rr;
    float v = (j >= 1 && j < r) ? base[(size_t)rr * TT] : 0.f;
    base[(size_t)rr * TT] = run;                 // FF (fp32, for ffsum/M)
    ebase[(size_t)rr * TT] = f2b(__expf(-run));  // E (bf16, for attention)
    run += v;
  }
}

// ---------------------------------------------------------------------------
// FF_sum[b,i] = sum_j clip(FF[b,i,j], 0, 1)
// ---------------------------------------------------------------------------
__global__ __launch_bounds__(256) void ffsum_kernel(
    const float* __restrict__ FF, float* __restrict__ ffsum) {
  int i = blockIdx.x, b = blockIdx.y;
  const float4* row = (const float4*)(FF + (size_t)(b * TT + i) * TT);
  float s = 0.f;
  for (int r = threadIdx.x; r < TT / 4; r += 256) {
    float4 v = row[r];
    s += fminf(fmaxf(v.x, 0.f), 1.f) + fminf(fmaxf(v.y, 0.f), 1.f) +
         fminf(fmaxf(v.z, 0.f), 1.f) + fminf(fmaxf(v.w, 0.f), 1.f);
  }
#pragma unroll
  for (int o = 1; o < 64; o <<= 1) s += __shfl_xor(s, o);
  __shared__ float ws[4];
  if ((threadIdx.x & 63) == 0) ws[threadIdx.x >> 6] = s;
  __syncthreads();
  if (threadIdx.x == 0) ffsum[b * TT + i] = ws[0] + ws[1] + ws[2] + ws[3];
}

// ---------------------------------------------------------------------------
// bf16 MFMA flash attention, E = exp(-FF) multiplicative penalty.
// FIXED-MAX softmax: logits are statistically bounded (|s| <~ 14, fp32 l/acc
// have 29 orders of headroom), so no online max tracking, no rescale, and
// the l-reduction is a per-lane partial summed once in the epilogue.
// Grid (24, 32): XCD = x%8 serves one batch / 3 heads (L2 locality).
// K/V staged to LDS via global_load_lds, double-buffered, XOR-swizzled.
// ---------------------------------------------------------------------------
__global__ __launch_bounds__(256, 3) void attn_mfma(
    const unsigned short* __restrict__ Qb, const unsigned short* __restrict__ Kb,
    const unsigned short* __restrict__ Vt, const unsigned short* __restrict__ Eb,
    unsigned short* __restrict__ yhb) {
  int xbh = blockIdx.x;
  int b = (xbh >> 2) & 1;
  int h = ((xbh >> 3) << 2) | (xbh & 3);
  int g4 = 31 - (int)blockIdx.y;
  int wave = threadIdx.x >> 6, lane = threadIdx.x & 63;
  int lr = lane & 15, lg = lane >> 4;
  int i0 = g4 * 64 + wave * 16;
  int bh = b * NH + h;
  const unsigned short* Qh = Qb + (size_t)bh * TT * HD;
  const unsigned short* Kh = Kb + (size_t)bh * TT * HD;
  const unsigned short* Vh = Vt + (size_t)bh * HD * TT;
  const unsigned short* Erow = Eb + ((size_t)(b * TT) + i0 + lg * 4) * TT + 4 * lr;

  // LDS: K/V double buffers (swizzled slots) + P tile. 42KB -> 3 blocks/CU.
  __shared__ __align__(16) unsigned short Ksh[2][64][64];
  __shared__ __align__(16) unsigned short Vsh[2][64][64];
  __shared__ __align__(16) unsigned short Plds[4][16][80];

  int rowoff = lane >> 3;            // 0..7 within an 8-row staging segment
  int sslot  = (lane & 7) ^ rowoff;  // pre-swizzled source slot (16B units)

  bf16x8 qf[2];
#pragma unroll
  for (int ks = 0; ks < 2; ++ks)
    qf[ks] = *(const bf16x8*)(Qh + (size_t)(i0 + lr) * HD + ks * 32 + lg * 8);

  f32x4 acc[4];
  float lrun[4] = {0.f, 0.f, 0.f, 0.f};  // per-lane partial of softmax denom
#pragma unroll
  for (int q = 0; q < 4; ++q) acc[q] = (f32x4){0.f, 0.f, 0.f, 0.f};

#define STAGE_KV(BUF, J0)                                                      \
  {                                                                            \
    _Pragma("unroll")                                                          \
    for (int p = 0; p < 2; ++p) {                                              \
      int r0 = wave * 16 + p * 8;                                              \
      gload_lds16(Kh + (size_t)((J0) + r0 + rowoff) * HD + sslot * 8,          \
                  &Ksh[BUF][r0][0]);                                           \
      gload_lds16(Vh + (size_t)(r0 + rowoff) * TT + (J0) + sslot * 8,          \
                  &Vsh[BUF][r0][0]);                                           \
    }                                                                          \
  }

  // prologue: stage tile 0 into buffer 0
  STAGE_KV(0, 0)
  __syncthreads();

  for (int kt = 0; kt <= g4; ++kt) {
    int cur = kt & 1;
    int j0 = kt * 64;
    if (kt < g4) STAGE_KV(cur ^ 1, j0 + 64)

    // E for current tile (4 x 8B vector loads, swizzled layout)
    ushort4 ev[4];
#pragma unroll
    for (int r = 0; r < 4; ++r)
      ev[r] = *(const ushort4*)(Erow + (size_t)r * TT + j0);

    // ---- QK^T from swizzled LDS ----
    f32x4 s[4];
    __builtin_amdgcn_s_setprio(1);
#pragma unroll
    for (int nj = 0; nj < 4; ++nj) {
      int row = nj * 16 + lr;
      int sw = row & 7;
      bf16x8 k0f = *(const bf16x8*)&Ksh[cur][row][(lg ^ sw) << 3];
      bf16x8 k1f = *(const bf16x8*)&Ksh[cur][row][((4 + lg) ^ sw) << 3];
      f32x4 z = (f32x4){0.f, 0.f, 0.f, 0.f};
      z = __builtin_amdgcn_mfma_f32_16x16x32_bf16(qf[0], k0f, z, 0, 0, 0);
      s[nj] = __builtin_amdgcn_mfma_f32_16x16x32_bf16(qf[1], k1f, z, 0, 0, 0);
    }
    __builtin_amdgcn_s_setprio(0);

    // ---- causal mask (diagonal tile only) ----
    int ibase = i0 + lg * 4;
    if (kt == g4) {
#pragma unroll
      for (int nj = 0; nj < 4; ++nj)
#pragma unroll
        for (int r = 0; r < 4; ++r)
          if (j0 + nj * 16 + lr > ibase + r) s[nj][r] = -1e30f;
    }

    // ---- P = E * exp(s); per-lane partial l; stash bf16 P in LDS ----
#pragma unroll
    for (int r = 0; r < 4; ++r) {
      float p0 = b2f(ev[r].x) * __expf(s[0][r]);
      float p1 = b2f(ev[r].y) * __expf(s[1][r]);
      float p2 = b2f(ev[r].z) * __expf(s[2][r]);
      float p3 = b2f(ev[r].w) * __expf(s[3][r]);
      lrun[r] += p0 + p1 + p2 + p3;
      Plds[wave][lg * 4 + r][0 * 16 + lr] = f2b(p0);
      Plds[wave][lg * 4 + r][1 * 16 + lr] = f2b(p1);
      Plds[wave][lg * 4 + r][2 * 16 + lr] = f2b(p2);
      Plds[wave][lg * 4 + r][3 * 16 + lr] = f2b(p3);
    }

    // ---- PV from swizzled LDS ----
    bf16x8 pa0 = *(const bf16x8*)&Plds[wave][lr][lg * 8];
    bf16x8 pa1 = *(const bf16x8*)&Plds[wave][lr][32 + lg * 8];
    __builtin_amdgcn_s_setprio(1);
#pragma unroll
    for (int nd = 0; nd < 4; ++nd) {
      int row = nd * 16 + lr;
      int sw = row & 7;
      bf16x8 v0f = *(const bf16x8*)&Vsh[cur][row][(lg ^ sw) << 3];
      bf16x8 v1f = *(const bf16x8*)&Vsh[cur][row][((4 + lg) ^ sw) << 3];
      acc[nd] = __builtin_amdgcn_mfma_f32_16x16x32_bf16(pa0, v0f, acc[nd], 0, 0, 0);
      acc[nd] = __builtin_amdgcn_mfma_f32_16x16x32_bf16(pa1, v1f, acc[nd], 0, 0, 0);
    }
    __builtin_amdgcn_s_setprio(0);

    // staging for kt+1 complete (compiler drains vmcnt before barrier);
    // all waves done reading buf[cur] -> next tile may overwrite it.
    __syncthreads();
  }
#undef STAGE_KV

  // ---- epilogue: one l-reduction across the 16 lr lanes, then store ----
#pragma unroll
  for (int r = 0; r < 4; ++r) {
    lrun[r] += __shfl_xor(lrun[r], 1);
    lrun[r] += __shfl_xor(lrun[r], 2);
    lrun[r] += __shfl_xor(lrun[r], 4);
    lrun[r] += __shfl_xor(lrun[r], 8);
    float inv = 1.f / lrun[r];
    int ig = i0 + lg * 4 + r;
    unsigned short* ob = yhb + (size_t)(b * TT + ig) * CC + h * HD;
#pragma unroll
    for (int nd = 0; nd < 4; ++nd)
      ob[nd * 16 + lr] = f2b(acc[nd][r] * inv);
  }
}

// ---------------------------------------------------------------------------
// M[0,b,i,j] = i - ffsum[b,j]
// ---------------------------------------------------------------------------
__global__ __launch_bounds__(256) void m_kernel(
    const float* __restrict__ ffsum, float* __restrict__ Mout) {
  int idx = blockIdx.x * blockDim.x + threadIdx.x;
  int stride = gridDim.x * blockDim.x;
  for (; idx < M_ELEMS; idx += stride) {
    int j = idx & (TT - 1);
    int i = (idx >> 11) & (TT - 1);
    int b = idx >> 22;
    Mout[idx] = (float)i - ffsum[(b << 11) + j];
  }
}

// ---------------------------------------------------------------------------
extern "C" void kernel_launch(void* const* d_in, const int* in_sizes, int n_in,
                              void* d_out, int out_size, void* d_ws, size_t ws_size,
                              hipStream_t stream) {
  const float* x      = (const float*)d_in[0];
  const float* w_attn = (const float*)d_in[1];
  const float* b_attn = (const float*)d_in[2];
  const float* w_proj = (const float*)d_in[3];
  const float* b_proj = (const float*)d_in[4];

  float* y    = (float*)d_out;          // [B,T,C]
  float* Mreg = y + Y_ELEMS;            // [B,T,T]: S0 -> FF (scratch) -> M (final)

  float* ws = (float*)d_ws;
  float* q0       = ws;                         // B*T*64
  float* k0       = q0 + (size_t)BB * TT * HD;
  float* partials = k0 + (size_t)BB * TT * HD;  // B*16*T
  float* ffsum    = partials + BB * 16 * TT;    // B*T
  unsigned short* xb  = (unsigned short*)(ffsum + BB * TT);   // B*T*C
  unsigned short* wbT = xb + (size_t)Y_ELEMS;                 // 2304*768
  unsigned short* wpT = wbT + (size_t)N3 * CC;                // 768*768
  unsigned short* Qb  = wpT + (size_t)CC * CC;                // B*NH*T*HD
  unsigned short* Kb  = Qb + (size_t)BB * NH * TT * HD;
  unsigned short* Vt  = Kb + (size_t)BB * NH * TT * HD;
  unsigned short* yhb = Vt + (size_t)BB * NH * TT * HD;       // B*T*C
  unsigned short* Eb  = yhb + (size_t)Y_ELEMS;                // B*T*T bf16 (16.8MB)
  // total ws usage ~= 46 MB

  // 1. packs: x -> bf16; weights -> transposed bf16
  pack_x<<<Y_ELEMS / (256 * 8), 256, 0, stream>>>(x, xb);
  transpose_pack<<<dim3(CC / 64, N3 / 64), 256, 0, stream>>>(w_attn, wbT, N3);
  transpose_pack<<<dim3(CC / 64, CC / 64), 256, 0, stream>>>(w_proj, wpT, CC);
  // 2. bf16 MFMA QKV GEMM (LDS-staged dbuf) -> packed Qb (1/8) / Kb / Vt
  gemm_qkv_bf16<<<dim3(32, 36), 256, 0, stream>>>(xb, wbT, b_attn, Qb, Kb, Vt);
  // 3. fp32 head-0 q,k (precision-critical FF path)
  sgemm_qk0<<<dim3(64, 2), 256, 0, stream>>>(x, w_attn, b_attn, q0, k0);
  // 4. head-0 scores (relu'd, fp32) into Mreg
  score0_kernel<<<dim3(32, 32, BB), 256, 0, stream>>>(q0, k0, Mreg);
  // 5. column-wise exclusive scan (in place): Mreg = FF; also E = exp(-FF) bf16
  scan_partial<<<dim3(8, 16, BB), 256, 0, stream>>>(Mreg, partials);
  scan_write<<<dim3(8, 16, BB), 256, 0, stream>>>(Mreg, partials, Eb);
  // 6. FF_sum (reads fp32 FF)
  ffsum_kernel<<<dim3(TT, BB), 256, 0, stream>>>(Mreg, ffsum);
  // 7. MFMA flash attention (fixed-max softmax, LDS-staged K/V, XCD grid)
  attn_mfma<<<dim3(24, 32), 256, 0, stream>>>(Qb, Kb, Vt, Eb, yhb);
  // 8. M output (after attn so its dirty lines don't flush during attn)
  m_kernel<<<4096, 256, 0, stream>>>(ffsum, Mreg);
  // 9. y = yhb @ w_proj + b_proj (bf16 MFMA, LDS-staged dbuf)
  gemm_proj_bf16<<<dim3(32, 12), 256, 0, stream>>>(yhb, wpT, b_proj, y);
}

// Round 10
// 215.282 us; speedup vs baseline: 2.3449x; 1.0395x over previous
//
#include <hip/hip_runtime.h>
#include <cstddef>

// Problem constants
#define TT 2048
#define BB 2
#define CC 768
#define NH 12
#define HD 64
#define N3 2304          // 3*NH*HD
#define Y_ELEMS (BB*TT*CC)          // 3145728
#define M_ELEMS (BB*TT*TT)          // 8388608

typedef __attribute__((ext_vector_type(8))) short bf16x8;
typedef __attribute__((ext_vector_type(4))) float f32x4;

__device__ inline unsigned short f2b(float f) {
  union { float f; unsigned u; } v; v.f = f;
  unsigned r = (v.u + 0x7FFFu + ((v.u >> 16) & 1u)) >> 16;
  return (unsigned short)r;
}
__device__ inline float b2f(unsigned short u) {
  union { unsigned u; float f; } v; v.u = (unsigned)u << 16; return v.f;
}

// async global -> LDS, 16B per lane; lds dest is wave-uniform base, HW adds lane*16
__device__ inline void gload_lds16(const unsigned short* g, unsigned short* l) {
  __builtin_amdgcn_global_load_lds(
      (const __attribute__((address_space(1))) unsigned int*)g,
      (__attribute__((address_space(3))) unsigned int*)l, 16, 0, 0);
}

// ---------------------------------------------------------------------------
// pack x (fp32) -> xb (bf16). 8 elems/thread.
// ---------------------------------------------------------------------------
__global__ __launch_bounds__(256) void pack_x(
    const float* __restrict__ x, unsigned short* __restrict__ xb) {
  size_t i = ((size_t)blockIdx.x * 256 + threadIdx.x) * 8;
  float4 a = *(const float4*)(x + i);
  float4 b = *(const float4*)(x + i + 4);
  ushort4 o0, o1;
  o0.x = f2b(a.x); o0.y = f2b(a.y); o0.z = f2b(a.z); o0.w = f2b(a.w);
  o1.x = f2b(b.x); o1.y = f2b(b.y); o1.z = f2b(b.z); o1.w = f2b(b.w);
  *(ushort4*)(xb + i) = o0;
  *(ushort4*)(xb + i + 4) = o1;
}

// ---------------------------------------------------------------------------
// W [768][N] fp32 -> WT [N][768] bf16 (transposed pack). Block=(kt,nt) 64x64.
// ---------------------------------------------------------------------------
__global__ __launch_bounds__(256) void transpose_pack(
    const float* __restrict__ W, unsigned short* __restrict__ WT, int N) {
  __shared__ float tile[64][65];
  int kt = blockIdx.x, nt = blockIdx.y;
  int tid = threadIdx.x;
  int r = tid >> 4, c4 = (tid & 15) << 2;
#pragma unroll
  for (int rep = 0; rep < 4; ++rep) {
    int row = rep * 16 + r;
    float4 v = *(const float4*)(W + (size_t)(kt * 64 + row) * N + nt * 64 + c4);
    tile[row][c4 + 0] = v.x; tile[row][c4 + 1] = v.y;
    tile[row][c4 + 2] = v.z; tile[row][c4 + 3] = v.w;
  }
  __syncthreads();
#pragma unroll
  for (int rep = 0; rep < 4; ++rep) {
    int nrow = rep * 16 + r;
    ushort4 o;
    o.x = f2b(tile[c4 + 0][nrow]); o.y = f2b(tile[c4 + 1][nrow]);
    o.z = f2b(tile[c4 + 2][nrow]); o.w = f2b(tile[c4 + 3][nrow]);
    *(ushort4*)(WT + (size_t)(nt * 64 + nrow) * CC + kt * 64 + c4) = o;
  }
}

// ---------------------------------------------------------------------------
// bf16 MFMA GEMM: qkv = xb @ wbT^T + b_attn -> packed Qb (pre-scaled by
// 0.125*log2(e) for the exp2 softmax), Kb, Vt (transposed via LDS).
// Grid (32 mtiles of 128, 36 ntiles of 64). LDS-staged dbuf, slot-swizzled.
// ---------------------------------------------------------------------------
__global__ __launch_bounds__(256, 3) void gemm_qkv_bf16(
    const unsigned short* __restrict__ xb, const unsigned short* __restrict__ wbT,
    const float* __restrict__ b_attn,
    unsigned short* __restrict__ Qb, unsigned short* __restrict__ Kb,
    unsigned short* __restrict__ Vt) {
  __shared__ __align__(16) unsigned short Alds[2][128][32];
  __shared__ __align__(16) unsigned short Blds[2][64][32];
  __shared__ __align__(16) unsigned short Vlds[128][72];
  int mt = blockIdx.x, nt = blockIdx.y;
  int sec = nt / NH, h = nt % NH;
  int wave = threadIdx.x >> 6, lane = threadIdx.x & 63;
  int lr = lane & 15, lg = lane >> 4;
  int m0 = mt * 128;
  int n0 = nt * 64;

  int srow = lane >> 2;                 // 0..15 staging row within segment
  int sslot = (lane & 3) ^ (srow & 3);  // pre-swizzled source k-slot (16B units)

#define STAGE_AB(BUF, K0)                                                       \
  {                                                                             \
    _Pragma("unroll")                                                           \
    for (int p = 0; p < 2; ++p) {                                               \
      int ar = wave * 32 + p * 16 + srow;                                       \
      gload_lds16(xb + (size_t)(m0 + ar) * CC + (K0) + (sslot << 3),            \
                  &Alds[BUF][wave * 32 + p * 16][0]);                           \
    }                                                                           \
    int br = wave * 16 + srow;                                                  \
    gload_lds16(wbT + (size_t)(n0 + br) * CC + (K0) + (sslot << 3),             \
                &Blds[BUF][wave * 16][0]);                                      \
  }

  f32x4 acc[2][4];
#pragma unroll
  for (int mi = 0; mi < 2; ++mi)
#pragma unroll
    for (int nj = 0; nj < 4; ++nj) acc[mi][nj] = (f32x4){0.f, 0.f, 0.f, 0.f};

  STAGE_AB(0, 0)
  __syncthreads();

  int fslot = lg ^ (lr & 3);  // frag read slot (same involution)
  for (int kt = 0; kt < 24; ++kt) {
    int cur = kt & 1;
    if (kt < 23) STAGE_AB(cur ^ 1, (kt + 1) * 32)
    bf16x8 af[2], bf[4];
#pragma unroll
    for (int mi = 0; mi < 2; ++mi)
      af[mi] = *(const bf16x8*)&Alds[cur][wave * 32 + mi * 16 + lr][fslot << 3];
#pragma unroll
    for (int nj = 0; nj < 4; ++nj)
      bf[nj] = *(const bf16x8*)&Blds[cur][nj * 16 + lr][fslot << 3];
    __builtin_amdgcn_s_setprio(1);
#pragma unroll
    for (int nj = 0; nj < 4; ++nj)
#pragma unroll
      for (int mi = 0; mi < 2; ++mi)
        acc[mi][nj] = __builtin_amdgcn_mfma_f32_16x16x32_bf16(af[mi], bf[nj], acc[mi][nj], 0, 0, 0);
    __builtin_amdgcn_s_setprio(0);
    __syncthreads();
  }
#undef STAGE_AB

  int b = m0 >> 11;
  int bh = b * NH + h;
  float bias[4];
#pragma unroll
  for (int nj = 0; nj < 4; ++nj) bias[nj] = b_attn[n0 + nj * 16 + lr];

  if (sec < 2) {
    // Q pre-scaled by (1/8)*log2(e) so attention uses exp2 directly
    float qscale = (sec == 0) ? 0.18033688f : 1.0f;
    unsigned short* Out = (sec == 0 ? Qb : Kb) + (size_t)bh * TT * HD;
    int tbase = (m0 & 2047) + wave * 32 + lg * 4;
#pragma unroll
    for (int mi = 0; mi < 2; ++mi)
#pragma unroll
      for (int r = 0; r < 4; ++r) {
        int t = tbase + mi * 16 + r;
#pragma unroll
        for (int nj = 0; nj < 4; ++nj)
          Out[(size_t)t * HD + nj * 16 + lr] = f2b((acc[mi][nj][r] + bias[nj]) * qscale);
      }
  } else {
    int tl = wave * 32 + lg * 4;
#pragma unroll
    for (int mi = 0; mi < 2; ++mi)
#pragma unroll
      for (int r = 0; r < 4; ++r)
#pragma unroll
        for (int nj = 0; nj < 4; ++nj)
          Vlds[tl + mi * 16 + r][nj * 16 + lr] = f2b(acc[mi][nj][r] + bias[nj]);
    __syncthreads();
    int d = threadIdx.x & 63, tc = threadIdx.x >> 6;
    int tblk = (mt * 128) & 2047;
    unsigned short* Ov = Vt + ((size_t)bh * HD + d) * TT + tblk + tc * 32;
#pragma unroll
    for (int i8 = 0; i8 < 4; ++i8) {
      ushort4 o0, o1;
      o0.x = Vlds[tc * 32 + i8 * 8 + 0][d]; o0.y = Vlds[tc * 32 + i8 * 8 + 1][d];
      o0.z = Vlds[tc * 32 + i8 * 8 + 2][d]; o0.w = Vlds[tc * 32 + i8 * 8 + 3][d];
      o1.x = Vlds[tc * 32 + i8 * 8 + 4][d]; o1.y = Vlds[tc * 32 + i8 * 8 + 5][d];
      o1.z = Vlds[tc * 32 + i8 * 8 + 6][d]; o1.w = Vlds[tc * 32 + i8 * 8 + 7][d];
      *(ushort4*)(Ov + i8 * 8) = o0;
      *(ushort4*)(Ov + i8 * 8 + 4) = o1;
    }
  }
}

// ---------------------------------------------------------------------------
// bf16 MFMA GEMM: y = yhb @ wpT^T + b_proj (fp32 out). Grid (32, 12).
// ---------------------------------------------------------------------------
__global__ __launch_bounds__(256, 3) void gemm_proj_bf16(
    const unsigned short* __restrict__ yhb, const unsigned short* __restrict__ wpT,
    const float* __restrict__ b_proj, float* __restrict__ y) {
  __shared__ __align__(16) unsigned short Alds[2][128][32];
  __shared__ __align__(16) unsigned short Blds[2][64][32];
  int mt = blockIdx.x, nt = blockIdx.y;
  int wave = threadIdx.x >> 6, lane = threadIdx.x & 63;
  int lr = lane & 15, lg = lane >> 4;
  int m0 = mt * 128;
  int n0 = nt * 64;

  int srow = lane >> 2;
  int sslot = (lane & 3) ^ (srow & 3);

#define STAGE_AB(BUF, K0)                                                       \
  {                                                                             \
    _Pragma("unroll")                                                           \
    for (int p = 0; p < 2; ++p) {                                               \
      int ar = wave * 32 + p * 16 + srow;                                       \
      gload_lds16(yhb + (size_t)(m0 + ar) * CC + (K0) + (sslot << 3),           \
                  &Alds[BUF][wave * 32 + p * 16][0]);                           \
    }                                                                           \
    int br = wave * 16 + srow;                                                  \
    gload_lds16(wpT + (size_t)(n0 + br) * CC + (K0) + (sslot << 3),             \
                &Blds[BUF][wave * 16][0]);                                      \
  }

  f32x4 acc[2][4];
#pragma unroll
  for (int mi = 0; mi < 2; ++mi)
#pragma unroll
    for (int nj = 0; nj < 4; ++nj) acc[mi][nj] = (f32x4){0.f, 0.f, 0.f, 0.f};

  STAGE_AB(0, 0)
  __syncthreads();

  int fslot = lg ^ (lr & 3);
  for (int kt = 0; kt < 24; ++kt) {
    int cur = kt & 1;
    if (kt < 23) STAGE_AB(cur ^ 1, (kt + 1) * 32)
    bf16x8 af[2], bf[4];
#pragma unroll
    for (int mi = 0; mi < 2; ++mi)
      af[mi] = *(const bf16x8*)&Alds[cur][wave * 32 + mi * 16 + lr][fslot << 3];
#pragma unroll
    for (int nj = 0; nj < 4; ++nj)
      bf[nj] = *(const bf16x8*)&Blds[cur][nj * 16 + lr][fslot << 3];
    __builtin_amdgcn_s_setprio(1);
#pragma unroll
    for (int nj = 0; nj < 4; ++nj)
#pragma unroll
      for (int mi = 0; mi < 2; ++mi)
        acc[mi][nj] = __builtin_amdgcn_mfma_f32_16x16x32_bf16(af[mi], bf[nj], acc[mi][nj], 0, 0, 0);
    __builtin_amdgcn_s_setprio(0);
    __syncthreads();
  }
#undef STAGE_AB

  float bias[4];
#pragma unroll
  for (int nj = 0; nj < 4; ++nj) bias[nj] = b_proj[n0 + nj * 16 + lr];
#pragma unroll
  for (int mi = 0; mi < 2; ++mi)
#pragma unroll
    for (int r = 0; r < 4; ++r) {
      int m = m0 + wave * 32 + mi * 16 + lg * 4 + r;
#pragma unroll
      for (int nj = 0; nj < 4; ++nj)
        y[(size_t)m * CC + n0 + nj * 16 + lr] = acc[mi][nj][r] + bias[nj];
    }
}

// ---------------------------------------------------------------------------
// fp32 GEMM for head-0 q,k only (precision-critical FF path). Grid (64, 2).
// ---------------------------------------------------------------------------
__global__ __launch_bounds__(256) void sgemm_qk0(
    const float* __restrict__ x, const float* __restrict__ w_attn,
    const float* __restrict__ b_attn, float* __restrict__ q0,
    float* __restrict__ k0) {
  __shared__ float As[16][64];
  __shared__ float Bs[16][64];
  int sec = blockIdx.y;
  const float* Bw = w_attn + sec * CC;
  float* Out = sec ? k0 : q0;
  int tid = threadIdx.x;
  int tx = tid & 15, ty = tid >> 4;
  int m0 = blockIdx.x * 64;

  int arow = tid >> 2;
  int acol4 = (tid & 3) << 2;
  int brow = tid >> 4;
  int bcol4 = (tid & 15) << 2;

  const float* Aptr = x + (size_t)(m0 + arow) * CC + acol4;
  const float* Bptr = Bw + (size_t)brow * N3 + bcol4;

  float acc[4][4] = {};

  for (int k0_ = 0; k0_ < CC; k0_ += 16) {
    float4 av = *(const float4*)(Aptr + k0_);
    float4 bv = *(const float4*)(Bptr + (size_t)k0_ * N3);
    As[acol4 + 0][arow] = av.x;
    As[acol4 + 1][arow] = av.y;
    As[acol4 + 2][arow] = av.z;
    As[acol4 + 3][arow] = av.w;
    *(float4*)&Bs[brow][bcol4] = bv;
    __syncthreads();
#pragma unroll
    for (int kk = 0; kk < 16; ++kk) {
      float4 a4 = *(const float4*)&As[kk][ty << 2];
      float4 b4 = *(const float4*)&Bs[kk][tx << 2];
      float a[4] = {a4.x, a4.y, a4.z, a4.w};
      float b[4] = {b4.x, b4.y, b4.z, b4.w};
#pragma unroll
      for (int ii = 0; ii < 4; ++ii)
#pragma unroll
        for (int jj = 0; jj < 4; ++jj) acc[ii][jj] += a[ii] * b[jj];
    }
    __syncthreads();
  }

  float4 bv = *(const float4*)(b_attn + sec * CC + (tx << 2));
#pragma unroll
  for (int ii = 0; ii < 4; ++ii) {
    int m = m0 + (ty << 2) + ii;
    float4 o;
    o.x = acc[ii][0] + bv.x;
    o.y = acc[ii][1] + bv.y;
    o.z = acc[ii][2] + bv.z;
    o.w = acc[ii][3] + bv.w;
    *(float4*)(Out + (size_t)m * HD + (tx << 2)) = o;
  }
}

// ---------------------------------------------------------------------------
// Head-0 scores (fp32): Sbuf[b,i,j] = relu(dot(q0,k0)/8), lower-tri tiles.
// FUSED: also emits per-64-row-chunk masked column sums into partials
// (replaces the scan_partial kernel). mask = (j>=1 && j<r).
// partials layout: [B][32][TT]. Upper-tri blocks write zeros.
// ---------------------------------------------------------------------------
__global__ __launch_bounds__(256) void score0_kernel(
    const float* __restrict__ q0, const float* __restrict__ k0,
    float* __restrict__ Sbuf, float* __restrict__ partials) {
  int it = blockIdx.x, jt = blockIdx.y, b = blockIdx.z;
  int tid = threadIdx.x;
  int i0 = it * 64, j0 = jt * 64;
  if (jt > it) {  // mask kills everything above the diagonal
    if (tid < 64) partials[((size_t)(b * 32 + it)) * TT + j0 + tid] = 0.f;
    return;
  }
  __shared__ float Qs[64][64];
  __shared__ float Ks[64][64];
  int row = tid >> 2;
  int dq = (tid & 3) << 2;
  const float* qb = q0 + (size_t)((b * TT) + i0 + row) * HD;
  const float* kb = k0 + (size_t)((b * TT) + j0 + row) * HD;
#pragma unroll
  for (int rep = 0; rep < 4; ++rep) {
    int d = dq + rep * 16;
    float4 qv = *(const float4*)(qb + d);
    float4 kv = *(const float4*)(kb + d);
    Qs[d + 0][row] = qv.x; Qs[d + 1][row] = qv.y;
    Qs[d + 2][row] = qv.z; Qs[d + 3][row] = qv.w;
    Ks[d + 0][row] = kv.x; Ks[d + 1][row] = kv.y;
    Ks[d + 2][row] = kv.z; Ks[d + 3][row] = kv.w;
  }
  __syncthreads();
  int tx = tid & 15, ty = tid >> 4;
  float acc[4][4] = {};
#pragma unroll 8
  for (int kk = 0; kk < 64; ++kk) {
    float4 a4 = *(const float4*)&Qs[kk][ty << 2];
    float4 b4 = *(const float4*)&Ks[kk][tx << 2];
    float a[4] = {a4.x, a4.y, a4.z, a4.w};
    float b[4] = {b4.x, b4.y, b4.z, b4.w};
#pragma unroll
    for (int ii = 0; ii < 4; ++ii)
#pragma unroll
      for (int jj = 0; jj < 4; ++jj) acc[ii][jj] += a[ii] * b[jj];
  }
  float red4[4] = {0.f, 0.f, 0.f, 0.f};
#pragma unroll
  for (int ii = 0; ii < 4; ++ii) {
    int r = i0 + (ty << 2) + ii;           // global row (within T)
    int gi = (b * TT) + r;
    float ov[4];
#pragma unroll
    for (int jj = 0; jj < 4; ++jj) {
      ov[jj] = fmaxf(acc[ii][jj] * 0.125f, 0.f);
      int j = j0 + (tx << 2) + jj;
      if (j >= 1 && j < r) red4[jj] += ov[jj];
    }
    float4 o; o.x = ov[0]; o.y = ov[1]; o.z = ov[2]; o.w = ov[3];
    *(float4*)(Sbuf + (size_t)gi * TT + j0 + (tx << 2)) = o;
  }
  // reduce the 16 ty-groups per column via reused LDS
  __syncthreads();  // everyone done reading Qs
  *(float4*)&Qs[ty][tx << 2] = *(float4*)red4;
  __syncthreads();
  if (tid < 64) {
    float cs = 0.f;
#pragma unroll
    for (int t = 0; t < 16; ++t) cs += Qs[t][tid];
    partials[((size_t)(b * 32 + it)) * TT + j0 + tid] = cs;
  }
}

// ---------------------------------------------------------------------------
// Column-wise exclusive prefix scan over rows (64-row chunks; partial sums
// come fused from score0). Emits FF fp32 (in place) and E = exp(-FF) bf16
// in natural j-layout.
// ---------------------------------------------------------------------------
__global__ __launch_bounds__(256) void scan_write(
    float* __restrict__ Sbuf, const float* __restrict__ partials,
    unsigned short* __restrict__ Eb) {
  int j = blockIdx.x * 256 + threadIdx.x;
  int chunk = blockIdx.y, b = blockIdx.z;
  float run = 0.f;
  for (int c = 0; c < chunk; ++c) run += partials[((size_t)(b * 32 + c)) * TT + j];
  int r0 = chunk * 64;
  float* base = Sbuf + (size_t)(b * TT + r0) * TT + j;
  unsigned short* ebase = Eb + (size_t)(b * TT + r0) * TT + j;
  for (int rr = 0; rr < 64; ++rr) {
    int r = r0 + rr;
    float v = (j >= 1 && j < r) ? base[(size_t)rr * TT] : 0.f;
    base[(size_t)rr * TT] = run;                 // FF (fp32, for ffsum/M)
    ebase[(size_t)rr * TT] = f2b(__expf(-run));  // E (bf16, for attention)
    run += v;
  }
}

// ---------------------------------------------------------------------------
// FF_sum[b,i] = sum_j clip(FF[b,i,j], 0, 1)
// ---------------------------------------------------------------------------
__global__ __launch_bounds__(256) void ffsum_kernel(
    const float* __restrict__ FF, float* __restrict__ ffsum) {
  int i = blockIdx.x, b = blockIdx.y;
  const float4* row = (const float4*)(FF + (size_t)(b * TT + i) * TT);
  float s = 0.f;
  for (int r = threadIdx.x; r < TT / 4; r += 256) {
    float4 v = row[r];
    s += fminf(fmaxf(v.x, 0.f), 1.f) + fminf(fmaxf(v.y, 0.f), 1.f) +
         fminf(fmaxf(v.z, 0.f), 1.f) + fminf(fmaxf(v.w, 0.f), 1.f);
  }
#pragma unroll
  for (int o = 1; o < 64; o <<= 1) s += __shfl_xor(s, o);
  __shared__ float ws[4];
  if ((threadIdx.x & 63) == 0) ws[threadIdx.x >> 6] = s;
  __syncthreads();
  if (threadIdx.x == 0) ffsum[b * TT + i] = ws[0] + ws[1] + ws[2] + ws[3];
}

// ---------------------------------------------------------------------------
// bf16 MFMA flash attention, E = exp(-FF) multiplicative, fixed-max exp2
// softmax. SWAPPED QK^T: S^T = mfma(K,Q) puts a full q-row in each lane
// (q = lr), so P packs via v_cvt_pk_bf16_f32 pairs -> ds_write_b64, the
// l-sum is a per-lane scalar (reduced once at the epilogue via shfl +
// ds_bpermute), and E loads are 4 natural ushort4s.
// Grid (24, 32): XCD = x%8 serves one batch / 3 heads (L2 locality).
// K/V staged to LDS via global_load_lds, double-buffered, XOR-swizzled.
// Plds stride 72 shorts (36 words) -> pa reads are 2-way (free).
// ---------------------------------------------------------------------------
__global__ __launch_bounds__(256, 3) void attn_mfma(
    const unsigned short* __restrict__ Qb, const unsigned short* __restrict__ Kb,
    const unsigned short* __restrict__ Vt, const unsigned short* __restrict__ Eb,
    unsigned short* __restrict__ yhb) {
  int xbh = blockIdx.x;
  int b = (xbh >> 2) & 1;
  int h = ((xbh >> 3) << 2) | (xbh & 3);
  int g4 = 31 - (int)blockIdx.y;
  int wave = threadIdx.x >> 6, lane = threadIdx.x & 63;
  int lr = lane & 15, lg = lane >> 4;
  int i0 = g4 * 64 + wave * 16;
  int bh = b * NH + h;
  const unsigned short* Qh = Qb + (size_t)bh * TT * HD;
  const unsigned short* Kh = Kb + (size_t)bh * TT * HD;
  const unsigned short* Vh = Vt + (size_t)bh * HD * TT;
  const unsigned short* Erow = Eb + ((size_t)(b * TT) + i0 + lr) * TT;

  __shared__ __align__(16) unsigned short Ksh[2][64][64];
  __shared__ __align__(16) unsigned short Vsh[2][64][64];
  __shared__ __align__(16) unsigned short Plds[4][16][72];

  int rowoff = lane >> 3;            // 0..7 within an 8-row staging segment
  int sslot  = (lane & 7) ^ rowoff;  // pre-swizzled source slot (16B units)

  bf16x8 qf[2];
#pragma unroll
  for (int ks = 0; ks < 2; ++ks)
    qf[ks] = *(const bf16x8*)(Qh + (size_t)(i0 + lr) * HD + ks * 32 + lg * 8);

  f32x4 acc[4];
  float lrun = 0.f;  // per-lane partial softmax denom for q-row = i0+lr
#pragma unroll
  for (int q = 0; q < 4; ++q) acc[q] = (f32x4){0.f, 0.f, 0.f, 0.f};

#define STAGE_KV(BUF, J0)                                                      \
  {                                                                            \
    _Pragma("unroll")                                                          \
    for (int p = 0; p < 2; ++p) {                                              \
      int r0 = wave * 16 + p * 8;                                              \
      gload_lds16(Kh + (size_t)((J0) + r0 + rowoff) * HD + sslot * 8,          \
                  &Ksh[BUF][r0][0]);                                           \
      gload_lds16(Vh + (size_t)(r0 + rowoff) * TT + (J0) + sslot * 8,          \
                  &Vsh[BUF][r0][0]);                                           \
    }                                                                          \
  }

  STAGE_KV(0, 0)
  __syncthreads();

  for (int kt = 0; kt <= g4; ++kt) {
    int cur = kt & 1;
    int j0 = kt * 64;
    if (kt < g4) STAGE_KV(cur ^ 1, j0 + 64)

    // E for this tile: 4 consecutive j per lane, natural layout
    ushort4 ev[4];
#pragma unroll
    for (int nj = 0; nj < 4; ++nj)
      ev[nj] = *(const ushort4*)(Erow + j0 + nj * 16 + lg * 4);

    // ---- S^T = K·Q^T from swizzled LDS (swapped operands) ----
    f32x4 s[4];
    __builtin_amdgcn_s_setprio(1);
#pragma unroll
    for (int nj = 0; nj < 4; ++nj) {
      int row = nj * 16 + lr;
      int sw = row & 7;
      bf16x8 k0f = *(const bf16x8*)&Ksh[cur][row][(lg ^ sw) << 3];
      bf16x8 k1f = *(const bf16x8*)&Ksh[cur][row][((4 + lg) ^ sw) << 3];
      f32x4 z = (f32x4){0.f, 0.f, 0.f, 0.f};
      z = __builtin_amdgcn_mfma_f32_16x16x32_bf16(k0f, qf[0], z, 0, 0, 0);
      s[nj] = __builtin_amdgcn_mfma_f32_16x16x32_bf16(k1f, qf[1], s[nj] = z, 0, 0, 0);
    }
    __builtin_amdgcn_s_setprio(0);

    // ---- causal mask (diagonal tile only): j > q -> -inf ----
    int qrow = i0 + lr;
    if (kt == g4) {
#pragma unroll
      for (int nj = 0; nj < 4; ++nj)
#pragma unroll
        for (int r = 0; r < 4; ++r)
          if (j0 + nj * 16 + lg * 4 + r > qrow) s[nj][r] = -1e30f;
    }

    // ---- P = E * exp2(s); pack pairs; ds_write_b64 into Plds[q][j] ----
#pragma unroll
    for (int nj = 0; nj < 4; ++nj) {
      float p0 = b2f(ev[nj].x) * exp2f(s[nj][0]);
      float p1 = b2f(ev[nj].y) * exp2f(s[nj][1]);
      float p2 = b2f(ev[nj].z) * exp2f(s[nj][2]);
      float p3 = b2f(ev[nj].w) * exp2f(s[nj][3]);
      lrun += (p0 + p1) + (p2 + p3);
      unsigned w0, w1;
      asm("v_cvt_pk_bf16_f32 %0, %1, %2" : "=v"(w0) : "v"(p0), "v"(p1));
      asm("v_cvt_pk_bf16_f32 %0, %1, %2" : "=v"(w1) : "v"(p2), "v"(p3));
      *(uint2*)&Plds[wave][lr][nj * 16 + lg * 4] = make_uint2(w0, w1);
    }

    // ---- PV from swizzled LDS ----
    bf16x8 pa0 = *(const bf16x8*)&Plds[wave][lr][lg * 8];
    bf16x8 pa1 = *(const bf16x8*)&Plds[wave][lr][32 + lg * 8];
    __builtin_amdgcn_s_setprio(1);
#pragma unroll
    for (int nd = 0; nd < 4; ++nd) {
      int row = nd * 16 + lr;
      int sw = row & 7;
      bf16x8 v0f = *(const bf16x8*)&Vsh[cur][row][(lg ^ sw) << 3];
      bf16x8 v1f = *(const bf16x8*)&Vsh[cur][row][((4 + lg) ^ sw) << 3];
      acc[nd] = __builtin_amdgcn_mfma_f32_16x16x32_bf16(pa0, v0f, acc[nd], 0, 0, 0);
      acc[nd] = __builtin_amdgcn_mfma_f32_16x16x32_bf16(pa1, v1f, acc[nd], 0, 0, 0);
    }
    __builtin_amdgcn_s_setprio(0);

    __syncthreads();
  }
#undef STAGE_KV

  // ---- epilogue: finish l across lg groups; fetch l for own acc rows ----
  lrun += __shfl_xor(lrun, 16);
  lrun += __shfl_xor(lrun, 32);
#pragma unroll
  for (int r = 0; r < 4; ++r) {
    float l = __int_as_float(
        __builtin_amdgcn_ds_bpermute((lg * 4 + r) << 2, __float_as_int(lrun)));
    float inv = 1.f / l;
    int ig = i0 + lg * 4 + r;
    unsigned short* ob = yhb + (size_t)(b * TT + ig) * CC + h * HD;
#pragma unroll
    for (int nd = 0; nd < 4; ++nd)
      ob[nd * 16 + lr] = f2b(acc[nd][r] * inv);
  }
}

// ---------------------------------------------------------------------------
// M[0,b,i,j] = i - ffsum[b,j]
// ---------------------------------------------------------------------------
__global__ __launch_bounds__(256) void m_kernel(
    const float* __restrict__ ffsum, float* __restrict__ Mout) {
  int idx = blockIdx.x * blockDim.x + threadIdx.x;
  int stride = gridDim.x * blockDim.x;
  for (; idx < M_ELEMS; idx += stride) {
    int j = idx & (TT - 1);
    int i = (idx >> 11) & (TT - 1);
    int b = idx >> 22;
    Mout[idx] = (float)i - ffsum[(b << 11) + j];
  }
}

// ---------------------------------------------------------------------------
extern "C" void kernel_launch(void* const* d_in, const int* in_sizes, int n_in,
                              void* d_out, int out_size, void* d_ws, size_t ws_size,
                              hipStream_t stream) {
  const float* x      = (const float*)d_in[0];
  const float* w_attn = (const float*)d_in[1];
  const float* b_attn = (const float*)d_in[2];
  const float* w_proj = (const float*)d_in[3];
  const float* b_proj = (const float*)d_in[4];

  float* y    = (float*)d_out;          // [B,T,C]
  float* Mreg = y + Y_ELEMS;            // [B,T,T]: S0 -> FF (scratch) -> M (final)

  float* ws = (float*)d_ws;
  float* q0       = ws;                         // B*T*64
  float* k0       = q0 + (size_t)BB * TT * HD;
  float* partials = k0 + (size_t)BB * TT * HD;  // B*32*T
  float* ffsum    = partials + (size_t)BB * 32 * TT;  // B*T
  unsigned short* xb  = (unsigned short*)(ffsum + BB * TT);   // B*T*C
  unsigned short* wbT = xb + (size_t)Y_ELEMS;                 // 2304*768
  unsigned short* wpT = wbT + (size_t)N3 * CC;                // 768*768
  unsigned short* Qb  = wpT + (size_t)CC * CC;                // B*NH*T*HD
  unsigned short* Kb  = Qb + (size_t)BB * NH * TT * HD;
  unsigned short* Vt  = Kb + (size_t)BB * NH * TT * HD;
  unsigned short* yhb = Vt + (size_t)BB * NH * TT * HD;       // B*T*C
  unsigned short* Eb  = yhb + (size_t)Y_ELEMS;                // B*T*T bf16 (16.8MB)
  // total ws usage ~= 46 MB

  // 1. packs: x -> bf16; weights -> transposed bf16
  pack_x<<<Y_ELEMS / (256 * 8), 256, 0, stream>>>(x, xb);
  transpose_pack<<<dim3(CC / 64, N3 / 64), 256, 0, stream>>>(w_attn, wbT, N3);
  transpose_pack<<<dim3(CC / 64, CC / 64), 256, 0, stream>>>(w_proj, wpT, CC);
  // 2. bf16 MFMA QKV GEMM (LDS-staged dbuf) -> packed Qb (scaled) / Kb / Vt
  gemm_qkv_bf16<<<dim3(32, 36), 256, 0, stream>>>(xb, wbT, b_attn, Qb, Kb, Vt);
  // 3. fp32 head-0 q,k (precision-critical FF path)
  sgemm_qk0<<<dim3(64, 2), 256, 0, stream>>>(x, w_attn, b_attn, q0, k0);
  // 4. head-0 scores (fp32) into Mreg + fused per-chunk column partial sums
  score0_kernel<<<dim3(32, 32, BB), 256, 0, stream>>>(q0, k0, Mreg, partials);
  // 5. column-wise exclusive scan (in place): Mreg = FF; also E = exp(-FF) bf16
  scan_write<<<dim3(8, 32, BB), 256, 0, stream>>>(Mreg, partials, Eb);
  // 6. FF_sum (reads fp32 FF)
  ffsum_kernel<<<dim3(TT, BB), 256, 0, stream>>>(Mreg, ffsum);
  // 7. MFMA flash attention (swapped-QK exp2 softmax, LDS-staged K/V)
  attn_mfma<<<dim3(24, 32), 256, 0, stream>>>(Qb, Kb, Vt, Eb, yhb);
  // 8. M output (after attn so its dirty lines don't flush during attn)
  m_kernel<<<4096, 256, 0, stream>>>(ffsum, Mreg);
  // 9. y = yhb @ w_proj + b_proj (bf16 MFMA, LDS-staged dbuf)
  gemm_proj_bf16<<<dim3(32, 12), 256, 0, stream>>>(yhb, wpT, b_proj, y);
}

// Round 11
// 203.469 us; speedup vs baseline: 2.4810x; 1.0581x over previous
//
#include <hip/hip_runtime.h>
#include <cstddef>

// Problem constants
#define TT 2048
#define BB 2
#define CC 768
#define NH 12
#define HD 64
#define N3 2304          // 3*NH*HD
#define Y_ELEMS (BB*TT*CC)          // 3145728
#define M_ELEMS (BB*TT*TT)          // 8388608

typedef __attribute__((ext_vector_type(8))) short bf16x8;
typedef __attribute__((ext_vector_type(4))) float f32x4;

__device__ inline unsigned short f2b(float f) {
  union { float f; unsigned u; } v; v.f = f;
  unsigned r = (v.u + 0x7FFFu + ((v.u >> 16) & 1u)) >> 16;
  return (unsigned short)r;
}
__device__ inline float b2f(unsigned short u) {
  union { unsigned u; float f; } v; v.u = (unsigned)u << 16; return v.f;
}

// async global -> LDS, 16B per lane; lds dest is wave-uniform base, HW adds lane*16
__device__ inline void gload_lds16(const unsigned short* g, unsigned short* l) {
  __builtin_amdgcn_global_load_lds(
      (const __attribute__((address_space(1))) unsigned int*)g,
      (__attribute__((address_space(3))) unsigned int*)l, 16, 0, 0);
}

// ---------------------------------------------------------------------------
// pack x (fp32) -> xb (bf16). 8 elems/thread.
// ---------------------------------------------------------------------------
__global__ __launch_bounds__(256) void pack_x(
    const float* __restrict__ x, unsigned short* __restrict__ xb) {
  size_t i = ((size_t)blockIdx.x * 256 + threadIdx.x) * 8;
  float4 a = *(const float4*)(x + i);
  float4 b = *(const float4*)(x + i + 4);
  ushort4 o0, o1;
  o0.x = f2b(a.x); o0.y = f2b(a.y); o0.z = f2b(a.z); o0.w = f2b(a.w);
  o1.x = f2b(b.x); o1.y = f2b(b.y); o1.z = f2b(b.z); o1.w = f2b(b.w);
  *(ushort4*)(xb + i) = o0;
  *(ushort4*)(xb + i + 4) = o1;
}

// ---------------------------------------------------------------------------
// W [768][N] fp32 -> WT [N][768] bf16 (transposed pack). Block=(kt,nt) 64x64.
// ---------------------------------------------------------------------------
__global__ __launch_bounds__(256) void transpose_pack(
    const float* __restrict__ W, unsigned short* __restrict__ WT, int N) {
  __shared__ float tile[64][65];
  int kt = blockIdx.x, nt = blockIdx.y;
  int tid = threadIdx.x;
  int r = tid >> 4, c4 = (tid & 15) << 2;
#pragma unroll
  for (int rep = 0; rep < 4; ++rep) {
    int row = rep * 16 + r;
    float4 v = *(const float4*)(W + (size_t)(kt * 64 + row) * N + nt * 64 + c4);
    tile[row][c4 + 0] = v.x; tile[row][c4 + 1] = v.y;
    tile[row][c4 + 2] = v.z; tile[row][c4 + 3] = v.w;
  }
  __syncthreads();
#pragma unroll
  for (int rep = 0; rep < 4; ++rep) {
    int nrow = rep * 16 + r;
    ushort4 o;
    o.x = f2b(tile[c4 + 0][nrow]); o.y = f2b(tile[c4 + 1][nrow]);
    o.z = f2b(tile[c4 + 2][nrow]); o.w = f2b(tile[c4 + 3][nrow]);
    *(ushort4*)(WT + (size_t)(nt * 64 + nrow) * CC + kt * 64 + c4) = o;
  }
}

// ---------------------------------------------------------------------------
// bf16 MFMA GEMM: qkv = xb @ wbT^T + b_attn -> packed Qb (pre-scaled by
// 0.125*log2(e) for the exp2 softmax), Kb, Vt (transposed via LDS).
// 128x128 tiles: grid (32 mtiles, 18 ntiles); each ntile = 2 heads of one
// q/k/v section (no tile crosses a section). A/B K-tiles staged to LDS
// (global_load_lds 16B), double-buffered, slot-swizzled both sides.
// Vlds (V-transpose epilogue) is UNION-overlaid on the A/B buffers —
// first touched only after the K-loop's final barrier.
// ---------------------------------------------------------------------------
__global__ __launch_bounds__(256, 3) void gemm_qkv_bf16(
    const unsigned short* __restrict__ xb, const unsigned short* __restrict__ wbT,
    const float* __restrict__ b_attn,
    unsigned short* __restrict__ Qb, unsigned short* __restrict__ Kb,
    unsigned short* __restrict__ Vt) {
  __shared__ __align__(16) unsigned short smem_u[17408];  // 34816 B
  unsigned short (*Alds)[128][32] = (unsigned short(*)[128][32])smem_u;
  unsigned short (*Blds)[128][32] = (unsigned short(*)[128][32])(smem_u + 8192);
  unsigned short (*Vlds)[136]     = (unsigned short(*)[136])smem_u;

  int mt = blockIdx.x, nt = blockIdx.y;
  int sec = nt / 6, h0 = (nt % 6) * 2;
  int wave = threadIdx.x >> 6, lane = threadIdx.x & 63;
  int lr = lane & 15, lg = lane >> 4;
  int m0 = mt * 128;
  int n0 = nt * 128;

  int srow = lane >> 2;                 // 0..15 staging row within segment
  int sslot = (lane & 3) ^ (srow & 3);  // pre-swizzled source k-slot (16B units)

#define STAGE_AB(BUF, K0)                                                       \
  {                                                                             \
    _Pragma("unroll")                                                           \
    for (int p = 0; p < 2; ++p) {                                               \
      int ar = wave * 32 + p * 16 + srow;                                       \
      gload_lds16(xb + (size_t)(m0 + ar) * CC + (K0) + (sslot << 3),            \
                  &Alds[BUF][wave * 32 + p * 16][0]);                           \
      gload_lds16(wbT + (size_t)(n0 + ar) * CC + (K0) + (sslot << 3),           \
                  &Blds[BUF][wave * 32 + p * 16][0]);                           \
    }                                                                           \
  }

  f32x4 acc[2][8];
#pragma unroll
  for (int mi = 0; mi < 2; ++mi)
#pragma unroll
    for (int nj = 0; nj < 8; ++nj) acc[mi][nj] = (f32x4){0.f, 0.f, 0.f, 0.f};

  STAGE_AB(0, 0)
  __syncthreads();

  int fslot = lg ^ (lr & 3);  // frag read slot (same involution)
  for (int kt = 0; kt < 24; ++kt) {
    int cur = kt & 1;
    if (kt < 23) STAGE_AB(cur ^ 1, (kt + 1) * 32)
    bf16x8 af[2], bf[8];
#pragma unroll
    for (int mi = 0; mi < 2; ++mi)
      af[mi] = *(const bf16x8*)&Alds[cur][wave * 32 + mi * 16 + lr][fslot << 3];
#pragma unroll
    for (int nj = 0; nj < 8; ++nj)
      bf[nj] = *(const bf16x8*)&Blds[cur][nj * 16 + lr][fslot << 3];
    __builtin_amdgcn_s_setprio(1);
#pragma unroll
    for (int nj = 0; nj < 8; ++nj)
#pragma unroll
      for (int mi = 0; mi < 2; ++mi)
        acc[mi][nj] = __builtin_amdgcn_mfma_f32_16x16x32_bf16(af[mi], bf[nj], acc[mi][nj], 0, 0, 0);
    __builtin_amdgcn_s_setprio(0);
    __syncthreads();
  }
#undef STAGE_AB

  int b = m0 >> 11;
  float bias[8];
#pragma unroll
  for (int nj = 0; nj < 8; ++nj) bias[nj] = b_attn[n0 + nj * 16 + lr];

  if (sec < 2) {
    // Q pre-scaled by (1/8)*log2(e) so attention uses exp2 directly
    float qscale = (sec == 0) ? 0.18033688f : 1.0f;
    unsigned short* OutB = (sec == 0 ? Qb : Kb);
    int tbase = (m0 & 2047) + wave * 32 + lg * 4;
#pragma unroll
    for (int nj = 0; nj < 8; ++nj) {
      int h = h0 + (nj >> 2);
      int d = (nj & 3) * 16 + lr;
      unsigned short* Out = OutB + (size_t)(b * NH + h) * TT * HD;
#pragma unroll
      for (int mi = 0; mi < 2; ++mi)
#pragma unroll
        for (int r = 0; r < 4; ++r) {
          int t = tbase + mi * 16 + r;
          Out[(size_t)t * HD + d] = f2b((acc[mi][nj][r] + bias[nj]) * qscale);
        }
    }
  } else {
    int tl = wave * 32 + lg * 4;
#pragma unroll
    for (int mi = 0; mi < 2; ++mi)
#pragma unroll
      for (int r = 0; r < 4; ++r)
#pragma unroll
        for (int nj = 0; nj < 8; ++nj)
          Vlds[tl + mi * 16 + r][nj * 16 + lr] = f2b(acc[mi][nj][r] + bias[nj]);
    __syncthreads();
    int d = threadIdx.x & 63, tc = threadIdx.x >> 6;
    int tblk = (m0 & 2047);
#pragma unroll
    for (int hh = 0; hh < 2; ++hh) {
      unsigned short* Ov = Vt + ((size_t)(b * NH + h0 + hh) * HD + d) * TT + tblk + tc * 32;
      int c = hh * 64 + d;
#pragma unroll
      for (int i8 = 0; i8 < 4; ++i8) {
        ushort4 o0, o1;
        o0.x = Vlds[tc * 32 + i8 * 8 + 0][c]; o0.y = Vlds[tc * 32 + i8 * 8 + 1][c];
        o0.z = Vlds[tc * 32 + i8 * 8 + 2][c]; o0.w = Vlds[tc * 32 + i8 * 8 + 3][c];
        o1.x = Vlds[tc * 32 + i8 * 8 + 4][c]; o1.y = Vlds[tc * 32 + i8 * 8 + 5][c];
        o1.z = Vlds[tc * 32 + i8 * 8 + 6][c]; o1.w = Vlds[tc * 32 + i8 * 8 + 7][c];
        *(ushort4*)(Ov + i8 * 8) = o0;
        *(ushort4*)(Ov + i8 * 8 + 4) = o1;
      }
    }
  }
}

// ---------------------------------------------------------------------------
// bf16 MFMA GEMM: y = yhb @ wpT^T + b_proj (fp32 out). Grid (32, 12).
// LDS-staged double-buffered (128x64 tile).
// ---------------------------------------------------------------------------
__global__ __launch_bounds__(256, 3) void gemm_proj_bf16(
    const unsigned short* __restrict__ yhb, const unsigned short* __restrict__ wpT,
    const float* __restrict__ b_proj, float* __restrict__ y) {
  __shared__ __align__(16) unsigned short Alds[2][128][32];
  __shared__ __align__(16) unsigned short Blds[2][64][32];
  int mt = blockIdx.x, nt = blockIdx.y;
  int wave = threadIdx.x >> 6, lane = threadIdx.x & 63;
  int lr = lane & 15, lg = lane >> 4;
  int m0 = mt * 128;
  int n0 = nt * 64;

  int srow = lane >> 2;
  int sslot = (lane & 3) ^ (srow & 3);

#define STAGE_AB(BUF, K0)                                                       \
  {                                                                             \
    _Pragma("unroll")                                                           \
    for (int p = 0; p < 2; ++p) {                                               \
      int ar = wave * 32 + p * 16 + srow;                                       \
      gload_lds16(yhb + (size_t)(m0 + ar) * CC + (K0) + (sslot << 3),           \
                  &Alds[BUF][wave * 32 + p * 16][0]);                           \
    }                                                                           \
    int br = wave * 16 + srow;                                                  \
    gload_lds16(wpT + (size_t)(n0 + br) * CC + (K0) + (sslot << 3),             \
                &Blds[BUF][wave * 16][0]);                                      \
  }

  f32x4 acc[2][4];
#pragma unroll
  for (int mi = 0; mi < 2; ++mi)
#pragma unroll
    for (int nj = 0; nj < 4; ++nj) acc[mi][nj] = (f32x4){0.f, 0.f, 0.f, 0.f};

  STAGE_AB(0, 0)
  __syncthreads();

  int fslot = lg ^ (lr & 3);
  for (int kt = 0; kt < 24; ++kt) {
    int cur = kt & 1;
    if (kt < 23) STAGE_AB(cur ^ 1, (kt + 1) * 32)
    bf16x8 af[2], bf[4];
#pragma unroll
    for (int mi = 0; mi < 2; ++mi)
      af[mi] = *(const bf16x8*)&Alds[cur][wave * 32 + mi * 16 + lr][fslot << 3];
#pragma unroll
    for (int nj = 0; nj < 4; ++nj)
      bf[nj] = *(const bf16x8*)&Blds[cur][nj * 16 + lr][fslot << 3];
    __builtin_amdgcn_s_setprio(1);
#pragma unroll
    for (int nj = 0; nj < 4; ++nj)
#pragma unroll
      for (int mi = 0; mi < 2; ++mi)
        acc[mi][nj] = __builtin_amdgcn_mfma_f32_16x16x32_bf16(af[mi], bf[nj], acc[mi][nj], 0, 0, 0);
    __builtin_amdgcn_s_setprio(0);
    __syncthreads();
  }
#undef STAGE_AB

  float bias[4];
#pragma unroll
  for (int nj = 0; nj < 4; ++nj) bias[nj] = b_proj[n0 + nj * 16 + lr];
#pragma unroll
  for (int mi = 0; mi < 2; ++mi)
#pragma unroll
    for (int r = 0; r < 4; ++r) {
      int m = m0 + wave * 32 + mi * 16 + lg * 4 + r;
#pragma unroll
      for (int nj = 0; nj < 4; ++nj)
        y[(size_t)m * CC + n0 + nj * 16 + lr] = acc[mi][nj][r] + bias[nj];
    }
}

// ---------------------------------------------------------------------------
// fp32 GEMM for head-0 q,k only (precision-critical FF path). Grid (64, 2).
// ---------------------------------------------------------------------------
__global__ __launch_bounds__(256) void sgemm_qk0(
    const float* __restrict__ x, const float* __restrict__ w_attn,
    const float* __restrict__ b_attn, float* __restrict__ q0,
    float* __restrict__ k0) {
  __shared__ float As[16][64];
  __shared__ float Bs[16][64];
  int sec = blockIdx.y;
  const float* Bw = w_attn + sec * CC;
  float* Out = sec ? k0 : q0;
  int tid = threadIdx.x;
  int tx = tid & 15, ty = tid >> 4;
  int m0 = blockIdx.x * 64;

  int arow = tid >> 2;
  int acol4 = (tid & 3) << 2;
  int brow = tid >> 4;
  int bcol4 = (tid & 15) << 2;

  const float* Aptr = x + (size_t)(m0 + arow) * CC + acol4;
  const float* Bptr = Bw + (size_t)brow * N3 + bcol4;

  float acc[4][4] = {};

  for (int k0_ = 0; k0_ < CC; k0_ += 16) {
    float4 av = *(const float4*)(Aptr + k0_);
    float4 bv = *(const float4*)(Bptr + (size_t)k0_ * N3);
    As[acol4 + 0][arow] = av.x;
    As[acol4 + 1][arow] = av.y;
    As[acol4 + 2][arow] = av.z;
    As[acol4 + 3][arow] = av.w;
    *(float4*)&Bs[brow][bcol4] = bv;
    __syncthreads();
#pragma unroll
    for (int kk = 0; kk < 16; ++kk) {
      float4 a4 = *(const float4*)&As[kk][ty << 2];
      float4 b4 = *(const float4*)&Bs[kk][tx << 2];
      float a[4] = {a4.x, a4.y, a4.z, a4.w};
      float b[4] = {b4.x, b4.y, b4.z, b4.w};
#pragma unroll
      for (int ii = 0; ii < 4; ++ii)
#pragma unroll
        for (int jj = 0; jj < 4; ++jj) acc[ii][jj] += a[ii] * b[jj];
    }
    __syncthreads();
  }

  float4 bv = *(const float4*)(b_attn + sec * CC + (tx << 2));
#pragma unroll
  for (int ii = 0; ii < 4; ++ii) {
    int m = m0 + (ty << 2) + ii;
    float4 o;
    o.x = acc[ii][0] + bv.x;
    o.y = acc[ii][1] + bv.y;
    o.z = acc[ii][2] + bv.z;
    o.w = acc[ii][3] + bv.w;
    *(float4*)(Out + (size_t)m * HD + (tx << 2)) = o;
  }
}

// ---------------------------------------------------------------------------
// Head-0 scores (fp32): Sbuf[b,i,j] = relu(dot(q0,k0)/8), lower-tri tiles.
// FUSED: also emits per-64-row-chunk masked column sums into partials
// (mask = j>=1 && j<r). partials layout: [B][32][TT].
// ---------------------------------------------------------------------------
__global__ __launch_bounds__(256) void score0_kernel(
    const float* __restrict__ q0, const float* __restrict__ k0,
    float* __restrict__ Sbuf, float* __restrict__ partials) {
  int it = blockIdx.x, jt = blockIdx.y, b = blockIdx.z;
  int tid = threadIdx.x;
  int i0 = it * 64, j0 = jt * 64;
  if (jt > it) {  // mask kills everything above the diagonal
    if (tid < 64) partials[((size_t)(b * 32 + it)) * TT + j0 + tid] = 0.f;
    return;
  }
  __shared__ float Qs[64][64];
  __shared__ float Ks[64][64];
  int row = tid >> 2;
  int dq = (tid & 3) << 2;
  const float* qb = q0 + (size_t)((b * TT) + i0 + row) * HD;
  const float* kb = k0 + (size_t)((b * TT) + j0 + row) * HD;
#pragma unroll
  for (int rep = 0; rep < 4; ++rep) {
    int d = dq + rep * 16;
    float4 qv = *(const float4*)(qb + d);
    float4 kv = *(const float4*)(kb + d);
    Qs[d + 0][row] = qv.x; Qs[d + 1][row] = qv.y;
    Qs[d + 2][row] = qv.z; Qs[d + 3][row] = qv.w;
    Ks[d + 0][row] = kv.x; Ks[d + 1][row] = kv.y;
    Ks[d + 2][row] = kv.z; Ks[d + 3][row] = kv.w;
  }
  __syncthreads();
  int tx = tid & 15, ty = tid >> 4;
  float acc[4][4] = {};
#pragma unroll 8
  for (int kk = 0; kk < 64; ++kk) {
    float4 a4 = *(const float4*)&Qs[kk][ty << 2];
    float4 b4 = *(const float4*)&Ks[kk][tx << 2];
    float a[4] = {a4.x, a4.y, a4.z, a4.w};
    float b[4] = {b4.x, b4.y, b4.z, b4.w};
#pragma unroll
    for (int ii = 0; ii < 4; ++ii)
#pragma unroll
      for (int jj = 0; jj < 4; ++jj) acc[ii][jj] += a[ii] * b[jj];
  }
  float red4[4] = {0.f, 0.f, 0.f, 0.f};
#pragma unroll
  for (int ii = 0; ii < 4; ++ii) {
    int r = i0 + (ty << 2) + ii;           // global row (within T)
    int gi = (b * TT) + r;
    float ov[4];
#pragma unroll
    for (int jj = 0; jj < 4; ++jj) {
      ov[jj] = fmaxf(acc[ii][jj] * 0.125f, 0.f);
      int j = j0 + (tx << 2) + jj;
      if (j >= 1 && j < r) red4[jj] += ov[jj];
    }
    float4 o; o.x = ov[0]; o.y = ov[1]; o.z = ov[2]; o.w = ov[3];
    *(float4*)(Sbuf + (size_t)gi * TT + j0 + (tx << 2)) = o;
  }
  // reduce the 16 ty-groups per column via reused LDS
  __syncthreads();  // everyone done reading Qs
  *(float4*)&Qs[ty][tx << 2] = *(float4*)red4;
  __syncthreads();
  if (tid < 64) {
    float cs = 0.f;
#pragma unroll
    for (int t = 0; t < 16; ++t) cs += Qs[t][tid];
    partials[((size_t)(b * 32 + it)) * TT + j0 + tid] = cs;
  }
}

// ---------------------------------------------------------------------------
// Column-wise exclusive prefix scan over rows (64-row chunks; partial sums
// fused from score0). Emits E = exp(-FF) bf16 (j-swizzled for attention)
// and per-jblock row sums of clip(FF,0,1) into ffpart[B][8][TT].
// FF fp32 is NOT materialized (nothing reads it anymore).
// ---------------------------------------------------------------------------
__global__ __launch_bounds__(256) void scan_write(
    const float* __restrict__ Sbuf, const float* __restrict__ partials,
    unsigned short* __restrict__ Eb, float* __restrict__ ffpart) {
  int j = blockIdx.x * 256 + threadIdx.x;
  int chunk = blockIdx.y, b = blockIdx.z;
  float run = 0.f;
  for (int c = 0; c < chunk; ++c) run += partials[((size_t)(b * 32 + c)) * TT + j];
  int r0 = chunk * 64;
  int jswz = (j & ~63) | ((j & 15) << 2) | ((j >> 4) & 3);
  const float* base = Sbuf + (size_t)(b * TT + r0) * TT + j;
  unsigned short* ebase = Eb + (size_t)(b * TT + r0) * TT + jswz;
  __shared__ float wsum[4][64];
  int wv = threadIdx.x >> 6;
  for (int rr = 0; rr < 64; ++rr) {
    int r = r0 + rr;
    float v = (j >= 1 && j < r) ? base[(size_t)rr * TT] : 0.f;
    ebase[(size_t)rr * TT] = f2b(__expf(-run));  // E (bf16, natural-e)
    float c1 = fminf(run, 1.f);                  // run >= 0 always
#pragma unroll
    for (int o = 1; o < 64; o <<= 1) c1 += __shfl_xor(c1, o);
    if ((threadIdx.x & 63) == 0) wsum[wv][rr] = c1;
    run += v;
  }
  __syncthreads();
  if (threadIdx.x < 64)
    ffpart[((size_t)(b * 8) + blockIdx.x) * TT + r0 + threadIdx.x] =
        wsum[0][threadIdx.x] + wsum[1][threadIdx.x] +
        wsum[2][threadIdx.x] + wsum[3][threadIdx.x];
}

// ---------------------------------------------------------------------------
// bf16 MFMA flash attention, E = exp(-FF) multiplicative, fixed-max exp2
// softmax (R9 structure: per-row D-layout, scalar f2b P writes, Plds[16][80],
// per-lane lrun[4] reduced once at the epilogue).
// Grid (24, 32): XCD = x%8 serves one batch / 3 heads (L2 locality).
// K/V staged to LDS via global_load_lds, double-buffered, XOR-swizzled.
// ---------------------------------------------------------------------------
__global__ __launch_bounds__(256, 3) void attn_mfma(
    const unsigned short* __restrict__ Qb, const unsigned short* __restrict__ Kb,
    const unsigned short* __restrict__ Vt, const unsigned short* __restrict__ Eb,
    unsigned short* __restrict__ yhb) {
  int xbh = blockIdx.x;
  int b = (xbh >> 2) & 1;
  int h = ((xbh >> 3) << 2) | (xbh & 3);
  int g4 = 31 - (int)blockIdx.y;
  int wave = threadIdx.x >> 6, lane = threadIdx.x & 63;
  int lr = lane & 15, lg = lane >> 4;
  int i0 = g4 * 64 + wave * 16;
  int bh = b * NH + h;
  const unsigned short* Qh = Qb + (size_t)bh * TT * HD;
  const unsigned short* Kh = Kb + (size_t)bh * TT * HD;
  const unsigned short* Vh = Vt + (size_t)bh * HD * TT;
  const unsigned short* Erow = Eb + ((size_t)(b * TT) + i0 + lg * 4) * TT + 4 * lr;

  __shared__ __align__(16) unsigned short Ksh[2][64][64];
  __shared__ __align__(16) unsigned short Vsh[2][64][64];
  __shared__ __align__(16) unsigned short Plds[4][16][80];

  int rowoff = lane >> 3;            // 0..7 within an 8-row staging segment
  int sslot  = (lane & 7) ^ rowoff;  // pre-swizzled source slot (16B units)

  bf16x8 qf[2];
#pragma unroll
  for (int ks = 0; ks < 2; ++ks)
    qf[ks] = *(const bf16x8*)(Qh + (size_t)(i0 + lr) * HD + ks * 32 + lg * 8);

  f32x4 acc[4];
  float lrun[4] = {0.f, 0.f, 0.f, 0.f};  // per-lane partial of softmax denom
#pragma unroll
  for (int q = 0; q < 4; ++q) acc[q] = (f32x4){0.f, 0.f, 0.f, 0.f};

#define STAGE_KV(BUF, J0)                                                      \
  {                                                                            \
    _Pragma("unroll")                                                          \
    for (int p = 0; p < 2; ++p) {                                              \
      int r0 = wave * 16 + p * 8;                                              \
      gload_lds16(Kh + (size_t)((J0) + r0 + rowoff) * HD + sslot * 8,          \
                  &Ksh[BUF][r0][0]);                                           \
      gload_lds16(Vh + (size_t)(r0 + rowoff) * TT + (J0) + sslot * 8,          \
                  &Vsh[BUF][r0][0]);                                           \
    }                                                                          \
  }

  STAGE_KV(0, 0)
  __syncthreads();

  for (int kt = 0; kt <= g4; ++kt) {
    int cur = kt & 1;
    int j0 = kt * 64;
    if (kt < g4) STAGE_KV(cur ^ 1, j0 + 64)

    // E for current tile (4 x 8B vector loads, swizzled layout)
    ushort4 ev[4];
#pragma unroll
    for (int r = 0; r < 4; ++r)
      ev[r] = *(const ushort4*)(Erow + (size_t)r * TT + j0);

    // ---- QK^T from swizzled LDS ----
    f32x4 s[4];
    __builtin_amdgcn_s_setprio(1);
#pragma unroll
    for (int nj = 0; nj < 4; ++nj) {
      int row = nj * 16 + lr;
      int sw = row & 7;
      bf16x8 k0f = *(const bf16x8*)&Ksh[cur][row][(lg ^ sw) << 3];
      bf16x8 k1f = *(const bf16x8*)&Ksh[cur][row][((4 + lg) ^ sw) << 3];
      f32x4 z = (f32x4){0.f, 0.f, 0.f, 0.f};
      z = __builtin_amdgcn_mfma_f32_16x16x32_bf16(qf[0], k0f, z, 0, 0, 0);
      s[nj] = __builtin_amdgcn_mfma_f32_16x16x32_bf16(qf[1], k1f, z, 0, 0, 0);
    }
    __builtin_amdgcn_s_setprio(0);

    // ---- causal mask (diagonal tile only) ----
    int ibase = i0 + lg * 4;
    if (kt == g4) {
#pragma unroll
      for (int nj = 0; nj < 4; ++nj)
#pragma unroll
        for (int r = 0; r < 4; ++r)
          if (j0 + nj * 16 + lr > ibase + r) s[nj][r] = -1e30f;
    }

    // ---- P = E * exp2(s); per-lane partial l; stash bf16 P in LDS ----
#pragma unroll
    for (int r = 0; r < 4; ++r) {
      float p0 = b2f(ev[r].x) * exp2f(s[0][r]);
      float p1 = b2f(ev[r].y) * exp2f(s[1][r]);
      float p2 = b2f(ev[r].z) * exp2f(s[2][r]);
      float p3 = b2f(ev[r].w) * exp2f(s[3][r]);
      lrun[r] += (p0 + p1) + (p2 + p3);
      Plds[wave][lg * 4 + r][0 * 16 + lr] = f2b(p0);
      Plds[wave][lg * 4 + r][1 * 16 + lr] = f2b(p1);
      Plds[wave][lg * 4 + r][2 * 16 + lr] = f2b(p2);
      Plds[wave][lg * 4 + r][3 * 16 + lr] = f2b(p3);
    }

    // ---- PV from swizzled LDS ----
    bf16x8 pa0 = *(const bf16x8*)&Plds[wave][lr][lg * 8];
    bf16x8 pa1 = *(const bf16x8*)&Plds[wave][lr][32 + lg * 8];
    __builtin_amdgcn_s_setprio(1);
#pragma unroll
    for (int nd = 0; nd < 4; ++nd) {
      int row = nd * 16 + lr;
      int sw = row & 7;
      bf16x8 v0f = *(const bf16x8*)&Vsh[cur][row][(lg ^ sw) << 3];
      bf16x8 v1f = *(const bf16x8*)&Vsh[cur][row][((4 + lg) ^ sw) << 3];
      acc[nd] = __builtin_amdgcn_mfma_f32_16x16x32_bf16(pa0, v0f, acc[nd], 0, 0, 0);
      acc[nd] = __builtin_amdgcn_mfma_f32_16x16x32_bf16(pa1, v1f, acc[nd], 0, 0, 0);
    }
    __builtin_amdgcn_s_setprio(0);

    __syncthreads();
  }
#undef STAGE_KV

  // ---- epilogue: one l-reduction across the 16 lr lanes, then store ----
#pragma unroll
  for (int r = 0; r < 4; ++r) {
    lrun[r] += __shfl_xor(lrun[r], 1);
    lrun[r] += __shfl_xor(lrun[r], 2);
    lrun[r] += __shfl_xor(lrun[r], 4);
    lrun[r] += __shfl_xor(lrun[r], 8);
    float inv = 1.f / lrun[r];
    int ig = i0 + lg * 4 + r;
    unsigned short* ob = yhb + (size_t)(b * TT + ig) * CC + h * HD;
#pragma unroll
    for (int nd = 0; nd < 4; ++nd)
      ob[nd * 16 + lr] = f2b(acc[nd][r] * inv);
  }
}

// ---------------------------------------------------------------------------
// M[0,b,i,j] = i - sum_jb ffpart[b][jb][j]   (8 L1-resident partial reads)
// ---------------------------------------------------------------------------
__global__ __launch_bounds__(256) void m_kernel(
    const float* __restrict__ ffpart, float* __restrict__ Mout) {
  int idx = blockIdx.x * blockDim.x + threadIdx.x;
  int stride = gridDim.x * blockDim.x;
  for (; idx < M_ELEMS; idx += stride) {
    int j = idx & (TT - 1);
    int i = (idx >> 11) & (TT - 1);
    int b = idx >> 22;
    const float* fp = ffpart + ((size_t)(b * 8)) * TT + j;
    float s = ((fp[0] + fp[TT]) + (fp[2 * TT] + fp[3 * TT])) +
              ((fp[4 * TT] + fp[5 * TT]) + (fp[6 * TT] + fp[7 * TT]));
    Mout[idx] = (float)i - s;
  }
}

// ---------------------------------------------------------------------------
extern "C" void kernel_launch(void* const* d_in, const int* in_sizes, int n_in,
                              void* d_out, int out_size, void* d_ws, size_t ws_size,
                              hipStream_t stream) {
  const float* x      = (const float*)d_in[0];
  const float* w_attn = (const float*)d_in[1];
  const float* b_attn = (const float*)d_in[2];
  const float* w_proj = (const float*)d_in[3];
  const float* b_proj = (const float*)d_in[4];

  float* y    = (float*)d_out;          // [B,T,C]
  float* Mreg = y + Y_ELEMS;            // [B,T,T]: S0 (scratch) -> M (final)

  float* ws = (float*)d_ws;
  float* q0       = ws;                               // B*T*64
  float* k0       = q0 + (size_t)BB * TT * HD;
  float* partials = k0 + (size_t)BB * TT * HD;        // B*32*T
  float* ffpart   = partials + (size_t)BB * 32 * TT;  // B*8*T
  unsigned short* xb  = (unsigned short*)(ffpart + (size_t)BB * 8 * TT);  // B*T*C
  unsigned short* wbT = xb + (size_t)Y_ELEMS;                 // 2304*768
  unsigned short* wpT = wbT + (size_t)N3 * CC;                // 768*768
  unsigned short* Qb  = wpT + (size_t)CC * CC;                // B*NH*T*HD
  unsigned short* Kb  = Qb + (size_t)BB * NH * TT * HD;
  unsigned short* Vt  = Kb + (size_t)BB * NH * TT * HD;
  unsigned short* yhb = Vt + (size_t)BB * NH * TT * HD;       // B*T*C
  unsigned short* Eb  = yhb + (size_t)Y_ELEMS;                // B*T*T bf16 (16.8MB)
  // total ws usage ~= 46 MB

  // 1. packs: x -> bf16; weights -> transposed bf16
  pack_x<<<Y_ELEMS / (256 * 8), 256, 0, stream>>>(x, xb);
  transpose_pack<<<dim3(CC / 64, N3 / 64), 256, 0, stream>>>(w_attn, wbT, N3);
  transpose_pack<<<dim3(CC / 64, CC / 64), 256, 0, stream>>>(w_proj, wpT, CC);
  // 2. bf16 MFMA QKV GEMM (128x128 tiles, LDS dbuf) -> Qb (scaled) / Kb / Vt
  gemm_qkv_bf16<<<dim3(32, 18), 256, 0, stream>>>(xb, wbT, b_attn, Qb, Kb, Vt);
  // 3. fp32 head-0 q,k (precision-critical FF path)
  sgemm_qk0<<<dim3(64, 2), 256, 0, stream>>>(x, w_attn, b_attn, q0, k0);
  // 4. head-0 scores (fp32) into Mreg + fused per-chunk column partial sums
  score0_kernel<<<dim3(32, 32, BB), 256, 0, stream>>>(q0, k0, Mreg, partials);
  // 5. scan: E = exp(-FF) bf16 (jswz) + ffpart row sums (FF never materialized)
  scan_write<<<dim3(8, 32, BB), 256, 0, stream>>>(Mreg, partials, Eb, ffpart);
  // 6. MFMA flash attention (R9 structure + exp2, LDS-staged K/V, XCD grid)
  attn_mfma<<<dim3(24, 32), 256, 0, stream>>>(Qb, Kb, Vt, Eb, yhb);
  // 7. M output (after attn so its dirty lines don't flush during attn)
  m_kernel<<<4096, 256, 0, stream>>>(ffpart, Mreg);
  // 8. y = yhb @ w_proj + b_proj (bf16 MFMA, LDS-staged dbuf)
  gemm_proj_bf16<<<dim3(32, 12), 256, 0, stream>>>(yhb, wpT, b_proj, y);
}

// Round 12
// 201.773 us; speedup vs baseline: 2.5019x; 1.0084x over previous
//
#include <hip/hip_runtime.h>
#include <cstddef>

// Problem constants
#define TT 2048
#define BB 2
#define CC 768
#define NH 12
#define HD 64
#define N3 2304          // 3*NH*HD
#define Y_ELEMS (BB*TT*CC)          // 3145728
#define M_ELEMS (BB*TT*TT)          // 8388608

typedef __attribute__((ext_vector_type(8))) short bf16x8;
typedef __attribute__((ext_vector_type(4))) float f32x4;

__device__ inline unsigned short f2b(float f) {
  union { float f; unsigned u; } v; v.f = f;
  unsigned r = (v.u + 0x7FFFu + ((v.u >> 16) & 1u)) >> 16;
  return (unsigned short)r;
}
__device__ inline float b2f(unsigned short u) {
  union { unsigned u; float f; } v; v.u = (unsigned)u << 16; return v.f;
}

// async global -> LDS, 16B per lane; lds dest is wave-uniform base, HW adds lane*16
__device__ inline void gload_lds16(const unsigned short* g, unsigned short* l) {
  __builtin_amdgcn_global_load_lds(
      (const __attribute__((address_space(1))) unsigned int*)g,
      (__attribute__((address_space(3))) unsigned int*)l, 16, 0, 0);
}

// ---------------------------------------------------------------------------
// pack x (fp32) -> xb (bf16). 8 elems/thread.
// ---------------------------------------------------------------------------
__global__ __launch_bounds__(256) void pack_x(
    const float* __restrict__ x, unsigned short* __restrict__ xb) {
  size_t i = ((size_t)blockIdx.x * 256 + threadIdx.x) * 8;
  float4 a = *(const float4*)(x + i);
  float4 b = *(const float4*)(x + i + 4);
  ushort4 o0, o1;
  o0.x = f2b(a.x); o0.y = f2b(a.y); o0.z = f2b(a.z); o0.w = f2b(a.w);
  o1.x = f2b(b.x); o1.y = f2b(b.y); o1.z = f2b(b.z); o1.w = f2b(b.w);
  *(ushort4*)(xb + i) = o0;
  *(ushort4*)(xb + i + 4) = o1;
}

// ---------------------------------------------------------------------------
// W [768][N] fp32 -> WT [N][768] bf16 (transposed pack). Block=(kt,nt) 64x64.
// ---------------------------------------------------------------------------
__global__ __launch_bounds__(256) void transpose_pack(
    const float* __restrict__ W, unsigned short* __restrict__ WT, int N) {
  __shared__ float tile[64][65];
  int kt = blockIdx.x, nt = blockIdx.y;
  int tid = threadIdx.x;
  int r = tid >> 4, c4 = (tid & 15) << 2;
#pragma unroll
  for (int rep = 0; rep < 4; ++rep) {
    int row = rep * 16 + r;
    float4 v = *(const float4*)(W + (size_t)(kt * 64 + row) * N + nt * 64 + c4);
    tile[row][c4 + 0] = v.x; tile[row][c4 + 1] = v.y;
    tile[row][c4 + 2] = v.z; tile[row][c4 + 3] = v.w;
  }
  __syncthreads();
#pragma unroll
  for (int rep = 0; rep < 4; ++rep) {
    int nrow = rep * 16 + r;
    ushort4 o;
    o.x = f2b(tile[c4 + 0][nrow]); o.y = f2b(tile[c4 + 1][nrow]);
    o.z = f2b(tile[c4 + 2][nrow]); o.w = f2b(tile[c4 + 3][nrow]);
    *(ushort4*)(WT + (size_t)(nt * 64 + nrow) * CC + kt * 64 + c4) = o;
  }
}

// ---------------------------------------------------------------------------
// bf16 MFMA GEMM: qkv = xb @ wbT^T + b_attn -> packed Qb (pre-scaled by
// 0.125*log2(e) for the exp2 softmax), Kb, Vt (transposed via LDS).
// 128x128 tiles: grid (32 mtiles, 18 ntiles). LDS-staged dbuf, slot-swizzled.
// Vlds epilogue UNION-overlaid on the A/B buffers.
// ---------------------------------------------------------------------------
__global__ __launch_bounds__(256, 3) void gemm_qkv_bf16(
    const unsigned short* __restrict__ xb, const unsigned short* __restrict__ wbT,
    const float* __restrict__ b_attn,
    unsigned short* __restrict__ Qb, unsigned short* __restrict__ Kb,
    unsigned short* __restrict__ Vt) {
  __shared__ __align__(16) unsigned short smem_u[17408];  // 34816 B
  unsigned short (*Alds)[128][32] = (unsigned short(*)[128][32])smem_u;
  unsigned short (*Blds)[128][32] = (unsigned short(*)[128][32])(smem_u + 8192);
  unsigned short (*Vlds)[136]     = (unsigned short(*)[136])smem_u;

  int mt = blockIdx.x, nt = blockIdx.y;
  int sec = nt / 6, h0 = (nt % 6) * 2;
  int wave = threadIdx.x >> 6, lane = threadIdx.x & 63;
  int lr = lane & 15, lg = lane >> 4;
  int m0 = mt * 128;
  int n0 = nt * 128;

  int srow = lane >> 2;                 // 0..15 staging row within segment
  int sslot = (lane & 3) ^ (srow & 3);  // pre-swizzled source k-slot (16B units)

#define STAGE_AB(BUF, K0)                                                       \
  {                                                                             \
    _Pragma("unroll")                                                           \
    for (int p = 0; p < 2; ++p) {                                               \
      int ar = wave * 32 + p * 16 + srow;                                       \
      gload_lds16(xb + (size_t)(m0 + ar) * CC + (K0) + (sslot << 3),            \
                  &Alds[BUF][wave * 32 + p * 16][0]);                           \
      gload_lds16(wbT + (size_t)(n0 + ar) * CC + (K0) + (sslot << 3),           \
                  &Blds[BUF][wave * 32 + p * 16][0]);                           \
    }                                                                           \
  }

  f32x4 acc[2][8];
#pragma unroll
  for (int mi = 0; mi < 2; ++mi)
#pragma unroll
    for (int nj = 0; nj < 8; ++nj) acc[mi][nj] = (f32x4){0.f, 0.f, 0.f, 0.f};

  STAGE_AB(0, 0)
  __syncthreads();

  int fslot = lg ^ (lr & 3);  // frag read slot (same involution)
  for (int kt = 0; kt < 24; ++kt) {
    int cur = kt & 1;
    if (kt < 23) STAGE_AB(cur ^ 1, (kt + 1) * 32)
    bf16x8 af[2], bf[8];
#pragma unroll
    for (int mi = 0; mi < 2; ++mi)
      af[mi] = *(const bf16x8*)&Alds[cur][wave * 32 + mi * 16 + lr][fslot << 3];
#pragma unroll
    for (int nj = 0; nj < 8; ++nj)
      bf[nj] = *(const bf16x8*)&Blds[cur][nj * 16 + lr][fslot << 3];
    __builtin_amdgcn_s_setprio(1);
#pragma unroll
    for (int nj = 0; nj < 8; ++nj)
#pragma unroll
      for (int mi = 0; mi < 2; ++mi)
        acc[mi][nj] = __builtin_amdgcn_mfma_f32_16x16x32_bf16(af[mi], bf[nj], acc[mi][nj], 0, 0, 0);
    __builtin_amdgcn_s_setprio(0);
    __syncthreads();
  }
#undef STAGE_AB

  int b = m0 >> 11;
  float bias[8];
#pragma unroll
  for (int nj = 0; nj < 8; ++nj) bias[nj] = b_attn[n0 + nj * 16 + lr];

  if (sec < 2) {
    // Q pre-scaled by (1/8)*log2(e) so attention uses exp2 directly
    float qscale = (sec == 0) ? 0.18033688f : 1.0f;
    unsigned short* OutB = (sec == 0 ? Qb : Kb);
    int tbase = (m0 & 2047) + wave * 32 + lg * 4;
#pragma unroll
    for (int nj = 0; nj < 8; ++nj) {
      int h = h0 + (nj >> 2);
      int d = (nj & 3) * 16 + lr;
      unsigned short* Out = OutB + (size_t)(b * NH + h) * TT * HD;
#pragma unroll
      for (int mi = 0; mi < 2; ++mi)
#pragma unroll
        for (int r = 0; r < 4; ++r) {
          int t = tbase + mi * 16 + r;
          Out[(size_t)t * HD + d] = f2b((acc[mi][nj][r] + bias[nj]) * qscale);
        }
    }
  } else {
    int tl = wave * 32 + lg * 4;
#pragma unroll
    for (int mi = 0; mi < 2; ++mi)
#pragma unroll
      for (int r = 0; r < 4; ++r)
#pragma unroll
        for (int nj = 0; nj < 8; ++nj)
          Vlds[tl + mi * 16 + r][nj * 16 + lr] = f2b(acc[mi][nj][r] + bias[nj]);
    __syncthreads();
    int d = threadIdx.x & 63, tc = threadIdx.x >> 6;
    int tblk = (m0 & 2047);
#pragma unroll
    for (int hh = 0; hh < 2; ++hh) {
      unsigned short* Ov = Vt + ((size_t)(b * NH + h0 + hh) * HD + d) * TT + tblk + tc * 32;
      int c = hh * 64 + d;
#pragma unroll
      for (int i8 = 0; i8 < 4; ++i8) {
        ushort4 o0, o1;
        o0.x = Vlds[tc * 32 + i8 * 8 + 0][c]; o0.y = Vlds[tc * 32 + i8 * 8 + 1][c];
        o0.z = Vlds[tc * 32 + i8 * 8 + 2][c]; o0.w = Vlds[tc * 32 + i8 * 8 + 3][c];
        o1.x = Vlds[tc * 32 + i8 * 8 + 4][c]; o1.y = Vlds[tc * 32 + i8 * 8 + 5][c];
        o1.z = Vlds[tc * 32 + i8 * 8 + 6][c]; o1.w = Vlds[tc * 32 + i8 * 8 + 7][c];
        *(ushort4*)(Ov + i8 * 8) = o0;
        *(ushort4*)(Ov + i8 * 8 + 4) = o1;
      }
    }
  }
}

// ---------------------------------------------------------------------------
// bf16 MFMA GEMM: y = yhb @ wpT^T + b_proj (fp32 out). Grid (32, 12).
// LDS-staged double-buffered (128x64 tile).
// ---------------------------------------------------------------------------
__global__ __launch_bounds__(256, 3) void gemm_proj_bf16(
    const unsigned short* __restrict__ yhb, const unsigned short* __restrict__ wpT,
    const float* __restrict__ b_proj, float* __restrict__ y) {
  __shared__ __align__(16) unsigned short Alds[2][128][32];
  __shared__ __align__(16) unsigned short Blds[2][64][32];
  int mt = blockIdx.x, nt = blockIdx.y;
  int wave = threadIdx.x >> 6, lane = threadIdx.x & 63;
  int lr = lane & 15, lg = lane >> 4;
  int m0 = mt * 128;
  int n0 = nt * 64;

  int srow = lane >> 2;
  int sslot = (lane & 3) ^ (srow & 3);

#define STAGE_AB(BUF, K0)                                                       \
  {                                                                             \
    _Pragma("unroll")                                                           \
    for (int p = 0; p < 2; ++p) {                                               \
      int ar = wave * 32 + p * 16 + srow;                                       \
      gload_lds16(yhb + (size_t)(m0 + ar) * CC + (K0) + (sslot << 3),           \
                  &Alds[BUF][wave * 32 + p * 16][0]);                           \
    }                                                                           \
    int br = wave * 16 + srow;                                                  \
    gload_lds16(wpT + (size_t)(n0 + br) * CC + (K0) + (sslot << 3),             \
                &Blds[BUF][wave * 16][0]);                                      \
  }

  f32x4 acc[2][4];
#pragma unroll
  for (int mi = 0; mi < 2; ++mi)
#pragma unroll
    for (int nj = 0; nj < 4; ++nj) acc[mi][nj] = (f32x4){0.f, 0.f, 0.f, 0.f};

  STAGE_AB(0, 0)
  __syncthreads();

  int fslot = lg ^ (lr & 3);
  for (int kt = 0; kt < 24; ++kt) {
    int cur = kt & 1;
    if (kt < 23) STAGE_AB(cur ^ 1, (kt + 1) * 32)
    bf16x8 af[2], bf[4];
#pragma unroll
    for (int mi = 0; mi < 2; ++mi)
      af[mi] = *(const bf16x8*)&Alds[cur][wave * 32 + mi * 16 + lr][fslot << 3];
#pragma unroll
    for (int nj = 0; nj < 4; ++nj)
      bf[nj] = *(const bf16x8*)&Blds[cur][nj * 16 + lr][fslot << 3];
    __builtin_amdgcn_s_setprio(1);
#pragma unroll
    for (int nj = 0; nj < 4; ++nj)
#pragma unroll
      for (int mi = 0; mi < 2; ++mi)
        acc[mi][nj] = __builtin_amdgcn_mfma_f32_16x16x32_bf16(af[mi], bf[nj], acc[mi][nj], 0, 0, 0);
    __builtin_amdgcn_s_setprio(0);
    __syncthreads();
  }
#undef STAGE_AB

  float bias[4];
#pragma unroll
  for (int nj = 0; nj < 4; ++nj) bias[nj] = b_proj[n0 + nj * 16 + lr];
#pragma unroll
  for (int mi = 0; mi < 2; ++mi)
#pragma unroll
    for (int r = 0; r < 4; ++r) {
      int m = m0 + wave * 32 + mi * 16 + lg * 4 + r;
#pragma unroll
      for (int nj = 0; nj < 4; ++nj)
        y[(size_t)m * CC + n0 + nj * 16 + lr] = acc[mi][nj][r] + bias[nj];
    }
}

// ---------------------------------------------------------------------------
// fp32 GEMM for head-0 q,k only (precision-critical FF path).
// 32x64 tiles, grid (128, 2) = 256 blocks (was 128 -> half-idle GPU).
// ---------------------------------------------------------------------------
__global__ __launch_bounds__(256) void sgemm_qk0(
    const float* __restrict__ x, const float* __restrict__ w_attn,
    const float* __restrict__ b_attn, float* __restrict__ q0,
    float* __restrict__ k0) {
  __shared__ float As[16][32];
  __shared__ float Bs[16][64];
  int sec = blockIdx.y;
  const float* Bw = w_attn + sec * CC;
  float* Out = sec ? k0 : q0;
  int tid = threadIdx.x;
  int tx = tid & 15, ty = tid >> 4;   // ty 0..15 (2 rows each), tx*4 cols
  int m0 = blockIdx.x * 32;

  int arow = tid >> 3;                // 0..31
  int acol2 = (tid & 7) << 1;         // 0,2,..,14
  int brow = tid >> 4;                // 0..15
  int bcol4 = (tid & 15) << 2;        // 0..60

  const float* Aptr = x + (size_t)(m0 + arow) * CC + acol2;
  const float* Bptr = Bw + (size_t)brow * N3 + bcol4;

  float acc[2][4] = {};

  for (int k0_ = 0; k0_ < CC; k0_ += 16) {
    float2 av = *(const float2*)(Aptr + k0_);
    float4 bv = *(const float4*)(Bptr + (size_t)k0_ * N3);
    As[acol2 + 0][arow] = av.x;
    As[acol2 + 1][arow] = av.y;
    *(float4*)&Bs[brow][bcol4] = bv;
    __syncthreads();
#pragma unroll
    for (int kk = 0; kk < 16; ++kk) {
      float2 a2 = *(const float2*)&As[kk][ty << 1];
      float4 b4 = *(const float4*)&Bs[kk][tx << 2];
      float a[2] = {a2.x, a2.y};
      float b[4] = {b4.x, b4.y, b4.z, b4.w};
#pragma unroll
      for (int ii = 0; ii < 2; ++ii)
#pragma unroll
        for (int jj = 0; jj < 4; ++jj) acc[ii][jj] += a[ii] * b[jj];
    }
    __syncthreads();
  }

  float4 bv = *(const float4*)(b_attn + sec * CC + (tx << 2));
#pragma unroll
  for (int ii = 0; ii < 2; ++ii) {
    int m = m0 + (ty << 1) + ii;
    float4 o;
    o.x = acc[ii][0] + bv.x;
    o.y = acc[ii][1] + bv.y;
    o.z = acc[ii][2] + bv.z;
    o.w = acc[ii][3] + bv.w;
    *(float4*)(Out + (size_t)m * HD + (tx << 2)) = o;
  }
}

// ---------------------------------------------------------------------------
// Head-0 scores (fp32): Sbuf[b,i,j] = relu(dot(q0,k0)/8), lower-tri tiles.
// FUSED: also emits per-64-row-chunk masked column sums into partials
// (mask = j>=1 && j<r). partials layout: [B][32][TT].
// ---------------------------------------------------------------------------
__global__ __launch_bounds__(256) void score0_kernel(
    const float* __restrict__ q0, const float* __restrict__ k0,
    float* __restrict__ Sbuf, float* __restrict__ partials) {
  int it = blockIdx.x, jt = blockIdx.y, b = blockIdx.z;
  int tid = threadIdx.x;
  int i0 = it * 64, j0 = jt * 64;
  if (jt > it) {  // mask kills everything above the diagonal
    if (tid < 64) partials[((size_t)(b * 32 + it)) * TT + j0 + tid] = 0.f;
    return;
  }
  __shared__ float Qs[64][64];
  __shared__ float Ks[64][64];
  int row = tid >> 2;
  int dq = (tid & 3) << 2;
  const float* qb = q0 + (size_t)((b * TT) + i0 + row) * HD;
  const float* kb = k0 + (size_t)((b * TT) + j0 + row) * HD;
#pragma unroll
  for (int rep = 0; rep < 4; ++rep) {
    int d = dq + rep * 16;
    float4 qv = *(const float4*)(qb + d);
    float4 kv = *(const float4*)(kb + d);
    Qs[d + 0][row] = qv.x; Qs[d + 1][row] = qv.y;
    Qs[d + 2][row] = qv.z; Qs[d + 3][row] = qv.w;
    Ks[d + 0][row] = kv.x; Ks[d + 1][row] = kv.y;
    Ks[d + 2][row] = kv.z; Ks[d + 3][row] = kv.w;
  }
  __syncthreads();
  int tx = tid & 15, ty = tid >> 4;
  float acc[4][4] = {};
#pragma unroll 8
  for (int kk = 0; kk < 64; ++kk) {
    float4 a4 = *(const float4*)&Qs[kk][ty << 2];
    float4 b4 = *(const float4*)&Ks[kk][tx << 2];
    float a[4] = {a4.x, a4.y, a4.z, a4.w};
    float b[4] = {b4.x, b4.y, b4.z, b4.w};
#pragma unroll
    for (int ii = 0; ii < 4; ++ii)
#pragma unroll
      for (int jj = 0; jj < 4; ++jj) acc[ii][jj] += a[ii] * b[jj];
  }
  float red4[4] = {0.f, 0.f, 0.f, 0.f};
#pragma unroll
  for (int ii = 0; ii < 4; ++ii) {
    int r = i0 + (ty << 2) + ii;           // global row (within T)
    int gi = (b * TT) + r;
    float ov[4];
#pragma unroll
    for (int jj = 0; jj < 4; ++jj) {
      ov[jj] = fmaxf(acc[ii][jj] * 0.125f, 0.f);
      int j = j0 + (tx << 2) + jj;
      if (j >= 1 && j < r) red4[jj] += ov[jj];
    }
    float4 o; o.x = ov[0]; o.y = ov[1]; o.z = ov[2]; o.w = ov[3];
    *(float4*)(Sbuf + (size_t)gi * TT + j0 + (tx << 2)) = o;
  }
  // reduce the 16 ty-groups per column via reused LDS
  __syncthreads();  // everyone done reading Qs
  *(float4*)&Qs[ty][tx << 2] = *(float4*)red4;
  __syncthreads();
  if (tid < 64) {
    float cs = 0.f;
#pragma unroll
    for (int t = 0; t < 16; ++t) cs += Qs[t][tid];
    partials[((size_t)(b * 32 + it)) * TT + j0 + tid] = cs;
  }
}

// ---------------------------------------------------------------------------
// Column-wise exclusive prefix scan over rows (64-row chunks; partial sums
// fused from score0). Emits E = exp(-FF) bf16 (NATURAL j-layout) and
// per-jblock row sums of clip(FF,0,1) into ffpart[B][8][TT].
// 8-row load batching cuts the serial-latency chain 8x.
// ---------------------------------------------------------------------------
__global__ __launch_bounds__(256) void scan_write(
    const float* __restrict__ Sbuf, const float* __restrict__ partials,
    unsigned short* __restrict__ Eb, float* __restrict__ ffpart) {
  int j = blockIdx.x * 256 + threadIdx.x;
  int chunk = blockIdx.y, b = blockIdx.z;
  float run = 0.f;
  for (int c = 0; c < chunk; ++c) run += partials[((size_t)(b * 32 + c)) * TT + j];
  int r0 = chunk * 64;
  const float* base = Sbuf + (size_t)(b * TT + r0) * TT + j;
  unsigned short* ebase = Eb + (size_t)(b * TT + r0) * TT + j;
  __shared__ float wsum[4][64];
  int wv = threadIdx.x >> 6;
  for (int rb = 0; rb < 64; rb += 8) {
    float v[8];
#pragma unroll
    for (int u = 0; u < 8; ++u) {
      int r = r0 + rb + u;
      v[u] = (j >= 1 && j < r) ? base[(size_t)(rb + u) * TT] : 0.f;
    }
#pragma unroll
    for (int u = 0; u < 8; ++u) {
      int rr = rb + u;
      ebase[(size_t)rr * TT] = f2b(__expf(-run));  // E (bf16, natural-e)
      float c1 = fminf(run, 1.f);                  // run >= 0 always
#pragma unroll
      for (int o = 1; o < 64; o <<= 1) c1 += __shfl_xor(c1, o);
      if ((threadIdx.x & 63) == 0) wsum[wv][rr] = c1;
      run += v[u];
    }
  }
  __syncthreads();
  if (threadIdx.x < 64)
    ffpart[((size_t)(b * 8) + blockIdx.x) * TT + r0 + threadIdx.x] =
        wsum[0][threadIdx.x] + wsum[1][threadIdx.x] +
        wsum[2][threadIdx.x] + wsum[3][threadIdx.x];
}

// ---------------------------------------------------------------------------
// bf16 MFMA flash attention, E = exp(-FF) multiplicative, fixed-max exp2
// softmax, SWAPPED QK^T (plain-C packing — no inline asm):
// s = mfma(K,Q) -> D row = j_local, col = q-row. Lane owns q-row (i0+lr),
// j in {nj*16 + lg*4 + 0..3}. P packs to uint2 -> 4 ds_write_b64/tile.
// lrun is a per-lane scalar; epilogue = 2 shfl + ds_bpermute.
// Grid (24, 32): XCD = x%8 serves one batch / 3 heads (L2 locality).
// K/V staged to LDS via global_load_lds, double-buffered, XOR-swizzled.
// ---------------------------------------------------------------------------
__global__ __launch_bounds__(256, 3) void attn_mfma(
    const unsigned short* __restrict__ Qb, const unsigned short* __restrict__ Kb,
    const unsigned short* __restrict__ Vt, const unsigned short* __restrict__ Eb,
    unsigned short* __restrict__ yhb) {
  int xbh = blockIdx.x;
  int b = (xbh >> 2) & 1;
  int h = ((xbh >> 3) << 2) | (xbh & 3);
  int g4 = 31 - (int)blockIdx.y;
  int wave = threadIdx.x >> 6, lane = threadIdx.x & 63;
  int lr = lane & 15, lg = lane >> 4;
  int i0 = g4 * 64 + wave * 16;
  int bh = b * NH + h;
  const unsigned short* Qh = Qb + (size_t)bh * TT * HD;
  const unsigned short* Kh = Kb + (size_t)bh * TT * HD;
  const unsigned short* Vh = Vt + (size_t)bh * HD * TT;
  const unsigned short* Erow = Eb + ((size_t)(b * TT) + i0 + lr) * TT;

  __shared__ __align__(16) unsigned short Ksh[2][64][64];
  __shared__ __align__(16) unsigned short Vsh[2][64][64];
  __shared__ __align__(16) unsigned short Plds[4][16][80];

  int rowoff = lane >> 3;            // 0..7 within an 8-row staging segment
  int sslot  = (lane & 7) ^ rowoff;  // pre-swizzled source slot (16B units)

  bf16x8 qf[2];
#pragma unroll
  for (int ks = 0; ks < 2; ++ks)
    qf[ks] = *(const bf16x8*)(Qh + (size_t)(i0 + lr) * HD + ks * 32 + lg * 8);

  f32x4 acc[4];
  float lrun = 0.f;  // per-lane partial softmax denom for q-row = i0+lr
#pragma unroll
  for (int q = 0; q < 4; ++q) acc[q] = (f32x4){0.f, 0.f, 0.f, 0.f};

#define STAGE_KV(BUF, J0)                                                      \
  {                                                                            \
    _Pragma("unroll")                                                          \
    for (int p = 0; p < 2; ++p) {                                              \
      int r0 = wave * 16 + p * 8;                                              \
      gload_lds16(Kh + (size_t)((J0) + r0 + rowoff) * HD + sslot * 8,          \
                  &Ksh[BUF][r0][0]);                                           \
      gload_lds16(Vh + (size_t)(r0 + rowoff) * TT + (J0) + sslot * 8,          \
                  &Vsh[BUF][r0][0]);                                           \
    }                                                                          \
  }

  STAGE_KV(0, 0)
  __syncthreads();

  for (int kt = 0; kt <= g4; ++kt) {
    int cur = kt & 1;
    int j0 = kt * 64;
    if (kt < g4) STAGE_KV(cur ^ 1, j0 + 64)

    // E for current tile: 4 x 8B natural-layout loads (j = nj*16 + lg*4 ..)
    ushort4 ev[4];
#pragma unroll
    for (int nj = 0; nj < 4; ++nj)
      ev[nj] = *(const ushort4*)(Erow + j0 + nj * 16 + lg * 4);

    // ---- S^T = mfma(K, Q) from swizzled LDS ----
    f32x4 s[4];
    __builtin_amdgcn_s_setprio(1);
#pragma unroll
    for (int nj = 0; nj < 4; ++nj) {
      int row = nj * 16 + lr;
      int sw = row & 7;
      bf16x8 k0f = *(const bf16x8*)&Ksh[cur][row][(lg ^ sw) << 3];
      bf16x8 k1f = *(const bf16x8*)&Ksh[cur][row][((4 + lg) ^ sw) << 3];
      f32x4 z = (f32x4){0.f, 0.f, 0.f, 0.f};
      z = __builtin_amdgcn_mfma_f32_16x16x32_bf16(k0f, qf[0], z, 0, 0, 0);
      s[nj] = __builtin_amdgcn_mfma_f32_16x16x32_bf16(k1f, qf[1], z, 0, 0, 0);
    }
    __builtin_amdgcn_s_setprio(0);

    // ---- causal mask (diagonal tile only): j > q-row -> -inf ----
    int qrow = i0 + lr;
    if (kt == g4) {
#pragma unroll
      for (int nj = 0; nj < 4; ++nj)
#pragma unroll
        for (int r = 0; r < 4; ++r)
          if (j0 + nj * 16 + lg * 4 + r > qrow) s[nj][r] = -1e30f;
    }

    // ---- P = E * exp2(s); pack (plain C) -> 4 ds_write_b64 ----
#pragma unroll
    for (int nj = 0; nj < 4; ++nj) {
      float p0 = b2f(ev[nj].x) * exp2f(s[nj][0]);
      float p1 = b2f(ev[nj].y) * exp2f(s[nj][1]);
      float p2 = b2f(ev[nj].z) * exp2f(s[nj][2]);
      float p3 = b2f(ev[nj].w) * exp2f(s[nj][3]);
      lrun += (p0 + p1) + (p2 + p3);
      unsigned w0 = (unsigned)f2b(p0) | ((unsigned)f2b(p1) << 16);
      unsigned w1 = (unsigned)f2b(p2) | ((unsigned)f2b(p3) << 16);
      *(uint2*)&Plds[wave][lr][nj * 16 + lg * 4] = make_uint2(w0, w1);
    }

    // ---- PV from swizzled LDS ----
    bf16x8 pa0 = *(const bf16x8*)&Plds[wave][lr][lg * 8];
    bf16x8 pa1 = *(const bf16x8*)&Plds[wave][lr][32 + lg * 8];
    __builtin_amdgcn_s_setprio(1);
#pragma unroll
    for (int nd = 0; nd < 4; ++nd) {
      int row = nd * 16 + lr;
      int sw = row & 7;
      bf16x8 v0f = *(const bf16x8*)&Vsh[cur][row][(lg ^ sw) << 3];
      bf16x8 v1f = *(const bf16x8*)&Vsh[cur][row][((4 + lg) ^ sw) << 3];
      acc[nd] = __builtin_amdgcn_mfma_f32_16x16x32_bf16(pa0, v0f, acc[nd], 0, 0, 0);
      acc[nd] = __builtin_amdgcn_mfma_f32_16x16x32_bf16(pa1, v1f, acc[nd], 0, 0, 0);
    }
    __builtin_amdgcn_s_setprio(0);

    __syncthreads();
  }
#undef STAGE_KV

  // ---- epilogue: finish l across lg groups; fetch l for own acc rows ----
  lrun += __shfl_xor(lrun, 16);
  lrun += __shfl_xor(lrun, 32);
#pragma unroll
  for (int r = 0; r < 4; ++r) {
    float l = __int_as_float(
        __builtin_amdgcn_ds_bpermute((lg * 4 + r) << 2, __float_as_int(lrun)));
    float inv = 1.f / l;
    int ig = i0 + lg * 4 + r;
    unsigned short* ob = yhb + (size_t)(b * TT + ig) * CC + h * HD;
#pragma unroll
    for (int nd = 0; nd < 4; ++nd)
      ob[nd * 16 + lr] = f2b(acc[nd][r] * inv);
  }
}

// ---------------------------------------------------------------------------
// M[0,b,i,j] = i - sum_jb ffpart[b][jb][j]   (8 L1-resident partial reads)
// ---------------------------------------------------------------------------
__global__ __launch_bounds__(256) void m_kernel(
    const float* __restrict__ ffpart, float* __restrict__ Mout) {
  int idx = blockIdx.x * blockDim.x + threadIdx.x;
  int stride = gridDim.x * blockDim.x;
  for (; idx < M_ELEMS; idx += stride) {
    int j = idx & (TT - 1);
    int i = (idx >> 11) & (TT - 1);
    int b = idx >> 22;
    const float* fp = ffpart + ((size_t)(b * 8)) * TT + j;
    float s = ((fp[0] + fp[TT]) + (fp[2 * TT] + fp[3 * TT])) +
              ((fp[4 * TT] + fp[5 * TT]) + (fp[6 * TT] + fp[7 * TT]));
    Mout[idx] = (float)i - s;
  }
}

// ---------------------------------------------------------------------------
extern "C" void kernel_launch(void* const* d_in, const int* in_sizes, int n_in,
                              void* d_out, int out_size, void* d_ws, size_t ws_size,
                              hipStream_t stream) {
  const float* x      = (const float*)d_in[0];
  const float* w_attn = (const float*)d_in[1];
  const float* b_attn = (const float*)d_in[2];
  const float* w_proj = (const float*)d_in[3];
  const float* b_proj = (const float*)d_in[4];

  float* y    = (float*)d_out;          // [B,T,C]
  float* Mreg = y + Y_ELEMS;            // [B,T,T]: S0 (scratch) -> M (final)

  float* ws = (float*)d_ws;
  float* q0       = ws;                               // B*T*64
  float* k0       = q0 + (size_t)BB * TT * HD;
  float* partials = k0 + (size_t)BB * TT * HD;        // B*32*T
  float* ffpart   = partials + (size_t)BB * 32 * TT;  // B*8*T
  unsigned short* xb  = (unsigned short*)(ffpart + (size_t)BB * 8 * TT);  // B*T*C
  unsigned short* wbT = xb + (size_t)Y_ELEMS;                 // 2304*768
  unsigned short* wpT = wbT + (size_t)N3 * CC;                // 768*768
  unsigned short* Qb  = wpT + (size_t)CC * CC;                // B*NH*T*HD
  unsigned short* Kb  = Qb + (size_t)BB * NH * TT * HD;
  unsigned short* Vt  = Kb + (size_t)BB * NH * TT * HD;
  unsigned short* yhb = Vt + (size_t)BB * NH * TT * HD;       // B*T*C
  unsigned short* Eb  = yhb + (size_t)Y_ELEMS;                // B*T*T bf16 (16.8MB)
  // total ws usage ~= 46 MB

  // 1. packs: x -> bf16; weights -> transposed bf16
  pack_x<<<Y_ELEMS / (256 * 8), 256, 0, stream>>>(x, xb);
  transpose_pack<<<dim3(CC / 64, N3 / 64), 256, 0, stream>>>(w_attn, wbT, N3);
  transpose_pack<<<dim3(CC / 64, CC / 64), 256, 0, stream>>>(w_proj, wpT, CC);
  // 2. bf16 MFMA QKV GEMM (128x128 tiles, LDS dbuf) -> Qb (scaled) / Kb / Vt
  gemm_qkv_bf16<<<dim3(32, 18), 256, 0, stream>>>(xb, wbT, b_attn, Qb, Kb, Vt);
  // 3. fp32 head-0 q,k (precision-critical FF path; 256 blocks)
  sgemm_qk0<<<dim3(128, 2), 256, 0, stream>>>(x, w_attn, b_attn, q0, k0);
  // 4. head-0 scores (fp32) into Mreg + fused per-chunk column partial sums
  score0_kernel<<<dim3(32, 32, BB), 256, 0, stream>>>(q0, k0, Mreg, partials);
  // 5. scan: E = exp(-FF) bf16 (natural) + ffpart row sums (batched loads)
  scan_write<<<dim3(8, 32, BB), 256, 0, stream>>>(Mreg, partials, Eb, ffpart);
  // 6. MFMA flash attention (swapped-QK, plain-C pack, LDS-staged K/V)
  attn_mfma<<<dim3(24, 32), 256, 0, stream>>>(Qb, Kb, Vt, Eb, yhb);
  // 7. M output (after attn so its dirty lines don't flush during attn)
  m_kernel<<<4096, 256, 0, stream>>>(ffpart, Mreg);
  // 8. y = yhb @ w_proj + b_proj (bf16 MFMA, LDS-staged dbuf)
  gemm_proj_bf16<<<dim3(32, 12), 256, 0, stream>>>(yhb, wpT, b_proj, y);
}

// Round 13
// 192.273 us; speedup vs baseline: 2.6255x; 1.0494x over previous
//
#include <hip/hip_runtime.h>
#include <cstddef>

// Problem constants
#define TT 2048
#define BB 2
#define CC 768
#define NH 12
#define HD 64
#define N3 2304          // 3*NH*HD
#define Y_ELEMS (BB*TT*CC)          // 3145728
#define M_ELEMS (BB*TT*TT)          // 8388608

typedef __attribute__((ext_vector_type(8))) short bf16x8;
typedef __attribute__((ext_vector_type(4))) float f32x4;

__device__ inline unsigned short f2b(float f) {
  union { float f; unsigned u; } v; v.f = f;
  unsigned r = (v.u + 0x7FFFu + ((v.u >> 16) & 1u)) >> 16;
  return (unsigned short)r;
}
__device__ inline float b2f(unsigned short u) {
  union { unsigned u; float f; } v; v.u = (unsigned)u << 16; return v.f;
}

// async global -> LDS, 16B per lane; lds dest is wave-uniform base, HW adds lane*16
__device__ inline void gload_lds16(const unsigned short* g, unsigned short* l) {
  __builtin_amdgcn_global_load_lds(
      (const __attribute__((address_space(1))) unsigned int*)g,
      (__attribute__((address_space(3))) unsigned int*)l, 16, 0, 0);
}

// ---------------------------------------------------------------------------
// pack x (fp32) -> xb (bf16). 8 elems/thread.
// ---------------------------------------------------------------------------
__global__ __launch_bounds__(256) void pack_x(
    const float* __restrict__ x, unsigned short* __restrict__ xb) {
  size_t i = ((size_t)blockIdx.x * 256 + threadIdx.x) * 8;
  float4 a = *(const float4*)(x + i);
  float4 b = *(const float4*)(x + i + 4);
  ushort4 o0, o1;
  o0.x = f2b(a.x); o0.y = f2b(a.y); o0.z = f2b(a.z); o0.w = f2b(a.w);
  o1.x = f2b(b.x); o1.y = f2b(b.y); o1.z = f2b(b.z); o1.w = f2b(b.w);
  *(ushort4*)(xb + i) = o0;
  *(ushort4*)(xb + i + 4) = o1;
}

// ---------------------------------------------------------------------------
// W [768][N] fp32 -> WT [N][768] bf16 (transposed pack). Block=(kt,nt) 64x64.
// ---------------------------------------------------------------------------
__global__ __launch_bounds__(256) void transpose_pack(
    const float* __restrict__ W, unsigned short* __restrict__ WT, int N) {
  __shared__ float tile[64][65];
  int kt = blockIdx.x, nt = blockIdx.y;
  int tid = threadIdx.x;
  int r = tid >> 4, c4 = (tid & 15) << 2;
#pragma unroll
  for (int rep = 0; rep < 4; ++rep) {
    int row = rep * 16 + r;
    float4 v = *(const float4*)(W + (size_t)(kt * 64 + row) * N + nt * 64 + c4);
    tile[row][c4 + 0] = v.x; tile[row][c4 + 1] = v.y;
    tile[row][c4 + 2] = v.z; tile[row][c4 + 3] = v.w;
  }
  __syncthreads();
#pragma unroll
  for (int rep = 0; rep < 4; ++rep) {
    int nrow = rep * 16 + r;
    ushort4 o;
    o.x = f2b(tile[c4 + 0][nrow]); o.y = f2b(tile[c4 + 1][nrow]);
    o.z = f2b(tile[c4 + 2][nrow]); o.w = f2b(tile[c4 + 3][nrow]);
    *(ushort4*)(WT + (size_t)(nt * 64 + nrow) * CC + kt * 64 + c4) = o;
  }
}

// ---------------------------------------------------------------------------
// bf16 MFMA GEMM: qkv = xb @ wbT^T + b_attn -> packed Qb (pre-scaled 1/8),
// Kb, Vt (transposed via LDS). 128x128 tiles: grid (32, 18).
// LDS-staged dbuf, slot-swizzled. Vlds epilogue UNION-overlaid on A/B bufs.
// ---------------------------------------------------------------------------
__global__ __launch_bounds__(256, 3) void gemm_qkv_bf16(
    const unsigned short* __restrict__ xb, const unsigned short* __restrict__ wbT,
    const float* __restrict__ b_attn,
    unsigned short* __restrict__ Qb, unsigned short* __restrict__ Kb,
    unsigned short* __restrict__ Vt) {
  __shared__ __align__(16) unsigned short smem_u[17408];  // 34816 B
  unsigned short (*Alds)[128][32] = (unsigned short(*)[128][32])smem_u;
  unsigned short (*Blds)[128][32] = (unsigned short(*)[128][32])(smem_u + 8192);
  unsigned short (*Vlds)[136]     = (unsigned short(*)[136])smem_u;

  int mt = blockIdx.x, nt = blockIdx.y;
  int sec = nt / 6, h0 = (nt % 6) * 2;
  int wave = threadIdx.x >> 6, lane = threadIdx.x & 63;
  int lr = lane & 15, lg = lane >> 4;
  int m0 = mt * 128;
  int n0 = nt * 128;

  int srow = lane >> 2;                 // 0..15 staging row within segment
  int sslot = (lane & 3) ^ (srow & 3);  // pre-swizzled source k-slot (16B units)

#define STAGE_AB(BUF, K0)                                                       \
  {                                                                             \
    _Pragma("unroll")                                                           \
    for (int p = 0; p < 2; ++p) {                                               \
      int ar = wave * 32 + p * 16 + srow;                                       \
      gload_lds16(xb + (size_t)(m0 + ar) * CC + (K0) + (sslot << 3),            \
                  &Alds[BUF][wave * 32 + p * 16][0]);                           \
      gload_lds16(wbT + (size_t)(n0 + ar) * CC + (K0) + (sslot << 3),           \
                  &Blds[BUF][wave * 32 + p * 16][0]);                           \
    }                                                                           \
  }

  f32x4 acc[2][8];
#pragma unroll
  for (int mi = 0; mi < 2; ++mi)
#pragma unroll
    for (int nj = 0; nj < 8; ++nj) acc[mi][nj] = (f32x4){0.f, 0.f, 0.f, 0.f};

  STAGE_AB(0, 0)
  __syncthreads();

  int fslot = lg ^ (lr & 3);  // frag read slot (same involution)
  for (int kt = 0; kt < 24; ++kt) {
    int cur = kt & 1;
    if (kt < 23) STAGE_AB(cur ^ 1, (kt + 1) * 32)
    bf16x8 af[2], bf[8];
#pragma unroll
    for (int mi = 0; mi < 2; ++mi)
      af[mi] = *(const bf16x8*)&Alds[cur][wave * 32 + mi * 16 + lr][fslot << 3];
#pragma unroll
    for (int nj = 0; nj < 8; ++nj)
      bf[nj] = *(const bf16x8*)&Blds[cur][nj * 16 + lr][fslot << 3];
    __builtin_amdgcn_s_setprio(1);
#pragma unroll
    for (int nj = 0; nj < 8; ++nj)
#pragma unroll
      for (int mi = 0; mi < 2; ++mi)
        acc[mi][nj] = __builtin_amdgcn_mfma_f32_16x16x32_bf16(af[mi], bf[nj], acc[mi][nj], 0, 0, 0);
    __builtin_amdgcn_s_setprio(0);
    __syncthreads();
  }
#undef STAGE_AB

  int b = m0 >> 11;
  float bias[8];
#pragma unroll
  for (int nj = 0; nj < 8; ++nj) bias[nj] = b_attn[n0 + nj * 16 + lr];

  if (sec < 2) {
    // Q is pre-scaled by 1/8 (exact in bf16: exponent shift only)
    float qscale = (sec == 0) ? 0.125f : 1.0f;
    unsigned short* OutB = (sec == 0 ? Qb : Kb);
    int tbase = (m0 & 2047) + wave * 32 + lg * 4;
#pragma unroll
    for (int nj = 0; nj < 8; ++nj) {
      int h = h0 + (nj >> 2);
      int d = (nj & 3) * 16 + lr;
      unsigned short* Out = OutB + (size_t)(b * NH + h) * TT * HD;
#pragma unroll
      for (int mi = 0; mi < 2; ++mi)
#pragma unroll
        for (int r = 0; r < 4; ++r) {
          int t = tbase + mi * 16 + r;
          Out[(size_t)t * HD + d] = f2b((acc[mi][nj][r] + bias[nj]) * qscale);
        }
    }
  } else {
    int tl = wave * 32 + lg * 4;
#pragma unroll
    for (int mi = 0; mi < 2; ++mi)
#pragma unroll
      for (int r = 0; r < 4; ++r)
#pragma unroll
        for (int nj = 0; nj < 8; ++nj)
          Vlds[tl + mi * 16 + r][nj * 16 + lr] = f2b(acc[mi][nj][r] + bias[nj]);
    __syncthreads();
    int d = threadIdx.x & 63, tc = threadIdx.x >> 6;
    int tblk = (m0 & 2047);
#pragma unroll
    for (int hh = 0; hh < 2; ++hh) {
      unsigned short* Ov = Vt + ((size_t)(b * NH + h0 + hh) * HD + d) * TT + tblk + tc * 32;
      int c = hh * 64 + d;
#pragma unroll
      for (int i8 = 0; i8 < 4; ++i8) {
        ushort4 o0, o1;
        o0.x = Vlds[tc * 32 + i8 * 8 + 0][c]; o0.y = Vlds[tc * 32 + i8 * 8 + 1][c];
        o0.z = Vlds[tc * 32 + i8 * 8 + 2][c]; o0.w = Vlds[tc * 32 + i8 * 8 + 3][c];
        o1.x = Vlds[tc * 32 + i8 * 8 + 4][c]; o1.y = Vlds[tc * 32 + i8 * 8 + 5][c];
        o1.z = Vlds[tc * 32 + i8 * 8 + 6][c]; o1.w = Vlds[tc * 32 + i8 * 8 + 7][c];
        *(ushort4*)(Ov + i8 * 8) = o0;
        *(ushort4*)(Ov + i8 * 8 + 4) = o1;
      }
    }
  }
}

// ---------------------------------------------------------------------------
// bf16 MFMA GEMM: y = yhb @ wpT^T + b_proj (fp32 out). Grid (32, 12).
// LDS-staged double-buffered (128x64 tile).
// ---------------------------------------------------------------------------
__global__ __launch_bounds__(256, 3) void gemm_proj_bf16(
    const unsigned short* __restrict__ yhb, const unsigned short* __restrict__ wpT,
    const float* __restrict__ b_proj, float* __restrict__ y) {
  __shared__ __align__(16) unsigned short Alds[2][128][32];
  __shared__ __align__(16) unsigned short Blds[2][64][32];
  int mt = blockIdx.x, nt = blockIdx.y;
  int wave = threadIdx.x >> 6, lane = threadIdx.x & 63;
  int lr = lane & 15, lg = lane >> 4;
  int m0 = mt * 128;
  int n0 = nt * 64;

  int srow = lane >> 2;
  int sslot = (lane & 3) ^ (srow & 3);

#define STAGE_AB(BUF, K0)                                                       \
  {                                                                             \
    _Pragma("unroll")                                                           \
    for (int p = 0; p < 2; ++p) {                                               \
      int ar = wave * 32 + p * 16 + srow;                                       \
      gload_lds16(yhb + (size_t)(m0 + ar) * CC + (K0) + (sslot << 3),           \
                  &Alds[BUF][wave * 32 + p * 16][0]);                           \
    }                                                                           \
    int br = wave * 16 + srow;                                                  \
    gload_lds16(wpT + (size_t)(n0 + br) * CC + (K0) + (sslot << 3),             \
                &Blds[BUF][wave * 16][0]);                                      \
  }

  f32x4 acc[2][4];
#pragma unroll
  for (int mi = 0; mi < 2; ++mi)
#pragma unroll
    for (int nj = 0; nj < 4; ++nj) acc[mi][nj] = (f32x4){0.f, 0.f, 0.f, 0.f};

  STAGE_AB(0, 0)
  __syncthreads();

  int fslot = lg ^ (lr & 3);
  for (int kt = 0; kt < 24; ++kt) {
    int cur = kt & 1;
    if (kt < 23) STAGE_AB(cur ^ 1, (kt + 1) * 32)
    bf16x8 af[2], bf[4];
#pragma unroll
    for (int mi = 0; mi < 2; ++mi)
      af[mi] = *(const bf16x8*)&Alds[cur][wave * 32 + mi * 16 + lr][fslot << 3];
#pragma unroll
    for (int nj = 0; nj < 4; ++nj)
      bf[nj] = *(const bf16x8*)&Blds[cur][nj * 16 + lr][fslot << 3];
    __builtin_amdgcn_s_setprio(1);
#pragma unroll
    for (int nj = 0; nj < 4; ++nj)
#pragma unroll
      for (int mi = 0; mi < 2; ++mi)
        acc[mi][nj] = __builtin_amdgcn_mfma_f32_16x16x32_bf16(af[mi], bf[nj], acc[mi][nj], 0, 0, 0);
    __builtin_amdgcn_s_setprio(0);
    __syncthreads();
  }
#undef STAGE_AB

  float bias[4];
#pragma unroll
  for (int nj = 0; nj < 4; ++nj) bias[nj] = b_proj[n0 + nj * 16 + lr];
#pragma unroll
  for (int mi = 0; mi < 2; ++mi)
#pragma unroll
    for (int r = 0; r < 4; ++r) {
      int m = m0 + wave * 32 + mi * 16 + lg * 4 + r;
#pragma unroll
      for (int nj = 0; nj < 4; ++nj)
        y[(size_t)m * CC + n0 + nj * 16 + lr] = acc[mi][nj][r] + bias[nj];
    }
}

// ---------------------------------------------------------------------------
// fp32 GEMM for head-0 q,k only (precision-critical FF path).
// 32x64 tiles, grid (128, 2) = 256 blocks.
// ---------------------------------------------------------------------------
__global__ __launch_bounds__(256) void sgemm_qk0(
    const float* __restrict__ x, const float* __restrict__ w_attn,
    const float* __restrict__ b_attn, float* __restrict__ q0,
    float* __restrict__ k0) {
  __shared__ float As[16][32];
  __shared__ float Bs[16][64];
  int sec = blockIdx.y;
  const float* Bw = w_attn + sec * CC;
  float* Out = sec ? k0 : q0;
  int tid = threadIdx.x;
  int tx = tid & 15, ty = tid >> 4;   // ty 0..15 (2 rows each), tx*4 cols
  int m0 = blockIdx.x * 32;

  int arow = tid >> 3;                // 0..31
  int acol2 = (tid & 7) << 1;         // 0,2,..,14
  int brow = tid >> 4;                // 0..15
  int bcol4 = (tid & 15) << 2;        // 0..60

  const float* Aptr = x + (size_t)(m0 + arow) * CC + acol2;
  const float* Bptr = Bw + (size_t)brow * N3 + bcol4;

  float acc[2][4] = {};

  for (int k0_ = 0; k0_ < CC; k0_ += 16) {
    float2 av = *(const float2*)(Aptr + k0_);
    float4 bv = *(const float4*)(Bptr + (size_t)k0_ * N3);
    As[acol2 + 0][arow] = av.x;
    As[acol2 + 1][arow] = av.y;
    *(float4*)&Bs[brow][bcol4] = bv;
    __syncthreads();
#pragma unroll
    for (int kk = 0; kk < 16; ++kk) {
      float2 a2 = *(const float2*)&As[kk][ty << 1];
      float4 b4 = *(const float4*)&Bs[kk][tx << 2];
      float a[2] = {a2.x, a2.y};
      float b[4] = {b4.x, b4.y, b4.z, b4.w};
#pragma unroll
      for (int ii = 0; ii < 2; ++ii)
#pragma unroll
        for (int jj = 0; jj < 4; ++jj) acc[ii][jj] += a[ii] * b[jj];
    }
    __syncthreads();
  }

  float4 bv = *(const float4*)(b_attn + sec * CC + (tx << 2));
#pragma unroll
  for (int ii = 0; ii < 2; ++ii) {
    int m = m0 + (ty << 1) + ii;
    float4 o;
    o.x = acc[ii][0] + bv.x;
    o.y = acc[ii][1] + bv.y;
    o.z = acc[ii][2] + bv.z;
    o.w = acc[ii][3] + bv.w;
    *(float4*)(Out + (size_t)m * HD + (tx << 2)) = o;
  }
}

// ---------------------------------------------------------------------------
// Head-0 scores (fp32): Sbuf[b,i,j] = relu(dot(q0,k0)/8), lower-tri tiles.
// FUSED: also emits per-64-row-chunk masked column sums into partials
// (mask = j>=1 && j<r). partials layout: [B][32][TT].
// ---------------------------------------------------------------------------
__global__ __launch_bounds__(256) void score0_kernel(
    const float* __restrict__ q0, const float* __restrict__ k0,
    float* __restrict__ Sbuf, float* __restrict__ partials) {
  int it = blockIdx.x, jt = blockIdx.y, b = blockIdx.z;
  int tid = threadIdx.x;
  int i0 = it * 64, j0 = jt * 64;
  if (jt > it) {  // mask kills everything above the diagonal
    if (tid < 64) partials[((size_t)(b * 32 + it)) * TT + j0 + tid] = 0.f;
    return;
  }
  __shared__ float Qs[64][64];
  __shared__ float Ks[64][64];
  int row = tid >> 2;
  int dq = (tid & 3) << 2;
  const float* qb = q0 + (size_t)((b * TT) + i0 + row) * HD;
  const float* kb = k0 + (size_t)((b * TT) + j0 + row) * HD;
#pragma unroll
  for (int rep = 0; rep < 4; ++rep) {
    int d = dq + rep * 16;
    float4 qv = *(const float4*)(qb + d);
    float4 kv = *(const float4*)(kb + d);
    Qs[d + 0][row] = qv.x; Qs[d + 1][row] = qv.y;
    Qs[d + 2][row] = qv.z; Qs[d + 3][row] = qv.w;
    Ks[d + 0][row] = kv.x; Ks[d + 1][row] = kv.y;
    Ks[d + 2][row] = kv.z; Ks[d + 3][row] = kv.w;
  }
  __syncthreads();
  int tx = tid & 15, ty = tid >> 4;
  float acc[4][4] = {};
#pragma unroll 8
  for (int kk = 0; kk < 64; ++kk) {
    float4 a4 = *(const float4*)&Qs[kk][ty << 2];
    float4 b4 = *(const float4*)&Ks[kk][tx << 2];
    float a[4] = {a4.x, a4.y, a4.z, a4.w};
    float b[4] = {b4.x, b4.y, b4.z, b4.w};
#pragma unroll
    for (int ii = 0; ii < 4; ++ii)
#pragma unroll
      for (int jj = 0; jj < 4; ++jj) acc[ii][jj] += a[ii] * b[jj];
  }
  float red4[4] = {0.f, 0.f, 0.f, 0.f};
#pragma unroll
  for (int ii = 0; ii < 4; ++ii) {
    int r = i0 + (ty << 2) + ii;           // global row (within T)
    int gi = (b * TT) + r;
    float ov[4];
#pragma unroll
    for (int jj = 0; jj < 4; ++jj) {
      ov[jj] = fmaxf(acc[ii][jj] * 0.125f, 0.f);
      int j = j0 + (tx << 2) + jj;
      if (j >= 1 && j < r) red4[jj] += ov[jj];
    }
    float4 o; o.x = ov[0]; o.y = ov[1]; o.z = ov[2]; o.w = ov[3];
    *(float4*)(Sbuf + (size_t)gi * TT + j0 + (tx << 2)) = o;
  }
  // reduce the 16 ty-groups per column via reused LDS
  __syncthreads();  // everyone done reading Qs
  *(float4*)&Qs[ty][tx << 2] = *(float4*)red4;
  __syncthreads();
  if (tid < 64) {
    float cs = 0.f;
#pragma unroll
    for (int t = 0; t < 16; ++t) cs += Qs[t][tid];
    partials[((size_t)(b * 32 + it)) * TT + j0 + tid] = cs;
  }
}

// ---------------------------------------------------------------------------
// Column-wise exclusive prefix scan over rows (64-row chunks; partial sums
// fused from score0). Emits E = exp(-FF) bf16 with the j-swizzled layout
// (within each 64-col tile: j -> ((j&15)<<2)|((j>>4)&3)) and per-jblock
// row sums of clip(FF,0,1) into ffpart[B][8][TT]. 8-row load batching.
// ---------------------------------------------------------------------------
__global__ __launch_bounds__(256) void scan_write(
    const float* __restrict__ Sbuf, const float* __restrict__ partials,
    unsigned short* __restrict__ Eb, float* __restrict__ ffpart) {
  int j = blockIdx.x * 256 + threadIdx.x;
  int chunk = blockIdx.y, b = blockIdx.z;
  float run = 0.f;
  for (int c = 0; c < chunk; ++c) run += partials[((size_t)(b * 32 + c)) * TT + j];
  int r0 = chunk * 64;
  int jswz = (j & ~63) | ((j & 15) << 2) | ((j >> 4) & 3);
  const float* base = Sbuf + (size_t)(b * TT + r0) * TT + j;
  unsigned short* ebase = Eb + (size_t)(b * TT + r0) * TT + jswz;
  __shared__ float wsum[4][64];
  int wv = threadIdx.x >> 6;
  for (int rb = 0; rb < 64; rb += 8) {
    float v[8];
#pragma unroll
    for (int u = 0; u < 8; ++u) {
      int r = r0 + rb + u;
      v[u] = (j >= 1 && j < r) ? base[(size_t)(rb + u) * TT] : 0.f;
    }
#pragma unroll
    for (int u = 0; u < 8; ++u) {
      int rr = rb + u;
      ebase[(size_t)rr * TT] = f2b(__expf(-run));  // E (bf16, natural-e)
      float c1 = fminf(run, 1.f);                  // run >= 0 always
#pragma unroll
      for (int o = 1; o < 64; o <<= 1) c1 += __shfl_xor(c1, o);
      if ((threadIdx.x & 63) == 0) wsum[wv][rr] = c1;
      run += v[u];
    }
  }
  __syncthreads();
  if (threadIdx.x < 64)
    ffpart[((size_t)(b * 8) + blockIdx.x) * TT + r0 + threadIdx.x] =
        wsum[0][threadIdx.x] + wsum[1][threadIdx.x] +
        wsum[2][threadIdx.x] + wsum[3][threadIdx.x];
}

// ---------------------------------------------------------------------------
// bf16 MFMA flash attention (R9-exact measured-best form):
// E = exp(-FF) multiplicative, fixed-max softmax via __expf, forward
// mfma(Q,K), per-lane lrun[4] partial denom reduced once at the epilogue,
// scalar f2b P writes into Plds[16][80].
// Grid (24, 32): XCD = x%8 serves one batch / 3 heads (L2 locality).
// K/V staged to LDS via global_load_lds, double-buffered, XOR-swizzled.
// ---------------------------------------------------------------------------
__global__ __launch_bounds__(256, 3) void attn_mfma(
    const unsigned short* __restrict__ Qb, const unsigned short* __restrict__ Kb,
    const unsigned short* __restrict__ Vt, const unsigned short* __restrict__ Eb,
    unsigned short* __restrict__ yhb) {
  int xbh = blockIdx.x;
  int b = (xbh >> 2) & 1;
  int h = ((xbh >> 3) << 2) | (xbh & 3);
  int g4 = 31 - (int)blockIdx.y;
  int wave = threadIdx.x >> 6, lane = threadIdx.x & 63;
  int lr = lane & 15, lg = lane >> 4;
  int i0 = g4 * 64 + wave * 16;
  int bh = b * NH + h;
  const unsigned short* Qh = Qb + (size_t)bh * TT * HD;
  const unsigned short* Kh = Kb + (size_t)bh * TT * HD;
  const unsigned short* Vh = Vt + (size_t)bh * HD * TT;
  const unsigned short* Erow = Eb + ((size_t)(b * TT) + i0 + lg * 4) * TT + 4 * lr;

  __shared__ __align__(16) unsigned short Ksh[2][64][64];
  __shared__ __align__(16) unsigned short Vsh[2][64][64];
  __shared__ __align__(16) unsigned short Plds[4][16][80];

  int rowoff = lane >> 3;            // 0..7 within an 8-row staging segment
  int sslot  = (lane & 7) ^ rowoff;  // pre-swizzled source slot (16B units)

  bf16x8 qf[2];
#pragma unroll
  for (int ks = 0; ks < 2; ++ks)
    qf[ks] = *(const bf16x8*)(Qh + (size_t)(i0 + lr) * HD + ks * 32 + lg * 8);

  f32x4 acc[4];
  float lrun[4] = {0.f, 0.f, 0.f, 0.f};  // per-lane partial of softmax denom
#pragma unroll
  for (int q = 0; q < 4; ++q) acc[q] = (f32x4){0.f, 0.f, 0.f, 0.f};

#define STAGE_KV(BUF, J0)                                                      \
  {                                                                            \
    _Pragma("unroll")                                                          \
    for (int p = 0; p < 2; ++p) {                                              \
      int r0 = wave * 16 + p * 8;                                              \
      gload_lds16(Kh + (size_t)((J0) + r0 + rowoff) * HD + sslot * 8,          \
                  &Ksh[BUF][r0][0]);                                           \
      gload_lds16(Vh + (size_t)(r0 + rowoff) * TT + (J0) + sslot * 8,          \
                  &Vsh[BUF][r0][0]);                                           \
    }                                                                          \
  }

  STAGE_KV(0, 0)
  __syncthreads();

  for (int kt = 0; kt <= g4; ++kt) {
    int cur = kt & 1;
    int j0 = kt * 64;
    if (kt < g4) STAGE_KV(cur ^ 1, j0 + 64)

    // E for current tile (4 x 8B vector loads, swizzled layout)
    ushort4 ev[4];
#pragma unroll
    for (int r = 0; r < 4; ++r)
      ev[r] = *(const ushort4*)(Erow + (size_t)r * TT + j0);

    // ---- QK^T from swizzled LDS ----
    f32x4 s[4];
    __builtin_amdgcn_s_setprio(1);
#pragma unroll
    for (int nj = 0; nj < 4; ++nj) {
      int row = nj * 16 + lr;
      int sw = row & 7;
      bf16x8 k0f = *(const bf16x8*)&Ksh[cur][row][(lg ^ sw) << 3];
      bf16x8 k1f = *(const bf16x8*)&Ksh[cur][row][((4 + lg) ^ sw) << 3];
      f32x4 z = (f32x4){0.f, 0.f, 0.f, 0.f};
      z = __builtin_amdgcn_mfma_f32_16x16x32_bf16(qf[0], k0f, z, 0, 0, 0);
      s[nj] = __builtin_amdgcn_mfma_f32_16x16x32_bf16(qf[1], k1f, z, 0, 0, 0);
    }
    __builtin_amdgcn_s_setprio(0);

    // ---- causal mask (diagonal tile only) ----
    int ibase = i0 + lg * 4;
    if (kt == g4) {
#pragma unroll
      for (int nj = 0; nj < 4; ++nj)
#pragma unroll
        for (int r = 0; r < 4; ++r)
          if (j0 + nj * 16 + lr > ibase + r) s[nj][r] = -1e30f;
    }

    // ---- P = E * exp(s); per-lane partial l; stash bf16 P in LDS ----
#pragma unroll
    for (int r = 0; r < 4; ++r) {
      float p0 = b2f(ev[r].x) * __expf(s[0][r]);
      float p1 = b2f(ev[r].y) * __expf(s[1][r]);
      float p2 = b2f(ev[r].z) * __expf(s[2][r]);
      float p3 = b2f(ev[r].w) * __expf(s[3][r]);
      lrun[r] += (p0 + p1) + (p2 + p3);
      Plds[wave][lg * 4 + r][0 * 16 + lr] = f2b(p0);
      Plds[wave][lg * 4 + r][1 * 16 + lr] = f2b(p1);
      Plds[wave][lg * 4 + r][2 * 16 + lr] = f2b(p2);
      Plds[wave][lg * 4 + r][3 * 16 + lr] = f2b(p3);
    }

    // ---- PV from swizzled LDS ----
    bf16x8 pa0 = *(const bf16x8*)&Plds[wave][lr][lg * 8];
    bf16x8 pa1 = *(const bf16x8*)&Plds[wave][lr][32 + lg * 8];
    __builtin_amdgcn_s_setprio(1);
#pragma unroll
    for (int nd = 0; nd < 4; ++nd) {
      int row = nd * 16 + lr;
      int sw = row & 7;
      bf16x8 v0f = *(const bf16x8*)&Vsh[cur][row][(lg ^ sw) << 3];
      bf16x8 v1f = *(const bf16x8*)&Vsh[cur][row][((4 + lg) ^ sw) << 3];
      acc[nd] = __builtin_amdgcn_mfma_f32_16x16x32_bf16(pa0, v0f, acc[nd], 0, 0, 0);
      acc[nd] = __builtin_amdgcn_mfma_f32_16x16x32_bf16(pa1, v1f, acc[nd], 0, 0, 0);
    }
    __builtin_amdgcn_s_setprio(0);

    __syncthreads();
  }
#undef STAGE_KV

  // ---- epilogue: one l-reduction across the 16 lr lanes, then store ----
#pragma unroll
  for (int r = 0; r < 4; ++r) {
    lrun[r] += __shfl_xor(lrun[r], 1);
    lrun[r] += __shfl_xor(lrun[r], 2);
    lrun[r] += __shfl_xor(lrun[r], 4);
    lrun[r] += __shfl_xor(lrun[r], 8);
    float inv = 1.f / lrun[r];
    int ig = i0 + lg * 4 + r;
    unsigned short* ob = yhb + (size_t)(b * TT + ig) * CC + h * HD;
#pragma unroll
    for (int nd = 0; nd < 4; ++nd)
      ob[nd * 16 + lr] = f2b(acc[nd][r] * inv);
  }
}

// ---------------------------------------------------------------------------
// M[0,b,i,j] = i - sum_jb ffpart[b][jb][j], float4-vectorized stores.
// ---------------------------------------------------------------------------
__global__ __launch_bounds__(256) void m_kernel(
    const float* __restrict__ ffpart, float* __restrict__ Mout) {
  int idx4 = blockIdx.x * blockDim.x + threadIdx.x;   // index over float4s
  int stride = gridDim.x * blockDim.x;
  for (; idx4 < M_ELEMS / 4; idx4 += stride) {
    int idx = idx4 << 2;
    int j = idx & (TT - 1);
    int i = (idx >> 11) & (TT - 1);
    int b = idx >> 22;
    const float* fp = ffpart + ((size_t)(b * 8)) * TT + j;
    float4 s = make_float4(0.f, 0.f, 0.f, 0.f);
#pragma unroll
    for (int p = 0; p < 8; ++p) {
      float4 v = *(const float4*)(fp + (size_t)p * TT);
      s.x += v.x; s.y += v.y; s.z += v.z; s.w += v.w;
    }
    float fi = (float)i;
    float4 o = make_float4(fi - s.x, fi - s.y, fi - s.z, fi - s.w);
    *(float4*)(Mout + idx) = o;
  }
}

// ---------------------------------------------------------------------------
extern "C" void kernel_launch(void* const* d_in, const int* in_sizes, int n_in,
                              void* d_out, int out_size, void* d_ws, size_t ws_size,
                              hipStream_t stream) {
  const float* x      = (const float*)d_in[0];
  const float* w_attn = (const float*)d_in[1];
  const float* b_attn = (const float*)d_in[2];
  const float* w_proj = (const float*)d_in[3];
  const float* b_proj = (const float*)d_in[4];

  float* y    = (float*)d_out;          // [B,T,C]
  float* Mreg = y + Y_ELEMS;            // [B,T,T]: S0 (scratch) -> M (final)

  float* ws = (float*)d_ws;
  float* q0       = ws;                               // B*T*64
  float* k0       = q0 + (size_t)BB * TT * HD;
  float* partials = k0 + (size_t)BB * TT * HD;        // B*32*T
  float* ffpart   = partials + (size_t)BB * 32 * TT;  // B*8*T
  unsigned short* xb  = (unsigned short*)(ffpart + (size_t)BB * 8 * TT);  // B*T*C
  unsigned short* wbT = xb + (size_t)Y_ELEMS;                 // 2304*768
  unsigned short* wpT = wbT + (size_t)N3 * CC;                // 768*768
  unsigned short* Qb  = wpT + (size_t)CC * CC;                // B*NH*T*HD
  unsigned short* Kb  = Qb + (size_t)BB * NH * TT * HD;
  unsigned short* Vt  = Kb + (size_t)BB * NH * TT * HD;
  unsigned short* yhb = Vt + (size_t)BB * NH * TT * HD;       // B*T*C
  unsigned short* Eb  = yhb + (size_t)Y_ELEMS;                // B*T*T bf16 (16.8MB)
  // total ws usage ~= 46 MB

  // 1. packs: x -> bf16; weights -> transposed bf16
  pack_x<<<Y_ELEMS / (256 * 8), 256, 0, stream>>>(x, xb);
  transpose_pack<<<dim3(CC / 64, N3 / 64), 256, 0, stream>>>(w_attn, wbT, N3);
  transpose_pack<<<dim3(CC / 64, CC / 64), 256, 0, stream>>>(w_proj, wpT, CC);
  // 2. bf16 MFMA QKV GEMM (128x128 tiles, LDS dbuf) -> Qb (1/8) / Kb / Vt
  gemm_qkv_bf16<<<dim3(32, 18), 256, 0, stream>>>(xb, wbT, b_attn, Qb, Kb, Vt);
  // 3. fp32 head-0 q,k (precision-critical FF path; 256 blocks)
  sgemm_qk0<<<dim3(128, 2), 256, 0, stream>>>(x, w_attn, b_attn, q0, k0);
  // 4. head-0 scores (fp32) into Mreg + fused per-chunk column partial sums
  score0_kernel<<<dim3(32, 32, BB), 256, 0, stream>>>(q0, k0, Mreg, partials);
  // 5. scan: E = exp(-FF) bf16 (jswz) + ffpart row sums (batched loads)
  scan_write<<<dim3(8, 32, BB), 256, 0, stream>>>(Mreg, partials, Eb, ffpart);
  // 6. MFMA flash attention (R9-exact form, LDS-staged K/V, XCD grid)
  attn_mfma<<<dim3(24, 32), 256, 0, stream>>>(Qb, Kb, Vt, Eb, yhb);
  // 7. M output (after attn so its dirty lines don't flush during attn)
  m_kernel<<<4096, 256, 0, stream>>>(ffpart, Mreg);
  // 8. y = yhb @ w_proj + b_proj (bf16 MFMA, LDS-staged dbuf)
  gemm_proj_bf16<<<dim3(32, 12), 256, 0, stream>>>(yhb, wpT, b_proj, y);
}

// Round 14
// 191.410 us; speedup vs baseline: 2.6374x; 1.0045x over previous
//
#include <hip/hip_runtime.h>
#include <cstddef>

// Problem constants
#define TT 2048
#define BB 2
#define CC 768
#define NH 12
#define HD 64
#define N3 2304          // 3*NH*HD
#define Y_ELEMS (BB*TT*CC)          // 3145728
#define M_ELEMS (BB*TT*TT)          // 8388608

typedef __attribute__((ext_vector_type(8))) short bf16x8;
typedef __attribute__((ext_vector_type(4))) float f32x4;

__device__ inline unsigned short f2b(float f) {
  union { float f; unsigned u; } v; v.f = f;
  unsigned r = (v.u + 0x7FFFu + ((v.u >> 16) & 1u)) >> 16;
  return (unsigned short)r;
}
__device__ inline float b2f(unsigned short u) {
  union { unsigned u; float f; } v; v.u = (unsigned)u << 16; return v.f;
}

// async global -> LDS, 16B per lane; lds dest is wave-uniform base, HW adds lane*16
__device__ inline void gload_lds16(const unsigned short* g, unsigned short* l) {
  __builtin_amdgcn_global_load_lds(
      (const __attribute__((address_space(1))) unsigned int*)g,
      (__attribute__((address_space(3))) unsigned int*)l, 16, 0, 0);
}

// ---------------------------------------------------------------------------
// FUSED prep kernel (1D grid, 2112 blocks):
//   bid <  1536 : pack x (fp32 -> bf16), 8 elems/thread
//   bid <  1968 : transpose-pack w_attn -> wbT [N3][768] bf16
//   else        : transpose-pack w_proj -> wpT [768][768] bf16
// ---------------------------------------------------------------------------
__global__ __launch_bounds__(256) void prep_fused(
    const float* __restrict__ x, const float* __restrict__ w_attn,
    const float* __restrict__ w_proj,
    unsigned short* __restrict__ xb, unsigned short* __restrict__ wbT,
    unsigned short* __restrict__ wpT) {
  int bid = blockIdx.x;
  int tid = threadIdx.x;
  if (bid < 1536) {
    size_t i = ((size_t)bid * 256 + tid) * 8;
    float4 a = *(const float4*)(x + i);
    float4 b = *(const float4*)(x + i + 4);
    ushort4 o0, o1;
    o0.x = f2b(a.x); o0.y = f2b(a.y); o0.z = f2b(a.z); o0.w = f2b(a.w);
    o1.x = f2b(b.x); o1.y = f2b(b.y); o1.z = f2b(b.z); o1.w = f2b(b.w);
    *(ushort4*)(xb + i) = o0;
    *(ushort4*)(xb + i + 4) = o1;
    return;
  }
  const float* W;
  unsigned short* WT;
  int N, kt, nt;
  if (bid < 1968) {
    int t = bid - 1536;
    W = w_attn; WT = wbT; N = N3;
    kt = t % 12; nt = t / 12;
  } else {
    int t = bid - 1968;
    W = w_proj; WT = wpT; N = CC;
    kt = t % 12; nt = t / 12;
  }
  __shared__ float tile[64][65];
  int r = tid >> 4, c4 = (tid & 15) << 2;
#pragma unroll
  for (int rep = 0; rep < 4; ++rep) {
    int row = rep * 16 + r;
    float4 v = *(const float4*)(W + (size_t)(kt * 64 + row) * N + nt * 64 + c4);
    tile[row][c4 + 0] = v.x; tile[row][c4 + 1] = v.y;
    tile[row][c4 + 2] = v.z; tile[row][c4 + 3] = v.w;
  }
  __syncthreads();
#pragma unroll
  for (int rep = 0; rep < 4; ++rep) {
    int nrow = rep * 16 + r;
    ushort4 o;
    o.x = f2b(tile[c4 + 0][nrow]); o.y = f2b(tile[c4 + 1][nrow]);
    o.z = f2b(tile[c4 + 2][nrow]); o.w = f2b(tile[c4 + 3][nrow]);
    *(ushort4*)(WT + (size_t)(nt * 64 + nrow) * CC + kt * 64 + c4) = o;
  }
}

// ---------------------------------------------------------------------------
// FUSED QKV GEMM + head-0 fp32 q,k. Grid (32, 20):
//   nt < 18 : bf16 MFMA qkv -> Qb (pre-scaled 1/8) / Kb / Vt (128x128 tile)
//   nt 18/19: fp32 VALU q0/k0 (128x64 tile) — co-scheduled with MFMA blocks.
// LDS (34.8 KB) shared/overlaid by all paths.
// ---------------------------------------------------------------------------
__global__ __launch_bounds__(256, 3) void gemm_qkv_fused(
    const unsigned short* __restrict__ xb, const unsigned short* __restrict__ wbT,
    const float* __restrict__ b_attn,
    unsigned short* __restrict__ Qb, unsigned short* __restrict__ Kb,
    unsigned short* __restrict__ Vt,
    const float* __restrict__ x, const float* __restrict__ w_attn,
    float* __restrict__ q0, float* __restrict__ k0) {
  __shared__ __align__(16) unsigned short smem_u[17408];  // 34816 B
  int mt = blockIdx.x, nt = blockIdx.y;

  if (nt >= 18) {
    // ---------------- fp32 head-0 q/k path ----------------
    int sec = nt - 18;
    const float* Bw = w_attn + sec * CC;
    float* Out = sec ? k0 : q0;
    float (*As)[132] = (float(*)[132])smem_u;                 // [16][132] f32
    float (*Bs)[68]  = (float(*)[68])(smem_u + 4224 * 2);     // [16][68]  f32
    int tid = threadIdx.x;
    int tx = tid & 15, ty = tid >> 4;
    int m0 = mt * 128;
    int arow = tid >> 2, acol4 = (tid & 3) << 2;   // 64 rows x 16 cols per rep
    int brow = tid >> 4, bcol4 = (tid & 15) << 2;

    const float* Aptr = x + (size_t)(m0 + arow) * CC + acol4;
    const float* Bptr = Bw + (size_t)brow * N3 + bcol4;

    float acc[8][4] = {};
    for (int k0_ = 0; k0_ < CC; k0_ += 16) {
#pragma unroll
      for (int rep = 0; rep < 2; ++rep) {
        float4 av = *(const float4*)(Aptr + (size_t)rep * 64 * CC + k0_);
        As[acol4 + 0][arow + rep * 64] = av.x;
        As[acol4 + 1][arow + rep * 64] = av.y;
        As[acol4 + 2][arow + rep * 64] = av.z;
        As[acol4 + 3][arow + rep * 64] = av.w;
      }
      float4 bv = *(const float4*)(Bptr + (size_t)k0_ * N3);
      *(float4*)&Bs[brow][bcol4] = bv;
      __syncthreads();
#pragma unroll
      for (int kk = 0; kk < 16; ++kk) {
        float b4[4];
        *(float4*)b4 = *(const float4*)&Bs[kk][tx << 2];
#pragma unroll
        for (int ii = 0; ii < 8; ++ii) {
          float a = As[kk][ty * 8 + ii];
#pragma unroll
          for (int jj = 0; jj < 4; ++jj) acc[ii][jj] += a * b4[jj];
        }
      }
      __syncthreads();
    }
    float4 bv = *(const float4*)(b_attn + sec * CC + (tx << 2));
#pragma unroll
    for (int ii = 0; ii < 8; ++ii) {
      int m = m0 + ty * 8 + ii;
      float4 o;
      o.x = acc[ii][0] + bv.x;
      o.y = acc[ii][1] + bv.y;
      o.z = acc[ii][2] + bv.z;
      o.w = acc[ii][3] + bv.w;
      *(float4*)(Out + (size_t)m * HD + (tx << 2)) = o;
    }
    return;
  }

  // ---------------- bf16 MFMA qkv path ----------------
  unsigned short (*Alds)[128][32] = (unsigned short(*)[128][32])smem_u;
  unsigned short (*Blds)[128][32] = (unsigned short(*)[128][32])(smem_u + 8192);
  unsigned short (*Vlds)[136]     = (unsigned short(*)[136])smem_u;

  int sec = nt / 6, h0 = (nt % 6) * 2;
  int wave = threadIdx.x >> 6, lane = threadIdx.x & 63;
  int lr = lane & 15, lg = lane >> 4;
  int m0 = mt * 128;
  int n0 = nt * 128;

  int srow = lane >> 2;                 // 0..15 staging row within segment
  int sslot = (lane & 3) ^ (srow & 3);  // pre-swizzled source k-slot (16B units)

#define STAGE_AB(BUF, K0)                                                       \
  {                                                                             \
    _Pragma("unroll")                                                           \
    for (int p = 0; p < 2; ++p) {                                               \
      int ar = wave * 32 + p * 16 + srow;                                       \
      gload_lds16(xb + (size_t)(m0 + ar) * CC + (K0) + (sslot << 3),            \
                  &Alds[BUF][wave * 32 + p * 16][0]);                           \
      gload_lds16(wbT + (size_t)(n0 + ar) * CC + (K0) + (sslot << 3),           \
                  &Blds[BUF][wave * 32 + p * 16][0]);                           \
    }                                                                           \
  }

  f32x4 acc[2][8];
#pragma unroll
  for (int mi = 0; mi < 2; ++mi)
#pragma unroll
    for (int nj = 0; nj < 8; ++nj) acc[mi][nj] = (f32x4){0.f, 0.f, 0.f, 0.f};

  STAGE_AB(0, 0)
  __syncthreads();

  int fslot = lg ^ (lr & 3);  // frag read slot (same involution)
  for (int kt = 0; kt < 24; ++kt) {
    int cur = kt & 1;
    if (kt < 23) STAGE_AB(cur ^ 1, (kt + 1) * 32)
    bf16x8 af[2], bf[8];
#pragma unroll
    for (int mi = 0; mi < 2; ++mi)
      af[mi] = *(const bf16x8*)&Alds[cur][wave * 32 + mi * 16 + lr][fslot << 3];
#pragma unroll
    for (int nj = 0; nj < 8; ++nj)
      bf[nj] = *(const bf16x8*)&Blds[cur][nj * 16 + lr][fslot << 3];
    __builtin_amdgcn_s_setprio(1);
#pragma unroll
    for (int nj = 0; nj < 8; ++nj)
#pragma unroll
      for (int mi = 0; mi < 2; ++mi)
        acc[mi][nj] = __builtin_amdgcn_mfma_f32_16x16x32_bf16(af[mi], bf[nj], acc[mi][nj], 0, 0, 0);
    __builtin_amdgcn_s_setprio(0);
    __syncthreads();
  }
#undef STAGE_AB

  int b = m0 >> 11;
  float bias[8];
#pragma unroll
  for (int nj = 0; nj < 8; ++nj) bias[nj] = b_attn[n0 + nj * 16 + lr];

  if (sec < 2) {
    // Q is pre-scaled by 1/8 (exact in bf16: exponent shift only)
    float qscale = (sec == 0) ? 0.125f : 1.0f;
    unsigned short* OutB = (sec == 0 ? Qb : Kb);
    int tbase = (m0 & 2047) + wave * 32 + lg * 4;
#pragma unroll
    for (int nj = 0; nj < 8; ++nj) {
      int h = h0 + (nj >> 2);
      int d = (nj & 3) * 16 + lr;
      unsigned short* Out = OutB + (size_t)(b * NH + h) * TT * HD;
#pragma unroll
      for (int mi = 0; mi < 2; ++mi)
#pragma unroll
        for (int r = 0; r < 4; ++r) {
          int t = tbase + mi * 16 + r;
          Out[(size_t)t * HD + d] = f2b((acc[mi][nj][r] + bias[nj]) * qscale);
        }
    }
  } else {
    int tl = wave * 32 + lg * 4;
#pragma unroll
    for (int mi = 0; mi < 2; ++mi)
#pragma unroll
      for (int r = 0; r < 4; ++r)
#pragma unroll
        for (int nj = 0; nj < 8; ++nj)
          Vlds[tl + mi * 16 + r][nj * 16 + lr] = f2b(acc[mi][nj][r] + bias[nj]);
    __syncthreads();
    int d = threadIdx.x & 63, tc = threadIdx.x >> 6;
    int tblk = (m0 & 2047);
#pragma unroll
    for (int hh = 0; hh < 2; ++hh) {
      unsigned short* Ov = Vt + ((size_t)(b * NH + h0 + hh) * HD + d) * TT + tblk + tc * 32;
      int c = hh * 64 + d;
#pragma unroll
      for (int i8 = 0; i8 < 4; ++i8) {
        ushort4 o0, o1;
        o0.x = Vlds[tc * 32 + i8 * 8 + 0][c]; o0.y = Vlds[tc * 32 + i8 * 8 + 1][c];
        o0.z = Vlds[tc * 32 + i8 * 8 + 2][c]; o0.w = Vlds[tc * 32 + i8 * 8 + 3][c];
        o1.x = Vlds[tc * 32 + i8 * 8 + 4][c]; o1.y = Vlds[tc * 32 + i8 * 8 + 5][c];
        o1.z = Vlds[tc * 32 + i8 * 8 + 6][c]; o1.w = Vlds[tc * 32 + i8 * 8 + 7][c];
        *(ushort4*)(Ov + i8 * 8) = o0;
        *(ushort4*)(Ov + i8 * 8 + 4) = o1;
      }
    }
  }
}

// ---------------------------------------------------------------------------
// Head-0 scores (fp32): Sbuf[b,i,j] = relu(dot(q0,k0)/8), lower-tri tiles.
// FUSED: also emits per-64-row-chunk masked column sums into partials
// (mask = j>=1 && j<r). partials layout: [B][32][TT].
// ---------------------------------------------------------------------------
__global__ __launch_bounds__(256) void score0_kernel(
    const float* __restrict__ q0, const float* __restrict__ k0,
    float* __restrict__ Sbuf, float* __restrict__ partials) {
  int it = blockIdx.x, jt = blockIdx.y, b = blockIdx.z;
  int tid = threadIdx.x;
  int i0 = it * 64, j0 = jt * 64;
  if (jt > it) {  // mask kills everything above the diagonal
    if (tid < 64) partials[((size_t)(b * 32 + it)) * TT + j0 + tid] = 0.f;
    return;
  }
  __shared__ float Qs[64][64];
  __shared__ float Ks[64][64];
  int row = tid >> 2;
  int dq = (tid & 3) << 2;
  const float* qb = q0 + (size_t)((b * TT) + i0 + row) * HD;
  const float* kb = k0 + (size_t)((b * TT) + j0 + row) * HD;
#pragma unroll
  for (int rep = 0; rep < 4; ++rep) {
    int d = dq + rep * 16;
    float4 qv = *(const float4*)(qb + d);
    float4 kv = *(const float4*)(kb + d);
    Qs[d + 0][row] = qv.x; Qs[d + 1][row] = qv.y;
    Qs[d + 2][row] = qv.z; Qs[d + 3][row] = qv.w;
    Ks[d + 0][row] = kv.x; Ks[d + 1][row] = kv.y;
    Ks[d + 2][row] = kv.z; Ks[d + 3][row] = kv.w;
  }
  __syncthreads();
  int tx = tid & 15, ty = tid >> 4;
  float acc[4][4] = {};
#pragma unroll 8
  for (int kk = 0; kk < 64; ++kk) {
    float4 a4 = *(const float4*)&Qs[kk][ty << 2];
    float4 b4 = *(const float4*)&Ks[kk][tx << 2];
    float a[4] = {a4.x, a4.y, a4.z, a4.w};
    float b[4] = {b4.x, b4.y, b4.z, b4.w};
#pragma unroll
    for (int ii = 0; ii < 4; ++ii)
#pragma unroll
      for (int jj = 0; jj < 4; ++jj) acc[ii][jj] += a[ii] * b[jj];
  }
  float red4[4] = {0.f, 0.f, 0.f, 0.f};
#pragma unroll
  for (int ii = 0; ii < 4; ++ii) {
    int r = i0 + (ty << 2) + ii;           // global row (within T)
    int gi = (b * TT) + r;
    float ov[4];
#pragma unroll
    for (int jj = 0; jj < 4; ++jj) {
      ov[jj] = fmaxf(acc[ii][jj] * 0.125f, 0.f);
      int j = j0 + (tx << 2) + jj;
      if (j >= 1 && j < r) red4[jj] += ov[jj];
    }
    float4 o; o.x = ov[0]; o.y = ov[1]; o.z = ov[2]; o.w = ov[3];
    *(float4*)(Sbuf + (size_t)gi * TT + j0 + (tx << 2)) = o;
  }
  // reduce the 16 ty-groups per column via reused LDS
  __syncthreads();  // everyone done reading Qs
  *(float4*)&Qs[ty][tx << 2] = *(float4*)red4;
  __syncthreads();
  if (tid < 64) {
    float cs = 0.f;
#pragma unroll
    for (int t = 0; t < 16; ++t) cs += Qs[t][tid];
    partials[((size_t)(b * 32 + it)) * TT + j0 + tid] = cs;
  }
}

// ---------------------------------------------------------------------------
// Column-wise exclusive prefix scan over rows (64-row chunks; partial sums
// fused from score0). Emits E = exp(-FF) bf16 with the j-swizzled layout
// (within each 64-col tile: j -> ((j&15)<<2)|((j>>4)&3)) and per-jblock
// row sums of clip(FF,0,1) into ffpart[B][8][TT]. 8-row load batching.
// ---------------------------------------------------------------------------
__global__ __launch_bounds__(256) void scan_write(
    const float* __restrict__ Sbuf, const float* __restrict__ partials,
    unsigned short* __restrict__ Eb, float* __restrict__ ffpart) {
  int j = blockIdx.x * 256 + threadIdx.x;
  int chunk = blockIdx.y, b = blockIdx.z;
  float run = 0.f;
  for (int c = 0; c < chunk; ++c) run += partials[((size_t)(b * 32 + c)) * TT + j];
  int r0 = chunk * 64;
  int jswz = (j & ~63) | ((j & 15) << 2) | ((j >> 4) & 3);
  const float* base = Sbuf + (size_t)(b * TT + r0) * TT + j;
  unsigned short* ebase = Eb + (size_t)(b * TT + r0) * TT + jswz;
  __shared__ float wsum[4][64];
  int wv = threadIdx.x >> 6;
  for (int rb = 0; rb < 64; rb += 8) {
    float v[8];
#pragma unroll
    for (int u = 0; u < 8; ++u) {
      int r = r0 + rb + u;
      v[u] = (j >= 1 && j < r) ? base[(size_t)(rb + u) * TT] : 0.f;
    }
#pragma unroll
    for (int u = 0; u < 8; ++u) {
      int rr = rb + u;
      ebase[(size_t)rr * TT] = f2b(__expf(-run));  // E (bf16, natural-e)
      float c1 = fminf(run, 1.f);                  // run >= 0 always
#pragma unroll
      for (int o = 1; o < 64; o <<= 1) c1 += __shfl_xor(c1, o);
      if ((threadIdx.x & 63) == 0) wsum[wv][rr] = c1;
      run += v[u];
    }
  }
  __syncthreads();
  if (threadIdx.x < 64)
    ffpart[((size_t)(b * 8) + blockIdx.x) * TT + r0 + threadIdx.x] =
        wsum[0][threadIdx.x] + wsum[1][threadIdx.x] +
        wsum[2][threadIdx.x] + wsum[3][threadIdx.x];
}

// ---------------------------------------------------------------------------
// bf16 MFMA flash attention (R9-exact measured-best form) + CU-load-balanced
// g4 permutation: consecutive dispatch waves alternate heavy/light q-blocks
// so each CU's 3 resident blocks sum to ~uniform work.
// Grid (24, 32): XCD = x%8 serves one batch / 3 heads (L2 locality).
// ---------------------------------------------------------------------------
__global__ __launch_bounds__(256, 3) void attn_mfma(
    const unsigned short* __restrict__ Qb, const unsigned short* __restrict__ Kb,
    const unsigned short* __restrict__ Vt, const unsigned short* __restrict__ Eb,
    unsigned short* __restrict__ yhb) {
  int xbh = blockIdx.x;
  int b = (xbh >> 2) & 1;
  int h = ((xbh >> 3) << 2) | (xbh & 3);
  int yy = blockIdx.y;
  int g4 = (yy & 1) ? (yy >> 1) : (31 - (yy >> 1));  // balanced interleave
  int wave = threadIdx.x >> 6, lane = threadIdx.x & 63;
  int lr = lane & 15, lg = lane >> 4;
  int i0 = g4 * 64 + wave * 16;
  int bh = b * NH + h;
  const unsigned short* Qh = Qb + (size_t)bh * TT * HD;
  const unsigned short* Kh = Kb + (size_t)bh * TT * HD;
  const unsigned short* Vh = Vt + (size_t)bh * HD * TT;
  const unsigned short* Erow = Eb + ((size_t)(b * TT) + i0 + lg * 4) * TT + 4 * lr;

  __shared__ __align__(16) unsigned short Ksh[2][64][64];
  __shared__ __align__(16) unsigned short Vsh[2][64][64];
  __shared__ __align__(16) unsigned short Plds[4][16][80];

  int rowoff = lane >> 3;            // 0..7 within an 8-row staging segment
  int sslot  = (lane & 7) ^ rowoff;  // pre-swizzled source slot (16B units)

  bf16x8 qf[2];
#pragma unroll
  for (int ks = 0; ks < 2; ++ks)
    qf[ks] = *(const bf16x8*)(Qh + (size_t)(i0 + lr) * HD + ks * 32 + lg * 8);

  f32x4 acc[4];
  float lrun[4] = {0.f, 0.f, 0.f, 0.f};  // per-lane partial of softmax denom
#pragma unroll
  for (int q = 0; q < 4; ++q) acc[q] = (f32x4){0.f, 0.f, 0.f, 0.f};

#define STAGE_KV(BUF, J0)                                                      \
  {                                                                            \
    _Pragma("unroll")                                                          \
    for (int p = 0; p < 2; ++p) {                                              \
      int r0 = wave * 16 + p * 8;                                              \
      gload_lds16(Kh + (size_t)((J0) + r0 + rowoff) * HD + sslot * 8,          \
                  &Ksh[BUF][r0][0]);                                           \
      gload_lds16(Vh + (size_t)(r0 + rowoff) * TT + (J0) + sslot * 8,          \
                  &Vsh[BUF][r0][0]);                                           \
    }                                                                          \
  }

  STAGE_KV(0, 0)
  __syncthreads();

  for (int kt = 0; kt <= g4; ++kt) {
    int cur = kt & 1;
    int j0 = kt * 64;
    if (kt < g4) STAGE_KV(cur ^ 1, j0 + 64)

    // E for current tile (4 x 8B vector loads, swizzled layout)
    ushort4 ev[4];
#pragma unroll
    for (int r = 0; r < 4; ++r)
      ev[r] = *(const ushort4*)(Erow + (size_t)r * TT + j0);

    // ---- QK^T from swizzled LDS ----
    f32x4 s[4];
    __builtin_amdgcn_s_setprio(1);
#pragma unroll
    for (int nj = 0; nj < 4; ++nj) {
      int row = nj * 16 + lr;
      int sw = row & 7;
      bf16x8 k0f = *(const bf16x8*)&Ksh[cur][row][(lg ^ sw) << 3];
      bf16x8 k1f = *(const bf16x8*)&Ksh[cur][row][((4 + lg) ^ sw) << 3];
      f32x4 z = (f32x4){0.f, 0.f, 0.f, 0.f};
      z = __builtin_amdgcn_mfma_f32_16x16x32_bf16(qf[0], k0f, z, 0, 0, 0);
      s[nj] = __builtin_amdgcn_mfma_f32_16x16x32_bf16(qf[1], k1f, z, 0, 0, 0);
    }
    __builtin_amdgcn_s_setprio(0);

    // ---- causal mask (diagonal tile only) ----
    int ibase = i0 + lg * 4;
    if (kt == g4) {
#pragma unroll
      for (int nj = 0; nj < 4; ++nj)
#pragma unroll
        for (int r = 0; r < 4; ++r)
          if (j0 + nj * 16 + lr > ibase + r) s[nj][r] = -1e30f;
    }

    // ---- P = E * exp(s); per-lane partial l; stash bf16 P in LDS ----
#pragma unroll
    for (int r = 0; r < 4; ++r) {
      float p0 = b2f(ev[r].x) * __expf(s[0][r]);
      float p1 = b2f(ev[r].y) * __expf(s[1][r]);
      float p2 = b2f(ev[r].z) * __expf(s[2][r]);
      float p3 = b2f(ev[r].w) * __expf(s[3][r]);
      lrun[r] += (p0 + p1) + (p2 + p3);
      Plds[wave][lg * 4 + r][0 * 16 + lr] = f2b(p0);
      Plds[wave][lg * 4 + r][1 * 16 + lr] = f2b(p1);
      Plds[wave][lg * 4 + r][2 * 16 + lr] = f2b(p2);
      Plds[wave][lg * 4 + r][3 * 16 + lr] = f2b(p3);
    }

    // ---- PV from swizzled LDS ----
    bf16x8 pa0 = *(const bf16x8*)&Plds[wave][lr][lg * 8];
    bf16x8 pa1 = *(const bf16x8*)&Plds[wave][lr][32 + lg * 8];
    __builtin_amdgcn_s_setprio(1);
#pragma unroll
    for (int nd = 0; nd < 4; ++nd) {
      int row = nd * 16 + lr;
      int sw = row & 7;
      bf16x8 v0f = *(const bf16x8*)&Vsh[cur][row][(lg ^ sw) << 3];
      bf16x8 v1f = *(const bf16x8*)&Vsh[cur][row][((4 + lg) ^ sw) << 3];
      acc[nd] = __builtin_amdgcn_mfma_f32_16x16x32_bf16(pa0, v0f, acc[nd], 0, 0, 0);
      acc[nd] = __builtin_amdgcn_mfma_f32_16x16x32_bf16(pa1, v1f, acc[nd], 0, 0, 0);
    }
    __builtin_amdgcn_s_setprio(0);

    __syncthreads();
  }
#undef STAGE_KV

  // ---- epilogue: one l-reduction across the 16 lr lanes, then store ----
#pragma unroll
  for (int r = 0; r < 4; ++r) {
    lrun[r] += __shfl_xor(lrun[r], 1);
    lrun[r] += __shfl_xor(lrun[r], 2);
    lrun[r] += __shfl_xor(lrun[r], 4);
    lrun[r] += __shfl_xor(lrun[r], 8);
    float inv = 1.f / lrun[r];
    int ig = i0 + lg * 4 + r;
    unsigned short* ob = yhb + (size_t)(b * TT + ig) * CC + h * HD;
#pragma unroll
    for (int nd = 0; nd < 4; ++nd)
      ob[nd * 16 + lr] = f2b(acc[nd][r] * inv);
  }
}

// ---------------------------------------------------------------------------
// FUSED proj GEMM + M writer (1D grid, 1408 blocks):
//   bid < 384 : y = yhb @ wpT^T + b_proj (128x64 MFMA tile)
//   else      : M[0,b,i,j] = i - sum_jb ffpart[b][jb][j] (float4, grid-stride)
// M's pure HBM-store traffic overlaps the proj blocks' MFMA work.
// ---------------------------------------------------------------------------
__global__ __launch_bounds__(256, 3) void proj_m_fused(
    const unsigned short* __restrict__ yhb, const unsigned short* __restrict__ wpT,
    const float* __restrict__ b_proj, float* __restrict__ y,
    const float* __restrict__ ffpart, float* __restrict__ Mout) {
  int bid = blockIdx.x;
  if (bid >= 384) {
    int idx4 = (bid - 384) * 256 + threadIdx.x;
    int stride = (gridDim.x - 384) * 256;
    for (; idx4 < M_ELEMS / 4; idx4 += stride) {
      int idx = idx4 << 2;
      int j = idx & (TT - 1);
      int i = (idx >> 11) & (TT - 1);
      int b = idx >> 22;
      const float* fp = ffpart + ((size_t)(b * 8)) * TT + j;
      float4 s = make_float4(0.f, 0.f, 0.f, 0.f);
#pragma unroll
      for (int p = 0; p < 8; ++p) {
        float4 v = *(const float4*)(fp + (size_t)p * TT);
        s.x += v.x; s.y += v.y; s.z += v.z; s.w += v.w;
      }
      float fi = (float)i;
      float4 o = make_float4(fi - s.x, fi - s.y, fi - s.z, fi - s.w);
      *(float4*)(Mout + idx) = o;
    }
    return;
  }
  __shared__ __align__(16) unsigned short Alds[2][128][32];
  __shared__ __align__(16) unsigned short Blds[2][64][32];
  int mt = bid & 31, nt = bid >> 5;
  int wave = threadIdx.x >> 6, lane = threadIdx.x & 63;
  int lr = lane & 15, lg = lane >> 4;
  int m0 = mt * 128;
  int n0 = nt * 64;

  int srow = lane >> 2;
  int sslot = (lane & 3) ^ (srow & 3);

#define STAGE_AB(BUF, K0)                                                       \
  {                                                                             \
    _Pragma("unroll")                                                           \
    for (int p = 0; p < 2; ++p) {                                               \
      int ar = wave * 32 + p * 16 + srow;                                       \
      gload_lds16(yhb + (size_t)(m0 + ar) * CC + (K0) + (sslot << 3),           \
                  &Alds[BUF][wave * 32 + p * 16][0]);                           \
    }                                                                           \
    int br = wave * 16 + srow;                                                  \
    gload_lds16(wpT + (size_t)(n0 + br) * CC + (K0) + (sslot << 3),             \
                &Blds[BUF][wave * 16][0]);                                      \
  }

  f32x4 acc[2][4];
#pragma unroll
  for (int mi = 0; mi < 2; ++mi)
#pragma unroll
    for (int nj = 0; nj < 4; ++nj) acc[mi][nj] = (f32x4){0.f, 0.f, 0.f, 0.f};

  STAGE_AB(0, 0)
  __syncthreads();

  int fslot = lg ^ (lr & 3);
  for (int kt = 0; kt < 24; ++kt) {
    int cur = kt & 1;
    if (kt < 23) STAGE_AB(cur ^ 1, (kt + 1) * 32)
    bf16x8 af[2], bf[4];
#pragma unroll
    for (int mi = 0; mi < 2; ++mi)
      af[mi] = *(const bf16x8*)&Alds[cur][wave * 32 + mi * 16 + lr][fslot << 3];
#pragma unroll
    for (int nj = 0; nj < 4; ++nj)
      bf[nj] = *(const bf16x8*)&Blds[cur][nj * 16 + lr][fslot << 3];
    __builtin_amdgcn_s_setprio(1);
#pragma unroll
    for (int nj = 0; nj < 4; ++nj)
#pragma unroll
      for (int mi = 0; mi < 2; ++mi)
        acc[mi][nj] = __builtin_amdgcn_mfma_f32_16x16x32_bf16(af[mi], bf[nj], acc[mi][nj], 0, 0, 0);
    __builtin_amdgcn_s_setprio(0);
    __syncthreads();
  }
#undef STAGE_AB

  float bias[4];
#pragma unroll
  for (int nj = 0; nj < 4; ++nj) bias[nj] = b_proj[n0 + nj * 16 + lr];
#pragma unroll
  for (int mi = 0; mi < 2; ++mi)
#pragma unroll
    for (int r = 0; r < 4; ++r) {
      int m = m0 + wave * 32 + mi * 16 + lg * 4 + r;
#pragma unroll
      for (int nj = 0; nj < 4; ++nj)
        y[(size_t)m * CC + n0 + nj * 16 + lr] = acc[mi][nj][r] + bias[nj];
    }
}

// ---------------------------------------------------------------------------
extern "C" void kernel_launch(void* const* d_in, const int* in_sizes, int n_in,
                              void* d_out, int out_size, void* d_ws, size_t ws_size,
                              hipStream_t stream) {
  const float* x      = (const float*)d_in[0];
  const float* w_attn = (const float*)d_in[1];
  const float* b_attn = (const float*)d_in[2];
  const float* w_proj = (const float*)d_in[3];
  const float* b_proj = (const float*)d_in[4];

  float* y    = (float*)d_out;          // [B,T,C]
  float* Mreg = y + Y_ELEMS;            // [B,T,T]: S0 (scratch) -> M (final)

  float* ws = (float*)d_ws;
  float* q0       = ws;                               // B*T*64
  float* k0       = q0 + (size_t)BB * TT * HD;
  float* partials = k0 + (size_t)BB * TT * HD;        // B*32*T
  float* ffpart   = partials + (size_t)BB * 32 * TT;  // B*8*T
  unsigned short* xb  = (unsigned short*)(ffpart + (size_t)BB * 8 * TT);  // B*T*C
  unsigned short* wbT = xb + (size_t)Y_ELEMS;                 // 2304*768
  unsigned short* wpT = wbT + (size_t)N3 * CC;                // 768*768
  unsigned short* Qb  = wpT + (size_t)CC * CC;                // B*NH*T*HD
  unsigned short* Kb  = Qb + (size_t)BB * NH * TT * HD;
  unsigned short* Vt  = Kb + (size_t)BB * NH * TT * HD;
  unsigned short* yhb = Vt + (size_t)BB * NH * TT * HD;       // B*T*C
  unsigned short* Eb  = yhb + (size_t)Y_ELEMS;                // B*T*T bf16 (16.8MB)
  // total ws usage ~= 46 MB

  // 1. fused packs: x -> bf16; w_attn/w_proj -> transposed bf16
  prep_fused<<<2112, 256, 0, stream>>>(x, w_attn, w_proj, xb, wbT, wpT);
  // 2. fused QKV MFMA GEMM + fp32 head-0 q,k (co-scheduled VALU/MFMA)
  gemm_qkv_fused<<<dim3(32, 20), 256, 0, stream>>>(
      xb, wbT, b_attn, Qb, Kb, Vt, x, w_attn, q0, k0);
  // 3. head-0 scores (fp32) into Mreg + fused per-chunk column partial sums
  score0_kernel<<<dim3(32, 32, BB), 256, 0, stream>>>(q0, k0, Mreg, partials);
  // 4. scan: E = exp(-FF) bf16 (jswz) + ffpart row sums (batched loads)
  scan_write<<<dim3(8, 32, BB), 256, 0, stream>>>(Mreg, partials, Eb, ffpart);
  // 5. MFMA flash attention (R9 form + balanced g4 permutation)
  attn_mfma<<<dim3(24, 32), 256, 0, stream>>>(Qb, Kb, Vt, Eb, yhb);
  // 6. fused proj GEMM + M writer (M's store traffic overlaps proj MFMA)
  proj_m_fused<<<1408, 256, 0, stream>>>(yhb, wpT, b_proj, y, ffpart, Mreg);
}

// Round 15
// 177.316 us; speedup vs baseline: 2.8470x; 1.0795x over previous
//
#include <hip/hip_runtime.h>
#include <cstddef>

// Problem constants
#define TT 2048
#define BB 2
#define CC 768
#define NH 12
#define HD 64
#define N3 2304          // 3*NH*HD
#define Y_ELEMS (BB*TT*CC)          // 3145728
#define M_ELEMS (BB*TT*TT)          // 8388608

typedef __attribute__((ext_vector_type(8))) short bf16x8;
typedef __attribute__((ext_vector_type(4))) float f32x4;

__device__ inline unsigned short f2b(float f) {
  union { float f; unsigned u; } v; v.f = f;
  unsigned r = (v.u + 0x7FFFu + ((v.u >> 16) & 1u)) >> 16;
  return (unsigned short)r;
}
__device__ inline float b2f(unsigned short u) {
  union { unsigned u; float f; } v; v.u = (unsigned)u << 16; return v.f;
}

// async global -> LDS, 16B per lane; lds dest is wave-uniform base, HW adds lane*16
__device__ inline void gload_lds16(const unsigned short* g, unsigned short* l) {
  __builtin_amdgcn_global_load_lds(
      (const __attribute__((address_space(1))) unsigned int*)g,
      (__attribute__((address_space(3))) unsigned int*)l, 16, 0, 0);
}

// ---------------------------------------------------------------------------
// FUSED prep kernel (1D grid, 2112 blocks):
//   bid <  1536 : pack x (fp32 -> bf16), 8 elems/thread
//   bid <  1968 : transpose-pack w_attn -> wbT [N3][768] bf16
//   else        : transpose-pack w_proj -> wpT [768][768] bf16
// ---------------------------------------------------------------------------
__global__ __launch_bounds__(256) void prep_fused(
    const float* __restrict__ x, const float* __restrict__ w_attn,
    const float* __restrict__ w_proj,
    unsigned short* __restrict__ xb, unsigned short* __restrict__ wbT,
    unsigned short* __restrict__ wpT) {
  int bid = blockIdx.x;
  int tid = threadIdx.x;
  if (bid < 1536) {
    size_t i = ((size_t)bid * 256 + tid) * 8;
    float4 a = *(const float4*)(x + i);
    float4 b = *(const float4*)(x + i + 4);
    ushort4 o0, o1;
    o0.x = f2b(a.x); o0.y = f2b(a.y); o0.z = f2b(a.z); o0.w = f2b(a.w);
    o1.x = f2b(b.x); o1.y = f2b(b.y); o1.z = f2b(b.z); o1.w = f2b(b.w);
    *(ushort4*)(xb + i) = o0;
    *(ushort4*)(xb + i + 4) = o1;
    return;
  }
  const float* W;
  unsigned short* WT;
  int N, kt, nt;
  if (bid < 1968) {
    int t = bid - 1536;
    W = w_attn; WT = wbT; N = N3;
    kt = t % 12; nt = t / 12;
  } else {
    int t = bid - 1968;
    W = w_proj; WT = wpT; N = CC;
    kt = t % 12; nt = t / 12;
  }
  __shared__ float tile[64][65];
  int r = tid >> 4, c4 = (tid & 15) << 2;
#pragma unroll
  for (int rep = 0; rep < 4; ++rep) {
    int row = rep * 16 + r;
    float4 v = *(const float4*)(W + (size_t)(kt * 64 + row) * N + nt * 64 + c4);
    tile[row][c4 + 0] = v.x; tile[row][c4 + 1] = v.y;
    tile[row][c4 + 2] = v.z; tile[row][c4 + 3] = v.w;
  }
  __syncthreads();
#pragma unroll
  for (int rep = 0; rep < 4; ++rep) {
    int nrow = rep * 16 + r;
    ushort4 o;
    o.x = f2b(tile[c4 + 0][nrow]); o.y = f2b(tile[c4 + 1][nrow]);
    o.z = f2b(tile[c4 + 2][nrow]); o.w = f2b(tile[c4 + 3][nrow]);
    *(ushort4*)(WT + (size_t)(nt * 64 + nrow) * CC + kt * 64 + c4) = o;
  }
}

// ---------------------------------------------------------------------------
// bf16 MFMA GEMM: qkv = xb @ wbT^T + b_attn -> packed Qb (pre-scaled 1/8),
// Kb, Vt (transposed via LDS). 128x128 tiles: grid (32, 18).
// LDS-staged dbuf, slot-swizzled. Vlds epilogue UNION-overlaid on A/B bufs.
// ---------------------------------------------------------------------------
__global__ __launch_bounds__(256, 3) void gemm_qkv_bf16(
    const unsigned short* __restrict__ xb, const unsigned short* __restrict__ wbT,
    const float* __restrict__ b_attn,
    unsigned short* __restrict__ Qb, unsigned short* __restrict__ Kb,
    unsigned short* __restrict__ Vt) {
  __shared__ __align__(16) unsigned short smem_u[17408];  // 34816 B
  unsigned short (*Alds)[128][32] = (unsigned short(*)[128][32])smem_u;
  unsigned short (*Blds)[128][32] = (unsigned short(*)[128][32])(smem_u + 8192);
  unsigned short (*Vlds)[136]     = (unsigned short(*)[136])smem_u;

  int mt = blockIdx.x, nt = blockIdx.y;
  int sec = nt / 6, h0 = (nt % 6) * 2;
  int wave = threadIdx.x >> 6, lane = threadIdx.x & 63;
  int lr = lane & 15, lg = lane >> 4;
  int m0 = mt * 128;
  int n0 = nt * 128;

  int srow = lane >> 2;                 // 0..15 staging row within segment
  int sslot = (lane & 3) ^ (srow & 3);  // pre-swizzled source k-slot (16B units)

#define STAGE_AB(BUF, K0)                                                       \
  {                                                                             \
    _Pragma("unroll")                                                           \
    for (int p = 0; p < 2; ++p) {                                               \
      int ar = wave * 32 + p * 16 + srow;                                       \
      gload_lds16(xb + (size_t)(m0 + ar) * CC + (K0) + (sslot << 3),            \
                  &Alds[BUF][wave * 32 + p * 16][0]);                           \
      gload_lds16(wbT + (size_t)(n0 + ar) * CC + (K0) + (sslot << 3),           \
                  &Blds[BUF][wave * 32 + p * 16][0]);                           \
    }                                                                           \
  }

  f32x4 acc[2][8];
#pragma unroll
  for (int mi = 0; mi < 2; ++mi)
#pragma unroll
    for (int nj = 0; nj < 8; ++nj) acc[mi][nj] = (f32x4){0.f, 0.f, 0.f, 0.f};

  STAGE_AB(0, 0)
  __syncthreads();

  int fslot = lg ^ (lr & 3);  // frag read slot (same involution)
  for (int kt = 0; kt < 24; ++kt) {
    int cur = kt & 1;
    if (kt < 23) STAGE_AB(cur ^ 1, (kt + 1) * 32)
    bf16x8 af[2], bf[8];
#pragma unroll
    for (int mi = 0; mi < 2; ++mi)
      af[mi] = *(const bf16x8*)&Alds[cur][wave * 32 + mi * 16 + lr][fslot << 3];
#pragma unroll
    for (int nj = 0; nj < 8; ++nj)
      bf[nj] = *(const bf16x8*)&Blds[cur][nj * 16 + lr][fslot << 3];
    __builtin_amdgcn_s_setprio(1);
#pragma unroll
    for (int nj = 0; nj < 8; ++nj)
#pragma unroll
      for (int mi = 0; mi < 2; ++mi)
        acc[mi][nj] = __builtin_amdgcn_mfma_f32_16x16x32_bf16(af[mi], bf[nj], acc[mi][nj], 0, 0, 0);
    __builtin_amdgcn_s_setprio(0);
    __syncthreads();
  }
#undef STAGE_AB

  int b = m0 >> 11;
  float bias[8];
#pragma unroll
  for (int nj = 0; nj < 8; ++nj) bias[nj] = b_attn[n0 + nj * 16 + lr];

  if (sec < 2) {
    // Q is pre-scaled by 1/8 (exact in bf16: exponent shift only)
    float qscale = (sec == 0) ? 0.125f : 1.0f;
    unsigned short* OutB = (sec == 0 ? Qb : Kb);
    int tbase = (m0 & 2047) + wave * 32 + lg * 4;
#pragma unroll
    for (int nj = 0; nj < 8; ++nj) {
      int h = h0 + (nj >> 2);
      int d = (nj & 3) * 16 + lr;
      unsigned short* Out = OutB + (size_t)(b * NH + h) * TT * HD;
#pragma unroll
      for (int mi = 0; mi < 2; ++mi)
#pragma unroll
        for (int r = 0; r < 4; ++r) {
          int t = tbase + mi * 16 + r;
          Out[(size_t)t * HD + d] = f2b((acc[mi][nj][r] + bias[nj]) * qscale);
        }
    }
  } else {
    int tl = wave * 32 + lg * 4;
#pragma unroll
    for (int mi = 0; mi < 2; ++mi)
#pragma unroll
      for (int r = 0; r < 4; ++r)
#pragma unroll
        for (int nj = 0; nj < 8; ++nj)
          Vlds[tl + mi * 16 + r][nj * 16 + lr] = f2b(acc[mi][nj][r] + bias[nj]);
    __syncthreads();
    int d = threadIdx.x & 63, tc = threadIdx.x >> 6;
    int tblk = (m0 & 2047);
#pragma unroll
    for (int hh = 0; hh < 2; ++hh) {
      unsigned short* Ov = Vt + ((size_t)(b * NH + h0 + hh) * HD + d) * TT + tblk + tc * 32;
      int c = hh * 64 + d;
#pragma unroll
      for (int i8 = 0; i8 < 4; ++i8) {
        ushort4 o0, o1;
        o0.x = Vlds[tc * 32 + i8 * 8 + 0][c]; o0.y = Vlds[tc * 32 + i8 * 8 + 1][c];
        o0.z = Vlds[tc * 32 + i8 * 8 + 2][c]; o0.w = Vlds[tc * 32 + i8 * 8 + 3][c];
        o1.x = Vlds[tc * 32 + i8 * 8 + 4][c]; o1.y = Vlds[tc * 32 + i8 * 8 + 5][c];
        o1.z = Vlds[tc * 32 + i8 * 8 + 6][c]; o1.w = Vlds[tc * 32 + i8 * 8 + 7][c];
        *(ushort4*)(Ov + i8 * 8) = o0;
        *(ushort4*)(Ov + i8 * 8 + 4) = o1;
      }
    }
  }
}

// ---------------------------------------------------------------------------
// fp32 GEMM for head-0 q,k only (precision-critical FF path).
// 32x64 tiles, grid (128, 2) = 256 blocks.
// ---------------------------------------------------------------------------
__global__ __launch_bounds__(256) void sgemm_qk0(
    const float* __restrict__ x, const float* __restrict__ w_attn,
    const float* __restrict__ b_attn, float* __restrict__ q0,
    float* __restrict__ k0) {
  __shared__ float As[16][32];
  __shared__ float Bs[16][64];
  int sec = blockIdx.y;
  const float* Bw = w_attn + sec * CC;
  float* Out = sec ? k0 : q0;
  int tid = threadIdx.x;
  int tx = tid & 15, ty = tid >> 4;   // ty 0..15 (2 rows each), tx*4 cols
  int m0 = blockIdx.x * 32;

  int arow = tid >> 3;                // 0..31
  int acol2 = (tid & 7) << 1;         // 0,2,..,14
  int brow = tid >> 4;                // 0..15
  int bcol4 = (tid & 15) << 2;        // 0..60

  const float* Aptr = x + (size_t)(m0 + arow) * CC + acol2;
  const float* Bptr = Bw + (size_t)brow * N3 + bcol4;

  float acc[2][4] = {};

  for (int k0_ = 0; k0_ < CC; k0_ += 16) {
    float2 av = *(const float2*)(Aptr + k0_);
    float4 bv = *(const float4*)(Bptr + (size_t)k0_ * N3);
    As[acol2 + 0][arow] = av.x;
    As[acol2 + 1][arow] = av.y;
    *(float4*)&Bs[brow][bcol4] = bv;
    __syncthreads();
#pragma unroll
    for (int kk = 0; kk < 16; ++kk) {
      float2 a2 = *(const float2*)&As[kk][ty << 1];
      float4 b4 = *(const float4*)&Bs[kk][tx << 2];
      float a[2] = {a2.x, a2.y};
      float b[4] = {b4.x, b4.y, b4.z, b4.w};
#pragma unroll
      for (int ii = 0; ii < 2; ++ii)
#pragma unroll
        for (int jj = 0; jj < 4; ++jj) acc[ii][jj] += a[ii] * b[jj];
    }
    __syncthreads();
  }

  float4 bv = *(const float4*)(b_attn + sec * CC + (tx << 2));
#pragma unroll
  for (int ii = 0; ii < 2; ++ii) {
    int m = m0 + (ty << 1) + ii;
    float4 o;
    o.x = acc[ii][0] + bv.x;
    o.y = acc[ii][1] + bv.y;
    o.z = acc[ii][2] + bv.z;
    o.w = acc[ii][3] + bv.w;
    *(float4*)(Out + (size_t)m * HD + (tx << 2)) = o;
  }
}

// ---------------------------------------------------------------------------
// Head-0 scores (fp32): Sbuf[b,i,j] = relu(dot(q0,k0)/8), lower-tri tiles.
// FUSED: also emits per-64-row-chunk masked column sums into partials
// (mask = j>=1 && j<r). partials layout: [B][32][TT].
// ---------------------------------------------------------------------------
__global__ __launch_bounds__(256) void score0_kernel(
    const float* __restrict__ q0, const float* __restrict__ k0,
    float* __restrict__ Sbuf, float* __restrict__ partials) {
  int it = blockIdx.x, jt = blockIdx.y, b = blockIdx.z;
  int tid = threadIdx.x;
  int i0 = it * 64, j0 = jt * 64;
  if (jt > it) {  // mask kills everything above the diagonal
    if (tid < 64) partials[((size_t)(b * 32 + it)) * TT + j0 + tid] = 0.f;
    return;
  }
  __shared__ float Qs[64][64];
  __shared__ float Ks[64][64];
  int row = tid >> 2;
  int dq = (tid & 3) << 2;
  const float* qb = q0 + (size_t)((b * TT) + i0 + row) * HD;
  const float* kb = k0 + (size_t)((b * TT) + j0 + row) * HD;
#pragma unroll
  for (int rep = 0; rep < 4; ++rep) {
    int d = dq + rep * 16;
    float4 qv = *(const float4*)(qb + d);
    float4 kv = *(const float4*)(kb + d);
    Qs[d + 0][row] = qv.x; Qs[d + 1][row] = qv.y;
    Qs[d + 2][row] = qv.z; Qs[d + 3][row] = qv.w;
    Ks[d + 0][row] = kv.x; Ks[d + 1][row] = kv.y;
    Ks[d + 2][row] = kv.z; Ks[d + 3][row] = kv.w;
  }
  __syncthreads();
  int tx = tid & 15, ty = tid >> 4;
  float acc[4][4] = {};
#pragma unroll 8
  for (int kk = 0; kk < 64; ++kk) {
    float4 a4 = *(const float4*)&Qs[kk][ty << 2];
    float4 b4 = *(const float4*)&Ks[kk][tx << 2];
    float a[4] = {a4.x, a4.y, a4.z, a4.w};
    float b[4] = {b4.x, b4.y, b4.z, b4.w};
#pragma unroll
    for (int ii = 0; ii < 4; ++ii)
#pragma unroll
      for (int jj = 0; jj < 4; ++jj) acc[ii][jj] += a[ii] * b[jj];
  }
  float red4[4] = {0.f, 0.f, 0.f, 0.f};
#pragma unroll
  for (int ii = 0; ii < 4; ++ii) {
    int r = i0 + (ty << 2) + ii;           // global row (within T)
    int gi = (b * TT) + r;
    float ov[4];
#pragma unroll
    for (int jj = 0; jj < 4; ++jj) {
      ov[jj] = fmaxf(acc[ii][jj] * 0.125f, 0.f);
      int j = j0 + (tx << 2) + jj;
      if (j >= 1 && j < r) red4[jj] += ov[jj];
    }
    float4 o; o.x = ov[0]; o.y = ov[1]; o.z = ov[2]; o.w = ov[3];
    *(float4*)(Sbuf + (size_t)gi * TT + j0 + (tx << 2)) = o;
  }
  // reduce the 16 ty-groups per column via reused LDS
  __syncthreads();  // everyone done reading Qs
  *(float4*)&Qs[ty][tx << 2] = *(float4*)red4;
  __syncthreads();
  if (tid < 64) {
    float cs = 0.f;
#pragma unroll
    for (int t = 0; t < 16; ++t) cs += Qs[t][tid];
    partials[((size_t)(b * 32 + it)) * TT + j0 + tid] = cs;
  }
}

// ---------------------------------------------------------------------------
// Column-wise exclusive prefix scan over rows (64-row chunks; partial sums
// fused from score0). Emits E = exp(-FF) bf16 with the j-swizzled layout
// (within each 64-col tile: j -> ((j&15)<<2)|((j>>4)&3)) and per-jblock
// row sums of clip(FF,0,1) into ffpart[B][8][TT]. 8-row load batching.
// ---------------------------------------------------------------------------
__global__ __launch_bounds__(256) void scan_write(
    const float* __restrict__ Sbuf, const float* __restrict__ partials,
    unsigned short* __restrict__ Eb, float* __restrict__ ffpart) {
  int j = blockIdx.x * 256 + threadIdx.x;
  int chunk = blockIdx.y, b = blockIdx.z;
  float run = 0.f;
  for (int c = 0; c < chunk; ++c) run += partials[((size_t)(b * 32 + c)) * TT + j];
  int r0 = chunk * 64;
  int jswz = (j & ~63) | ((j & 15) << 2) | ((j >> 4) & 3);
  const float* base = Sbuf + (size_t)(b * TT + r0) * TT + j;
  unsigned short* ebase = Eb + (size_t)(b * TT + r0) * TT + jswz;
  __shared__ float wsum[4][64];
  int wv = threadIdx.x >> 6;
  for (int rb = 0; rb < 64; rb += 8) {
    float v[8];
#pragma unroll
    for (int u = 0; u < 8; ++u) {
      int r = r0 + rb + u;
      v[u] = (j >= 1 && j < r) ? base[(size_t)(rb + u) * TT] : 0.f;
    }
#pragma unroll
    for (int u = 0; u < 8; ++u) {
      int rr = rb + u;
      ebase[(size_t)rr * TT] = f2b(__expf(-run));  // E (bf16, natural-e)
      float c1 = fminf(run, 1.f);                  // run >= 0 always
#pragma unroll
      for (int o = 1; o < 64; o <<= 1) c1 += __shfl_xor(c1, o);
      if ((threadIdx.x & 63) == 0) wsum[wv][rr] = c1;
      run += v[u];
    }
  }
  __syncthreads();
  if (threadIdx.x < 64)
    ffpart[((size_t)(b * 8) + blockIdx.x) * TT + r0 + threadIdx.x] =
        wsum[0][threadIdx.x] + wsum[1][threadIdx.x] +
        wsum[2][threadIdx.x] + wsum[3][threadIdx.x];
}

// ---------------------------------------------------------------------------
// bf16 MFMA flash attention (R9-exact measured-best form) + CU-load-balanced
// g4 permutation: consecutive dispatch waves alternate heavy/light q-blocks
// so each CU's 3 resident blocks sum to ~uniform work.
// Grid (24, 32): XCD = x%8 serves one batch / 3 heads (L2 locality).
// ---------------------------------------------------------------------------
__global__ __launch_bounds__(256, 3) void attn_mfma(
    const unsigned short* __restrict__ Qb, const unsigned short* __restrict__ Kb,
    const unsigned short* __restrict__ Vt, const unsigned short* __restrict__ Eb,
    unsigned short* __restrict__ yhb) {
  int xbh = blockIdx.x;
  int b = (xbh >> 2) & 1;
  int h = ((xbh >> 3) << 2) | (xbh & 3);
  int yy = blockIdx.y;
  int g4 = (yy & 1) ? (yy >> 1) : (31 - (yy >> 1));  // balanced interleave
  int wave = threadIdx.x >> 6, lane = threadIdx.x & 63;
  int lr = lane & 15, lg = lane >> 4;
  int i0 = g4 * 64 + wave * 16;
  int bh = b * NH + h;
  const unsigned short* Qh = Qb + (size_t)bh * TT * HD;
  const unsigned short* Kh = Kb + (size_t)bh * TT * HD;
  const unsigned short* Vh = Vt + (size_t)bh * HD * TT;
  const unsigned short* Erow = Eb + ((size_t)(b * TT) + i0 + lg * 4) * TT + 4 * lr;

  __shared__ __align__(16) unsigned short Ksh[2][64][64];
  __shared__ __align__(16) unsigned short Vsh[2][64][64];
  __shared__ __align__(16) unsigned short Plds[4][16][80];

  int rowoff = lane >> 3;            // 0..7 within an 8-row staging segment
  int sslot  = (lane & 7) ^ rowoff;  // pre-swizzled source slot (16B units)

  bf16x8 qf[2];
#pragma unroll
  for (int ks = 0; ks < 2; ++ks)
    qf[ks] = *(const bf16x8*)(Qh + (size_t)(i0 + lr) * HD + ks * 32 + lg * 8);

  f32x4 acc[4];
  float lrun[4] = {0.f, 0.f, 0.f, 0.f};  // per-lane partial of softmax denom
#pragma unroll
  for (int q = 0; q < 4; ++q) acc[q] = (f32x4){0.f, 0.f, 0.f, 0.f};

#define STAGE_KV(BUF, J0)                                                      \
  {                                                                            \
    _Pragma("unroll")                                                          \
    for (int p = 0; p < 2; ++p) {                                              \
      int r0 = wave * 16 + p * 8;                                              \
      gload_lds16(Kh + (size_t)((J0) + r0 + rowoff) * HD + sslot * 8,          \
                  &Ksh[BUF][r0][0]);                                           \
      gload_lds16(Vh + (size_t)(r0 + rowoff) * TT + (J0) + sslot * 8,          \
                  &Vsh[BUF][r0][0]);                                           \
    }                                                                          \
  }

  STAGE_KV(0, 0)
  __syncthreads();

  for (int kt = 0; kt <= g4; ++kt) {
    int cur = kt & 1;
    int j0 = kt * 64;
    if (kt < g4) STAGE_KV(cur ^ 1, j0 + 64)

    // E for current tile (4 x 8B vector loads, swizzled layout)
    ushort4 ev[4];
#pragma unroll
    for (int r = 0; r < 4; ++r)
      ev[r] = *(const ushort4*)(Erow + (size_t)r * TT + j0);

    // ---- QK^T from swizzled LDS ----
    f32x4 s[4];
    __builtin_amdgcn_s_setprio(1);
#pragma unroll
    for (int nj = 0; nj < 4; ++nj) {
      int row = nj * 16 + lr;
      int sw = row & 7;
      bf16x8 k0f = *(const bf16x8*)&Ksh[cur][row][(lg ^ sw) << 3];
      bf16x8 k1f = *(const bf16x8*)&Ksh[cur][row][((4 + lg) ^ sw) << 3];
      f32x4 z = (f32x4){0.f, 0.f, 0.f, 0.f};
      z = __builtin_amdgcn_mfma_f32_16x16x32_bf16(qf[0], k0f, z, 0, 0, 0);
      s[nj] = __builtin_amdgcn_mfma_f32_16x16x32_bf16(qf[1], k1f, z, 0, 0, 0);
    }
    __builtin_amdgcn_s_setprio(0);

    // ---- causal mask (diagonal tile only) ----
    int ibase = i0 + lg * 4;
    if (kt == g4) {
#pragma unroll
      for (int nj = 0; nj < 4; ++nj)
#pragma unroll
        for (int r = 0; r < 4; ++r)
          if (j0 + nj * 16 + lr > ibase + r) s[nj][r] = -1e30f;
    }

    // ---- P = E * exp(s); per-lane partial l; stash bf16 P in LDS ----
#pragma unroll
    for (int r = 0; r < 4; ++r) {
      float p0 = b2f(ev[r].x) * __expf(s[0][r]);
      float p1 = b2f(ev[r].y) * __expf(s[1][r]);
      float p2 = b2f(ev[r].z) * __expf(s[2][r]);
      float p3 = b2f(ev[r].w) * __expf(s[3][r]);
      lrun[r] += (p0 + p1) + (p2 + p3);
      Plds[wave][lg * 4 + r][0 * 16 + lr] = f2b(p0);
      Plds[wave][lg * 4 + r][1 * 16 + lr] = f2b(p1);
      Plds[wave][lg * 4 + r][2 * 16 + lr] = f2b(p2);
      Plds[wave][lg * 4 + r][3 * 16 + lr] = f2b(p3);
    }

    // ---- PV from swizzled LDS ----
    bf16x8 pa0 = *(const bf16x8*)&Plds[wave][lr][lg * 8];
    bf16x8 pa1 = *(const bf16x8*)&Plds[wave][lr][32 + lg * 8];
    __builtin_amdgcn_s_setprio(1);
#pragma unroll
    for (int nd = 0; nd < 4; ++nd) {
      int row = nd * 16 + lr;
      int sw = row & 7;
      bf16x8 v0f = *(const bf16x8*)&Vsh[cur][row][(lg ^ sw) << 3];
      bf16x8 v1f = *(const bf16x8*)&Vsh[cur][row][((4 + lg) ^ sw) << 3];
      acc[nd] = __builtin_amdgcn_mfma_f32_16x16x32_bf16(pa0, v0f, acc[nd], 0, 0, 0);
      acc[nd] = __builtin_amdgcn_mfma_f32_16x16x32_bf16(pa1, v1f, acc[nd], 0, 0, 0);
    }
    __builtin_amdgcn_s_setprio(0);

    __syncthreads();
  }
#undef STAGE_KV

  // ---- epilogue: one l-reduction across the 16 lr lanes, then store ----
#pragma unroll
  for (int r = 0; r < 4; ++r) {
    lrun[r] += __shfl_xor(lrun[r], 1);
    lrun[r] += __shfl_xor(lrun[r], 2);
    lrun[r] += __shfl_xor(lrun[r], 4);
    lrun[r] += __shfl_xor(lrun[r], 8);
    float inv = 1.f / lrun[r];
    int ig = i0 + lg * 4 + r;
    unsigned short* ob = yhb + (size_t)(b * TT + ig) * CC + h * HD;
#pragma unroll
    for (int nd = 0; nd < 4; ++nd)
      ob[nd * 16 + lr] = f2b(acc[nd][r] * inv);
  }
}

// ---------------------------------------------------------------------------
// FUSED proj GEMM + M writer (1D grid, 1408 blocks):
//   bid < 384 : y = yhb @ wpT^T + b_proj (128x64 MFMA tile)
//   else      : M[0,b,i,j] = i - sum_jb ffpart[b][jb][j] (float4, grid-stride)
// ---------------------------------------------------------------------------
__global__ __launch_bounds__(256, 3) void proj_m_fused(
    const unsigned short* __restrict__ yhb, const unsigned short* __restrict__ wpT,
    const float* __restrict__ b_proj, float* __restrict__ y,
    const float* __restrict__ ffpart, float* __restrict__ Mout) {
  int bid = blockIdx.x;
  if (bid >= 384) {
    int idx4 = (bid - 384) * 256 + threadIdx.x;
    int stride = (gridDim.x - 384) * 256;
    for (; idx4 < M_ELEMS / 4; idx4 += stride) {
      int idx = idx4 << 2;
      int j = idx & (TT - 1);
      int i = (idx >> 11) & (TT - 1);
      int b = idx >> 22;
      const float* fp = ffpart + ((size_t)(b * 8)) * TT + j;
      float4 s = make_float4(0.f, 0.f, 0.f, 0.f);
#pragma unroll
      for (int p = 0; p < 8; ++p) {
        float4 v = *(const float4*)(fp + (size_t)p * TT);
        s.x += v.x; s.y += v.y; s.z += v.z; s.w += v.w;
      }
      float fi = (float)i;
      float4 o = make_float4(fi - s.x, fi - s.y, fi - s.z, fi - s.w);
      *(float4*)(Mout + idx) = o;
    }
    return;
  }
  __shared__ __align__(16) unsigned short Alds[2][128][32];
  __shared__ __align__(16) unsigned short Blds[2][64][32];
  int mt = bid & 31, nt = bid >> 5;
  int wave = threadIdx.x >> 6, lane = threadIdx.x & 63;
  int lr = lane & 15, lg = lane >> 4;
  int m0 = mt * 128;
  int n0 = nt * 64;

  int srow = lane >> 2;
  int sslot = (lane & 3) ^ (srow & 3);

#define STAGE_AB(BUF, K0)                                                       \
  {                                                                             \
    _Pragma("unroll")                                                           \
    for (int p = 0; p < 2; ++p) {                                               \
      int ar = wave * 32 + p * 16 + srow;                                       \
      gload_lds16(yhb + (size_t)(m0 + ar) * CC + (K0) + (sslot << 3),           \
                  &Alds[BUF][wave * 32 + p * 16][0]);                           \
    }                                                                           \
    int br = wave * 16 + srow;                                                  \
    gload_lds16(wpT + (size_t)(n0 + br) * CC + (K0) + (sslot << 3),             \
                &Blds[BUF][wave * 16][0]);                                      \
  }

  f32x4 acc[2][4];
#pragma unroll
  for (int mi = 0; mi < 2; ++mi)
#pragma unroll
    for (int nj = 0; nj < 4; ++nj) acc[mi][nj] = (f32x4){0.f, 0.f, 0.f, 0.f};

  STAGE_AB(0, 0)
  __syncthreads();

  int fslot = lg ^ (lr & 3);
  for (int kt = 0; kt < 24; ++kt) {
    int cur = kt & 1;
    if (kt < 23) STAGE_AB(cur ^ 1, (kt + 1) * 32)
    bf16x8 af[2], bf[4];
#pragma unroll
    for (int mi = 0; mi < 2; ++mi)
      af[mi] = *(const bf16x8*)&Alds[cur][wave * 32 + mi * 16 + lr][fslot << 3];
#pragma unroll
    for (int nj = 0; nj < 4; ++nj)
      bf[nj] = *(const bf16x8*)&Blds[cur][nj * 16 + lr][fslot << 3];
    __builtin_amdgcn_s_setprio(1);
#pragma unroll
    for (int nj = 0; nj < 4; ++nj)
#pragma unroll
      for (int mi = 0; mi < 2; ++mi)
        acc[mi][nj] = __builtin_amdgcn_mfma_f32_16x16x32_bf16(af[mi], bf[nj], acc[mi][nj], 0, 0, 0);
    __builtin_amdgcn_s_setprio(0);
    __syncthreads();
  }
#undef STAGE_AB

  float bias[4];
#pragma unroll
  for (int nj = 0; nj < 4; ++nj) bias[nj] = b_proj[n0 + nj * 16 + lr];
#pragma unroll
  for (int mi = 0; mi < 2; ++mi)
#pragma unroll
    for (int r = 0; r < 4; ++r) {
      int m = m0 + wave * 32 + mi * 16 + lg * 4 + r;
#pragma unroll
      for (int nj = 0; nj < 4; ++nj)
        y[(size_t)m * CC + n0 + nj * 16 + lr] = acc[mi][nj][r] + bias[nj];
    }
}

// ---------------------------------------------------------------------------
extern "C" void kernel_launch(void* const* d_in, const int* in_sizes, int n_in,
                              void* d_out, int out_size, void* d_ws, size_t ws_size,
                              hipStream_t stream) {
  const float* x      = (const float*)d_in[0];
  const float* w_attn = (const float*)d_in[1];
  const float* b_attn = (const float*)d_in[2];
  const float* w_proj = (const float*)d_in[3];
  const float* b_proj = (const float*)d_in[4];

  float* y    = (float*)d_out;          // [B,T,C]
  float* Mreg = y + Y_ELEMS;            // [B,T,T]: S0 (scratch) -> M (final)

  float* ws = (float*)d_ws;
  float* q0       = ws;                               // B*T*64
  float* k0       = q0 + (size_t)BB * TT * HD;
  float* partials = k0 + (size_t)BB * TT * HD;        // B*32*T
  float* ffpart   = partials + (size_t)BB * 32 * TT;  // B*8*T
  unsigned short* xb  = (unsigned short*)(ffpart + (size_t)BB * 8 * TT);  // B*T*C
  unsigned short* wbT = xb + (size_t)Y_ELEMS;                 // 2304*768
  unsigned short* wpT = wbT + (size_t)N3 * CC;                // 768*768
  unsigned short* Qb  = wpT + (size_t)CC * CC;                // B*NH*T*HD
  unsigned short* Kb  = Qb + (size_t)BB * NH * TT * HD;
  unsigned short* Vt  = Kb + (size_t)BB * NH * TT * HD;
  unsigned short* yhb = Vt + (size_t)BB * NH * TT * HD;       // B*T*C
  unsigned short* Eb  = yhb + (size_t)Y_ELEMS;                // B*T*T bf16 (16.8MB)
  // total ws usage ~= 46 MB

  // 1. fused packs: x -> bf16; w_attn/w_proj -> transposed bf16
  prep_fused<<<2112, 256, 0, stream>>>(x, w_attn, w_proj, xb, wbT, wpT);
  // 2. bf16 MFMA QKV GEMM (standalone again — fused fp32 tail cost 33 µs)
  gemm_qkv_bf16<<<dim3(32, 18), 256, 0, stream>>>(xb, wbT, b_attn, Qb, Kb, Vt);
  // 3. fp32 head-0 q,k (standalone, 256 blocks)
  sgemm_qk0<<<dim3(128, 2), 256, 0, stream>>>(x, w_attn, b_attn, q0, k0);
  // 4. head-0 scores (fp32) into Mreg + fused per-chunk column partial sums
  score0_kernel<<<dim3(32, 32, BB), 256, 0, stream>>>(q0, k0, Mreg, partials);
  // 5. scan: E = exp(-FF) bf16 (jswz) + ffpart row sums (batched loads)
  scan_write<<<dim3(8, 32, BB), 256, 0, stream>>>(Mreg, partials, Eb, ffpart);
  // 6. MFMA flash attention (R9 form + balanced g4 permutation)
  attn_mfma<<<dim3(24, 32), 256, 0, stream>>>(Qb, Kb, Vt, Eb, yhb);
  // 7. fused proj GEMM + M writer
  proj_m_fused<<<1408, 256, 0, stream>>>(yhb, wpT, b_proj, y, ffpart, Mreg);
}

// Round 16
// 170.272 us; speedup vs baseline: 2.9648x; 1.0414x over previous
//
#include <hip/hip_runtime.h>
#include <cstddef>

// Problem constants
#define TT 2048
#define BB 2
#define CC 768
#define NH 12
#define HD 64
#define N3 2304          // 3*NH*HD
#define Y_ELEMS (BB*TT*CC)          // 3145728
#define M_ELEMS (BB*TT*TT)          // 8388608

typedef __attribute__((ext_vector_type(8))) short bf16x8;
typedef __attribute__((ext_vector_type(4))) float f32x4;

__device__ inline unsigned short f2b(float f) {
  union { float f; unsigned u; } v; v.f = f;
  unsigned r = (v.u + 0x7FFFu + ((v.u >> 16) & 1u)) >> 16;
  return (unsigned short)r;
}
__device__ inline float b2f(unsigned short u) {
  union { unsigned u; float f; } v; v.u = (unsigned)u << 16; return v.f;
}

// async global -> LDS, 16B per lane; lds dest is wave-uniform base, HW adds lane*16
__device__ inline void gload_lds16(const unsigned short* g, unsigned short* l) {
  __builtin_amdgcn_global_load_lds(
      (const __attribute__((address_space(1))) unsigned int*)g,
      (__attribute__((address_space(3))) unsigned int*)l, 16, 0, 0);
}

// ---------------------------------------------------------------------------
// FUSED prep + head-0 qk kernel (1D grid, 2368 blocks):
//   bid <   256 : fp32 GEMM q0/k0 (32x64 tile) — LONG blocks, dispatched
//                 first so the 2112 short prep blocks pack around them.
//   bid <  1792 : pack x (fp32 -> bf16), 8 elems/thread
//   bid <  2224 : transpose-pack w_attn -> wbT [N3][768] bf16
//   else        : transpose-pack w_proj -> wpT [768][768] bf16
// ---------------------------------------------------------------------------
__global__ __launch_bounds__(256) void prep_fused(
    const float* __restrict__ x, const float* __restrict__ w_attn,
    const float* __restrict__ w_proj, const float* __restrict__ b_attn,
    unsigned short* __restrict__ xb, unsigned short* __restrict__ wbT,
    unsigned short* __restrict__ wpT,
    float* __restrict__ q0, float* __restrict__ k0) {
  int bid = blockIdx.x;
  int tid = threadIdx.x;
  if (bid < 256) {
    // ---------------- fp32 head-0 q/k (32x64 tile) ----------------
    __shared__ float As[16][32];
    __shared__ float Bs[16][64];
    int sec = bid >> 7;                  // 0..1
    int mt = bid & 127;
    const float* Bw = w_attn + sec * CC;
    float* Out = sec ? k0 : q0;
    int tx = tid & 15, ty = tid >> 4;
    int m0 = mt * 32;

    int arow = tid >> 3;                // 0..31
    int acol2 = (tid & 7) << 1;         // 0,2,..,14
    int brow = tid >> 4;                // 0..15
    int bcol4 = (tid & 15) << 2;        // 0..60

    const float* Aptr = x + (size_t)(m0 + arow) * CC + acol2;
    const float* Bptr = Bw + (size_t)brow * N3 + bcol4;

    float acc[2][4] = {};
    for (int k0_ = 0; k0_ < CC; k0_ += 16) {
      float2 av = *(const float2*)(Aptr + k0_);
      float4 bv = *(const float4*)(Bptr + (size_t)k0_ * N3);
      As[acol2 + 0][arow] = av.x;
      As[acol2 + 1][arow] = av.y;
      *(float4*)&Bs[brow][bcol4] = bv;
      __syncthreads();
#pragma unroll
      for (int kk = 0; kk < 16; ++kk) {
        float2 a2 = *(const float2*)&As[kk][ty << 1];
        float4 b4 = *(const float4*)&Bs[kk][tx << 2];
        float a[2] = {a2.x, a2.y};
        float b[4] = {b4.x, b4.y, b4.z, b4.w};
#pragma unroll
        for (int ii = 0; ii < 2; ++ii)
#pragma unroll
          for (int jj = 0; jj < 4; ++jj) acc[ii][jj] += a[ii] * b[jj];
      }
      __syncthreads();
    }
    float4 bv = *(const float4*)(b_attn + sec * CC + (tx << 2));
#pragma unroll
    for (int ii = 0; ii < 2; ++ii) {
      int m = m0 + (ty << 1) + ii;
      float4 o;
      o.x = acc[ii][0] + bv.x;
      o.y = acc[ii][1] + bv.y;
      o.z = acc[ii][2] + bv.z;
      o.w = acc[ii][3] + bv.w;
      *(float4*)(Out + (size_t)m * HD + (tx << 2)) = o;
    }
    return;
  }
  if (bid < 1792) {
    size_t i = ((size_t)(bid - 256) * 256 + tid) * 8;
    float4 a = *(const float4*)(x + i);
    float4 b = *(const float4*)(x + i + 4);
    ushort4 o0, o1;
    o0.x = f2b(a.x); o0.y = f2b(a.y); o0.z = f2b(a.z); o0.w = f2b(a.w);
    o1.x = f2b(b.x); o1.y = f2b(b.y); o1.z = f2b(b.z); o1.w = f2b(b.w);
    *(ushort4*)(xb + i) = o0;
    *(ushort4*)(xb + i + 4) = o1;
    return;
  }
  const float* W;
  unsigned short* WT;
  int N, kt, nt;
  if (bid < 2224) {
    int t = bid - 1792;
    W = w_attn; WT = wbT; N = N3;
    kt = t % 12; nt = t / 12;
  } else {
    int t = bid - 2224;
    W = w_proj; WT = wpT; N = CC;
    kt = t % 12; nt = t / 12;
  }
  __shared__ float tile[64][65];
  int r = tid >> 4, c4 = (tid & 15) << 2;
#pragma unroll
  for (int rep = 0; rep < 4; ++rep) {
    int row = rep * 16 + r;
    float4 v = *(const float4*)(W + (size_t)(kt * 64 + row) * N + nt * 64 + c4);
    tile[row][c4 + 0] = v.x; tile[row][c4 + 1] = v.y;
    tile[row][c4 + 2] = v.z; tile[row][c4 + 3] = v.w;
  }
  __syncthreads();
#pragma unroll
  for (int rep = 0; rep < 4; ++rep) {
    int nrow = rep * 16 + r;
    ushort4 o;
    o.x = f2b(tile[c4 + 0][nrow]); o.y = f2b(tile[c4 + 1][nrow]);
    o.z = f2b(tile[c4 + 2][nrow]); o.w = f2b(tile[c4 + 3][nrow]);
    *(ushort4*)(WT + (size_t)(nt * 64 + nrow) * CC + kt * 64 + c4) = o;
  }
}

// ---------------------------------------------------------------------------
// bf16 MFMA GEMM: qkv = xb @ wbT^T + b_attn -> packed Qb (pre-scaled 1/8),
// Kb, Vt (transposed via LDS). 128x128 tiles: grid (32, 18).
// LDS-staged dbuf, slot-swizzled. Vlds epilogue UNION-overlaid on A/B bufs.
// ---------------------------------------------------------------------------
__global__ __launch_bounds__(256, 3) void gemm_qkv_bf16(
    const unsigned short* __restrict__ xb, const unsigned short* __restrict__ wbT,
    const float* __restrict__ b_attn,
    unsigned short* __restrict__ Qb, unsigned short* __restrict__ Kb,
    unsigned short* __restrict__ Vt) {
  __shared__ __align__(16) unsigned short smem_u[17408];  // 34816 B
  unsigned short (*Alds)[128][32] = (unsigned short(*)[128][32])smem_u;
  unsigned short (*Blds)[128][32] = (unsigned short(*)[128][32])(smem_u + 8192);
  unsigned short (*Vlds)[136]     = (unsigned short(*)[136])smem_u;

  int mt = blockIdx.x, nt = blockIdx.y;
  int sec = nt / 6, h0 = (nt % 6) * 2;
  int wave = threadIdx.x >> 6, lane = threadIdx.x & 63;
  int lr = lane & 15, lg = lane >> 4;
  int m0 = mt * 128;
  int n0 = nt * 128;

  int srow = lane >> 2;                 // 0..15 staging row within segment
  int sslot = (lane & 3) ^ (srow & 3);  // pre-swizzled source k-slot (16B units)

#define STAGE_AB(BUF, K0)                                                       \
  {                                                                             \
    _Pragma("unroll")                                                           \
    for (int p = 0; p < 2; ++p) {                                               \
      int ar = wave * 32 + p * 16 + srow;                                       \
      gload_lds16(xb + (size_t)(m0 + ar) * CC + (K0) + (sslot << 3),            \
                  &Alds[BUF][wave * 32 + p * 16][0]);                           \
      gload_lds16(wbT + (size_t)(n0 + ar) * CC + (K0) + (sslot << 3),           \
                  &Blds[BUF][wave * 32 + p * 16][0]);                           \
    }                                                                           \
  }

  f32x4 acc[2][8];
#pragma unroll
  for (int mi = 0; mi < 2; ++mi)
#pragma unroll
    for (int nj = 0; nj < 8; ++nj) acc[mi][nj] = (f32x4){0.f, 0.f, 0.f, 0.f};

  STAGE_AB(0, 0)
  __syncthreads();

  int fslot = lg ^ (lr & 3);  // frag read slot (same involution)
  for (int kt = 0; kt < 24; ++kt) {
    int cur = kt & 1;
    if (kt < 23) STAGE_AB(cur ^ 1, (kt + 1) * 32)
    bf16x8 af[2], bf[8];
#pragma unroll
    for (int mi = 0; mi < 2; ++mi)
      af[mi] = *(const bf16x8*)&Alds[cur][wave * 32 + mi * 16 + lr][fslot << 3];
#pragma unroll
    for (int nj = 0; nj < 8; ++nj)
      bf[nj] = *(const bf16x8*)&Blds[cur][nj * 16 + lr][fslot << 3];
    __builtin_amdgcn_s_setprio(1);
#pragma unroll
    for (int nj = 0; nj < 8; ++nj)
#pragma unroll
      for (int mi = 0; mi < 2; ++mi)
        acc[mi][nj] = __builtin_amdgcn_mfma_f32_16x16x32_bf16(af[mi], bf[nj], acc[mi][nj], 0, 0, 0);
    __builtin_amdgcn_s_setprio(0);
    __syncthreads();
  }
#undef STAGE_AB

  int b = m0 >> 11;
  float bias[8];
#pragma unroll
  for (int nj = 0; nj < 8; ++nj) bias[nj] = b_attn[n0 + nj * 16 + lr];

  if (sec < 2) {
    // Q is pre-scaled by 1/8 (exact in bf16: exponent shift only)
    float qscale = (sec == 0) ? 0.125f : 1.0f;
    unsigned short* OutB = (sec == 0 ? Qb : Kb);
    int tbase = (m0 & 2047) + wave * 32 + lg * 4;
#pragma unroll
    for (int nj = 0; nj < 8; ++nj) {
      int h = h0 + (nj >> 2);
      int d = (nj & 3) * 16 + lr;
      unsigned short* Out = OutB + (size_t)(b * NH + h) * TT * HD;
#pragma unroll
      for (int mi = 0; mi < 2; ++mi)
#pragma unroll
        for (int r = 0; r < 4; ++r) {
          int t = tbase + mi * 16 + r;
          Out[(size_t)t * HD + d] = f2b((acc[mi][nj][r] + bias[nj]) * qscale);
        }
    }
  } else {
    int tl = wave * 32 + lg * 4;
#pragma unroll
    for (int mi = 0; mi < 2; ++mi)
#pragma unroll
      for (int r = 0; r < 4; ++r)
#pragma unroll
        for (int nj = 0; nj < 8; ++nj)
          Vlds[tl + mi * 16 + r][nj * 16 + lr] = f2b(acc[mi][nj][r] + bias[nj]);
    __syncthreads();
    int d = threadIdx.x & 63, tc = threadIdx.x >> 6;
    int tblk = (m0 & 2047);
#pragma unroll
    for (int hh = 0; hh < 2; ++hh) {
      unsigned short* Ov = Vt + ((size_t)(b * NH + h0 + hh) * HD + d) * TT + tblk + tc * 32;
      int c = hh * 64 + d;
#pragma unroll
      for (int i8 = 0; i8 < 4; ++i8) {
        ushort4 o0, o1;
        o0.x = Vlds[tc * 32 + i8 * 8 + 0][c]; o0.y = Vlds[tc * 32 + i8 * 8 + 1][c];
        o0.z = Vlds[tc * 32 + i8 * 8 + 2][c]; o0.w = Vlds[tc * 32 + i8 * 8 + 3][c];
        o1.x = Vlds[tc * 32 + i8 * 8 + 4][c]; o1.y = Vlds[tc * 32 + i8 * 8 + 5][c];
        o1.z = Vlds[tc * 32 + i8 * 8 + 6][c]; o1.w = Vlds[tc * 32 + i8 * 8 + 7][c];
        *(ushort4*)(Ov + i8 * 8) = o0;
        *(ushort4*)(Ov + i8 * 8 + 4) = o1;
      }
    }
  }
}

// ---------------------------------------------------------------------------
// Head-0 scores (fp32): Sbuf[b,i,j] = relu(dot(q0,k0)/8), lower-tri tiles.
// FUSED: also emits per-64-row-chunk masked column sums into partials
// (mask = j>=1 && j<r). partials layout: [B][32][TT].
// ---------------------------------------------------------------------------
__global__ __launch_bounds__(256) void score0_kernel(
    const float* __restrict__ q0, const float* __restrict__ k0,
    float* __restrict__ Sbuf, float* __restrict__ partials) {
  int it = blockIdx.x, jt = blockIdx.y, b = blockIdx.z;
  int tid = threadIdx.x;
  int i0 = it * 64, j0 = jt * 64;
  if (jt > it) {  // mask kills everything above the diagonal
    if (tid < 64) partials[((size_t)(b * 32 + it)) * TT + j0 + tid] = 0.f;
    return;
  }
  __shared__ float Qs[64][64];
  __shared__ float Ks[64][64];
  int row = tid >> 2;
  int dq = (tid & 3) << 2;
  const float* qb = q0 + (size_t)((b * TT) + i0 + row) * HD;
  const float* kb = k0 + (size_t)((b * TT) + j0 + row) * HD;
#pragma unroll
  for (int rep = 0; rep < 4; ++rep) {
    int d = dq + rep * 16;
    float4 qv = *(const float4*)(qb + d);
    float4 kv = *(const float4*)(kb + d);
    Qs[d + 0][row] = qv.x; Qs[d + 1][row] = qv.y;
    Qs[d + 2][row] = qv.z; Qs[d + 3][row] = qv.w;
    Ks[d + 0][row] = kv.x; Ks[d + 1][row] = kv.y;
    Ks[d + 2][row] = kv.z; Ks[d + 3][row] = kv.w;
  }
  __syncthreads();
  int tx = tid & 15, ty = tid >> 4;
  float acc[4][4] = {};
#pragma unroll 8
  for (int kk = 0; kk < 64; ++kk) {
    float4 a4 = *(const float4*)&Qs[kk][ty << 2];
    float4 b4 = *(const float4*)&Ks[kk][tx << 2];
    float a[4] = {a4.x, a4.y, a4.z, a4.w};
    float b[4] = {b4.x, b4.y, b4.z, b4.w};
#pragma unroll
    for (int ii = 0; ii < 4; ++ii)
#pragma unroll
      for (int jj = 0; jj < 4; ++jj) acc[ii][jj] += a[ii] * b[jj];
  }
  float red4[4] = {0.f, 0.f, 0.f, 0.f};
#pragma unroll
  for (int ii = 0; ii < 4; ++ii) {
    int r = i0 + (ty << 2) + ii;           // global row (within T)
    int gi = (b * TT) + r;
    float ov[4];
#pragma unroll
    for (int jj = 0; jj < 4; ++jj) {
      ov[jj] = fmaxf(acc[ii][jj] * 0.125f, 0.f);
      int j = j0 + (tx << 2) + jj;
      if (j >= 1 && j < r) red4[jj] += ov[jj];
    }
    float4 o; o.x = ov[0]; o.y = ov[1]; o.z = ov[2]; o.w = ov[3];
    *(float4*)(Sbuf + (size_t)gi * TT + j0 + (tx << 2)) = o;
  }
  // reduce the 16 ty-groups per column via reused LDS
  __syncthreads();  // everyone done reading Qs
  *(float4*)&Qs[ty][tx << 2] = *(float4*)red4;
  __syncthreads();
  if (tid < 64) {
    float cs = 0.f;
#pragma unroll
    for (int t = 0; t < 16; ++t) cs += Qs[t][tid];
    partials[((size_t)(b * 32 + it)) * TT + j0 + tid] = cs;
  }
}

// ---------------------------------------------------------------------------
// Column-wise exclusive prefix scan over rows (64-row chunks; partial sums
// fused from score0). Emits E = exp(-FF) bf16 with the j-swizzled layout
// (within each 64-col tile: j -> ((j&15)<<2)|((j>>4)&3)) and per-jblock
// row sums of clip(FF,0,1) into ffpart[B][8][TT]. 8-row load batching.
// ---------------------------------------------------------------------------
__global__ __launch_bounds__(256) void scan_write(
    const float* __restrict__ Sbuf, const float* __restrict__ partials,
    unsigned short* __restrict__ Eb, float* __restrict__ ffpart) {
  int j = blockIdx.x * 256 + threadIdx.x;
  int chunk = blockIdx.y, b = blockIdx.z;
  float run = 0.f;
  for (int c = 0; c < chunk; ++c) run += partials[((size_t)(b * 32 + c)) * TT + j];
  int r0 = chunk * 64;
  int jswz = (j & ~63) | ((j & 15) << 2) | ((j >> 4) & 3);
  const float* base = Sbuf + (size_t)(b * TT + r0) * TT + j;
  unsigned short* ebase = Eb + (size_t)(b * TT + r0) * TT + jswz;
  __shared__ float wsum[4][64];
  int wv = threadIdx.x >> 6;
  for (int rb = 0; rb < 64; rb += 8) {
    float v[8];
#pragma unroll
    for (int u = 0; u < 8; ++u) {
      int r = r0 + rb + u;
      v[u] = (j >= 1 && j < r) ? base[(size_t)(rb + u) * TT] : 0.f;
    }
#pragma unroll
    for (int u = 0; u < 8; ++u) {
      int rr = rb + u;
      ebase[(size_t)rr * TT] = f2b(__expf(-run));  // E (bf16, natural-e)
      float c1 = fminf(run, 1.f);                  // run >= 0 always
#pragma unroll
      for (int o = 1; o < 64; o <<= 1) c1 += __shfl_xor(c1, o);
      if ((threadIdx.x & 63) == 0) wsum[wv][rr] = c1;
      run += v[u];
    }
  }
  __syncthreads();
  if (threadIdx.x < 64)
    ffpart[((size_t)(b * 8) + blockIdx.x) * TT + r0 + threadIdx.x] =
        wsum[0][threadIdx.x] + wsum[1][threadIdx.x] +
        wsum[2][threadIdx.x] + wsum[3][threadIdx.x];
}

// ---------------------------------------------------------------------------
// bf16 MFMA flash attention (R9-exact measured-best form) + CU-load-balanced
// g4 permutation: consecutive dispatch waves alternate heavy/light q-blocks
// so each CU's 3 resident blocks sum to ~uniform work.
// Grid (24, 32): XCD = x%8 serves one batch / 3 heads (L2 locality).
// ---------------------------------------------------------------------------
__global__ __launch_bounds__(256, 3) void attn_mfma(
    const unsigned short* __restrict__ Qb, const unsigned short* __restrict__ Kb,
    const unsigned short* __restrict__ Vt, const unsigned short* __restrict__ Eb,
    unsigned short* __restrict__ yhb) {
  int xbh = blockIdx.x;
  int b = (xbh >> 2) & 1;
  int h = ((xbh >> 3) << 2) | (xbh & 3);
  int yy = blockIdx.y;
  int g4 = (yy & 1) ? (yy >> 1) : (31 - (yy >> 1));  // balanced interleave
  int wave = threadIdx.x >> 6, lane = threadIdx.x & 63;
  int lr = lane & 15, lg = lane >> 4;
  int i0 = g4 * 64 + wave * 16;
  int bh = b * NH + h;
  const unsigned short* Qh = Qb + (size_t)bh * TT * HD;
  const unsigned short* Kh = Kb + (size_t)bh * TT * HD;
  const unsigned short* Vh = Vt + (size_t)bh * HD * TT;
  const unsigned short* Erow = Eb + ((size_t)(b * TT) + i0 + lg * 4) * TT + 4 * lr;

  __shared__ __align__(16) unsigned short Ksh[2][64][64];
  __shared__ __align__(16) unsigned short Vsh[2][64][64];
  __shared__ __align__(16) unsigned short Plds[4][16][80];

  int rowoff = lane >> 3;            // 0..7 within an 8-row staging segment
  int sslot  = (lane & 7) ^ rowoff;  // pre-swizzled source slot (16B units)

  bf16x8 qf[2];
#pragma unroll
  for (int ks = 0; ks < 2; ++ks)
    qf[ks] = *(const bf16x8*)(Qh + (size_t)(i0 + lr) * HD + ks * 32 + lg * 8);

  f32x4 acc[4];
  float lrun[4] = {0.f, 0.f, 0.f, 0.f};  // per-lane partial of softmax denom
#pragma unroll
  for (int q = 0; q < 4; ++q) acc[q] = (f32x4){0.f, 0.f, 0.f, 0.f};

#define STAGE_KV(BUF, J0)                                                      \
  {                                                                            \
    _Pragma("unroll")                                                          \
    for (int p = 0; p < 2; ++p) {                                              \
      int r0 = wave * 16 + p * 8;                                              \
      gload_lds16(Kh + (size_t)((J0) + r0 + rowoff) * HD + sslot * 8,          \
                  &Ksh[BUF][r0][0]);                                           \
      gload_lds16(Vh + (size_t)(r0 + rowoff) * TT + (J0) + sslot * 8,          \
                  &Vsh[BUF][r0][0]);                                           \
    }                                                                          \
  }

  STAGE_KV(0, 0)
  __syncthreads();

  for (int kt = 0; kt <= g4; ++kt) {
    int cur = kt & 1;
    int j0 = kt * 64;
    if (kt < g4) STAGE_KV(cur ^ 1, j0 + 64)

    // E for current tile (4 x 8B vector loads, swizzled layout)
    ushort4 ev[4];
#pragma unroll
    for (int r = 0; r < 4; ++r)
      ev[r] = *(const ushort4*)(Erow + (size_t)r * TT + j0);

    // ---- QK^T from swizzled LDS ----
    f32x4 s[4];
    __builtin_amdgcn_s_setprio(1);
#pragma unroll
    for (int nj = 0; nj < 4; ++nj) {
      int row = nj * 16 + lr;
      int sw = row & 7;
      bf16x8 k0f = *(const bf16x8*)&Ksh[cur][row][(lg ^ sw) << 3];
      bf16x8 k1f = *(const bf16x8*)&Ksh[cur][row][((4 + lg) ^ sw) << 3];
      f32x4 z = (f32x4){0.f, 0.f, 0.f, 0.f};
      z = __builtin_amdgcn_mfma_f32_16x16x32_bf16(qf[0], k0f, z, 0, 0, 0);
      s[nj] = __builtin_amdgcn_mfma_f32_16x16x32_bf16(qf[1], k1f, z, 0, 0, 0);
    }
    __builtin_amdgcn_s_setprio(0);

    // ---- causal mask (diagonal tile only) ----
    int ibase = i0 + lg * 4;
    if (kt == g4) {
#pragma unroll
      for (int nj = 0; nj < 4; ++nj)
#pragma unroll
        for (int r = 0; r < 4; ++r)
          if (j0 + nj * 16 + lr > ibase + r) s[nj][r] = -1e30f;
    }

    // ---- P = E * exp(s); per-lane partial l; stash bf16 P in LDS ----
#pragma unroll
    for (int r = 0; r < 4; ++r) {
      float p0 = b2f(ev[r].x) * __expf(s[0][r]);
      float p1 = b2f(ev[r].y) * __expf(s[1][r]);
      float p2 = b2f(ev[r].z) * __expf(s[2][r]);
      float p3 = b2f(ev[r].w) * __expf(s[3][r]);
      lrun[r] += (p0 + p1) + (p2 + p3);
      Plds[wave][lg * 4 + r][0 * 16 + lr] = f2b(p0);
      Plds[wave][lg * 4 + r][1 * 16 + lr] = f2b(p1);
      Plds[wave][lg * 4 + r][2 * 16 + lr] = f2b(p2);
      Plds[wave][lg * 4 + r][3 * 16 + lr] = f2b(p3);
    }

    // ---- PV from swizzled LDS ----
    bf16x8 pa0 = *(const bf16x8*)&Plds[wave][lr][lg * 8];
    bf16x8 pa1 = *(const bf16x8*)&Plds[wave][lr][32 + lg * 8];
    __builtin_amdgcn_s_setprio(1);
#pragma unroll
    for (int nd = 0; nd < 4; ++nd) {
      int row = nd * 16 + lr;
      int sw = row & 7;
      bf16x8 v0f = *(const bf16x8*)&Vsh[cur][row][(lg ^ sw) << 3];
      bf16x8 v1f = *(const bf16x8*)&Vsh[cur][row][((4 + lg) ^ sw) << 3];
      acc[nd] = __builtin_amdgcn_mfma_f32_16x16x32_bf16(pa0, v0f, acc[nd], 0, 0, 0);
      acc[nd] = __builtin_amdgcn_mfma_f32_16x16x32_bf16(pa1, v1f, acc[nd], 0, 0, 0);
    }
    __builtin_amdgcn_s_setprio(0);

    __syncthreads();
  }
#undef STAGE_KV

  // ---- epilogue: one l-reduction across the 16 lr lanes, then store ----
#pragma unroll
  for (int r = 0; r < 4; ++r) {
    lrun[r] += __shfl_xor(lrun[r], 1);
    lrun[r] += __shfl_xor(lrun[r], 2);
    lrun[r] += __shfl_xor(lrun[r], 4);
    lrun[r] += __shfl_xor(lrun[r], 8);
    float inv = 1.f / lrun[r];
    int ig = i0 + lg * 4 + r;
    unsigned short* ob = yhb + (size_t)(b * TT + ig) * CC + h * HD;
#pragma unroll
    for (int nd = 0; nd < 4; ++nd)
      ob[nd * 16 + lr] = f2b(acc[nd][r] * inv);
  }
}

// ---------------------------------------------------------------------------
// FUSED proj GEMM + M writer (1D grid, 1216 blocks):
//   bid < 192 : y = yhb @ wpT^T + b_proj (128x128 MFMA tile, 8 n-cols)
//   else      : M[0,b,i,j] = i - sum_jb ffpart[b][jb][j] (float4, grid-stride)
// ---------------------------------------------------------------------------
__global__ __launch_bounds__(256, 3) void proj_m_fused(
    const unsigned short* __restrict__ yhb, const unsigned short* __restrict__ wpT,
    const float* __restrict__ b_proj, float* __restrict__ y,
    const float* __restrict__ ffpart, float* __restrict__ Mout) {
  int bid = blockIdx.x;
  if (bid >= 192) {
    int idx4 = (bid - 192) * 256 + threadIdx.x;
    int stride = (gridDim.x - 192) * 256;
    for (; idx4 < M_ELEMS / 4; idx4 += stride) {
      int idx = idx4 << 2;
      int j = idx & (TT - 1);
      int i = (idx >> 11) & (TT - 1);
      int b = idx >> 22;
      const float* fp = ffpart + ((size_t)(b * 8)) * TT + j;
      float4 s = make_float4(0.f, 0.f, 0.f, 0.f);
#pragma unroll
      for (int p = 0; p < 8; ++p) {
        float4 v = *(const float4*)(fp + (size_t)p * TT);
        s.x += v.x; s.y += v.y; s.z += v.z; s.w += v.w;
      }
      float fi = (float)i;
      float4 o = make_float4(fi - s.x, fi - s.y, fi - s.z, fi - s.w);
      *(float4*)(Mout + idx) = o;
    }
    return;
  }
  __shared__ __align__(16) unsigned short Alds[2][128][32];
  __shared__ __align__(16) unsigned short Blds[2][128][32];
  int mt = bid & 31, nt = bid >> 5;   // nt 0..5
  int wave = threadIdx.x >> 6, lane = threadIdx.x & 63;
  int lr = lane & 15, lg = lane >> 4;
  int m0 = mt * 128;
  int n0 = nt * 128;

  int srow = lane >> 2;
  int sslot = (lane & 3) ^ (srow & 3);

#define STAGE_AB(BUF, K0)                                                       \
  {                                                                             \
    _Pragma("unroll")                                                           \
    for (int p = 0; p < 2; ++p) {                                               \
      int ar = wave * 32 + p * 16 + srow;                                       \
      gload_lds16(yhb + (size_t)(m0 + ar) * CC + (K0) + (sslot << 3),           \
                  &Alds[BUF][wave * 32 + p * 16][0]);                           \
      gload_lds16(wpT + (size_t)(n0 + ar) * CC + (K0) + (sslot << 3),           \
                  &Blds[BUF][wave * 32 + p * 16][0]);                           \
    }                                                                           \
  }

  f32x4 acc[2][8];
#pragma unroll
  for (int mi = 0; mi < 2; ++mi)
#pragma unroll
    for (int nj = 0; nj < 8; ++nj) acc[mi][nj] = (f32x4){0.f, 0.f, 0.f, 0.f};

  STAGE_AB(0, 0)
  __syncthreads();

  int fslot = lg ^ (lr & 3);
  for (int kt = 0; kt < 24; ++kt) {
    int cur = kt & 1;
    if (kt < 23) STAGE_AB(cur ^ 1, (kt + 1) * 32)
    bf16x8 af[2], bf[8];
#pragma unroll
    for (int mi = 0; mi < 2; ++mi)
      af[mi] = *(const bf16x8*)&Alds[cur][wave * 32 + mi * 16 + lr][fslot << 3];
#pragma unroll
    for (int nj = 0; nj < 8; ++nj)
      bf[nj] = *(const bf16x8*)&Blds[cur][nj * 16 + lr][fslot << 3];
    __builtin_amdgcn_s_setprio(1);
#pragma unroll
    for (int nj = 0; nj < 8; ++nj)
#pragma unroll
      for (int mi = 0; mi < 2; ++mi)
        acc[mi][nj] = __builtin_amdgcn_mfma_f32_16x16x32_bf16(af[mi], bf[nj], acc[mi][nj], 0, 0, 0);
    __builtin_amdgcn_s_setprio(0);
    __syncthreads();
  }
#undef STAGE_AB

  float bias[8];
#pragma unroll
  for (int nj = 0; nj < 8; ++nj) bias[nj] = b_proj[n0 + nj * 16 + lr];
#pragma unroll
  for (int mi = 0; mi < 2; ++mi)
#pragma unroll
    for (int r = 0; r < 4; ++r) {
      int m = m0 + wave * 32 + mi * 16 + lg * 4 + r;
#pragma unroll
      for (int nj = 0; nj < 8; ++nj)
        y[(size_t)m * CC + n0 + nj * 16 + lr] = acc[mi][nj][r] + bias[nj];
    }
}

// ---------------------------------------------------------------------------
extern "C" void kernel_launch(void* const* d_in, const int* in_sizes, int n_in,
                              void* d_out, int out_size, void* d_ws, size_t ws_size,
                              hipStream_t stream) {
  const float* x      = (const float*)d_in[0];
  const float* w_attn = (const float*)d_in[1];
  const float* b_attn = (const float*)d_in[2];
  const float* w_proj = (const float*)d_in[3];
  const float* b_proj = (const float*)d_in[4];

  float* y    = (float*)d_out;          // [B,T,C]
  float* Mreg = y + Y_ELEMS;            // [B,T,T]: S0 (scratch) -> M (final)

  float* ws = (float*)d_ws;
  float* q0       = ws;                               // B*T*64
  float* k0       = q0 + (size_t)BB * TT * HD;
  float* partials = k0 + (size_t)BB * TT * HD;        // B*32*T
  float* ffpart   = partials + (size_t)BB * 32 * TT;  // B*8*T
  unsigned short* xb  = (unsigned short*)(ffpart + (size_t)BB * 8 * TT);  // B*T*C
  unsigned short* wbT = xb + (size_t)Y_ELEMS;                 // 2304*768
  unsigned short* wpT = wbT + (size_t)N3 * CC;                // 768*768
  unsigned short* Qb  = wpT + (size_t)CC * CC;                // B*NH*T*HD
  unsigned short* Kb  = Qb + (size_t)BB * NH * TT * HD;
  unsigned short* Vt  = Kb + (size_t)BB * NH * TT * HD;
  unsigned short* yhb = Vt + (size_t)BB * NH * TT * HD;       // B*T*C
  unsigned short* Eb  = yhb + (size_t)Y_ELEMS;                // B*T*T bf16 (16.8MB)
  // total ws usage ~= 46 MB

  // 1. fused prep: qk0 (long blocks first) + packs + weight transposes
  prep_fused<<<2368, 256, 0, stream>>>(x, w_attn, w_proj, b_attn,
                                       xb, wbT, wpT, q0, k0);
  // 2. bf16 MFMA QKV GEMM
  gemm_qkv_bf16<<<dim3(32, 18), 256, 0, stream>>>(xb, wbT, b_attn, Qb, Kb, Vt);
  // 3. head-0 scores (fp32) into Mreg + fused per-chunk column partial sums
  score0_kernel<<<dim3(32, 32, BB), 256, 0, stream>>>(q0, k0, Mreg, partials);
  // 4. scan: E = exp(-FF) bf16 (jswz) + ffpart row sums (batched loads)
  scan_write<<<dim3(8, 32, BB), 256, 0, stream>>>(Mreg, partials, Eb, ffpart);
  // 5. MFMA flash attention (R9 form + balanced g4 permutation)
  attn_mfma<<<dim3(24, 32), 256, 0, stream>>>(Qb, Kb, Vt, Eb, yhb);
  // 6. fused proj GEMM (128x128) + M writer
  proj_m_fused<<<1216, 256, 0, stream>>>(yhb, wpT, b_proj, y, ffpart, Mreg);
}

// Round 17
// 160.086 us; speedup vs baseline: 3.1534x; 1.0636x over previous
//
#include <hip/hip_runtime.h>
#include <cstddef>

// Problem constants
#define TT 2048
#define BB 2
#define CC 768
#define NH 12
#define HD 64
#define N3 2304          // 3*NH*HD
#define Y_ELEMS (BB*TT*CC)          // 3145728
#define M_ELEMS (BB*TT*TT)          // 8388608

typedef __attribute__((ext_vector_type(8))) short bf16x8;
typedef __attribute__((ext_vector_type(4))) float f32x4;

__device__ inline unsigned short f2b(float f) {
  union { float f; unsigned u; } v; v.f = f;
  unsigned r = (v.u + 0x7FFFu + ((v.u >> 16) & 1u)) >> 16;
  return (unsigned short)r;
}
__device__ inline float b2f(unsigned short u) {
  union { unsigned u; float f; } v; v.u = (unsigned)u << 16; return v.f;
}

// async global -> LDS, 16B per lane; lds dest is wave-uniform base, HW adds lane*16
__device__ inline void gload_lds16(const unsigned short* g, unsigned short* l) {
  __builtin_amdgcn_global_load_lds(
      (const __attribute__((address_space(1))) unsigned int*)g,
      (__attribute__((address_space(3))) unsigned int*)l, 16, 0, 0);
}

// ---------------------------------------------------------------------------
// FUSED prep + head-0 qk kernel (1D grid, 2368 blocks):
//   bid <   256 : fp32 GEMM q0/k0 (32x64 tile) — LONG blocks first.
//   bid <  1792 : pack x (fp32 -> bf16)
//   bid <  2224 : transpose-pack w_attn -> wbT
//   else        : transpose-pack w_proj -> wpT
// ---------------------------------------------------------------------------
__global__ __launch_bounds__(256) void prep_fused(
    const float* __restrict__ x, const float* __restrict__ w_attn,
    const float* __restrict__ w_proj, const float* __restrict__ b_attn,
    unsigned short* __restrict__ xb, unsigned short* __restrict__ wbT,
    unsigned short* __restrict__ wpT,
    float* __restrict__ q0, float* __restrict__ k0) {
  int bid = blockIdx.x;
  int tid = threadIdx.x;
  if (bid < 256) {
    __shared__ float As[16][32];
    __shared__ float Bs[16][64];
    int sec = bid >> 7;
    int mt = bid & 127;
    const float* Bw = w_attn + sec * CC;
    float* Out = sec ? k0 : q0;
    int tx = tid & 15, ty = tid >> 4;
    int m0 = mt * 32;

    int arow = tid >> 3;
    int acol2 = (tid & 7) << 1;
    int brow = tid >> 4;
    int bcol4 = (tid & 15) << 2;

    const float* Aptr = x + (size_t)(m0 + arow) * CC + acol2;
    const float* Bptr = Bw + (size_t)brow * N3 + bcol4;

    float acc[2][4] = {};
    for (int k0_ = 0; k0_ < CC; k0_ += 16) {
      float2 av = *(const float2*)(Aptr + k0_);
      float4 bv = *(const float4*)(Bptr + (size_t)k0_ * N3);
      As[acol2 + 0][arow] = av.x;
      As[acol2 + 1][arow] = av.y;
      *(float4*)&Bs[brow][bcol4] = bv;
      __syncthreads();
#pragma unroll
      for (int kk = 0; kk < 16; ++kk) {
        float2 a2 = *(const float2*)&As[kk][ty << 1];
        float4 b4 = *(const float4*)&Bs[kk][tx << 2];
        float a[2] = {a2.x, a2.y};
        float b[4] = {b4.x, b4.y, b4.z, b4.w};
#pragma unroll
        for (int ii = 0; ii < 2; ++ii)
#pragma unroll
          for (int jj = 0; jj < 4; ++jj) acc[ii][jj] += a[ii] * b[jj];
      }
      __syncthreads();
    }
    float4 bv = *(const float4*)(b_attn + sec * CC + (tx << 2));
#pragma unroll
    for (int ii = 0; ii < 2; ++ii) {
      int m = m0 + (ty << 1) + ii;
      float4 o;
      o.x = acc[ii][0] + bv.x;
      o.y = acc[ii][1] + bv.y;
      o.z = acc[ii][2] + bv.z;
      o.w = acc[ii][3] + bv.w;
      *(float4*)(Out + (size_t)m * HD + (tx << 2)) = o;
    }
    return;
  }
  if (bid < 1792) {
    size_t i = ((size_t)(bid - 256) * 256 + tid) * 8;
    float4 a = *(const float4*)(x + i);
    float4 b = *(const float4*)(x + i + 4);
    ushort4 o0, o1;
    o0.x = f2b(a.x); o0.y = f2b(a.y); o0.z = f2b(a.z); o0.w = f2b(a.w);
    o1.x = f2b(b.x); o1.y = f2b(b.y); o1.z = f2b(b.z); o1.w = f2b(b.w);
    *(ushort4*)(xb + i) = o0;
    *(ushort4*)(xb + i + 4) = o1;
    return;
  }
  const float* W;
  unsigned short* WT;
  int N, kt, nt;
  if (bid < 2224) {
    int t = bid - 1792;
    W = w_attn; WT = wbT; N = N3;
    kt = t % 12; nt = t / 12;
  } else {
    int t = bid - 2224;
    W = w_proj; WT = wpT; N = CC;
    kt = t % 12; nt = t / 12;
  }
  __shared__ float tile[64][65];
  int r = tid >> 4, c4 = (tid & 15) << 2;
#pragma unroll
  for (int rep = 0; rep < 4; ++rep) {
    int row = rep * 16 + r;
    float4 v = *(const float4*)(W + (size_t)(kt * 64 + row) * N + nt * 64 + c4);
    tile[row][c4 + 0] = v.x; tile[row][c4 + 1] = v.y;
    tile[row][c4 + 2] = v.z; tile[row][c4 + 3] = v.w;
  }
  __syncthreads();
#pragma unroll
  for (int rep = 0; rep < 4; ++rep) {
    int nrow = rep * 16 + r;
    ushort4 o;
    o.x = f2b(tile[c4 + 0][nrow]); o.y = f2b(tile[c4 + 1][nrow]);
    o.z = f2b(tile[c4 + 2][nrow]); o.w = f2b(tile[c4 + 3][nrow]);
    *(ushort4*)(WT + (size_t)(nt * 64 + nrow) * CC + kt * 64 + c4) = o;
  }
}

// ---------------------------------------------------------------------------
// FUSED QKV MFMA GEMM + head-0 scores. 1D grid, 2624 blocks:
//   bid <  576 : bf16 MFMA qkv (128x128 tile) — LONG blocks, dispatched first
//   else       : score0 (fp32 64x64 tile + fused column partials) — short
//                blocks that backfill CUs as gemm blocks retire.
// LDS: one 34816B buffer overlaid by both paths.
// ---------------------------------------------------------------------------
__global__ __launch_bounds__(256, 3) void gemm_score_fused(
    const unsigned short* __restrict__ xb, const unsigned short* __restrict__ wbT,
    const float* __restrict__ b_attn,
    unsigned short* __restrict__ Qb, unsigned short* __restrict__ Kb,
    unsigned short* __restrict__ Vt,
    const float* __restrict__ q0, const float* __restrict__ k0,
    float* __restrict__ Sbuf, float* __restrict__ partials) {
  __shared__ __align__(16) unsigned short smem_u[17408];  // 34816 B
  int bid = blockIdx.x;
  int tid = threadIdx.x;

  if (bid >= 576) {
    // ---------------- score0 path (verbatim standalone structure) ----------
    int t = bid - 576;
    int b = t >> 10;
    int rem = t & 1023;
    int it = rem >> 5, jt = rem & 31;
    int i0 = it * 64, j0 = jt * 64;
    if (jt > it) {
      if (tid < 64) partials[((size_t)(b * 32 + it)) * TT + j0 + tid] = 0.f;
      return;
    }
    float (*Qs)[64] = (float(*)[64])smem_u;                  // 16384 B
    float (*Ks)[64] = (float(*)[64])(smem_u + 8192);         // 16384 B
    int row = tid >> 2;
    int dq = (tid & 3) << 2;
    const float* qb = q0 + (size_t)((b * TT) + i0 + row) * HD;
    const float* kb = k0 + (size_t)((b * TT) + j0 + row) * HD;
#pragma unroll
    for (int rep = 0; rep < 4; ++rep) {
      int d = dq + rep * 16;
      float4 qv = *(const float4*)(qb + d);
      float4 kv = *(const float4*)(kb + d);
      Qs[d + 0][row] = qv.x; Qs[d + 1][row] = qv.y;
      Qs[d + 2][row] = qv.z; Qs[d + 3][row] = qv.w;
      Ks[d + 0][row] = kv.x; Ks[d + 1][row] = kv.y;
      Ks[d + 2][row] = kv.z; Ks[d + 3][row] = kv.w;
    }
    __syncthreads();
    int tx = tid & 15, ty = tid >> 4;
    float acc[4][4] = {};
#pragma unroll 8
    for (int kk = 0; kk < 64; ++kk) {
      float4 a4 = *(const float4*)&Qs[kk][ty << 2];
      float4 b4 = *(const float4*)&Ks[kk][tx << 2];
      float a[4] = {a4.x, a4.y, a4.z, a4.w};
      float bb[4] = {b4.x, b4.y, b4.z, b4.w};
#pragma unroll
      for (int ii = 0; ii < 4; ++ii)
#pragma unroll
        for (int jj = 0; jj < 4; ++jj) acc[ii][jj] += a[ii] * bb[jj];
    }
    float red4[4] = {0.f, 0.f, 0.f, 0.f};
#pragma unroll
    for (int ii = 0; ii < 4; ++ii) {
      int r = i0 + (ty << 2) + ii;
      int gi = (b * TT) + r;
      float ov[4];
#pragma unroll
      for (int jj = 0; jj < 4; ++jj) {
        ov[jj] = fmaxf(acc[ii][jj] * 0.125f, 0.f);
        int j = j0 + (tx << 2) + jj;
        if (j >= 1 && j < r) red4[jj] += ov[jj];
      }
      float4 o; o.x = ov[0]; o.y = ov[1]; o.z = ov[2]; o.w = ov[3];
      *(float4*)(Sbuf + (size_t)gi * TT + j0 + (tx << 2)) = o;
    }
    __syncthreads();  // everyone done reading Qs
    *(float4*)&Qs[ty][tx << 2] = *(float4*)red4;
    __syncthreads();
    if (tid < 64) {
      float cs = 0.f;
#pragma unroll
      for (int t2 = 0; t2 < 16; ++t2) cs += Qs[t2][tid];
      partials[((size_t)(b * 32 + it)) * TT + j0 + tid] = cs;
    }
    return;
  }

  // ---------------- bf16 MFMA qkv path ----------------
  unsigned short (*Alds)[128][32] = (unsigned short(*)[128][32])smem_u;
  unsigned short (*Blds)[128][32] = (unsigned short(*)[128][32])(smem_u + 8192);
  unsigned short (*Vlds)[136]     = (unsigned short(*)[136])smem_u;

  int mt = bid & 31, nt = bid >> 5;
  int sec = nt / 6, h0 = (nt % 6) * 2;
  int wave = threadIdx.x >> 6, lane = threadIdx.x & 63;
  int lr = lane & 15, lg = lane >> 4;
  int m0 = mt * 128;
  int n0 = nt * 128;

  int srow = lane >> 2;                 // 0..15 staging row within segment
  int sslot = (lane & 3) ^ (srow & 3);  // pre-swizzled source k-slot (16B units)

#define STAGE_AB(BUF, K0)                                                       \
  {                                                                             \
    _Pragma("unroll")                                                           \
    for (int p = 0; p < 2; ++p) {                                               \
      int ar = wave * 32 + p * 16 + srow;                                       \
      gload_lds16(xb + (size_t)(m0 + ar) * CC + (K0) + (sslot << 3),            \
                  &Alds[BUF][wave * 32 + p * 16][0]);                           \
      gload_lds16(wbT + (size_t)(n0 + ar) * CC + (K0) + (sslot << 3),           \
                  &Blds[BUF][wave * 32 + p * 16][0]);                           \
    }                                                                           \
  }

  f32x4 acc[2][8];
#pragma unroll
  for (int mi = 0; mi < 2; ++mi)
#pragma unroll
    for (int nj = 0; nj < 8; ++nj) acc[mi][nj] = (f32x4){0.f, 0.f, 0.f, 0.f};

  STAGE_AB(0, 0)
  __syncthreads();

  int fslot = lg ^ (lr & 3);  // frag read slot (same involution)
  for (int kt = 0; kt < 24; ++kt) {
    int cur = kt & 1;
    if (kt < 23) STAGE_AB(cur ^ 1, (kt + 1) * 32)
    bf16x8 af[2], bf[8];
#pragma unroll
    for (int mi = 0; mi < 2; ++mi)
      af[mi] = *(const bf16x8*)&Alds[cur][wave * 32 + mi * 16 + lr][fslot << 3];
#pragma unroll
    for (int nj = 0; nj < 8; ++nj)
      bf[nj] = *(const bf16x8*)&Blds[cur][nj * 16 + lr][fslot << 3];
    __builtin_amdgcn_s_setprio(1);
#pragma unroll
    for (int nj = 0; nj < 8; ++nj)
#pragma unroll
      for (int mi = 0; mi < 2; ++mi)
        acc[mi][nj] = __builtin_amdgcn_mfma_f32_16x16x32_bf16(af[mi], bf[nj], acc[mi][nj], 0, 0, 0);
    __builtin_amdgcn_s_setprio(0);
    __syncthreads();
  }
#undef STAGE_AB

  int b = m0 >> 11;
  float bias[8];
#pragma unroll
  for (int nj = 0; nj < 8; ++nj) bias[nj] = b_attn[n0 + nj * 16 + lr];

  if (sec < 2) {
    // Q is pre-scaled by 1/8 (exact in bf16: exponent shift only)
    float qscale = (sec == 0) ? 0.125f : 1.0f;
    unsigned short* OutB = (sec == 0 ? Qb : Kb);
    int tbase = (m0 & 2047) + wave * 32 + lg * 4;
#pragma unroll
    for (int nj = 0; nj < 8; ++nj) {
      int h = h0 + (nj >> 2);
      int d = (nj & 3) * 16 + lr;
      unsigned short* Out = OutB + (size_t)(b * NH + h) * TT * HD;
#pragma unroll
      for (int mi = 0; mi < 2; ++mi)
#pragma unroll
        for (int r = 0; r < 4; ++r) {
          int t = tbase + mi * 16 + r;
          Out[(size_t)t * HD + d] = f2b((acc[mi][nj][r] + bias[nj]) * qscale);
        }
    }
  } else {
    int tl = wave * 32 + lg * 4;
#pragma unroll
    for (int mi = 0; mi < 2; ++mi)
#pragma unroll
      for (int r = 0; r < 4; ++r)
#pragma unroll
        for (int nj = 0; nj < 8; ++nj)
          Vlds[tl + mi * 16 + r][nj * 16 + lr] = f2b(acc[mi][nj][r] + bias[nj]);
    __syncthreads();
    int d = threadIdx.x & 63, tc = threadIdx.x >> 6;
    int tblk = (m0 & 2047);
#pragma unroll
    for (int hh = 0; hh < 2; ++hh) {
      unsigned short* Ov = Vt + ((size_t)(b * NH + h0 + hh) * HD + d) * TT + tblk + tc * 32;
      int c = hh * 64 + d;
#pragma unroll
      for (int i8 = 0; i8 < 4; ++i8) {
        ushort4 o0, o1;
        o0.x = Vlds[tc * 32 + i8 * 8 + 0][c]; o0.y = Vlds[tc * 32 + i8 * 8 + 1][c];
        o0.z = Vlds[tc * 32 + i8 * 8 + 2][c]; o0.w = Vlds[tc * 32 + i8 * 8 + 3][c];
        o1.x = Vlds[tc * 32 + i8 * 8 + 4][c]; o1.y = Vlds[tc * 32 + i8 * 8 + 5][c];
        o1.z = Vlds[tc * 32 + i8 * 8 + 6][c]; o1.w = Vlds[tc * 32 + i8 * 8 + 7][c];
        *(ushort4*)(Ov + i8 * 8) = o0;
        *(ushort4*)(Ov + i8 * 8 + 4) = o1;
      }
    }
  }
}

// ---------------------------------------------------------------------------
// Column-wise exclusive prefix scan over rows (64-row chunks). Emits
// E = exp(-FF) bf16 (j-swizzled) + ffpart row sums. 8-row load batching.
// EARLY EXIT for blocks whose whole column band lies strictly above the
// chunk's diagonal: FF == 0 there and attention never reads that E region
// (row i only loads j < (i_chunk+1)*64), so only ffpart zeros are written.
// ---------------------------------------------------------------------------
__global__ __launch_bounds__(256) void scan_write(
    const float* __restrict__ Sbuf, const float* __restrict__ partials,
    unsigned short* __restrict__ Eb, float* __restrict__ ffpart) {
  int jb = blockIdx.x;
  int chunk = blockIdx.y, b = blockIdx.z;
  int r0 = chunk * 64;
  if (jb * 256 >= r0 + 64) {  // entire band above diagonal: FF=0, E unread
    if (threadIdx.x < 64)
      ffpart[((size_t)(b * 8) + jb) * TT + r0 + threadIdx.x] = 0.f;
    return;
  }
  int j = jb * 256 + threadIdx.x;
  float run = 0.f;
  for (int c = 0; c < chunk; ++c) run += partials[((size_t)(b * 32 + c)) * TT + j];
  int jswz = (j & ~63) | ((j & 15) << 2) | ((j >> 4) & 3);
  const float* base = Sbuf + (size_t)(b * TT + r0) * TT + j;
  unsigned short* ebase = Eb + (size_t)(b * TT + r0) * TT + jswz;
  __shared__ float wsum[4][64];
  int wv = threadIdx.x >> 6;
  for (int rb = 0; rb < 64; rb += 8) {
    float v[8];
#pragma unroll
    for (int u = 0; u < 8; ++u) {
      int r = r0 + rb + u;
      v[u] = (j >= 1 && j < r) ? base[(size_t)(rb + u) * TT] : 0.f;
    }
#pragma unroll
    for (int u = 0; u < 8; ++u) {
      int rr = rb + u;
      ebase[(size_t)rr * TT] = f2b(__expf(-run));  // E (bf16, natural-e)
      float c1 = fminf(run, 1.f);                  // run >= 0 always
#pragma unroll
      for (int o = 1; o < 64; o <<= 1) c1 += __shfl_xor(c1, o);
      if ((threadIdx.x & 63) == 0) wsum[wv][rr] = c1;
      run += v[u];
    }
  }
  __syncthreads();
  if (threadIdx.x < 64)
    ffpart[((size_t)(b * 8) + jb) * TT + r0 + threadIdx.x] =
        wsum[0][threadIdx.x] + wsum[1][threadIdx.x] +
        wsum[2][threadIdx.x] + wsum[3][threadIdx.x];
}

// ---------------------------------------------------------------------------
// bf16 MFMA flash attention (R9-exact measured-best form) + CU-load-balanced
// g4 permutation. Grid (24, 32): XCD = x%8 serves one batch / 3 heads.
// ---------------------------------------------------------------------------
__global__ __launch_bounds__(256, 3) void attn_mfma(
    const unsigned short* __restrict__ Qb, const unsigned short* __restrict__ Kb,
    const unsigned short* __restrict__ Vt, const unsigned short* __restrict__ Eb,
    unsigned short* __restrict__ yhb) {
  int xbh = blockIdx.x;
  int b = (xbh >> 2) & 1;
  int h = ((xbh >> 3) << 2) | (xbh & 3);
  int yy = blockIdx.y;
  int g4 = (yy & 1) ? (yy >> 1) : (31 - (yy >> 1));  // balanced interleave
  int wave = threadIdx.x >> 6, lane = threadIdx.x & 63;
  int lr = lane & 15, lg = lane >> 4;
  int i0 = g4 * 64 + wave * 16;
  int bh = b * NH + h;
  const unsigned short* Qh = Qb + (size_t)bh * TT * HD;
  const unsigned short* Kh = Kb + (size_t)bh * TT * HD;
  const unsigned short* Vh = Vt + (size_t)bh * HD * TT;
  const unsigned short* Erow = Eb + ((size_t)(b * TT) + i0 + lg * 4) * TT + 4 * lr;

  __shared__ __align__(16) unsigned short Ksh[2][64][64];
  __shared__ __align__(16) unsigned short Vsh[2][64][64];
  __shared__ __align__(16) unsigned short Plds[4][16][80];

  int rowoff = lane >> 3;            // 0..7 within an 8-row staging segment
  int sslot  = (lane & 7) ^ rowoff;  // pre-swizzled source slot (16B units)

  bf16x8 qf[2];
#pragma unroll
  for (int ks = 0; ks < 2; ++ks)
    qf[ks] = *(const bf16x8*)(Qh + (size_t)(i0 + lr) * HD + ks * 32 + lg * 8);

  f32x4 acc[4];
  float lrun[4] = {0.f, 0.f, 0.f, 0.f};  // per-lane partial of softmax denom
#pragma unroll
  for (int q = 0; q < 4; ++q) acc[q] = (f32x4){0.f, 0.f, 0.f, 0.f};

#define STAGE_KV(BUF, J0)                                                      \
  {                                                                            \
    _Pragma("unroll")                                                          \
    for (int p = 0; p < 2; ++p) {                                              \
      int r0 = wave * 16 + p * 8;                                              \
      gload_lds16(Kh + (size_t)((J0) + r0 + rowoff) * HD + sslot * 8,          \
                  &Ksh[BUF][r0][0]);                                           \
      gload_lds16(Vh + (size_t)(r0 + rowoff) * TT + (J0) + sslot * 8,          \
                  &Vsh[BUF][r0][0]);                                           \
    }                                                                          \
  }

  STAGE_KV(0, 0)
  __syncthreads();

  for (int kt = 0; kt <= g4; ++kt) {
    int cur = kt & 1;
    int j0 = kt * 64;
    if (kt < g4) STAGE_KV(cur ^ 1, j0 + 64)

    // E for current tile (4 x 8B vector loads, swizzled layout)
    ushort4 ev[4];
#pragma unroll
    for (int r = 0; r < 4; ++r)
      ev[r] = *(const ushort4*)(Erow + (size_t)r * TT + j0);

    // ---- QK^T from swizzled LDS ----
    f32x4 s[4];
    __builtin_amdgcn_s_setprio(1);
#pragma unroll
    for (int nj = 0; nj < 4; ++nj) {
      int row = nj * 16 + lr;
      int sw = row & 7;
      bf16x8 k0f = *(const bf16x8*)&Ksh[cur][row][(lg ^ sw) << 3];
      bf16x8 k1f = *(const bf16x8*)&Ksh[cur][row][((4 + lg) ^ sw) << 3];
      f32x4 z = (f32x4){0.f, 0.f, 0.f, 0.f};
      z = __builtin_amdgcn_mfma_f32_16x16x32_bf16(qf[0], k0f, z, 0, 0, 0);
      s[nj] = __builtin_amdgcn_mfma_f32_16x16x32_bf16(qf[1], k1f, z, 0, 0, 0);
    }
    __builtin_amdgcn_s_setprio(0);

    // ---- causal mask (diagonal tile only) ----
    int ibase = i0 + lg * 4;
    if (kt == g4) {
#pragma unroll
      for (int nj = 0; nj < 4; ++nj)
#pragma unroll
        for (int r = 0; r < 4; ++r)
          if (j0 + nj * 16 + lr > ibase + r) s[nj][r] = -1e30f;
    }

    // ---- P = E * exp(s); per-lane partial l; stash bf16 P in LDS ----
#pragma unroll
    for (int r = 0; r < 4; ++r) {
      float p0 = b2f(ev[r].x) * __expf(s[0][r]);
      float p1 = b2f(ev[r].y) * __expf(s[1][r]);
      float p2 = b2f(ev[r].z) * __expf(s[2][r]);
      float p3 = b2f(ev[r].w) * __expf(s[3][r]);
      lrun[r] += (p0 + p1) + (p2 + p3);
      Plds[wave][lg * 4 + r][0 * 16 + lr] = f2b(p0);
      Plds[wave][lg * 4 + r][1 * 16 + lr] = f2b(p1);
      Plds[wave][lg * 4 + r][2 * 16 + lr] = f2b(p2);
      Plds[wave][lg * 4 + r][3 * 16 + lr] = f2b(p3);
    }

    // ---- PV from swizzled LDS ----
    bf16x8 pa0 = *(const bf16x8*)&Plds[wave][lr][lg * 8];
    bf16x8 pa1 = *(const bf16x8*)&Plds[wave][lr][32 + lg * 8];
    __builtin_amdgcn_s_setprio(1);
#pragma unroll
    for (int nd = 0; nd < 4; ++nd) {
      int row = nd * 16 + lr;
      int sw = row & 7;
      bf16x8 v0f = *(const bf16x8*)&Vsh[cur][row][(lg ^ sw) << 3];
      bf16x8 v1f = *(const bf16x8*)&Vsh[cur][row][((4 + lg) ^ sw) << 3];
      acc[nd] = __builtin_amdgcn_mfma_f32_16x16x32_bf16(pa0, v0f, acc[nd], 0, 0, 0);
      acc[nd] = __builtin_amdgcn_mfma_f32_16x16x32_bf16(pa1, v1f, acc[nd], 0, 0, 0);
    }
    __builtin_amdgcn_s_setprio(0);

    __syncthreads();
  }
#undef STAGE_KV

  // ---- epilogue: one l-reduction across the 16 lr lanes, then store ----
#pragma unroll
  for (int r = 0; r < 4; ++r) {
    lrun[r] += __shfl_xor(lrun[r], 1);
    lrun[r] += __shfl_xor(lrun[r], 2);
    lrun[r] += __shfl_xor(lrun[r], 4);
    lrun[r] += __shfl_xor(lrun[r], 8);
    float inv = 1.f / lrun[r];
    int ig = i0 + lg * 4 + r;
    unsigned short* ob = yhb + (size_t)(b * TT + ig) * CC + h * HD;
#pragma unroll
    for (int nd = 0; nd < 4; ++nd)
      ob[nd * 16 + lr] = f2b(acc[nd][r] * inv);
  }
}

// ---------------------------------------------------------------------------
// FUSED proj GEMM + M writer (1D grid, 1216 blocks):
//   bid < 192 : y = yhb @ wpT^T + b_proj (128x128 MFMA tile)
//   else      : M[0,b,i,j] = i - sum_jb ffpart[b][jb][j] (float4, grid-stride)
// ---------------------------------------------------------------------------
__global__ __launch_bounds__(256, 3) void proj_m_fused(
    const unsigned short* __restrict__ yhb, const unsigned short* __restrict__ wpT,
    const float* __restrict__ b_proj, float* __restrict__ y,
    const float* __restrict__ ffpart, float* __restrict__ Mout) {
  int bid = blockIdx.x;
  if (bid >= 192) {
    int idx4 = (bid - 192) * 256 + threadIdx.x;
    int stride = (gridDim.x - 192) * 256;
    for (; idx4 < M_ELEMS / 4; idx4 += stride) {
      int idx = idx4 << 2;
      int j = idx & (TT - 1);
      int i = (idx >> 11) & (TT - 1);
      int b = idx >> 22;
      const float* fp = ffpart + ((size_t)(b * 8)) * TT + j;
      float4 s = make_float4(0.f, 0.f, 0.f, 0.f);
#pragma unroll
      for (int p = 0; p < 8; ++p) {
        float4 v = *(const float4*)(fp + (size_t)p * TT);
        s.x += v.x; s.y += v.y; s.z += v.z; s.w += v.w;
      }
      float fi = (float)i;
      float4 o = make_float4(fi - s.x, fi - s.y, fi - s.z, fi - s.w);
      *(float4*)(Mout + idx) = o;
    }
    return;
  }
  __shared__ __align__(16) unsigned short Alds[2][128][32];
  __shared__ __align__(16) unsigned short Blds[2][128][32];
  int mt = bid & 31, nt = bid >> 5;   // nt 0..5
  int wave = threadIdx.x >> 6, lane = threadIdx.x & 63;
  int lr = lane & 15, lg = lane >> 4;
  int m0 = mt * 128;
  int n0 = nt * 128;

  int srow = lane >> 2;
  int sslot = (lane & 3) ^ (srow & 3);

#define STAGE_AB(BUF, K0)                                                       \
  {                                                                             \
    _Pragma("unroll")                                                           \
    for (int p = 0; p < 2; ++p) {                                               \
      int ar = wave * 32 + p * 16 + srow;                                       \
      gload_lds16(yhb + (size_t)(m0 + ar) * CC + (K0) + (sslot << 3),           \
                  &Alds[BUF][wave * 32 + p * 16][0]);                           \
      gload_lds16(wpT + (size_t)(n0 + ar) * CC + (K0) + (sslot << 3),           \
                  &Blds[BUF][wave * 32 + p * 16][0]);                           \
    }                                                                           \
  }

  f32x4 acc[2][8];
#pragma unroll
  for (int mi = 0; mi < 2; ++mi)
#pragma unroll
    for (int nj = 0; nj < 8; ++nj) acc[mi][nj] = (f32x4){0.f, 0.f, 0.f, 0.f};

  STAGE_AB(0, 0)
  __syncthreads();

  int fslot = lg ^ (lr & 3);
  for (int kt = 0; kt < 24; ++kt) {
    int cur = kt & 1;
    if (kt < 23) STAGE_AB(cur ^ 1, (kt + 1) * 32)
    bf16x8 af[2], bf[8];
#pragma unroll
    for (int mi = 0; mi < 2; ++mi)
      af[mi] = *(const bf16x8*)&Alds[cur][wave * 32 + mi * 16 + lr][fslot << 3];
#pragma unroll
    for (int nj = 0; nj < 8; ++nj)
      bf[nj] = *(const bf16x8*)&Blds[cur][nj * 16 + lr][fslot << 3];
    __builtin_amdgcn_s_setprio(1);
#pragma unroll
    for (int nj = 0; nj < 8; ++nj)
#pragma unroll
      for (int mi = 0; mi < 2; ++mi)
        acc[mi][nj] = __builtin_amdgcn_mfma_f32_16x16x32_bf16(af[mi], bf[nj], acc[mi][nj], 0, 0, 0);
    __builtin_amdgcn_s_setprio(0);
    __syncthreads();
  }
#undef STAGE_AB

  float bias[8];
#pragma unroll
  for (int nj = 0; nj < 8; ++nj) bias[nj] = b_proj[n0 + nj * 16 + lr];
#pragma unroll
  for (int mi = 0; mi < 2; ++mi)
#pragma unroll
    for (int r = 0; r < 4; ++r) {
      int m = m0 + wave * 32 + mi * 16 + lg * 4 + r;
#pragma unroll
      for (int nj = 0; nj < 8; ++nj)
        y[(size_t)m * CC + n0 + nj * 16 + lr] = acc[mi][nj][r] + bias[nj];
    }
}

// ---------------------------------------------------------------------------
extern "C" void kernel_launch(void* const* d_in, const int* in_sizes, int n_in,
                              void* d_out, int out_size, void* d_ws, size_t ws_size,
                              hipStream_t stream) {
  const float* x      = (const float*)d_in[0];
  const float* w_attn = (const float*)d_in[1];
  const float* b_attn = (const float*)d_in[2];
  const float* w_proj = (const float*)d_in[3];
  const float* b_proj = (const float*)d_in[4];

  float* y    = (float*)d_out;          // [B,T,C]
  float* Mreg = y + Y_ELEMS;            // [B,T,T]: S0 (scratch) -> M (final)

  float* ws = (float*)d_ws;
  float* q0       = ws;                               // B*T*64
  float* k0       = q0 + (size_t)BB * TT * HD;
  float* partials = k0 + (size_t)BB * TT * HD;        // B*32*T
  float* ffpart   = partials + (size_t)BB * 32 * TT;  // B*8*T
  unsigned short* xb  = (unsigned short*)(ffpart + (size_t)BB * 8 * TT);  // B*T*C
  unsigned short* wbT = xb + (size_t)Y_ELEMS;                 // 2304*768
  unsigned short* wpT = wbT + (size_t)N3 * CC;                // 768*768
  unsigned short* Qb  = wpT + (size_t)CC * CC;                // B*NH*T*HD
  unsigned short* Kb  = Qb + (size_t)BB * NH * TT * HD;
  unsigned short* Vt  = Kb + (size_t)BB * NH * TT * HD;
  unsigned short* yhb = Vt + (size_t)BB * NH * TT * HD;       // B*T*C
  unsigned short* Eb  = yhb + (size_t)Y_ELEMS;                // B*T*T bf16 (16.8MB)
  // total ws usage ~= 46 MB

  // 1. fused prep: qk0 (long blocks first) + packs + weight transposes
  prep_fused<<<2368, 256, 0, stream>>>(x, w_attn, w_proj, b_attn,
                                       xb, wbT, wpT, q0, k0);
  // 2. fused QKV MFMA GEMM (576 long blocks first) + score0 (short backfill)
  gemm_score_fused<<<2624, 256, 0, stream>>>(
      xb, wbT, b_attn, Qb, Kb, Vt, q0, k0, Mreg, partials);
  // 3. scan: E = exp(-FF) bf16 (jswz) + ffpart row sums; upper-tri early-exit
  scan_write<<<dim3(8, 32, BB), 256, 0, stream>>>(Mreg, partials, Eb, ffpart);
  // 4. MFMA flash attention (R9 form + balanced g4 permutation)
  attn_mfma<<<dim3(24, 32), 256, 0, stream>>>(Qb, Kb, Vt, Eb, yhb);
  // 5. fused proj GEMM (128x128) + M writer
  proj_m_fused<<<1216, 256, 0, stream>>>(yhb, wpT, b_proj, y, ffpart, Mreg);
}

// Round 18
// 159.765 us; speedup vs baseline: 3.1597x; 1.0020x over previous
//
#include <hip/hip_runtime.h>
#include <cstddef>

// Problem constants
#define TT 2048
#define BB 2
#define CC 768
#define NH 12
#define HD 64
#define N3 2304          // 3*NH*HD
#define Y_ELEMS (BB*TT*CC)          // 3145728
#define M_ELEMS (BB*TT*TT)          // 8388608

typedef __attribute__((ext_vector_type(8))) short bf16x8;
typedef __attribute__((ext_vector_type(4))) float f32x4;

__device__ inline unsigned short f2b(float f) {
  union { float f; unsigned u; } v; v.f = f;
  unsigned r = (v.u + 0x7FFFu + ((v.u >> 16) & 1u)) >> 16;
  return (unsigned short)r;
}
__device__ inline float b2f(unsigned short u) {
  union { unsigned u; float f; } v; v.u = (unsigned)u << 16; return v.f;
}

// async global -> LDS, 16B per lane; lds dest is wave-uniform base, HW adds lane*16
__device__ inline void gload_lds16(const unsigned short* g, unsigned short* l) {
  __builtin_amdgcn_global_load_lds(
      (const __attribute__((address_space(1))) unsigned int*)g,
      (__attribute__((address_space(3))) unsigned int*)l, 16, 0, 0);
}

// ---------------------------------------------------------------------------
// FUSED prep + head-0 qk kernel (1D grid, 2368 blocks):
//   bid <   256 : fp32 GEMM q0/k0 (32x64 tile) — LONG blocks first.
//   bid <  1792 : pack x (fp32 -> bf16)
//   bid <  2224 : transpose-pack w_attn -> wbT
//   else        : transpose-pack w_proj -> wpT
// ---------------------------------------------------------------------------
__global__ __launch_bounds__(256) void prep_fused(
    const float* __restrict__ x, const float* __restrict__ w_attn,
    const float* __restrict__ w_proj, const float* __restrict__ b_attn,
    unsigned short* __restrict__ xb, unsigned short* __restrict__ wbT,
    unsigned short* __restrict__ wpT,
    float* __restrict__ q0, float* __restrict__ k0) {
  int bid = blockIdx.x;
  int tid = threadIdx.x;
  if (bid < 256) {
    __shared__ float As[16][32];
    __shared__ float Bs[16][64];
    int sec = bid >> 7;
    int mt = bid & 127;
    const float* Bw = w_attn + sec * CC;
    float* Out = sec ? k0 : q0;
    int tx = tid & 15, ty = tid >> 4;
    int m0 = mt * 32;

    int arow = tid >> 3;
    int acol2 = (tid & 7) << 1;
    int brow = tid >> 4;
    int bcol4 = (tid & 15) << 2;

    const float* Aptr = x + (size_t)(m0 + arow) * CC + acol2;
    const float* Bptr = Bw + (size_t)brow * N3 + bcol4;

    float acc[2][4] = {};
    for (int k0_ = 0; k0_ < CC; k0_ += 16) {
      float2 av = *(const float2*)(Aptr + k0_);
      float4 bv = *(const float4*)(Bptr + (size_t)k0_ * N3);
      As[acol2 + 0][arow] = av.x;
      As[acol2 + 1][arow] = av.y;
      *(float4*)&Bs[brow][bcol4] = bv;
      __syncthreads();
#pragma unroll
      for (int kk = 0; kk < 16; ++kk) {
        float2 a2 = *(const float2*)&As[kk][ty << 1];
        float4 b4 = *(const float4*)&Bs[kk][tx << 2];
        float a[2] = {a2.x, a2.y};
        float b[4] = {b4.x, b4.y, b4.z, b4.w};
#pragma unroll
        for (int ii = 0; ii < 2; ++ii)
#pragma unroll
          for (int jj = 0; jj < 4; ++jj) acc[ii][jj] += a[ii] * b[jj];
      }
      __syncthreads();
    }
    float4 bv = *(const float4*)(b_attn + sec * CC + (tx << 2));
#pragma unroll
    for (int ii = 0; ii < 2; ++ii) {
      int m = m0 + (ty << 1) + ii;
      float4 o;
      o.x = acc[ii][0] + bv.x;
      o.y = acc[ii][1] + bv.y;
      o.z = acc[ii][2] + bv.z;
      o.w = acc[ii][3] + bv.w;
      *(float4*)(Out + (size_t)m * HD + (tx << 2)) = o;
    }
    return;
  }
  if (bid < 1792) {
    size_t i = ((size_t)(bid - 256) * 256 + tid) * 8;
    float4 a = *(const float4*)(x + i);
    float4 b = *(const float4*)(x + i + 4);
    ushort4 o0, o1;
    o0.x = f2b(a.x); o0.y = f2b(a.y); o0.z = f2b(a.z); o0.w = f2b(a.w);
    o1.x = f2b(b.x); o1.y = f2b(b.y); o1.z = f2b(b.z); o1.w = f2b(b.w);
    *(ushort4*)(xb + i) = o0;
    *(ushort4*)(xb + i + 4) = o1;
    return;
  }
  const float* W;
  unsigned short* WT;
  int N, kt, nt;
  if (bid < 2224) {
    int t = bid - 1792;
    W = w_attn; WT = wbT; N = N3;
    kt = t % 12; nt = t / 12;
  } else {
    int t = bid - 2224;
    W = w_proj; WT = wpT; N = CC;
    kt = t % 12; nt = t / 12;
  }
  __shared__ float tile[64][65];
  int r = tid >> 4, c4 = (tid & 15) << 2;
#pragma unroll
  for (int rep = 0; rep < 4; ++rep) {
    int row = rep * 16 + r;
    float4 v = *(const float4*)(W + (size_t)(kt * 64 + row) * N + nt * 64 + c4);
    tile[row][c4 + 0] = v.x; tile[row][c4 + 1] = v.y;
    tile[row][c4 + 2] = v.z; tile[row][c4 + 3] = v.w;
  }
  __syncthreads();
#pragma unroll
  for (int rep = 0; rep < 4; ++rep) {
    int nrow = rep * 16 + r;
    ushort4 o;
    o.x = f2b(tile[c4 + 0][nrow]); o.y = f2b(tile[c4 + 1][nrow]);
    o.z = f2b(tile[c4 + 2][nrow]); o.w = f2b(tile[c4 + 3][nrow]);
    *(ushort4*)(WT + (size_t)(nt * 64 + nrow) * CC + kt * 64 + c4) = o;
  }
}

// ---------------------------------------------------------------------------
// FUSED QKV MFMA GEMM + head-0 scores. 1D grid, 2624 blocks:
//   bid <  576 : bf16 MFMA qkv (128x128 tile) — LONG blocks, dispatched first
//   else       : score0 (fp32 64x64 tile + fused column partials) — short
//                blocks that backfill CUs as gemm blocks retire.
// LDS: one 34816B buffer overlaid by both paths.
// ---------------------------------------------------------------------------
__global__ __launch_bounds__(256, 3) void gemm_score_fused(
    const unsigned short* __restrict__ xb, const unsigned short* __restrict__ wbT,
    const float* __restrict__ b_attn,
    unsigned short* __restrict__ Qb, unsigned short* __restrict__ Kb,
    unsigned short* __restrict__ Vt,
    const float* __restrict__ q0, const float* __restrict__ k0,
    float* __restrict__ Sbuf, float* __restrict__ partials) {
  __shared__ __align__(16) unsigned short smem_u[17408];  // 34816 B
  int bid = blockIdx.x;
  int tid = threadIdx.x;

  if (bid >= 576) {
    // ---------------- score0 path (verbatim standalone structure) ----------
    int t = bid - 576;
    int b = t >> 10;
    int rem = t & 1023;
    int it = rem >> 5, jt = rem & 31;
    int i0 = it * 64, j0 = jt * 64;
    if (jt > it) {
      if (tid < 64) partials[((size_t)(b * 32 + it)) * TT + j0 + tid] = 0.f;
      return;
    }
    float (*Qs)[64] = (float(*)[64])smem_u;                  // 16384 B
    float (*Ks)[64] = (float(*)[64])(smem_u + 8192);         // 16384 B
    int row = tid >> 2;
    int dq = (tid & 3) << 2;
    const float* qb = q0 + (size_t)((b * TT) + i0 + row) * HD;
    const float* kb = k0 + (size_t)((b * TT) + j0 + row) * HD;
#pragma unroll
    for (int rep = 0; rep < 4; ++rep) {
      int d = dq + rep * 16;
      float4 qv = *(const float4*)(qb + d);
      float4 kv = *(const float4*)(kb + d);
      Qs[d + 0][row] = qv.x; Qs[d + 1][row] = qv.y;
      Qs[d + 2][row] = qv.z; Qs[d + 3][row] = qv.w;
      Ks[d + 0][row] = kv.x; Ks[d + 1][row] = kv.y;
      Ks[d + 2][row] = kv.z; Ks[d + 3][row] = kv.w;
    }
    __syncthreads();
    int tx = tid & 15, ty = tid >> 4;
    float acc[4][4] = {};
#pragma unroll 8
    for (int kk = 0; kk < 64; ++kk) {
      float4 a4 = *(const float4*)&Qs[kk][ty << 2];
      float4 b4 = *(const float4*)&Ks[kk][tx << 2];
      float a[4] = {a4.x, a4.y, a4.z, a4.w};
      float bb[4] = {b4.x, b4.y, b4.z, b4.w};
#pragma unroll
      for (int ii = 0; ii < 4; ++ii)
#pragma unroll
        for (int jj = 0; jj < 4; ++jj) acc[ii][jj] += a[ii] * bb[jj];
    }
    float red4[4] = {0.f, 0.f, 0.f, 0.f};
#pragma unroll
    for (int ii = 0; ii < 4; ++ii) {
      int r = i0 + (ty << 2) + ii;
      int gi = (b * TT) + r;
      float ov[4];
#pragma unroll
      for (int jj = 0; jj < 4; ++jj) {
        ov[jj] = fmaxf(acc[ii][jj] * 0.125f, 0.f);
        int j = j0 + (tx << 2) + jj;
        if (j >= 1 && j < r) red4[jj] += ov[jj];
      }
      float4 o; o.x = ov[0]; o.y = ov[1]; o.z = ov[2]; o.w = ov[3];
      *(float4*)(Sbuf + (size_t)gi * TT + j0 + (tx << 2)) = o;
    }
    __syncthreads();  // everyone done reading Qs
    *(float4*)&Qs[ty][tx << 2] = *(float4*)red4;
    __syncthreads();
    if (tid < 64) {
      float cs = 0.f;
#pragma unroll
      for (int t2 = 0; t2 < 16; ++t2) cs += Qs[t2][tid];
      partials[((size_t)(b * 32 + it)) * TT + j0 + tid] = cs;
    }
    return;
  }

  // ---------------- bf16 MFMA qkv path ----------------
  unsigned short (*Alds)[128][32] = (unsigned short(*)[128][32])smem_u;
  unsigned short (*Blds)[128][32] = (unsigned short(*)[128][32])(smem_u + 8192);
  unsigned short (*Vlds)[136]     = (unsigned short(*)[136])smem_u;

  int mt = bid & 31, nt = bid >> 5;
  int sec = nt / 6, h0 = (nt % 6) * 2;
  int wave = threadIdx.x >> 6, lane = threadIdx.x & 63;
  int lr = lane & 15, lg = lane >> 4;
  int m0 = mt * 128;
  int n0 = nt * 128;

  int srow = lane >> 2;                 // 0..15 staging row within segment
  int sslot = (lane & 3) ^ (srow & 3);  // pre-swizzled source k-slot (16B units)

#define STAGE_AB(BUF, K0)                                                       \
  {                                                                             \
    _Pragma("unroll")                                                           \
    for (int p = 0; p < 2; ++p) {                                               \
      int ar = wave * 32 + p * 16 + srow;                                       \
      gload_lds16(xb + (size_t)(m0 + ar) * CC + (K0) + (sslot << 3),            \
                  &Alds[BUF][wave * 32 + p * 16][0]);                           \
      gload_lds16(wbT + (size_t)(n0 + ar) * CC + (K0) + (sslot << 3),           \
                  &Blds[BUF][wave * 32 + p * 16][0]);                           \
    }                                                                           \
  }

  f32x4 acc[2][8];
#pragma unroll
  for (int mi = 0; mi < 2; ++mi)
#pragma unroll
    for (int nj = 0; nj < 8; ++nj) acc[mi][nj] = (f32x4){0.f, 0.f, 0.f, 0.f};

  STAGE_AB(0, 0)
  __syncthreads();

  int fslot = lg ^ (lr & 3);  // frag read slot (same involution)
  for (int kt = 0; kt < 24; ++kt) {
    int cur = kt & 1;
    if (kt < 23) STAGE_AB(cur ^ 1, (kt + 1) * 32)
    bf16x8 af[2], bf[8];
#pragma unroll
    for (int mi = 0; mi < 2; ++mi)
      af[mi] = *(const bf16x8*)&Alds[cur][wave * 32 + mi * 16 + lr][fslot << 3];
#pragma unroll
    for (int nj = 0; nj < 8; ++nj)
      bf[nj] = *(const bf16x8*)&Blds[cur][nj * 16 + lr][fslot << 3];
    __builtin_amdgcn_s_setprio(1);
#pragma unroll
    for (int nj = 0; nj < 8; ++nj)
#pragma unroll
      for (int mi = 0; mi < 2; ++mi)
        acc[mi][nj] = __builtin_amdgcn_mfma_f32_16x16x32_bf16(af[mi], bf[nj], acc[mi][nj], 0, 0, 0);
    __builtin_amdgcn_s_setprio(0);
    __syncthreads();
  }
#undef STAGE_AB

  int b = m0 >> 11;
  float bias[8];
#pragma unroll
  for (int nj = 0; nj < 8; ++nj) bias[nj] = b_attn[n0 + nj * 16 + lr];

  if (sec < 2) {
    // Q is pre-scaled by 1/8 (exact in bf16: exponent shift only)
    float qscale = (sec == 0) ? 0.125f : 1.0f;
    unsigned short* OutB = (sec == 0 ? Qb : Kb);
    int tbase = (m0 & 2047) + wave * 32 + lg * 4;
#pragma unroll
    for (int nj = 0; nj < 8; ++nj) {
      int h = h0 + (nj >> 2);
      int d = (nj & 3) * 16 + lr;
      unsigned short* Out = OutB + (size_t)(b * NH + h) * TT * HD;
#pragma unroll
      for (int mi = 0; mi < 2; ++mi)
#pragma unroll
        for (int r = 0; r < 4; ++r) {
          int t = tbase + mi * 16 + r;
          Out[(size_t)t * HD + d] = f2b((acc[mi][nj][r] + bias[nj]) * qscale);
        }
    }
  } else {
    int tl = wave * 32 + lg * 4;
#pragma unroll
    for (int mi = 0; mi < 2; ++mi)
#pragma unroll
      for (int r = 0; r < 4; ++r)
#pragma unroll
        for (int nj = 0; nj < 8; ++nj)
          Vlds[tl + mi * 16 + r][nj * 16 + lr] = f2b(acc[mi][nj][r] + bias[nj]);
    __syncthreads();
    int d = threadIdx.x & 63, tc = threadIdx.x >> 6;
    int tblk = (m0 & 2047);
#pragma unroll
    for (int hh = 0; hh < 2; ++hh) {
      unsigned short* Ov = Vt + ((size_t)(b * NH + h0 + hh) * HD + d) * TT + tblk + tc * 32;
      int c = hh * 64 + d;
#pragma unroll
      for (int i8 = 0; i8 < 4; ++i8) {
        ushort4 o0, o1;
        o0.x = Vlds[tc * 32 + i8 * 8 + 0][c]; o0.y = Vlds[tc * 32 + i8 * 8 + 1][c];
        o0.z = Vlds[tc * 32 + i8 * 8 + 2][c]; o0.w = Vlds[tc * 32 + i8 * 8 + 3][c];
        o1.x = Vlds[tc * 32 + i8 * 8 + 4][c]; o1.y = Vlds[tc * 32 + i8 * 8 + 5][c];
        o1.z = Vlds[tc * 32 + i8 * 8 + 6][c]; o1.w = Vlds[tc * 32 + i8 * 8 + 7][c];
        *(ushort4*)(Ov + i8 * 8) = o0;
        *(ushort4*)(Ov + i8 * 8 + 4) = o1;
      }
    }
  }
}

// ---------------------------------------------------------------------------
// Column-wise exclusive prefix scan over rows (64-row chunks). Emits
// E = exp(-FF) bf16 (j-swizzled) + ffpart row sums. 8-row load batching.
// EARLY EXIT for blocks whose whole column band lies above the diagonal.
// ---------------------------------------------------------------------------
__global__ __launch_bounds__(256) void scan_write(
    const float* __restrict__ Sbuf, const float* __restrict__ partials,
    unsigned short* __restrict__ Eb, float* __restrict__ ffpart) {
  int jb = blockIdx.x;
  int chunk = blockIdx.y, b = blockIdx.z;
  int r0 = chunk * 64;
  if (jb * 256 >= r0 + 64) {  // entire band above diagonal: FF=0, E unread
    if (threadIdx.x < 64)
      ffpart[((size_t)(b * 8) + jb) * TT + r0 + threadIdx.x] = 0.f;
    return;
  }
  int j = jb * 256 + threadIdx.x;
  float run = 0.f;
  for (int c = 0; c < chunk; ++c) run += partials[((size_t)(b * 32 + c)) * TT + j];
  int jswz = (j & ~63) | ((j & 15) << 2) | ((j >> 4) & 3);
  const float* base = Sbuf + (size_t)(b * TT + r0) * TT + j;
  unsigned short* ebase = Eb + (size_t)(b * TT + r0) * TT + jswz;
  __shared__ float wsum[4][64];
  int wv = threadIdx.x >> 6;
  for (int rb = 0; rb < 64; rb += 8) {
    float v[8];
#pragma unroll
    for (int u = 0; u < 8; ++u) {
      int r = r0 + rb + u;
      v[u] = (j >= 1 && j < r) ? base[(size_t)(rb + u) * TT] : 0.f;
    }
#pragma unroll
    for (int u = 0; u < 8; ++u) {
      int rr = rb + u;
      ebase[(size_t)rr * TT] = f2b(__expf(-run));  // E (bf16, natural-e)
      float c1 = fminf(run, 1.f);                  // run >= 0 always
#pragma unroll
      for (int o = 1; o < 64; o <<= 1) c1 += __shfl_xor(c1, o);
      if ((threadIdx.x & 63) == 0) wsum[wv][rr] = c1;
      run += v[u];
    }
  }
  __syncthreads();
  if (threadIdx.x < 64)
    ffpart[((size_t)(b * 8) + jb) * TT + r0 + threadIdx.x] =
        wsum[0][threadIdx.x] + wsum[1][threadIdx.x] +
        wsum[2][threadIdx.x] + wsum[3][threadIdx.x];
}

// ---------------------------------------------------------------------------
// FUSED attention + M writer (1D grid, 1280 blocks):
//   bid <  768 : bf16 MFMA flash attention (R9 form + balanced g4) — LONG
//                blocks first; XCD = bid%8 serves one batch / 3 heads.
//   else       : M[0,b,i,j] = i - sum_jb ffpart[b][jb][j] — short HBM-store
//                blocks that backfill as light attn blocks retire (attn uses
//                only ~9% HBM BW; attn never reads Mreg).
// ---------------------------------------------------------------------------
__global__ __launch_bounds__(256, 3) void attn_m_fused(
    const unsigned short* __restrict__ Qb, const unsigned short* __restrict__ Kb,
    const unsigned short* __restrict__ Vt, const unsigned short* __restrict__ Eb,
    unsigned short* __restrict__ yhb,
    const float* __restrict__ ffpart, float* __restrict__ Mout) {
  int bid = blockIdx.x;
  if (bid >= 768) {
    int idx4 = (bid - 768) * 256 + threadIdx.x;
    int stride = (gridDim.x - 768) * 256;
    for (; idx4 < M_ELEMS / 4; idx4 += stride) {
      int idx = idx4 << 2;
      int j = idx & (TT - 1);
      int i = (idx >> 11) & (TT - 1);
      int b = idx >> 22;
      const float* fp = ffpart + ((size_t)(b * 8)) * TT + j;
      float4 s = make_float4(0.f, 0.f, 0.f, 0.f);
#pragma unroll
      for (int p = 0; p < 8; ++p) {
        float4 v = *(const float4*)(fp + (size_t)p * TT);
        s.x += v.x; s.y += v.y; s.z += v.z; s.w += v.w;
      }
      float fi = (float)i;
      float4 o = make_float4(fi - s.x, fi - s.y, fi - s.z, fi - s.w);
      *(float4*)(Mout + idx) = o;
    }
    return;
  }
  int xbh = bid % 24;
  int b = (xbh >> 2) & 1;
  int h = ((xbh >> 3) << 2) | (xbh & 3);
  int yy = bid / 24;
  int g4 = (yy & 1) ? (yy >> 1) : (31 - (yy >> 1));  // balanced interleave
  int wave = threadIdx.x >> 6, lane = threadIdx.x & 63;
  int lr = lane & 15, lg = lane >> 4;
  int i0 = g4 * 64 + wave * 16;
  int bh = b * NH + h;
  const unsigned short* Qh = Qb + (size_t)bh * TT * HD;
  const unsigned short* Kh = Kb + (size_t)bh * TT * HD;
  const unsigned short* Vh = Vt + (size_t)bh * HD * TT;
  const unsigned short* Erow = Eb + ((size_t)(b * TT) + i0 + lg * 4) * TT + 4 * lr;

  __shared__ __align__(16) unsigned short Ksh[2][64][64];
  __shared__ __align__(16) unsigned short Vsh[2][64][64];
  __shared__ __align__(16) unsigned short Plds[4][16][80];

  int rowoff = lane >> 3;            // 0..7 within an 8-row staging segment
  int sslot  = (lane & 7) ^ rowoff;  // pre-swizzled source slot (16B units)

  bf16x8 qf[2];
#pragma unroll
  for (int ks = 0; ks < 2; ++ks)
    qf[ks] = *(const bf16x8*)(Qh + (size_t)(i0 + lr) * HD + ks * 32 + lg * 8);

  f32x4 acc[4];
  float lrun[4] = {0.f, 0.f, 0.f, 0.f};  // per-lane partial of softmax denom
#pragma unroll
  for (int q = 0; q < 4; ++q) acc[q] = (f32x4){0.f, 0.f, 0.f, 0.f};

#define STAGE_KV(BUF, J0)                                                      \
  {                                                                            \
    _Pragma("unroll")                                                          \
    for (int p = 0; p < 2; ++p) {                                              \
      int r0 = wave * 16 + p * 8;                                              \
      gload_lds16(Kh + (size_t)((J0) + r0 + rowoff) * HD + sslot * 8,          \
                  &Ksh[BUF][r0][0]);                                           \
      gload_lds16(Vh + (size_t)(r0 + rowoff) * TT + (J0) + sslot * 8,          \
                  &Vsh[BUF][r0][0]);                                           \
    }                                                                          \
  }

  STAGE_KV(0, 0)
  __syncthreads();

  for (int kt = 0; kt <= g4; ++kt) {
    int cur = kt & 1;
    int j0 = kt * 64;
    if (kt < g4) STAGE_KV(cur ^ 1, j0 + 64)

    // E for current tile (4 x 8B vector loads, swizzled layout)
    ushort4 ev[4];
#pragma unroll
    for (int r = 0; r < 4; ++r)
      ev[r] = *(const ushort4*)(Erow + (size_t)r * TT + j0);

    // ---- QK^T from swizzled LDS ----
    f32x4 s[4];
    __builtin_amdgcn_s_setprio(1);
#pragma unroll
    for (int nj = 0; nj < 4; ++nj) {
      int row = nj * 16 + lr;
      int sw = row & 7;
      bf16x8 k0f = *(const bf16x8*)&Ksh[cur][row][(lg ^ sw) << 3];
      bf16x8 k1f = *(const bf16x8*)&Ksh[cur][row][((4 + lg) ^ sw) << 3];
      f32x4 z = (f32x4){0.f, 0.f, 0.f, 0.f};
      z = __builtin_amdgcn_mfma_f32_16x16x32_bf16(qf[0], k0f, z, 0, 0, 0);
      s[nj] = __builtin_amdgcn_mfma_f32_16x16x32_bf16(qf[1], k1f, z, 0, 0, 0);
    }
    __builtin_amdgcn_s_setprio(0);

    // ---- causal mask (diagonal tile only) ----
    int ibase = i0 + lg * 4;
    if (kt == g4) {
#pragma unroll
      for (int nj = 0; nj < 4; ++nj)
#pragma unroll
        for (int r = 0; r < 4; ++r)
          if (j0 + nj * 16 + lr > ibase + r) s[nj][r] = -1e30f;
    }

    // ---- P = E * exp(s); per-lane partial l; stash bf16 P in LDS ----
#pragma unroll
    for (int r = 0; r < 4; ++r) {
      float p0 = b2f(ev[r].x) * __expf(s[0][r]);
      float p1 = b2f(ev[r].y) * __expf(s[1][r]);
      float p2 = b2f(ev[r].z) * __expf(s[2][r]);
      float p3 = b2f(ev[r].w) * __expf(s[3][r]);
      lrun[r] += (p0 + p1) + (p2 + p3);
      Plds[wave][lg * 4 + r][0 * 16 + lr] = f2b(p0);
      Plds[wave][lg * 4 + r][1 * 16 + lr] = f2b(p1);
      Plds[wave][lg * 4 + r][2 * 16 + lr] = f2b(p2);
      Plds[wave][lg * 4 + r][3 * 16 + lr] = f2b(p3);
    }

    // ---- PV from swizzled LDS ----
    bf16x8 pa0 = *(const bf16x8*)&Plds[wave][lr][lg * 8];
    bf16x8 pa1 = *(const bf16x8*)&Plds[wave][lr][32 + lg * 8];
    __builtin_amdgcn_s_setprio(1);
#pragma unroll
    for (int nd = 0; nd < 4; ++nd) {
      int row = nd * 16 + lr;
      int sw = row & 7;
      bf16x8 v0f = *(const bf16x8*)&Vsh[cur][row][(lg ^ sw) << 3];
      bf16x8 v1f = *(const bf16x8*)&Vsh[cur][row][((4 + lg) ^ sw) << 3];
      acc[nd] = __builtin_amdgcn_mfma_f32_16x16x32_bf16(pa0, v0f, acc[nd], 0, 0, 0);
      acc[nd] = __builtin_amdgcn_mfma_f32_16x16x32_bf16(pa1, v1f, acc[nd], 0, 0, 0);
    }
    __builtin_amdgcn_s_setprio(0);

    __syncthreads();
  }
#undef STAGE_KV

  // ---- epilogue: one l-reduction across the 16 lr lanes, then store ----
#pragma unroll
  for (int r = 0; r < 4; ++r) {
    lrun[r] += __shfl_xor(lrun[r], 1);
    lrun[r] += __shfl_xor(lrun[r], 2);
    lrun[r] += __shfl_xor(lrun[r], 4);
    lrun[r] += __shfl_xor(lrun[r], 8);
    float inv = 1.f / lrun[r];
    int ig = i0 + lg * 4 + r;
    unsigned short* ob = yhb + (size_t)(b * TT + ig) * CC + h * HD;
#pragma unroll
    for (int nd = 0; nd < 4; ++nd)
      ob[nd * 16 + lr] = f2b(acc[nd][r] * inv);
  }
}

// ---------------------------------------------------------------------------
// proj GEMM: y = yhb @ wpT^T + b_proj (128x128 MFMA tile). Grid (32, 6).
// ---------------------------------------------------------------------------
__global__ __launch_bounds__(256, 3) void gemm_proj_bf16(
    const unsigned short* __restrict__ yhb, const unsigned short* __restrict__ wpT,
    const float* __restrict__ b_proj, float* __restrict__ y) {
  __shared__ __align__(16) unsigned short Alds[2][128][32];
  __shared__ __align__(16) unsigned short Blds[2][128][32];
  int mt = blockIdx.x, nt = blockIdx.y;
  int wave = threadIdx.x >> 6, lane = threadIdx.x & 63;
  int lr = lane & 15, lg = lane >> 4;
  int m0 = mt * 128;
  int n0 = nt * 128;

  int srow = lane >> 2;
  int sslot = (lane & 3) ^ (srow & 3);

#define STAGE_AB(BUF, K0)                                                       \
  {                                                                             \
    _Pragma("unroll")                                                           \
    for (int p = 0; p < 2; ++p) {                                               \
      int ar = wave * 32 + p * 16 + srow;                                       \
      gload_lds16(yhb + (size_t)(m0 + ar) * CC + (K0) + (sslot << 3),           \
                  &Alds[BUF][wave * 32 + p * 16][0]);                           \
      gload_lds16(wpT + (size_t)(n0 + ar) * CC + (K0) + (sslot << 3),           \
                  &Blds[BUF][wave * 32 + p * 16][0]);                           \
    }                                                                           \
  }

  f32x4 acc[2][8];
#pragma unroll
  for (int mi = 0; mi < 2; ++mi)
#pragma unroll
    for (int nj = 0; nj < 8; ++nj) acc[mi][nj] = (f32x4){0.f, 0.f, 0.f, 0.f};

  STAGE_AB(0, 0)
  __syncthreads();

  int fslot = lg ^ (lr & 3);
  for (int kt = 0; kt < 24; ++kt) {
    int cur = kt & 1;
    if (kt < 23) STAGE_AB(cur ^ 1, (kt + 1) * 32)
    bf16x8 af[2], bf[8];
#pragma unroll
    for (int mi = 0; mi < 2; ++mi)
      af[mi] = *(const bf16x8*)&Alds[cur][wave * 32 + mi * 16 + lr][fslot << 3];
#pragma unroll
    for (int nj = 0; nj < 8; ++nj)
      bf[nj] = *(const bf16x8*)&Blds[cur][nj * 16 + lr][fslot << 3];
    __builtin_amdgcn_s_setprio(1);
#pragma unroll
    for (int nj = 0; nj < 8; ++nj)
#pragma unroll
      for (int mi = 0; mi < 2; ++mi)
        acc[mi][nj] = __builtin_amdgcn_mfma_f32_16x16x32_bf16(af[mi], bf[nj], acc[mi][nj], 0, 0, 0);
    __builtin_amdgcn_s_setprio(0);
    __syncthreads();
  }
#undef STAGE_AB

  float bias[8];
#pragma unroll
  for (int nj = 0; nj < 8; ++nj) bias[nj] = b_proj[n0 + nj * 16 + lr];
#pragma unroll
  for (int mi = 0; mi < 2; ++mi)
#pragma unroll
    for (int r = 0; r < 4; ++r) {
      int m = m0 + wave * 32 + mi * 16 + lg * 4 + r;
#pragma unroll
      for (int nj = 0; nj < 8; ++nj)
        y[(size_t)m * CC + n0 + nj * 16 + lr] = acc[mi][nj][r] + bias[nj];
    }
}

// ---------------------------------------------------------------------------
extern "C" void kernel_launch(void* const* d_in, const int* in_sizes, int n_in,
                              void* d_out, int out_size, void* d_ws, size_t ws_size,
                              hipStream_t stream) {
  const float* x      = (const float*)d_in[0];
  const float* w_attn = (const float*)d_in[1];
  const float* b_attn = (const float*)d_in[2];
  const float* w_proj = (const float*)d_in[3];
  const float* b_proj = (const float*)d_in[4];

  float* y    = (float*)d_out;          // [B,T,C]
  float* Mreg = y + Y_ELEMS;            // [B,T,T]: S0 (scratch) -> M (final)

  float* ws = (float*)d_ws;
  float* q0       = ws;                               // B*T*64
  float* k0       = q0 + (size_t)BB * TT * HD;
  float* partials = k0 + (size_t)BB * TT * HD;        // B*32*T
  float* ffpart   = partials + (size_t)BB * 32 * TT;  // B*8*T
  unsigned short* xb  = (unsigned short*)(ffpart + (size_t)BB * 8 * TT);  // B*T*C
  unsigned short* wbT = xb + (size_t)Y_ELEMS;                 // 2304*768
  unsigned short* wpT = wbT + (size_t)N3 * CC;                // 768*768
  unsigned short* Qb  = wpT + (size_t)CC * CC;                // B*NH*T*HD
  unsigned short* Kb  = Qb + (size_t)BB * NH * TT * HD;
  unsigned short* Vt  = Kb + (size_t)BB * NH * TT * HD;
  unsigned short* yhb = Vt + (size_t)BB * NH * TT * HD;       // B*T*C
  unsigned short* Eb  = yhb + (size_t)Y_ELEMS;                // B*T*T bf16 (16.8MB)
  // total ws usage ~= 46 MB

  // 1. fused prep: qk0 (long blocks first) + packs + weight transposes
  prep_fused<<<2368, 256, 0, stream>>>(x, w_attn, w_proj, b_attn,
                                       xb, wbT, wpT, q0, k0);
  // 2. fused QKV MFMA GEMM (576 long blocks first) + score0 (short backfill)
  gemm_score_fused<<<2624, 256, 0, stream>>>(
      xb, wbT, b_attn, Qb, Kb, Vt, q0, k0, Mreg, partials);
  // 3. scan: E = exp(-FF) bf16 (jswz) + ffpart row sums; upper-tri early-exit
  scan_write<<<dim3(8, 32, BB), 256, 0, stream>>>(Mreg, partials, Eb, ffpart);
  // 4. fused attention (768 long blocks first) + M writer (backfill stores)
  attn_m_fused<<<1280, 256, 0, stream>>>(Qb, Kb, Vt, Eb, yhb, ffpart, Mreg);
  // 5. proj GEMM (128x128)
  gemm_proj_bf16<<<dim3(32, 6), 256, 0, stream>>>(yhb, wpT, b_proj, y);
}